// Round 1
// baseline (2989.523 us; speedup 1.0000x reference)
//
#include <hip/hip_runtime.h>
#include <hip/hip_bf16.h>
#include <math.h>

#define NH 32
#define NKV 8
#define HD 64
#define NSLOTS 11
#define TOPK 128
#define KBROW (NSLOTS * NH * HD)   // 22528
#define KBIDX 0
#define PADF (-3.3895313892515355e+38f)
#define C0F  (-0.24686007793152578f)   // -ln(128)+ln(100)
#define SCALE 0.125f

// ---------------------------------------------------------------------------
// Tiled fp32 GEMM: C[M,N] = A[M,K] @ W[N,K]^T.  M,N % 64 == 0, K % 16 == 0.
// ---------------------------------------------------------------------------
__global__ __launch_bounds__(256) void gemm_nt_f32(
    const float* __restrict__ A, const float* __restrict__ W,
    float* __restrict__ C, int M, int N, int K) {
  __shared__ float As[16][68];  // [k][m], padded
  __shared__ float Ws[16][68];  // [k][n], padded
  const int t = threadIdx.x;
  const int bm = blockIdx.y * 64, bn = blockIdx.x * 64;
  const int lr = t >> 2;             // 0..63 (row within tile)
  const int lc = (t & 3) << 2;       // 0,4,8,12 (k within chunk)
  const int tr = (t >> 4) << 2;      // micro-tile row 0..60
  const int tc = (t & 15) << 2;      // micro-tile col 0..60
  float acc[4][4] = {};
  const float* Ap = A + (size_t)(bm + lr) * K + lc;
  const float* Wp = W + (size_t)(bn + lr) * K + lc;
  for (int k0 = 0; k0 < K; k0 += 16) {
    float4 a4 = *(const float4*)(Ap + k0);
    float4 w4 = *(const float4*)(Wp + k0);
    __syncthreads();
    As[lc + 0][lr] = a4.x; As[lc + 1][lr] = a4.y;
    As[lc + 2][lr] = a4.z; As[lc + 3][lr] = a4.w;
    Ws[lc + 0][lr] = w4.x; Ws[lc + 1][lr] = w4.y;
    Ws[lc + 2][lr] = w4.z; Ws[lc + 3][lr] = w4.w;
    __syncthreads();
#pragma unroll
    for (int kk = 0; kk < 16; ++kk) {
      float4 av = *(const float4*)&As[kk][tr];
      float4 wv = *(const float4*)&Ws[kk][tc];
      float a[4] = {av.x, av.y, av.z, av.w};
      float w[4] = {wv.x, wv.y, wv.z, wv.w};
#pragma unroll
      for (int i = 0; i < 4; ++i)
#pragma unroll
        for (int j = 0; j < 4; ++j) acc[i][j] += a[i] * w[j];
    }
  }
#pragma unroll
  for (int i = 0; i < 4; ++i) {
    float4 o = make_float4(acc[i][0], acc[i][1], acc[i][2], acc[i][3]);
    *(float4*)&C[(size_t)(bm + tr + i) * N + bn + tc] = o;
  }
}

// ---------------------------------------------------------------------------
// RoPE in-place on x laid out [rows][nheads*64]; cos/sin are [rows][64].
// One thread per (row, head, d<32) pair.
// ---------------------------------------------------------------------------
__global__ void rope_kernel(float* __restrict__ x, const float* __restrict__ c,
                            const float* __restrict__ s, int rows, int nheads) {
  int tid = blockIdx.x * blockDim.x + threadIdx.x;
  int total = rows * nheads * 32;
  if (tid >= total) return;
  int d = tid & 31;
  int h = (tid >> 5) % nheads;
  int row = tid / (32 * nheads);
  float* xr = x + ((size_t)row * nheads + h) * 64;
  float c1 = c[(size_t)row * 64 + d], c2 = c[(size_t)row * 64 + d + 32];
  float s1 = s[(size_t)row * 64 + d], s2 = s[(size_t)row * 64 + d + 32];
  float x1 = xr[d], x2 = xr[d + 32];
  xr[d]      = x1 * c1 - x2 * s1;
  xr[d + 32] = x2 * c2 + x1 * s2;
}

// ---------------------------------------------------------------------------
// Qs[b][c] = sum_s q2[b][s][c],  c in [0, 2048)
// ---------------------------------------------------------------------------
__global__ void colsum_kernel(const float* __restrict__ q2, float* __restrict__ Qs,
                              int B, int S) {
  int idx = blockIdx.x * blockDim.x + threadIdx.x;
  if (idx >= B * NH * HD) return;
  int b = idx / (NH * HD), c = idx % (NH * HD);
  const float* p = q2 + (size_t)b * S * (NH * HD) + c;
  double acc = 0.0;
  for (int s = 0; s < S; ++s) acc += (double)p[(size_t)s * (NH * HD)];
  Qs[idx] = (float)acc;
}

// ---------------------------------------------------------------------------
// scores[b][l] = 0.125 * dot(Qs[b,:], kb_keys[l, KBIDX*2048 : +2048]) (f64 acc)
// One wave per (b,l).
// ---------------------------------------------------------------------------
__global__ void scores_kernel(const float* __restrict__ Qs,
                              const float* __restrict__ kbk,
                              float* __restrict__ scores, int B, int KBL) {
  int task = (blockIdx.x * blockDim.x + threadIdx.x) >> 6;
  int lane = threadIdx.x & 63;
  if (task >= B * KBL) return;
  int b = task / KBL, l = task % KBL;
  const float* kr = kbk + (size_t)l * KBROW + KBIDX * NH * HD;
  const float* qd = Qs + (size_t)b * NH * HD;
  double acc = 0.0;
  for (int c = lane; c < NH * HD; c += 64) acc += (double)qd[c] * (double)kr[c];
#pragma unroll
  for (int off = 32; off; off >>= 1) acc += __shfl_xor(acc, off);
  if (lane == 0) scores[task] = (float)(0.125 * acc);
}

// ---------------------------------------------------------------------------
// Top-K (descending, ties -> lower index). One wave per batch.
// ---------------------------------------------------------------------------
__global__ void topk_kernel(const float* __restrict__ scores,
                            int* __restrict__ top_idx, int KBL) {
  __shared__ float ls[512];
  int b = blockIdx.x, lane = threadIdx.x;
  for (int i = lane; i < KBL; i += 64) ls[i] = scores[(size_t)b * KBL + i];
  __syncthreads();
  for (int it = 0; it < TOPK; ++it) {
    float bv = -3.4e38f; int bi = 0x7fffffff;
    for (int i = lane; i < KBL; i += 64) {
      float v = ls[i];
      if (v > bv || (v == bv && i < bi)) { bv = v; bi = i; }
    }
#pragma unroll
    for (int off = 32; off; off >>= 1) {
      float ov = __shfl_xor(bv, off);
      int oi = __shfl_xor(bi, off);
      if (ov > bv || (ov == bv && oi < bi)) { bv = ov; bi = oi; }
    }
    if (lane == 0) { top_idx[b * TOPK + it] = bi; ls[bi] = -3.4e38f; }
    __syncthreads();
  }
}

// ---------------------------------------------------------------------------
// padflag[b*S+s] = all(mask[b,0,s,:] < 0). One wave per row.
// ---------------------------------------------------------------------------
__global__ void padflag_kernel(const float* __restrict__ mask,
                               int* __restrict__ flags, int BS, int S) {
  int w = (blockIdx.x * blockDim.x + threadIdx.x) >> 6;
  int lane = threadIdx.x & 63;
  if (w >= BS) return;
  const float* row = mask + (size_t)w * S;
  bool ok = true;
  for (int j = lane; j < S; j += 64) ok = ok && (row[j] < 0.f);
  int allv = __all(ok ? 1 : 0);
  if (lane == 0) flags[w] = allv;
}

// ---------------------------------------------------------------------------
// Fused attention. Block = 256 threads, handles 8 query rows of one (b,h).
// Logits (KB 0..127 from q2, seq from roped q) -> softmax -> PV.
// Values: KB slots use kb_values[top_idx[j]], seq slots use v[b, js, h/4].
// ---------------------------------------------------------------------------
__global__ __launch_bounds__(256) void attn_kernel(
    const float* __restrict__ qbuf,   // [B*S][2048] roped
    const float* __restrict__ q2buf,  // [B*S][2048] un-roped
    const float* __restrict__ kbuf,   // [B*S][NKV*64] roped
    const float* __restrict__ vbuf,   // [B*S][NKV*64]
    const float* __restrict__ kb_keys,
    const float* __restrict__ kb_values,
    const float* __restrict__ mask,   // [B][S][S]
    const int* __restrict__ top_idx,  // [B][TOPK]
    const int* __restrict__ padflag,  // [B*S]
    float* __restrict__ attn,         // [B*S][2048]
    int B, int S) {
  const int nst = S >> 3;
  const int st = blockIdx.x % nst;
  const int h = (blockIdx.x / nst) % NH;
  const int b = blockIdx.x / (nst * NH);
  const int s0 = st * 8;
  const int g = h / (NH / NKV);
  const int NKEYS = TOPK + S;  // 1152

  __shared__ float qsm[2][8][64];  // [0]=q (roped), [1]=q2
  __shared__ float lg[8][1160];
  __shared__ float denom[8];
  __shared__ int idxs[TOPK];
  __shared__ int padf[8];

  const int t = threadIdx.x;
  // Phase A: stage q, q2 rows + top-k indices + pad flags
  for (int i = t; i < 2 * 8 * 64; i += 256) {
    int sel = i >> 9, r = (i >> 6) & 7, d = i & 63;
    const float* src = sel ? q2buf : qbuf;
    qsm[sel][r][d] = src[(size_t)(b * S + s0 + r) * (NH * HD) + h * 64 + d];
  }
  if (t < TOPK) idxs[t] = top_idx[b * TOPK + t];
  if (t < 8) padf[t] = padflag[b * S + s0 + t];
  __syncthreads();

  // Phase B: logits for 8 rows x NKEYS keys
  for (int jc = 0; jc < (NKEYS + 255) / 256; ++jc) {
    int j = jc * 256 + t;
    if (j < NKEYS) {
      bool iskb = (j < TOPK);
      const float* kp;
      bool skip = false;
      if (iskb) {
        kp = kb_keys + (size_t)j * KBROW + KBIDX * NH * HD + h * 64;
      } else {
        int js = j - TOPK;
        if (js > s0 + 7) {  // causally masked for every row in this tile
#pragma unroll
          for (int r = 0; r < 8; ++r) lg[r][j] = PADF;
          skip = true;
          kp = nullptr;
        } else {
          kp = kbuf + ((size_t)(b * S + js) * NKV + g) * 64;
        }
      }
      if (!skip) {
        float accr[8] = {};
        const float* qb = &qsm[iskb ? 1 : 0][0][0];
#pragma unroll
        for (int d0 = 0; d0 < 64; d0 += 4) {
          float4 kv = *(const float4*)(kp + d0);
#pragma unroll
          for (int r = 0; r < 8; ++r) {
            float4 qv = *(const float4*)(qb + r * 64 + d0);
            accr[r] += kv.x * qv.x + kv.y * qv.y + kv.z * qv.z + kv.w * qv.w;
          }
        }
        if (iskb) {
#pragma unroll
          for (int r = 0; r < 8; ++r)
            lg[r][j] = SCALE * accr[r] + C0F + (padf[r] ? PADF : 0.f);
        } else {
          int js = j - TOPK;
#pragma unroll
          for (int r = 0; r < 8; ++r)
            lg[r][j] = SCALE * accr[r] + mask[((size_t)b * S + s0 + r) * S + js];
        }
      }
    }
  }
  __syncthreads();

  // Phase C: per-row softmax (unnormalized exp in lg, denom saved)
  {
    int w = t >> 6, lane = t & 63;
    for (int rr = 0; rr < 2; ++rr) {
      int r = w + rr * 4;
      float m = -3.4e38f;
      for (int i = lane; i < NKEYS; i += 64) m = fmaxf(m, lg[r][i]);
#pragma unroll
      for (int off = 32; off; off >>= 1) m = fmaxf(m, __shfl_xor(m, off));
      float sum = 0.f;
      for (int i = lane; i < NKEYS; i += 64) {
        float e = __expf(lg[r][i] - m);
        lg[r][i] = e;
        sum += e;
      }
#pragma unroll
      for (int off = 32; off; off >>= 1) sum += __shfl_xor(sum, off);
      if (lane == 0) denom[r] = sum;
    }
  }
  __syncthreads();

  // Phase D: attn[r][d] = sum_j p[j] * V[j][d] / denom[r]
  {
    int r = t >> 5, d0 = (t & 31) << 1;
    float a0 = 0.f, a1 = 0.f;
    for (int j = 0; j < TOPK; ++j) {
      float p = lg[r][j];
      const float* vp =
          kb_values + (size_t)idxs[j] * KBROW + KBIDX * NH * HD + h * 64 + d0;
      float2 vv = *(const float2*)vp;
      a0 += p * vv.x; a1 += p * vv.y;
    }
    int smax = s0 + r + 1;  // causal bound: p == 0 beyond this
    const float* vb = vbuf + ((size_t)(b * S) * NKV + g) * 64 + d0;
    for (int js = 0; js < smax; ++js) {
      float p = lg[r][TOPK + js];
      float2 vv = *(const float2*)(vb + (size_t)js * NKV * 64);
      a0 += p * vv.x; a1 += p * vv.y;
    }
    float inv = 1.f / denom[r];
    size_t o = (size_t)(b * S + s0 + r) * (NH * HD) + h * 64 + d0;
    attn[o] = a0 * inv;
    attn[o + 1] = a1 * inv;
  }
}

// ---------------------------------------------------------------------------
extern "C" void kernel_launch(void* const* d_in, const int* in_sizes, int n_in,
                              void* d_out, int out_size, void* d_ws, size_t ws_size,
                              hipStream_t stream) {
  const float* hidden = (const float*)d_in[0];
  const float* cosb   = (const float*)d_in[1];
  const float* sinb   = (const float*)d_in[2];
  const float* mask   = (const float*)d_in[3];
  const float* kbk    = (const float*)d_in[4];
  const float* kbv    = (const float*)d_in[5];
  const float* Wq     = (const float*)d_in[6];
  const float* Wq2    = (const float*)d_in[7];
  const float* Wk     = (const float*)d_in[8];
  const float* Wv     = (const float*)d_in[9];
  const float* Wo     = (const float*)d_in[10];
  float* out = (float*)d_out;

  const int H   = in_sizes[6] / (NH * HD);          // 2048
  const int KBL = in_sizes[4] / KBROW;              // 400
  const long long BSll = (long long)in_sizes[0] / H;
  const int S = (int)((long long)in_sizes[3] / BSll);  // 1024
  const int B = (int)(BSll / S);                       // 2
  const int BS = B * S;                                // 2048
  const int NQ = NH * HD;                              // 2048
  const int NKVD = NKV * HD;                           // 512

  float* ws = (float*)d_ws;
  size_t off = 0;
  float* qb   = ws + off; off += (size_t)BS * NQ;
  float* q2b  = ws + off; off += (size_t)BS * NQ;
  float* kb   = ws + off; off += (size_t)BS * NKVD;
  float* vb   = ws + off; off += (size_t)BS * NKVD;
  float* attn = ws + off; off += (size_t)BS * NQ;
  float* Qs   = ws + off; off += (size_t)B * NQ;
  float* sc   = ws + off; off += (size_t)B * KBL;
  int* topi   = (int*)(ws + off); off += (size_t)B * TOPK;
  int* padfl  = (int*)(ws + off); off += (size_t)BS;
  (void)ws_size; (void)n_in; (void)out_size;

  // 1-4: projections
  gemm_nt_f32<<<dim3(NQ / 64, BS / 64), 256, 0, stream>>>(hidden, Wq, qb, BS, NQ, H);
  gemm_nt_f32<<<dim3(NQ / 64, BS / 64), 256, 0, stream>>>(hidden, Wq2, q2b, BS, NQ, H);
  gemm_nt_f32<<<dim3(NKVD / 64, BS / 64), 256, 0, stream>>>(hidden, Wk, kb, BS, NKVD, H);
  gemm_nt_f32<<<dim3(NKVD / 64, BS / 64), 256, 0, stream>>>(hidden, Wv, vb, BS, NKVD, H);

  // 5-6: RoPE on q and k
  {
    int tq = BS * NH * 32;
    rope_kernel<<<(tq + 255) / 256, 256, 0, stream>>>(qb, cosb, sinb, BS, NH);
    int tk = BS * NKV * 32;
    rope_kernel<<<(tk + 255) / 256, 256, 0, stream>>>(kb, cosb, sinb, BS, NKV);
  }

  // 7-9: scores + top-k
  colsum_kernel<<<(B * NQ + 255) / 256, 256, 0, stream>>>(q2b, Qs, B, S);
  scores_kernel<<<(B * KBL * 64 + 255) / 256, 256, 0, stream>>>(Qs, kbk, sc, B, KBL);
  topk_kernel<<<B, 64, 0, stream>>>(sc, topi, KBL);

  // 10: padding flags
  padflag_kernel<<<(BS * 64 + 255) / 256, 256, 0, stream>>>(mask, padfl, BS, S);

  // 11: fused attention
  attn_kernel<<<B * NH * (S / 8), 256, 0, stream>>>(
      qb, q2b, kb, vb, kbk, kbv, mask, topi, padfl, attn, B, S);

  // 12: output projection
  gemm_nt_f32<<<dim3(H / 64, BS / 64), 256, 0, stream>>>(attn, Wo, out, BS, H, NQ);
}

// Round 2
// 1815.042 us; speedup vs baseline: 1.6471x; 1.6471x over previous
//
#include <hip/hip_runtime.h>
#include <hip/hip_bf16.h>
#include <math.h>

#define NH 32
#define NKV 8
#define HD 64
#define NSLOTS 11
#define TOPK 128
#define KBROW (NSLOTS * NH * HD)   // 22528
#define PADF (-3.3895313892515355e+38f)
#define C0F  (-0.24686007793152578f)   // -ln(128)+ln(100)
#define SCALE 0.125f

#define QBLK 16
#define KC 64
#define LPAD 68

// ---------------------------------------------------------------------------
// Tiled fp32 GEMM: C[M,N] = A[M,K] @ W[N,K]^T.  M,N % 64 == 0, K % 16 == 0.
// ---------------------------------------------------------------------------
__global__ __launch_bounds__(256) void gemm_nt_f32(
    const float* __restrict__ A, const float* __restrict__ W,
    float* __restrict__ C, int M, int N, int K) {
  __shared__ float As[16][68];  // [k][m], padded
  __shared__ float Ws[16][68];  // [k][n], padded
  const int t = threadIdx.x;
  const int bm = blockIdx.y * 64, bn = blockIdx.x * 64;
  const int lr = t >> 2;             // 0..63 (row within tile)
  const int lc = (t & 3) << 2;       // 0,4,8,12 (k within chunk)
  const int tr = (t >> 4) << 2;      // micro-tile row 0..60
  const int tc = (t & 15) << 2;      // micro-tile col 0..60
  float acc[4][4] = {};
  const float* Ap = A + (size_t)(bm + lr) * K + lc;
  const float* Wp = W + (size_t)(bn + lr) * K + lc;
  for (int k0 = 0; k0 < K; k0 += 16) {
    float4 a4 = *(const float4*)(Ap + k0);
    float4 w4 = *(const float4*)(Wp + k0);
    __syncthreads();
    As[lc + 0][lr] = a4.x; As[lc + 1][lr] = a4.y;
    As[lc + 2][lr] = a4.z; As[lc + 3][lr] = a4.w;
    Ws[lc + 0][lr] = w4.x; Ws[lc + 1][lr] = w4.y;
    Ws[lc + 2][lr] = w4.z; Ws[lc + 3][lr] = w4.w;
    __syncthreads();
#pragma unroll
    for (int kk = 0; kk < 16; ++kk) {
      float4 av = *(const float4*)&As[kk][tr];
      float4 wv = *(const float4*)&Ws[kk][tc];
      float a[4] = {av.x, av.y, av.z, av.w};
      float w[4] = {wv.x, wv.y, wv.z, wv.w};
#pragma unroll
      for (int i = 0; i < 4; ++i)
#pragma unroll
        for (int j = 0; j < 4; ++j) acc[i][j] += a[i] * w[j];
    }
  }
#pragma unroll
  for (int i = 0; i < 4; ++i) {
    float4 o = make_float4(acc[i][0], acc[i][1], acc[i][2], acc[i][3]);
    *(float4*)&C[(size_t)(bm + tr + i) * N + bn + tc] = o;
  }
}

// ---------------------------------------------------------------------------
// RoPE in-place on x laid out [rows][nheads*64]; cos/sin are [rows][64].
// ---------------------------------------------------------------------------
__global__ void rope_kernel(float* __restrict__ x, const float* __restrict__ c,
                            const float* __restrict__ s, int rows, int nheads) {
  int tid = blockIdx.x * blockDim.x + threadIdx.x;
  int total = rows * nheads * 32;
  if (tid >= total) return;
  int d = tid & 31;
  int h = (tid >> 5) % nheads;
  int row = tid / (32 * nheads);
  float* xr = x + ((size_t)row * nheads + h) * 64;
  float c1 = c[(size_t)row * 64 + d], c2 = c[(size_t)row * 64 + d + 32];
  float s1 = s[(size_t)row * 64 + d], s2 = s[(size_t)row * 64 + d + 32];
  float x1 = xr[d], x2 = xr[d + 32];
  xr[d]      = x1 * c1 - x2 * s1;
  xr[d + 32] = x2 * c2 + x1 * s2;
}

// ---------------------------------------------------------------------------
// Qs[b][c] = sum_s q2[b][s][c]
// ---------------------------------------------------------------------------
__global__ void colsum_kernel(const float* __restrict__ q2, float* __restrict__ Qs,
                              int B, int S) {
  int idx = blockIdx.x * blockDim.x + threadIdx.x;
  if (idx >= B * NH * HD) return;
  int b = idx / (NH * HD), c = idx % (NH * HD);
  const float* p = q2 + (size_t)b * S * (NH * HD) + c;
  double acc = 0.0;
  for (int s = 0; s < S; ++s) acc += (double)p[(size_t)s * (NH * HD)];
  Qs[idx] = (float)acc;
}

// ---------------------------------------------------------------------------
// scores[b][l] = 0.125 * dot(Qs[b,:], kb_keys[l, 0:2048]) (f64 acc)
// ---------------------------------------------------------------------------
__global__ void scores_kernel(const float* __restrict__ Qs,
                              const float* __restrict__ kbk,
                              float* __restrict__ scores, int B, int KBL) {
  int task = (blockIdx.x * blockDim.x + threadIdx.x) >> 6;
  int lane = threadIdx.x & 63;
  if (task >= B * KBL) return;
  int b = task / KBL, l = task % KBL;
  const float* kr = kbk + (size_t)l * KBROW;
  const float* qd = Qs + (size_t)b * NH * HD;
  double acc = 0.0;
  for (int c = lane; c < NH * HD; c += 64) acc += (double)qd[c] * (double)kr[c];
#pragma unroll
  for (int off = 32; off; off >>= 1) acc += __shfl_xor(acc, off);
  if (lane == 0) scores[task] = (float)(0.125 * acc);
}

// ---------------------------------------------------------------------------
// Top-K (descending, ties -> lower index). One wave per batch.
// ---------------------------------------------------------------------------
__global__ void topk_kernel(const float* __restrict__ scores,
                            int* __restrict__ top_idx, int KBL) {
  __shared__ float ls[512];
  int b = blockIdx.x, lane = threadIdx.x;
  for (int i = lane; i < KBL; i += 64) ls[i] = scores[(size_t)b * KBL + i];
  __syncthreads();
  for (int it = 0; it < TOPK; ++it) {
    float bv = -3.4e38f; int bi = 0x7fffffff;
    for (int i = lane; i < KBL; i += 64) {
      float v = ls[i];
      if (v > bv || (v == bv && i < bi)) { bv = v; bi = i; }
    }
#pragma unroll
    for (int off = 32; off; off >>= 1) {
      float ov = __shfl_xor(bv, off);
      int oi = __shfl_xor(bi, off);
      if (ov > bv || (ov == bv && oi < bi)) { bv = ov; bi = oi; }
    }
    if (lane == 0) { top_idx[b * TOPK + it] = bi; ls[bi] = -3.4e38f; }
    __syncthreads();
  }
}

// ---------------------------------------------------------------------------
// padflag[b*S+s] = all(mask[b,0,s,:] < 0)
// ---------------------------------------------------------------------------
__global__ void padflag_kernel(const float* __restrict__ mask,
                               int* __restrict__ flags, int BS, int S) {
  int w = (blockIdx.x * blockDim.x + threadIdx.x) >> 6;
  int lane = threadIdx.x & 63;
  if (w >= BS) return;
  const float* row = mask + (size_t)w * S;
  bool ok = true;
  for (int j = lane; j < S; j += 64) ok = ok && (row[j] < 0.f);
  int allv = __all(ok ? 1 : 0);
  if (lane == 0) flags[w] = allv;
}

// ---------------------------------------------------------------------------
// Flash-style fused attention. Block = 256 threads = 16 query rows x 16 lanes.
// Thread (r = t>>4, i = t&15): logits for keys j = i+16*jj (jj<4) of row r,
// PV output cols i*4..i*4+3 of row r. Online softmax, 64-key chunks.
// Chunks 0..1: KB keys 0..127 (q2, +C0F, padflag; V gathered via top_idx).
// Chunks 2.. : sequence keys (roped q, +mask), causally pruned.
// ---------------------------------------------------------------------------
__global__ __launch_bounds__(256) void attn_flash(
    const float* __restrict__ qbuf,   // [B*S][2048] roped
    const float* __restrict__ q2buf,  // [B*S][2048] un-roped
    const float* __restrict__ kbuf,   // [B*S][NKV*64] roped
    const float* __restrict__ vbuf,   // [B*S][NKV*64]
    const float* __restrict__ kb_keys,
    const float* __restrict__ kb_values,
    const float* __restrict__ mask,   // [B][S][S]
    const int* __restrict__ top_idx,  // [B][TOPK]
    const int* __restrict__ padflag,  // [B*S]
    float* __restrict__ attn,         // [B*S][2048]
    int B, int S) {
  const int nst = S / QBLK;
  const int st = blockIdx.x % nst;
  const int h  = (blockIdx.x / nst) % NH;
  const int b  = blockIdx.x / (nst * NH);
  const int s0 = st * QBLK;
  const int g  = h / (NH / NKV);

  __shared__ float qt[2][QBLK][LPAD];  // [0]=q roped, [1]=q2
  __shared__ float kt[KC][LPAD];
  __shared__ float vt[KC][LPAD];
  __shared__ float pm[QBLK][LPAD];     // mask during logits, then p
  __shared__ int   idxs[TOPK];
  __shared__ int   padf[QBLK];

  const int t = threadIdx.x;
  const int r = t >> 4;   // query row 0..15
  const int i = t & 15;   // lane-in-row

  // stage q / q2 tiles
  for (int f = t; f < 2 * QBLK * 16; f += 256) {
    int sel = f >> 8;
    int rr = (f >> 4) & (QBLK - 1);
    int c4 = (f & 15) * 4;
    const float* src = sel ? q2buf : qbuf;
    *(float4*)&qt[sel][rr][c4] =
        *(const float4*)&src[(size_t)(b * S + s0 + rr) * (NH * HD) + h * 64 + c4];
  }
  if (t < TOPK) idxs[t] = top_idx[b * TOPK + t];
  if (t < QBLK) padf[t] = padflag[b * S + s0 + t];

  float m = -3.4e38f, l = 0.f;
  float4 acc = make_float4(0.f, 0.f, 0.f, 0.f);

  const int nch_kb = TOPK / KC;                      // 2
  const int nch_seq = (s0 + QBLK + KC - 1) / KC;     // causal prune
  const int nch = nch_kb + nch_seq;

  for (int ch = 0; ch < nch; ++ch) {
    const bool iskb = (ch < nch_kb);
    const int j0 = iskb ? ch * KC : (ch - nch_kb) * KC;
    __syncthreads();   // prev chunk fully consumed; q/idxs visible on ch==0
    // stage K and V chunk
    for (int f = t; f < KC * 16; f += 256) {
      int row = f >> 4, c4 = (f & 15) * 4;
      const float *kp, *vp;
      if (iskb) {
        int jk = j0 + row;
        kp = kb_keys   + (size_t)jk * KBROW + h * 64 + c4;
        vp = kb_values + (size_t)idxs[jk] * KBROW + h * 64 + c4;
      } else {
        int js = j0 + row;
        kp = kbuf + ((size_t)(b * S + js) * NKV + g) * 64 + c4;
        vp = vbuf + ((size_t)(b * S + js) * NKV + g) * 64 + c4;
      }
      *(float4*)&kt[row][c4] = *(const float4*)kp;
      *(float4*)&vt[row][c4] = *(const float4*)vp;
    }
    if (!iskb) {  // stage mask tile [16][64]
      for (int f = t; f < QBLK * 16; f += 256) {
        int rr = f >> 4, c4 = (f & 15) * 4;
        *(float4*)&pm[rr][c4] =
            *(const float4*)&mask[((size_t)(b * S) + s0 + rr) * S + j0 + c4];
      }
    }
    __syncthreads();

    // logits: 4 keys per thread, d-outer loop reuses q vector
    const float* qrow = qt[iskb ? 1 : 0][r];
    float lg0 = 0.f, lg1 = 0.f, lg2 = 0.f, lg3 = 0.f;
#pragma unroll
    for (int d = 0; d < 64; d += 4) {
      float4 qv = *(const float4*)&qrow[d];
      float4 k0 = *(const float4*)&kt[i][d];
      float4 k1 = *(const float4*)&kt[i + 16][d];
      float4 k2 = *(const float4*)&kt[i + 32][d];
      float4 k3 = *(const float4*)&kt[i + 48][d];
      lg0 += qv.x * k0.x + qv.y * k0.y + qv.z * k0.z + qv.w * k0.w;
      lg1 += qv.x * k1.x + qv.y * k1.y + qv.z * k1.z + qv.w * k1.w;
      lg2 += qv.x * k2.x + qv.y * k2.y + qv.z * k2.z + qv.w * k2.w;
      lg3 += qv.x * k3.x + qv.y * k3.y + qv.z * k3.z + qv.w * k3.w;
    }
    float lg[4];
    if (iskb) {
      float addk = C0F + (padf[r] ? PADF : 0.f);
      lg[0] = SCALE * lg0 + addk;
      lg[1] = SCALE * lg1 + addk;
      lg[2] = SCALE * lg2 + addk;
      lg[3] = SCALE * lg3 + addk;
    } else {
      lg[0] = SCALE * lg0 + pm[r][i];
      lg[1] = SCALE * lg1 + pm[r][i + 16];
      lg[2] = SCALE * lg2 + pm[r][i + 32];
      lg[3] = SCALE * lg3 + pm[r][i + 48];
    }

    // online softmax across the 16 lanes of this row
    float cmax = fmaxf(fmaxf(lg[0], lg[1]), fmaxf(lg[2], lg[3]));
#pragma unroll
    for (int off = 8; off; off >>= 1) cmax = fmaxf(cmax, __shfl_xor(cmax, off));
    float mn = fmaxf(m, cmax);
    float fs = __expf(m - mn);
    float csum = 0.f;
#pragma unroll
    for (int jj = 0; jj < 4; ++jj) {
      float p = __expf(lg[jj] - mn);
      pm[r][i + 16 * jj] = p;   // same lanes that read mask; same-wave ordering
      csum += p;
    }
#pragma unroll
    for (int off = 8; off; off >>= 1) csum += __shfl_xor(csum, off);
    m = mn;
    l = l * fs + csum;
    acc.x *= fs; acc.y *= fs; acc.z *= fs; acc.w *= fs;

    // PV: row r, cols i*4..+3 over all 64 keys of the chunk
#pragma unroll
    for (int j = 0; j < KC; j += 4) {
      float4 p4 = *(const float4*)&pm[r][j];
      float4 v0 = *(const float4*)&vt[j][i * 4];
      float4 v1 = *(const float4*)&vt[j + 1][i * 4];
      float4 v2 = *(const float4*)&vt[j + 2][i * 4];
      float4 v3 = *(const float4*)&vt[j + 3][i * 4];
      acc.x += p4.x * v0.x + p4.y * v1.x + p4.z * v2.x + p4.w * v3.x;
      acc.y += p4.x * v0.y + p4.y * v1.y + p4.z * v2.y + p4.w * v3.y;
      acc.z += p4.x * v0.z + p4.y * v1.z + p4.z * v2.z + p4.w * v3.z;
      acc.w += p4.x * v0.w + p4.y * v1.w + p4.z * v2.w + p4.w * v3.w;
    }
  }

  float inv = 1.f / l;
  size_t o = (size_t)(b * S + s0 + r) * (NH * HD) + h * 64 + i * 4;
  *(float4*)&attn[o] = make_float4(acc.x * inv, acc.y * inv, acc.z * inv, acc.w * inv);
}

// ---------------------------------------------------------------------------
extern "C" void kernel_launch(void* const* d_in, const int* in_sizes, int n_in,
                              void* d_out, int out_size, void* d_ws, size_t ws_size,
                              hipStream_t stream) {
  const float* hidden = (const float*)d_in[0];
  const float* cosb   = (const float*)d_in[1];
  const float* sinb   = (const float*)d_in[2];
  const float* mask   = (const float*)d_in[3];
  const float* kbk    = (const float*)d_in[4];
  const float* kbv    = (const float*)d_in[5];
  const float* Wq     = (const float*)d_in[6];
  const float* Wq2    = (const float*)d_in[7];
  const float* Wk     = (const float*)d_in[8];
  const float* Wv     = (const float*)d_in[9];
  const float* Wo     = (const float*)d_in[10];
  float* out = (float*)d_out;

  const int H   = in_sizes[6] / (NH * HD);             // 2048
  const int KBL = in_sizes[4] / KBROW;                 // 400
  const long long BSll = (long long)in_sizes[0] / H;
  const int S = (int)((long long)in_sizes[3] / BSll);  // 1024
  const int B = (int)(BSll / S);                       // 2
  const int BS = B * S;
  const int NQ = NH * HD;                              // 2048
  const int NKVD = NKV * HD;                           // 512

  float* ws = (float*)d_ws;
  size_t off = 0;
  float* qb   = ws + off; off += (size_t)BS * NQ;
  float* q2b  = ws + off; off += (size_t)BS * NQ;
  float* kb   = ws + off; off += (size_t)BS * NKVD;
  float* vb   = ws + off; off += (size_t)BS * NKVD;
  float* attn = ws + off; off += (size_t)BS * NQ;
  float* Qs   = ws + off; off += (size_t)B * NQ;
  float* sc   = ws + off; off += (size_t)B * KBL;
  int* topi   = (int*)(ws + off); off += (size_t)B * TOPK;
  int* padfl  = (int*)(ws + off); off += (size_t)BS;
  (void)ws_size; (void)n_in; (void)out_size;

  gemm_nt_f32<<<dim3(NQ / 64, BS / 64), 256, 0, stream>>>(hidden, Wq, qb, BS, NQ, H);
  gemm_nt_f32<<<dim3(NQ / 64, BS / 64), 256, 0, stream>>>(hidden, Wq2, q2b, BS, NQ, H);
  gemm_nt_f32<<<dim3(NKVD / 64, BS / 64), 256, 0, stream>>>(hidden, Wk, kb, BS, NKVD, H);
  gemm_nt_f32<<<dim3(NKVD / 64, BS / 64), 256, 0, stream>>>(hidden, Wv, vb, BS, NKVD, H);

  {
    int tq = BS * NH * 32;
    rope_kernel<<<(tq + 255) / 256, 256, 0, stream>>>(qb, cosb, sinb, BS, NH);
    int tk = BS * NKV * 32;
    rope_kernel<<<(tk + 255) / 256, 256, 0, stream>>>(kb, cosb, sinb, BS, NKV);
  }

  colsum_kernel<<<(B * NQ + 255) / 256, 256, 0, stream>>>(q2b, Qs, B, S);
  scores_kernel<<<(B * KBL * 64 + 255) / 256, 256, 0, stream>>>(Qs, kbk, sc, B, KBL);
  topk_kernel<<<B, 64, 0, stream>>>(sc, topi, KBL);
  padflag_kernel<<<(BS * 64 + 255) / 256, 256, 0, stream>>>(mask, padfl, BS, S);

  attn_flash<<<B * NH * (S / QBLK), 256, 0, stream>>>(
      qb, q2b, kb, vb, kbk, kbv, mask, topi, padfl, attn, B, S);

  gemm_nt_f32<<<dim3(H / 64, BS / 64), 256, 0, stream>>>(attn, Wo, out, BS, H, NQ);
}

// Round 4
// 1215.297 us; speedup vs baseline: 2.4599x; 1.4935x over previous
//
#include <hip/hip_runtime.h>
#include <hip/hip_bf16.h>
#include <math.h>

#define NH 32
#define NKV 8
#define HD 64
#define NSLOTS 11
#define TOPK 128
#define KBROW (NSLOTS * NH * HD)   // 22528
#define PADF (-3.3895313892515355e+38f)
#define C0F  (-0.24686007793152578f)   // -ln(128)+ln(100)
#define SCALE 0.125f

#define QBLK 16
#define KC 64
#define LPAD 68

typedef __attribute__((ext_vector_type(8))) __bf16 bf16x8;
typedef __attribute__((ext_vector_type(4))) float f32x4;

#define GLDS16(gp, lp)                                                        \
  __builtin_amdgcn_global_load_lds(                                           \
      (__attribute__((address_space(1))) void*)(gp),                          \
      (__attribute__((address_space(3))) void*)(lp), 16, 0, 0)

__device__ __forceinline__ unsigned short f2bf(float f) {
  unsigned int u = __float_as_uint(f);
  u = (u + 0x7fffu + ((u >> 16) & 1u)) >> 16;
  return (unsigned short)u;
}

// ---------------------------------------------------------------------------
// fp32 -> bf16 (RTNE), 4 elems/thread.
// ---------------------------------------------------------------------------
__global__ void f2bf_kernel(const float* __restrict__ in,
                            unsigned short* __restrict__ out, int n4) {
  int i = blockIdx.x * blockDim.x + threadIdx.x;
  if (i >= n4) return;
  float4 v = ((const float4*)in)[i];
  ushort4 o;
  o.x = f2bf(v.x); o.y = f2bf(v.y); o.z = f2bf(v.z); o.w = f2bf(v.w);
  ((ushort4*)out)[i] = o;
}

// ---------------------------------------------------------------------------
// bf16 MFMA GEMM (m97 structure): C[M,N] f32 = A[M,K] @ B[N,K]^T.
// Tile 128x128, BK=32, 4 waves (2x2), 16x16x32 MFMA. M,N %128, K %32.
// ---------------------------------------------------------------------------
__global__ __launch_bounds__(256) void gemm_nt_bf16(
    const unsigned short* __restrict__ A, const unsigned short* __restrict__ B,
    float* __restrict__ C, int M, int N, int K) {
  __shared__ unsigned short ldsA[128 * 32];
  __shared__ unsigned short ldsB[128 * 32];
  const int t = threadIdx.x;
  const int l = t & 63, w = t >> 6;
  const int wr = w >> 1, wc = w & 1;
  const int lr = l & 15;
  const int kb = (l >> 4) * 16;
  const int bm = blockIdx.y * 128, bn = blockIdx.x * 128;

  f32x4 acc[4][4] = {};

  for (int k0 = 0; k0 < K; k0 += 32) {
    __syncthreads();
#pragma unroll
    for (int it = 0; it < 2; ++it) {
      int s = it * 256 + t;
      int row = s >> 2, cs = (s & 3) * 8;
      GLDS16(A + (size_t)(bm + row) * K + k0 + cs,
             (char*)ldsA + (it * 4 + w) * 1024);
      GLDS16(B + (size_t)(bn + row) * K + k0 + cs,
             (char*)ldsB + (it * 4 + w) * 1024);
    }
    __syncthreads();

    bf16x8 a[4], b[4];
#pragma unroll
    for (int m = 0; m < 4; ++m)
      a[m] = *(const bf16x8*)((const char*)ldsA +
                              (wr * 64 + m * 16 + lr) * 64 + kb);
#pragma unroll
    for (int n = 0; n < 4; ++n)
      b[n] = *(const bf16x8*)((const char*)ldsB +
                              (wc * 64 + n * 16 + lr) * 64 + kb);
#pragma unroll
    for (int m = 0; m < 4; ++m)
#pragma unroll
      for (int n = 0; n < 4; ++n)
        acc[m][n] =
            __builtin_amdgcn_mfma_f32_16x16x32_bf16(a[m], b[n], acc[m][n], 0, 0, 0);
  }

#pragma unroll
  for (int m = 0; m < 4; ++m)
#pragma unroll
    for (int n = 0; n < 4; ++n) {
      int rbase = bm + wr * 64 + m * 16 + ((l >> 4) << 2);
      int cbase = bn + wc * 64 + n * 16 + lr;
#pragma unroll
      for (int j = 0; j < 4; ++j)
        C[(size_t)(rbase + j) * N + cbase] = acc[m][n][j];
    }
}

// ---------------------------------------------------------------------------
// RoPE in-place on x laid out [rows][nheads*64]; cos/sin are [rows][64].
// ---------------------------------------------------------------------------
__global__ void rope_kernel(float* __restrict__ x, const float* __restrict__ c,
                            const float* __restrict__ s, int rows, int nheads) {
  int tid = blockIdx.x * blockDim.x + threadIdx.x;
  int total = rows * nheads * 32;
  if (tid >= total) return;
  int d = tid & 31;
  int h = (tid >> 5) % nheads;
  int row = tid / (32 * nheads);
  float* xr = x + ((size_t)row * nheads + h) * 64;
  float c1 = c[(size_t)row * 64 + d], c2 = c[(size_t)row * 64 + d + 32];
  float s1 = s[(size_t)row * 64 + d], s2 = s[(size_t)row * 64 + d + 32];
  float x1 = xr[d], x2 = xr[d + 32];
  xr[d]      = x1 * c1 - x2 * s1;
  xr[d + 32] = x2 * c2 + x1 * s2;
}

// ---------------------------------------------------------------------------
// Hsum[b][c] = sum_s hidden[b][s][c]  (fp32 input, f64 accum) — exact scores
// path, independent of bf16 projections.
// ---------------------------------------------------------------------------
__global__ void hsum_kernel(const float* __restrict__ hidden,
                            float* __restrict__ Hsum, int B, int S, int H) {
  int idx = blockIdx.x * blockDim.x + threadIdx.x;
  if (idx >= B * H) return;
  int b = idx / H, c = idx % H;
  const float* p = hidden + (size_t)b * S * H + c;
  double acc = 0.0;
  for (int s = 0; s < S; ++s) acc += (double)p[(size_t)s * H];
  Hsum[idx] = (float)acc;
}

// ---------------------------------------------------------------------------
// Qs[b][c] = sum_k Hsum[b][k] * Wq2[c][k]  (fp32 inputs, f64 accum).
// One wave per (b,c).
// ---------------------------------------------------------------------------
__global__ void qs_kernel(const float* __restrict__ Hsum,
                          const float* __restrict__ Wq2,
                          float* __restrict__ Qs, int B, int H) {
  int task = (blockIdx.x * blockDim.x + threadIdx.x) >> 6;
  int lane = threadIdx.x & 63;
  if (task >= B * NH * HD) return;
  int b = task / (NH * HD), c = task % (NH * HD);
  const float* hs = Hsum + (size_t)b * H;
  const float* wr = Wq2 + (size_t)c * H;
  double acc = 0.0;
  for (int k = lane; k < H; k += 64) acc += (double)hs[k] * (double)wr[k];
#pragma unroll
  for (int off = 32; off; off >>= 1) acc += __shfl_xor(acc, off);
  if (lane == 0) Qs[task] = (float)acc;
}

// ---------------------------------------------------------------------------
// scores[b][l] = 0.125 * dot(Qs[b,:], kb_keys[l, 0:2048]) (f64 acc)
// ---------------------------------------------------------------------------
__global__ void scores_kernel(const float* __restrict__ Qs,
                              const float* __restrict__ kbk,
                              float* __restrict__ scores, int B, int KBL) {
  int task = (blockIdx.x * blockDim.x + threadIdx.x) >> 6;
  int lane = threadIdx.x & 63;
  if (task >= B * KBL) return;
  int b = task / KBL, l = task % KBL;
  const float* kr = kbk + (size_t)l * KBROW;
  const float* qd = Qs + (size_t)b * NH * HD;
  double acc = 0.0;
  for (int c = lane; c < NH * HD; c += 64) acc += (double)qd[c] * (double)kr[c];
#pragma unroll
  for (int off = 32; off; off >>= 1) acc += __shfl_xor(acc, off);
  if (lane == 0) scores[task] = (float)(0.125 * acc);
}

// ---------------------------------------------------------------------------
// Top-K (descending, ties -> lower index). One wave per batch.
// ---------------------------------------------------------------------------
__global__ void topk_kernel(const float* __restrict__ scores,
                            int* __restrict__ top_idx, int KBL) {
  __shared__ float ls[512];
  int b = blockIdx.x, lane = threadIdx.x;
  for (int i = lane; i < KBL; i += 64) ls[i] = scores[(size_t)b * KBL + i];
  __syncthreads();
  for (int it = 0; it < TOPK; ++it) {
    float bv = -3.4e38f; int bi = 0x7fffffff;
    for (int i = lane; i < KBL; i += 64) {
      float v = ls[i];
      if (v > bv || (v == bv && i < bi)) { bv = v; bi = i; }
    }
#pragma unroll
    for (int off = 32; off; off >>= 1) {
      float ov = __shfl_xor(bv, off);
      int oi = __shfl_xor(bi, off);
      if (ov > bv || (ov == bv && oi < bi)) { bv = ov; bi = oi; }
    }
    if (lane == 0) { top_idx[b * TOPK + it] = bi; ls[bi] = -3.4e38f; }
    __syncthreads();
  }
}

// ---------------------------------------------------------------------------
// padflag[b*S+s] = all(mask[b,0,s,:] < 0)
// ---------------------------------------------------------------------------
__global__ void padflag_kernel(const float* __restrict__ mask,
                               int* __restrict__ flags, int BS, int S) {
  int w = (blockIdx.x * blockDim.x + threadIdx.x) >> 6;
  int lane = threadIdx.x & 63;
  if (w >= BS) return;
  const float* row = mask + (size_t)w * S;
  bool ok = true;
  for (int j = lane; j < S; j += 64) ok = ok && (row[j] < 0.f);
  int allv = __all(ok ? 1 : 0);
  if (lane == 0) flags[w] = allv;
}

// ---------------------------------------------------------------------------
// Flash-style fused attention (unchanged). 16 q-rows x 16 lanes.
// ---------------------------------------------------------------------------
__global__ __launch_bounds__(256) void attn_flash(
    const float* __restrict__ qbuf,   // [B*S][2048] roped
    const float* __restrict__ q2buf,  // [B*S][2048] un-roped
    const float* __restrict__ kbuf,   // [B*S][NKV*64] roped
    const float* __restrict__ vbuf,   // [B*S][NKV*64]
    const float* __restrict__ kb_keys,
    const float* __restrict__ kb_values,
    const float* __restrict__ mask,   // [B][S][S]
    const int* __restrict__ top_idx,  // [B][TOPK]
    const int* __restrict__ padflag,  // [B*S]
    float* __restrict__ attn,         // [B*S][2048]
    int B, int S) {
  const int nst = S / QBLK;
  const int st = blockIdx.x % nst;
  const int h  = (blockIdx.x / nst) % NH;
  const int b  = blockIdx.x / (nst * NH);
  const int s0 = st * QBLK;
  const int g  = h / (NH / NKV);

  __shared__ float qt[2][QBLK][LPAD];
  __shared__ float kt[KC][LPAD];
  __shared__ float vt[KC][LPAD];
  __shared__ float pm[QBLK][LPAD];
  __shared__ int   idxs[TOPK];
  __shared__ int   padf[QBLK];

  const int t = threadIdx.x;
  const int r = t >> 4;
  const int i = t & 15;

  for (int f = t; f < 2 * QBLK * 16; f += 256) {
    int sel = f >> 8;
    int rr = (f >> 4) & (QBLK - 1);
    int c4 = (f & 15) * 4;
    const float* src = sel ? q2buf : qbuf;
    *(float4*)&qt[sel][rr][c4] =
        *(const float4*)&src[(size_t)(b * S + s0 + rr) * (NH * HD) + h * 64 + c4];
  }
  if (t < TOPK) idxs[t] = top_idx[b * TOPK + t];
  if (t < QBLK) padf[t] = padflag[b * S + s0 + t];

  float m = -3.4e38f, l = 0.f;
  float4 acc = make_float4(0.f, 0.f, 0.f, 0.f);

  const int nch_kb = TOPK / KC;
  const int nch_seq = (s0 + QBLK + KC - 1) / KC;
  const int nch = nch_kb + nch_seq;

  for (int ch = 0; ch < nch; ++ch) {
    const bool iskb = (ch < nch_kb);
    const int j0 = iskb ? ch * KC : (ch - nch_kb) * KC;
    __syncthreads();
    for (int f = t; f < KC * 16; f += 256) {
      int row = f >> 4, c4 = (f & 15) * 4;
      const float *kp, *vp;
      if (iskb) {
        int jk = j0 + row;
        kp = kb_keys   + (size_t)jk * KBROW + h * 64 + c4;
        vp = kb_values + (size_t)idxs[jk] * KBROW + h * 64 + c4;
      } else {
        int js = j0 + row;
        kp = kbuf + ((size_t)(b * S + js) * NKV + g) * 64 + c4;
        vp = vbuf + ((size_t)(b * S + js) * NKV + g) * 64 + c4;
      }
      *(float4*)&kt[row][c4] = *(const float4*)kp;
      *(float4*)&vt[row][c4] = *(const float4*)vp;
    }
    if (!iskb) {
      for (int f = t; f < QBLK * 16; f += 256) {
        int rr = f >> 4, c4 = (f & 15) * 4;
        *(float4*)&pm[rr][c4] =
            *(const float4*)&mask[((size_t)(b * S) + s0 + rr) * S + j0 + c4];
      }
    }
    __syncthreads();

    const float* qrow = qt[iskb ? 1 : 0][r];
    float lg0 = 0.f, lg1 = 0.f, lg2 = 0.f, lg3 = 0.f;
#pragma unroll
    for (int d = 0; d < 64; d += 4) {
      float4 qv = *(const float4*)&qrow[d];
      float4 k0 = *(const float4*)&kt[i][d];
      float4 k1 = *(const float4*)&kt[i + 16][d];
      float4 k2 = *(const float4*)&kt[i + 32][d];
      float4 k3 = *(const float4*)&kt[i + 48][d];
      lg0 += qv.x * k0.x + qv.y * k0.y + qv.z * k0.z + qv.w * k0.w;
      lg1 += qv.x * k1.x + qv.y * k1.y + qv.z * k1.z + qv.w * k1.w;
      lg2 += qv.x * k2.x + qv.y * k2.y + qv.z * k2.z + qv.w * k2.w;
      lg3 += qv.x * k3.x + qv.y * k3.y + qv.z * k3.z + qv.w * k3.w;
    }
    float lg[4];
    if (iskb) {
      float addk = C0F + (padf[r] ? PADF : 0.f);
      lg[0] = SCALE * lg0 + addk;
      lg[1] = SCALE * lg1 + addk;
      lg[2] = SCALE * lg2 + addk;
      lg[3] = SCALE * lg3 + addk;
    } else {
      lg[0] = SCALE * lg0 + pm[r][i];
      lg[1] = SCALE * lg1 + pm[r][i + 16];
      lg[2] = SCALE * lg2 + pm[r][i + 32];
      lg[3] = SCALE * lg3 + pm[r][i + 48];
    }

    float cmax = fmaxf(fmaxf(lg[0], lg[1]), fmaxf(lg[2], lg[3]));
#pragma unroll
    for (int off = 8; off; off >>= 1) cmax = fmaxf(cmax, __shfl_xor(cmax, off));
    float mn = fmaxf(m, cmax);
    float fs = __expf(m - mn);
    float csum = 0.f;
#pragma unroll
    for (int jj = 0; jj < 4; ++jj) {
      float p = __expf(lg[jj] - mn);
      pm[r][i + 16 * jj] = p;
      csum += p;
    }
#pragma unroll
    for (int off = 8; off; off >>= 1) csum += __shfl_xor(csum, off);
    m = mn;
    l = l * fs + csum;
    acc.x *= fs; acc.y *= fs; acc.z *= fs; acc.w *= fs;

#pragma unroll
    for (int j = 0; j < KC; j += 4) {
      float4 p4 = *(const float4*)&pm[r][j];
      float4 v0 = *(const float4*)&vt[j][i * 4];
      float4 v1 = *(const float4*)&vt[j + 1][i * 4];
      float4 v2 = *(const float4*)&vt[j + 2][i * 4];
      float4 v3 = *(const float4*)&vt[j + 3][i * 4];
      acc.x += p4.x * v0.x + p4.y * v1.x + p4.z * v2.x + p4.w * v3.x;
      acc.y += p4.x * v0.y + p4.y * v1.y + p4.z * v2.y + p4.w * v3.y;
      acc.z += p4.x * v0.z + p4.y * v1.z + p4.z * v2.z + p4.w * v3.z;
      acc.w += p4.x * v0.w + p4.y * v1.w + p4.z * v2.w + p4.w * v3.w;
    }
  }

  float inv = 1.f / l;
  size_t o = (size_t)(b * S + s0 + r) * (NH * HD) + h * 64 + i * 4;
  *(float4*)&attn[o] = make_float4(acc.x * inv, acc.y * inv, acc.z * inv, acc.w * inv);
}

// ---------------------------------------------------------------------------
extern "C" void kernel_launch(void* const* d_in, const int* in_sizes, int n_in,
                              void* d_out, int out_size, void* d_ws, size_t ws_size,
                              hipStream_t stream) {
  const float* hidden = (const float*)d_in[0];
  const float* cosb   = (const float*)d_in[1];
  const float* sinb   = (const float*)d_in[2];
  const float* mask   = (const float*)d_in[3];
  const float* kbk    = (const float*)d_in[4];
  const float* kbv    = (const float*)d_in[5];
  const float* Wq     = (const float*)d_in[6];
  const float* Wq2    = (const float*)d_in[7];
  const float* Wk     = (const float*)d_in[8];
  const float* Wv     = (const float*)d_in[9];
  const float* Wo     = (const float*)d_in[10];
  float* out = (float*)d_out;

  const int H   = in_sizes[6] / (NH * HD);             // 2048
  const int KBL = in_sizes[4] / KBROW;                 // 400
  const long long BSll = (long long)in_sizes[0] / H;
  const int S = (int)((long long)in_sizes[3] / BSll);  // 1024
  const int B = (int)(BSll / S);                       // 2
  const int BS = B * S;
  const int NQ = NH * HD;                              // 2048
  const int NKVD = NKV * HD;                           // 512

  float* ws = (float*)d_ws;
  size_t off = 0;
  float* qb   = ws + off; off += (size_t)BS * NQ;
  float* q2b  = ws + off; off += (size_t)BS * NQ;
  float* kb   = ws + off; off += (size_t)BS * NKVD;
  float* vb   = ws + off; off += (size_t)BS * NKVD;
  float* attn = ws + off; off += (size_t)BS * NQ;
  float* Hsum = ws + off; off += (size_t)B * H;
  float* Qs   = ws + off; off += (size_t)B * NQ;
  float* sc   = ws + off; off += (size_t)B * KBL;
  int* topi   = (int*)(ws + off); off += (size_t)B * TOPK;
  int* padfl  = (int*)(ws + off); off += (size_t)BS;
  unsigned short* hbf    = (unsigned short*)(ws + off); off += (size_t)BS * H / 2;
  unsigned short* wqbf   = (unsigned short*)(ws + off); off += (size_t)NQ * H / 2;
  unsigned short* wq2bf  = (unsigned short*)(ws + off); off += (size_t)NQ * H / 2;
  unsigned short* wkbf   = (unsigned short*)(ws + off); off += (size_t)NKVD * H / 2;
  unsigned short* wvbf   = (unsigned short*)(ws + off); off += (size_t)NKVD * H / 2;
  unsigned short* wobf   = (unsigned short*)(ws + off); off += (size_t)H * NQ / 2;
  unsigned short* attnbf = (unsigned short*)(ws + off); off += (size_t)BS * NQ / 2;
  (void)ws_size; (void)n_in; (void)out_size;

  // 0: fp32 -> bf16 conversions
  {
    int n;
    n = BS * H / 4;   f2bf_kernel<<<(n + 255) / 256, 256, 0, stream>>>(hidden, hbf, n);
    n = NQ * H / 4;   f2bf_kernel<<<(n + 255) / 256, 256, 0, stream>>>(Wq, wqbf, n);
    n = NQ * H / 4;   f2bf_kernel<<<(n + 255) / 256, 256, 0, stream>>>(Wq2, wq2bf, n);
    n = NKVD * H / 4; f2bf_kernel<<<(n + 255) / 256, 256, 0, stream>>>(Wk, wkbf, n);
    n = NKVD * H / 4; f2bf_kernel<<<(n + 255) / 256, 256, 0, stream>>>(Wv, wvbf, n);
    n = H * NQ / 4;   f2bf_kernel<<<(n + 255) / 256, 256, 0, stream>>>(Wo, wobf, n);
  }

  // 1-4: projections (bf16 MFMA)
  gemm_nt_bf16<<<dim3(NQ / 128, BS / 128), 256, 0, stream>>>(hbf, wqbf, qb, BS, NQ, H);
  gemm_nt_bf16<<<dim3(NQ / 128, BS / 128), 256, 0, stream>>>(hbf, wq2bf, q2b, BS, NQ, H);
  gemm_nt_bf16<<<dim3(NKVD / 128, BS / 128), 256, 0, stream>>>(hbf, wkbf, kb, BS, NKVD, H);
  gemm_nt_bf16<<<dim3(NKVD / 128, BS / 128), 256, 0, stream>>>(hbf, wvbf, vb, BS, NKVD, H);

  // 5-6: RoPE
  {
    int tq = BS * NH * 32;
    rope_kernel<<<(tq + 255) / 256, 256, 0, stream>>>(qb, cosb, sinb, BS, NH);
    int tk = BS * NKV * 32;
    rope_kernel<<<(tk + 255) / 256, 256, 0, stream>>>(kb, cosb, sinb, BS, NKV);
  }

  // 7-10: exact fp32 scores path (independent of bf16) + top-k + padding
  hsum_kernel<<<(B * H + 255) / 256, 256, 0, stream>>>(hidden, Hsum, B, S, H);
  qs_kernel<<<(B * NQ * 64 + 255) / 256, 256, 0, stream>>>(Hsum, Wq2, Qs, B, H);
  scores_kernel<<<(B * KBL * 64 + 255) / 256, 256, 0, stream>>>(Qs, kbk, sc, B, KBL);
  topk_kernel<<<B, 64, 0, stream>>>(sc, topi, KBL);
  padflag_kernel<<<(BS * 64 + 255) / 256, 256, 0, stream>>>(mask, padfl, BS, S);

  // 11: fused attention (fp32)
  attn_flash<<<B * NH * (S / QBLK), 256, 0, stream>>>(
      qb, q2b, kb, vb, kbk, kbv, mask, topi, padfl, attn, B, S);

  // 12: output projection (bf16 MFMA)
  {
    int n = BS * NQ / 4;
    f2bf_kernel<<<(n + 255) / 256, 256, 0, stream>>>(attn, attnbf, n);
  }
  gemm_nt_bf16<<<dim3(H / 128, BS / 128), 256, 0, stream>>>(attnbf, wobf, out, BS, H, NQ);
}

// Round 5
// 847.027 us; speedup vs baseline: 3.5294x; 1.4348x over previous
//
#include <hip/hip_runtime.h>
#include <hip/hip_bf16.h>
#include <math.h>

#define NH 32
#define NKV 8
#define HD 64
#define NSLOTS 11
#define TOPK 128
#define KBROW (NSLOTS * NH * HD)   // 22528
#define PADF (-3.3895313892515355e+38f)
#define C0F  (-0.24686007793152578f)   // -ln(128)+ln(100)
#define SCALE 0.125f

typedef __attribute__((ext_vector_type(8))) __bf16 bf16x8;
typedef __attribute__((ext_vector_type(4))) float f32x4;

#define GLDS16(gp, lp)                                                        \
  __builtin_amdgcn_global_load_lds(                                           \
      (__attribute__((address_space(1))) void*)(gp),                          \
      (__attribute__((address_space(3))) void*)(lp), 16, 0, 0)

__device__ __forceinline__ unsigned short f2bf(float f) {
  unsigned int u = __float_as_uint(f);
  u = (u + 0x7fffu + ((u >> 16) & 1u)) >> 16;
  return (unsigned short)u;
}

// byte offset into a 64-col bf16 tile (128 B/row) with XOR chunk swizzle
__device__ __forceinline__ int swz(int row, int chunk) {
  return row * 128 + ((chunk ^ (row & 7)) << 4);
}

// ---------------------------------------------------------------------------
// fp32 -> bf16 (RTNE), 4 elems/thread.
// ---------------------------------------------------------------------------
__global__ void f2bf_kernel(const float* __restrict__ in,
                            unsigned short* __restrict__ out, int n4) {
  int i = blockIdx.x * blockDim.x + threadIdx.x;
  if (i >= n4) return;
  float4 v = ((const float4*)in)[i];
  ushort4 o;
  o.x = f2bf(v.x); o.y = f2bf(v.y); o.z = f2bf(v.z); o.w = f2bf(v.w);
  ((ushort4*)out)[i] = o;
}

// ---------------------------------------------------------------------------
// bf16 MFMA GEMM (m97 structure): C[M,N] f32 = A[M,K] @ B[N,K]^T.
// Tile 128x128, BK=32, 4 waves (2x2), 16x16x32 MFMA. M,N %128, K %32.
// ---------------------------------------------------------------------------
__global__ __launch_bounds__(256) void gemm_nt_bf16(
    const unsigned short* __restrict__ A, const unsigned short* __restrict__ B,
    float* __restrict__ C, int M, int N, int K) {
  __shared__ unsigned short ldsA[128 * 32];
  __shared__ unsigned short ldsB[128 * 32];
  const int t = threadIdx.x;
  const int l = t & 63, w = t >> 6;
  const int wr = w >> 1, wc = w & 1;
  const int lr = l & 15;
  const int kb = (l >> 4) * 16;
  const int bm = blockIdx.y * 128, bn = blockIdx.x * 128;

  f32x4 acc[4][4] = {};

  for (int k0 = 0; k0 < K; k0 += 32) {
    __syncthreads();
#pragma unroll
    for (int it = 0; it < 2; ++it) {
      int s = it * 256 + t;
      int row = s >> 2, cs = (s & 3) * 8;
      GLDS16(A + (size_t)(bm + row) * K + k0 + cs,
             (char*)ldsA + (it * 4 + w) * 1024);
      GLDS16(B + (size_t)(bn + row) * K + k0 + cs,
             (char*)ldsB + (it * 4 + w) * 1024);
    }
    __syncthreads();

    bf16x8 a[4], b[4];
#pragma unroll
    for (int m = 0; m < 4; ++m)
      a[m] = *(const bf16x8*)((const char*)ldsA +
                              (wr * 64 + m * 16 + lr) * 64 + kb);
#pragma unroll
    for (int n = 0; n < 4; ++n)
      b[n] = *(const bf16x8*)((const char*)ldsB +
                              (wc * 64 + n * 16 + lr) * 64 + kb);
#pragma unroll
    for (int m = 0; m < 4; ++m)
#pragma unroll
      for (int n = 0; n < 4; ++n)
        acc[m][n] =
            __builtin_amdgcn_mfma_f32_16x16x32_bf16(a[m], b[n], acc[m][n], 0, 0, 0);
  }

#pragma unroll
  for (int m = 0; m < 4; ++m)
#pragma unroll
    for (int n = 0; n < 4; ++n) {
      int rbase = bm + wr * 64 + m * 16 + ((l >> 4) << 2);
      int cbase = bn + wc * 64 + n * 16 + lr;
#pragma unroll
      for (int j = 0; j < 4; ++j)
        C[(size_t)(rbase + j) * N + cbase] = acc[m][n][j];
    }
}

// ---------------------------------------------------------------------------
// RoPE in-place on x laid out [rows][nheads*64]; cos/sin are [rows][64].
// ---------------------------------------------------------------------------
__global__ void rope_kernel(float* __restrict__ x, const float* __restrict__ c,
                            const float* __restrict__ s, int rows, int nheads) {
  int tid = blockIdx.x * blockDim.x + threadIdx.x;
  int total = rows * nheads * 32;
  if (tid >= total) return;
  int d = tid & 31;
  int h = (tid >> 5) % nheads;
  int row = tid / (32 * nheads);
  float* xr = x + ((size_t)row * nheads + h) * 64;
  float c1 = c[(size_t)row * 64 + d], c2 = c[(size_t)row * 64 + d + 32];
  float s1 = s[(size_t)row * 64 + d], s2 = s[(size_t)row * 64 + d + 32];
  float x1 = xr[d], x2 = xr[d + 32];
  xr[d]      = x1 * c1 - x2 * s1;
  xr[d + 32] = x2 * c2 + x1 * s2;
}

// ---------------------------------------------------------------------------
// Hsum[b][c] = sum_s hidden[b][s][c]  (fp32, f64 accum) — exact scores path.
// ---------------------------------------------------------------------------
__global__ void hsum_kernel(const float* __restrict__ hidden,
                            float* __restrict__ Hsum, int B, int S, int H) {
  int idx = blockIdx.x * blockDim.x + threadIdx.x;
  if (idx >= B * H) return;
  int b = idx / H, c = idx % H;
  const float* p = hidden + (size_t)b * S * H + c;
  double acc = 0.0;
  for (int s = 0; s < S; ++s) acc += (double)p[(size_t)s * H];
  Hsum[idx] = (float)acc;
}

// ---------------------------------------------------------------------------
// Qs[b][c] = sum_k Hsum[b][k] * Wq2[c][k]  (fp32 inputs, f64 accum).
// ---------------------------------------------------------------------------
__global__ void qs_kernel(const float* __restrict__ Hsum,
                          const float* __restrict__ Wq2,
                          float* __restrict__ Qs, int B, int H) {
  int task = (blockIdx.x * blockDim.x + threadIdx.x) >> 6;
  int lane = threadIdx.x & 63;
  if (task >= B * NH * HD) return;
  int b = task / (NH * HD), c = task % (NH * HD);
  const float* hs = Hsum + (size_t)b * H;
  const float* wr = Wq2 + (size_t)c * H;
  double acc = 0.0;
  for (int k = lane; k < H; k += 64) acc += (double)hs[k] * (double)wr[k];
#pragma unroll
  for (int off = 32; off; off >>= 1) acc += __shfl_xor(acc, off);
  if (lane == 0) Qs[task] = (float)acc;
}

// ---------------------------------------------------------------------------
// scores[b][l] = 0.125 * dot(Qs[b,:], kb_keys[l, 0:2048]) (f64 acc)
// ---------------------------------------------------------------------------
__global__ void scores_kernel(const float* __restrict__ Qs,
                              const float* __restrict__ kbk,
                              float* __restrict__ scores, int B, int KBL) {
  int task = (blockIdx.x * blockDim.x + threadIdx.x) >> 6;
  int lane = threadIdx.x & 63;
  if (task >= B * KBL) return;
  int b = task / KBL, l = task % KBL;
  const float* kr = kbk + (size_t)l * KBROW;
  const float* qd = Qs + (size_t)b * NH * HD;
  double acc = 0.0;
  for (int c = lane; c < NH * HD; c += 64) acc += (double)qd[c] * (double)kr[c];
#pragma unroll
  for (int off = 32; off; off >>= 1) acc += __shfl_xor(acc, off);
  if (lane == 0) scores[task] = (float)(0.125 * acc);
}

// ---------------------------------------------------------------------------
// Top-K (descending, ties -> lower index). One wave per batch.
// ---------------------------------------------------------------------------
__global__ void topk_kernel(const float* __restrict__ scores,
                            int* __restrict__ top_idx, int KBL) {
  __shared__ float ls[512];
  int b = blockIdx.x, lane = threadIdx.x;
  for (int i = lane; i < KBL; i += 64) ls[i] = scores[(size_t)b * KBL + i];
  __syncthreads();
  for (int it = 0; it < TOPK; ++it) {
    float bv = -3.4e38f; int bi = 0x7fffffff;
    for (int i = lane; i < KBL; i += 64) {
      float v = ls[i];
      if (v > bv || (v == bv && i < bi)) { bv = v; bi = i; }
    }
#pragma unroll
    for (int off = 32; off; off >>= 1) {
      float ov = __shfl_xor(bv, off);
      int oi = __shfl_xor(bi, off);
      if (ov > bv || (ov == bv && oi < bi)) { bv = ov; bi = oi; }
    }
    if (lane == 0) { top_idx[b * TOPK + it] = bi; ls[bi] = -3.4e38f; }
    __syncthreads();
  }
}

// ---------------------------------------------------------------------------
// padflag[b*S+s] = all(mask[b,0,s,:] < 0)
// ---------------------------------------------------------------------------
__global__ void padflag_kernel(const float* __restrict__ mask,
                               int* __restrict__ flags, int BS, int S) {
  int w = (blockIdx.x * blockDim.x + threadIdx.x) >> 6;
  int lane = threadIdx.x & 63;
  if (w >= BS) return;
  const float* row = mask + (size_t)w * S;
  bool ok = true;
  for (int j = lane; j < S; j += 64) ok = ok && (row[j] < 0.f);
  int allv = __all(ok ? 1 : 0);
  if (lane == 0) flags[w] = allv;
}

// ---------------------------------------------------------------------------
// MFMA fused attention. Block = 256 thr = 4 waves; 64 q-rows of one (b,h).
// Wave w owns rows w*16..w*16+15. 64-key chunks: 2 KB chunks (q2, +C0F,
// gathered V), then st+1 causal seq chunks (roped q, analytic causal mask).
// QK^T and PV via mfma_f32_16x16x32_bf16; P via per-wave LDS tile (bf16).
// All LDS tiles 64-col bf16 with XOR chunk swizzle -> conflict-free b128.
// ---------------------------------------------------------------------------
__global__ __launch_bounds__(256) void attn_mfma(
    const float* __restrict__ qbuf,   // [B*S][2048] roped
    const float* __restrict__ q2buf,  // [B*S][2048] un-roped
    const float* __restrict__ kbuf,   // [B*S][NKV*64] roped
    const float* __restrict__ vbuf,   // [B*S][NKV*64]
    const float* __restrict__ kb_keys,
    const float* __restrict__ kb_values,
    const int* __restrict__ top_idx,  // [B][TOPK]
    const int* __restrict__ padflag,  // [B*S]
    float* __restrict__ attn,         // [B*S][2048]
    int B, int S) {
  const int nst = S >> 6;
  const int st = blockIdx.x % nst;
  const int h  = (blockIdx.x / nst) % NH;
  const int b  = blockIdx.x / (nst * NH);
  const int s0 = st * 64;
  const int g  = h / (NH / NKV);

  __shared__ unsigned short qt2[2][4096];  // [0]=q roped, [1]=q2 (64x64 bf16)
  __shared__ unsigned short kt[4096];      // K chunk   [key][d]
  __shared__ unsigned short vtt[4096];     // V^T chunk [d][key]
  __shared__ unsigned short pt[4][1024];   // per-wave P [row16][key64]
  __shared__ int idxs[TOPK];
  __shared__ int padf[64];

  const int t = threadIdx.x;
  const int w = t >> 6;
  const int li = t & 15;        // lane & 15
  const int lg4 = (t & 63) >> 4;  // lane >> 4  (0..3)

  // ---- phase A: stage q/q2 tiles (bf16, swizzled), idxs, padflags
  for (int slot = t; slot < 2048; slot += 256) {
    int sel = slot >> 10;
    int row = (slot >> 4) & 63;
    int d4 = (slot & 15) << 2;
    const float* src = sel ? q2buf : qbuf;
    float4 v = *(const float4*)&src[(size_t)(b * S + s0 + row) * (NH * HD) +
                                    h * 64 + d4];
    ushort4 o = {f2bf(v.x), f2bf(v.y), f2bf(v.z), f2bf(v.w)};
    *(ushort4*)((char*)qt2[sel] + swz(row, d4 >> 3) + ((d4 & 7) << 1)) = o;
  }
  if (t < TOPK) idxs[t] = top_idx[b * TOPK + t];
  if (t < 64) padf[t] = padflag[b * S + s0 + t];
  __syncthreads();

  // hoist q a-fragments (constant across chunks): row = w*16+li
  bf16x8 aq0[2], aq2[2];
#pragma unroll
  for (int kc = 0; kc < 2; ++kc) {
    aq0[kc] = *(const bf16x8*)((const char*)qt2[0] + swz(w * 16 + li, kc * 4 + lg4));
    aq2[kc] = *(const bf16x8*)((const char*)qt2[1] + swz(w * 16 + li, kc * 4 + lg4));
  }

  float m_[4] = {-3.4e38f, -3.4e38f, -3.4e38f, -3.4e38f};
  float l_[4] = {};
  f32x4 acc[4] = {};   // [d-block]; reg j = row g4*4+j

  const int nch = 2 + st + 1;
  for (int ch = 0; ch < nch; ++ch) {
    const bool iskb = ch < 2;
    const int j0 = iskb ? ch * 64 : (ch - 2) * 64;
    __syncthreads();  // all waves done reading prev K/V
    // ---- stage K chunk + V^T chunk (bf16, swizzled)
    for (int slot = t; slot < 1024; slot += 256) {
      int row = slot >> 4, d4 = (slot & 15) << 2;
      const float *kp, *vp;
      if (iskb) {
        kp = kb_keys + (size_t)(j0 + row) * KBROW + h * 64 + d4;
        vp = kb_values + (size_t)idxs[j0 + row] * KBROW + h * 64 + d4;
      } else {
        int js = j0 + row;
        kp = kbuf + ((size_t)(b * S + js) * NKV + g) * 64 + d4;
        vp = vbuf + ((size_t)(b * S + js) * NKV + g) * 64 + d4;
      }
      float4 kv = *(const float4*)kp;
      float4 vv = *(const float4*)vp;
      ushort4 ko = {f2bf(kv.x), f2bf(kv.y), f2bf(kv.z), f2bf(kv.w)};
      *(ushort4*)((char*)kt + swz(row, d4 >> 3) + ((d4 & 7) << 1)) = ko;
      unsigned short vo[4] = {f2bf(vv.x), f2bf(vv.y), f2bf(vv.z), f2bf(vv.w)};
#pragma unroll
      for (int i2 = 0; i2 < 4; ++i2) {
        int d = d4 + i2;
        *(unsigned short*)((char*)vtt + swz(d, row >> 3) + ((row & 7) << 1)) =
            vo[i2];
      }
    }
    __syncthreads();

    // ---- QK^T: 4 col-blocks x 2 k-chunks
    const bf16x8* aq = iskb ? aq2 : aq0;
    f32x4 cc[4];
#pragma unroll
    for (int cb = 0; cb < 4; ++cb) {
      bf16x8 b0 = *(const bf16x8*)((const char*)kt + swz(cb * 16 + li, lg4));
      bf16x8 b1 = *(const bf16x8*)((const char*)kt + swz(cb * 16 + li, 4 + lg4));
      f32x4 z = {};
      z = __builtin_amdgcn_mfma_f32_16x16x32_bf16(aq[0], b0, z, 0, 0, 0);
      z = __builtin_amdgcn_mfma_f32_16x16x32_bf16(aq[1], b1, z, 0, 0, 0);
      cc[cb] = z;
    }

    // ---- logits + online softmax (rows = g4*4+j, keys = cb*16+li)
    float lgv[4][4];
#pragma unroll
    for (int cb = 0; cb < 4; ++cb) {
#pragma unroll
      for (int j = 0; j < 4; ++j) {
        float v = SCALE * cc[cb][j];
        if (iskb) {
          v += C0F + (padf[w * 16 + lg4 * 4 + j] ? PADF : 0.f);
        } else {
          int key = j0 + cb * 16 + li;
          int srow = s0 + w * 16 + lg4 * 4 + j;
          v += (key <= srow) ? 0.f : PADF;
        }
        lgv[cb][j] = v;
      }
    }
#pragma unroll
    for (int j = 0; j < 4; ++j) {
      float rmax = fmaxf(fmaxf(lgv[0][j], lgv[1][j]), fmaxf(lgv[2][j], lgv[3][j]));
#pragma unroll
      for (int off = 8; off; off >>= 1) rmax = fmaxf(rmax, __shfl_xor(rmax, off));
      float mn = fmaxf(m_[j], rmax);
      float fs = __expf(m_[j] - mn);
      float csum = 0.f;
#pragma unroll
      for (int cb = 0; cb < 4; ++cb) {
        float p = __expf(lgv[cb][j] - mn);
        csum += p;
        int key = cb * 16 + li;
        int rloc = lg4 * 4 + j;
        *(unsigned short*)((char*)pt[w] + swz(rloc, key >> 3) +
                           ((key & 7) << 1)) = f2bf(p);
      }
#pragma unroll
      for (int off = 8; off; off >>= 1) csum += __shfl_xor(csum, off);
      m_[j] = mn;
      l_[j] = l_[j] * fs + csum;
#pragma unroll
      for (int db = 0; db < 4; ++db) acc[db][j] *= fs;
    }

    // ---- PV: A = P (rows x keys), B = V^T (d x keys)
    bf16x8 pa0 = *(const bf16x8*)((const char*)pt[w] + swz(li, lg4));
    bf16x8 pa1 = *(const bf16x8*)((const char*)pt[w] + swz(li, 4 + lg4));
#pragma unroll
    for (int db = 0; db < 4; ++db) {
      bf16x8 bv0 = *(const bf16x8*)((const char*)vtt + swz(db * 16 + li, lg4));
      bf16x8 bv1 = *(const bf16x8*)((const char*)vtt + swz(db * 16 + li, 4 + lg4));
      acc[db] = __builtin_amdgcn_mfma_f32_16x16x32_bf16(pa0, bv0, acc[db], 0, 0, 0);
      acc[db] = __builtin_amdgcn_mfma_f32_16x16x32_bf16(pa1, bv1, acc[db], 0, 0, 0);
    }
  }

  // ---- epilogue: normalize and store fp32
#pragma unroll
  for (int j = 0; j < 4; ++j) {
    float inv = 1.f / l_[j];
    size_t o = (size_t)(b * S + s0 + w * 16 + lg4 * 4 + j) * (NH * HD) + h * 64 + li;
#pragma unroll
    for (int db = 0; db < 4; ++db) attn[o + db * 16] = acc[db][j] * inv;
  }
}

// ---------------------------------------------------------------------------
extern "C" void kernel_launch(void* const* d_in, const int* in_sizes, int n_in,
                              void* d_out, int out_size, void* d_ws, size_t ws_size,
                              hipStream_t stream) {
  const float* hidden = (const float*)d_in[0];
  const float* cosb   = (const float*)d_in[1];
  const float* sinb   = (const float*)d_in[2];
  const float* mask   = (const float*)d_in[3];
  const float* kbk    = (const float*)d_in[4];
  const float* kbv    = (const float*)d_in[5];
  const float* Wq     = (const float*)d_in[6];
  const float* Wq2    = (const float*)d_in[7];
  const float* Wk     = (const float*)d_in[8];
  const float* Wv     = (const float*)d_in[9];
  const float* Wo     = (const float*)d_in[10];
  float* out = (float*)d_out;

  const int H   = in_sizes[6] / (NH * HD);             // 2048
  const int KBL = in_sizes[4] / KBROW;                 // 400
  const long long BSll = (long long)in_sizes[0] / H;
  const int S = (int)((long long)in_sizes[3] / BSll);  // 1024
  const int B = (int)(BSll / S);                       // 2
  const int BS = B * S;
  const int NQ = NH * HD;                              // 2048
  const int NKVD = NKV * HD;                           // 512

  float* ws = (float*)d_ws;
  size_t off = 0;
  float* qb   = ws + off; off += (size_t)BS * NQ;
  float* q2b  = ws + off; off += (size_t)BS * NQ;
  float* kb   = ws + off; off += (size_t)BS * NKVD;
  float* vb   = ws + off; off += (size_t)BS * NKVD;
  float* attn = ws + off; off += (size_t)BS * NQ;
  float* Hsum = ws + off; off += (size_t)B * H;
  float* Qs   = ws + off; off += (size_t)B * NQ;
  float* sc   = ws + off; off += (size_t)B * KBL;
  int* topi   = (int*)(ws + off); off += (size_t)B * TOPK;
  int* padfl  = (int*)(ws + off); off += (size_t)BS;
  unsigned short* hbf    = (unsigned short*)(ws + off); off += (size_t)BS * H / 2;
  unsigned short* wqbf   = (unsigned short*)(ws + off); off += (size_t)NQ * H / 2;
  unsigned short* wq2bf  = (unsigned short*)(ws + off); off += (size_t)NQ * H / 2;
  unsigned short* wkbf   = (unsigned short*)(ws + off); off += (size_t)NKVD * H / 2;
  unsigned short* wvbf   = (unsigned short*)(ws + off); off += (size_t)NKVD * H / 2;
  unsigned short* wobf   = (unsigned short*)(ws + off); off += (size_t)H * NQ / 2;
  unsigned short* attnbf = (unsigned short*)(ws + off); off += (size_t)BS * NQ / 2;
  (void)ws_size; (void)n_in; (void)out_size;

  // 0: fp32 -> bf16 conversions
  {
    int n;
    n = BS * H / 4;   f2bf_kernel<<<(n + 255) / 256, 256, 0, stream>>>(hidden, hbf, n);
    n = NQ * H / 4;   f2bf_kernel<<<(n + 255) / 256, 256, 0, stream>>>(Wq, wqbf, n);
    n = NQ * H / 4;   f2bf_kernel<<<(n + 255) / 256, 256, 0, stream>>>(Wq2, wq2bf, n);
    n = NKVD * H / 4; f2bf_kernel<<<(n + 255) / 256, 256, 0, stream>>>(Wk, wkbf, n);
    n = NKVD * H / 4; f2bf_kernel<<<(n + 255) / 256, 256, 0, stream>>>(Wv, wvbf, n);
    n = H * NQ / 4;   f2bf_kernel<<<(n + 255) / 256, 256, 0, stream>>>(Wo, wobf, n);
  }

  // 1-4: projections (bf16 MFMA)
  gemm_nt_bf16<<<dim3(NQ / 128, BS / 128), 256, 0, stream>>>(hbf, wqbf, qb, BS, NQ, H);
  gemm_nt_bf16<<<dim3(NQ / 128, BS / 128), 256, 0, stream>>>(hbf, wq2bf, q2b, BS, NQ, H);
  gemm_nt_bf16<<<dim3(NKVD / 128, BS / 128), 256, 0, stream>>>(hbf, wkbf, kb, BS, NKVD, H);
  gemm_nt_bf16<<<dim3(NKVD / 128, BS / 128), 256, 0, stream>>>(hbf, wvbf, vb, BS, NKVD, H);

  // 5-6: RoPE
  {
    int tq = BS * NH * 32;
    rope_kernel<<<(tq + 255) / 256, 256, 0, stream>>>(qb, cosb, sinb, BS, NH);
    int tk = BS * NKV * 32;
    rope_kernel<<<(tk + 255) / 256, 256, 0, stream>>>(kb, cosb, sinb, BS, NKV);
  }

  // 7-10: exact fp32 scores path + top-k + padding
  hsum_kernel<<<(B * H + 255) / 256, 256, 0, stream>>>(hidden, Hsum, B, S, H);
  qs_kernel<<<(B * NQ * 64 + 255) / 256, 256, 0, stream>>>(Hsum, Wq2, Qs, B, H);
  scores_kernel<<<(B * KBL * 64 + 255) / 256, 256, 0, stream>>>(Qs, kbk, sc, B, KBL);
  topk_kernel<<<B, 64, 0, stream>>>(sc, topi, KBL);
  padflag_kernel<<<(BS * 64 + 255) / 256, 256, 0, stream>>>(mask, padfl, BS, S);

  // 11: fused attention (bf16 MFMA)
  attn_mfma<<<B * NH * (S / 64), 256, 0, stream>>>(
      qb, q2b, kb, vb, kbk, kbv, topi, padfl, attn, B, S);

  // 12: output projection (bf16 MFMA)
  {
    int n = BS * NQ / 4;
    f2bf_kernel<<<(n + 255) / 256, 256, 0, stream>>>(attn, attnbf, n);
  }
  gemm_nt_bf16<<<dim3(H / 128, BS / 128), 256, 0, stream>>>(attnbf, wobf, out, BS, H, NQ);
}

// Round 6
// 620.869 us; speedup vs baseline: 4.8151x; 1.3643x over previous
//
#include <hip/hip_runtime.h>
#include <hip/hip_bf16.h>
#include <math.h>

#define NH 32
#define NKV 8
#define HD 64
#define NSLOTS 11
#define TOPK 128
#define KBROW (NSLOTS * NH * HD)   // 22528
#define PADF (-3.3895313892515355e+38f)
#define C0F  (-0.24686007793152578f)   // -ln(128)+ln(100)
#define SCALE 0.125f
#define HCH 32                         // S-chunks for hierarchical column sum

typedef __attribute__((ext_vector_type(8))) __bf16 bf16x8;
typedef __attribute__((ext_vector_type(4))) float f32x4;

#define GLDS16(gp, lp)                                                        \
  __builtin_amdgcn_global_load_lds(                                           \
      (__attribute__((address_space(1))) void*)(gp),                          \
      (__attribute__((address_space(3))) void*)(lp), 16, 0, 0)

__device__ __forceinline__ unsigned short f2bf(float f) {
  unsigned int u = __float_as_uint(f);
  u = (u + 0x7fffu + ((u >> 16) & 1u)) >> 16;
  return (unsigned short)u;
}

// byte offset into a 64-col bf16 tile (128 B/row) with XOR chunk swizzle
__device__ __forceinline__ int swz(int row, int chunk) {
  return row * 128 + ((chunk ^ (row & 7)) << 4);
}

// ---------------------------------------------------------------------------
// fp32 -> bf16 (RTNE), 4 elems/thread.
// ---------------------------------------------------------------------------
__global__ void f2bf_kernel(const float* __restrict__ in,
                            unsigned short* __restrict__ out, int n4) {
  int i = blockIdx.x * blockDim.x + threadIdx.x;
  if (i >= n4) return;
  float4 v = ((const float4*)in)[i];
  ushort4 o;
  o.x = f2bf(v.x); o.y = f2bf(v.y); o.z = f2bf(v.z); o.w = f2bf(v.w);
  ((ushort4*)out)[i] = o;
}

// ---------------------------------------------------------------------------
// bf16 MFMA GEMM (m97 structure): C[M,N] f32 = A[M,K] @ B[N,K]^T.
// Tile 128x128, BK=32, 4 waves (2x2), 16x16x32 MFMA. M,N %128, K %32.
// ---------------------------------------------------------------------------
__global__ __launch_bounds__(256) void gemm_nt_bf16(
    const unsigned short* __restrict__ A, const unsigned short* __restrict__ B,
    float* __restrict__ C, int M, int N, int K) {
  __shared__ unsigned short ldsA[128 * 32];
  __shared__ unsigned short ldsB[128 * 32];
  const int t = threadIdx.x;
  const int l = t & 63, w = t >> 6;
  const int wr = w >> 1, wc = w & 1;
  const int lr = l & 15;
  const int kb = (l >> 4) * 16;
  const int bm = blockIdx.y * 128, bn = blockIdx.x * 128;

  f32x4 acc[4][4] = {};

  for (int k0 = 0; k0 < K; k0 += 32) {
    __syncthreads();
#pragma unroll
    for (int it = 0; it < 2; ++it) {
      int s = it * 256 + t;
      int row = s >> 2, cs = (s & 3) * 8;
      GLDS16(A + (size_t)(bm + row) * K + k0 + cs,
             (char*)ldsA + (it * 4 + w) * 1024);
      GLDS16(B + (size_t)(bn + row) * K + k0 + cs,
             (char*)ldsB + (it * 4 + w) * 1024);
    }
    __syncthreads();

    bf16x8 a[4], b[4];
#pragma unroll
    for (int m = 0; m < 4; ++m)
      a[m] = *(const bf16x8*)((const char*)ldsA +
                              (wr * 64 + m * 16 + lr) * 64 + kb);
#pragma unroll
    for (int n = 0; n < 4; ++n)
      b[n] = *(const bf16x8*)((const char*)ldsB +
                              (wc * 64 + n * 16 + lr) * 64 + kb);
#pragma unroll
    for (int m = 0; m < 4; ++m)
#pragma unroll
      for (int n = 0; n < 4; ++n)
        acc[m][n] =
            __builtin_amdgcn_mfma_f32_16x16x32_bf16(a[m], b[n], acc[m][n], 0, 0, 0);
  }

#pragma unroll
  for (int m = 0; m < 4; ++m)
#pragma unroll
    for (int n = 0; n < 4; ++n) {
      int rbase = bm + wr * 64 + m * 16 + ((l >> 4) << 2);
      int cbase = bn + wc * 64 + n * 16 + lr;
#pragma unroll
      for (int j = 0; j < 4; ++j)
        C[(size_t)(rbase + j) * N + cbase] = acc[m][n][j];
    }
}

// ---------------------------------------------------------------------------
// RoPE in-place on x laid out [rows][nheads*64]; cos/sin are [rows][64].
// ---------------------------------------------------------------------------
__global__ void rope_kernel(float* __restrict__ x, const float* __restrict__ c,
                            const float* __restrict__ s, int rows, int nheads) {
  int tid = blockIdx.x * blockDim.x + threadIdx.x;
  int total = rows * nheads * 32;
  if (tid >= total) return;
  int d = tid & 31;
  int h = (tid >> 5) % nheads;
  int row = tid / (32 * nheads);
  float* xr = x + ((size_t)row * nheads + h) * 64;
  float c1 = c[(size_t)row * 64 + d], c2 = c[(size_t)row * 64 + d + 32];
  float s1 = s[(size_t)row * 64 + d], s2 = s[(size_t)row * 64 + d + 32];
  float x1 = xr[d], x2 = xr[d + 32];
  xr[d]      = x1 * c1 - x2 * s1;
  xr[d + 32] = x2 * c2 + x1 * s2;
}

// ---------------------------------------------------------------------------
// Column-sum stage 1: part[b][ch][c] = sum over 32-row chunk (f64).
// grid = B * HCH * (H/256); coalesced 256-col reads per row.
// ---------------------------------------------------------------------------
__global__ __launch_bounds__(256) void hsum1_kernel(
    const float* __restrict__ hidden, double* __restrict__ part,
    int B, int S, int H) {
  const int nhb = H >> 8;
  int hb = blockIdx.x % nhb;
  int ch = (blockIdx.x / nhb) % HCH;
  int b  = blockIdx.x / (nhb * HCH);
  int c  = hb * 256 + threadIdx.x;
  int rows = S / HCH;
  const float* p = hidden + ((size_t)b * S + (size_t)ch * rows) * H + c;
  double acc = 0.0;
  for (int s = 0; s < rows; ++s) acc += (double)p[(size_t)s * H];
  part[((size_t)b * HCH + ch) * H + c] = acc;
}

// ---------------------------------------------------------------------------
// Column-sum stage 2: Hsum[b][c] = sum_ch part[b][ch][c] (f64, fixed order).
// ---------------------------------------------------------------------------
__global__ void hsum2_kernel(const double* __restrict__ part,
                             float* __restrict__ Hsum, int B, int H) {
  int idx = blockIdx.x * blockDim.x + threadIdx.x;
  if (idx >= B * H) return;
  int b = idx / H, c = idx % H;
  const double* p = part + (size_t)b * HCH * H + c;
  double acc = 0.0;
#pragma unroll
  for (int ch = 0; ch < HCH; ++ch) acc += p[(size_t)ch * H];
  Hsum[idx] = (float)acc;
}

// ---------------------------------------------------------------------------
// Qs[b][c] = sum_k Hsum[b][k] * Wq2[c][k]  (fp32 inputs, f64 accum).
// ---------------------------------------------------------------------------
__global__ void qs_kernel(const float* __restrict__ Hsum,
                          const float* __restrict__ Wq2,
                          float* __restrict__ Qs, int B, int H) {
  int task = (blockIdx.x * blockDim.x + threadIdx.x) >> 6;
  int lane = threadIdx.x & 63;
  if (task >= B * NH * HD) return;
  int b = task / (NH * HD), c = task % (NH * HD);
  const float* hs = Hsum + (size_t)b * H;
  const float* wr = Wq2 + (size_t)c * H;
  double acc = 0.0;
  for (int k = lane; k < H; k += 64) acc += (double)hs[k] * (double)wr[k];
#pragma unroll
  for (int off = 32; off; off >>= 1) acc += __shfl_xor(acc, off);
  if (lane == 0) Qs[task] = (float)acc;
}

// ---------------------------------------------------------------------------
// scores[b][l] = 0.125 * dot(Qs[b,:], kb_keys[l, 0:2048]) (f64 acc)
// ---------------------------------------------------------------------------
__global__ void scores_kernel(const float* __restrict__ Qs,
                              const float* __restrict__ kbk,
                              float* __restrict__ scores, int B, int KBL) {
  int task = (blockIdx.x * blockDim.x + threadIdx.x) >> 6;
  int lane = threadIdx.x & 63;
  if (task >= B * KBL) return;
  int b = task / KBL, l = task % KBL;
  const float* kr = kbk + (size_t)l * KBROW;
  const float* qd = Qs + (size_t)b * NH * HD;
  double acc = 0.0;
  for (int c = lane; c < NH * HD; c += 64) acc += (double)qd[c] * (double)kr[c];
#pragma unroll
  for (int off = 32; off; off >>= 1) acc += __shfl_xor(acc, off);
  if (lane == 0) scores[task] = (float)(0.125 * acc);
}

// ---------------------------------------------------------------------------
// Top-K (descending, ties -> lower index). One wave per batch.
// ---------------------------------------------------------------------------
__global__ void topk_kernel(const float* __restrict__ scores,
                            int* __restrict__ top_idx, int KBL) {
  __shared__ float ls[512];
  int b = blockIdx.x, lane = threadIdx.x;
  for (int i = lane; i < KBL; i += 64) ls[i] = scores[(size_t)b * KBL + i];
  __syncthreads();
  for (int it = 0; it < TOPK; ++it) {
    float bv = -3.4e38f; int bi = 0x7fffffff;
    for (int i = lane; i < KBL; i += 64) {
      float v = ls[i];
      if (v > bv || (v == bv && i < bi)) { bv = v; bi = i; }
    }
#pragma unroll
    for (int off = 32; off; off >>= 1) {
      float ov = __shfl_xor(bv, off);
      int oi = __shfl_xor(bi, off);
      if (ov > bv || (ov == bv && oi < bi)) { bv = ov; bi = oi; }
    }
    if (lane == 0) { top_idx[b * TOPK + it] = bi; ls[bi] = -3.4e38f; }
    __syncthreads();
  }
}

// ---------------------------------------------------------------------------
// padflag[b*S+s] = all(mask[b,0,s,:] < 0)
// ---------------------------------------------------------------------------
__global__ void padflag_kernel(const float* __restrict__ mask,
                               int* __restrict__ flags, int BS, int S) {
  int w = (blockIdx.x * blockDim.x + threadIdx.x) >> 6;
  int lane = threadIdx.x & 63;
  if (w >= BS) return;
  const float* row = mask + (size_t)w * S;
  bool ok = true;
  for (int j = lane; j < S; j += 64) ok = ok && (row[j] < 0.f);
  int allv = __all(ok ? 1 : 0);
  if (lane == 0) flags[w] = allv;
}

// ---------------------------------------------------------------------------
// MFMA fused attention (unchanged from R5). Block = 4 waves; 64 q-rows.
// ---------------------------------------------------------------------------
__global__ __launch_bounds__(256) void attn_mfma(
    const float* __restrict__ qbuf,   // [B*S][2048] roped
    const float* __restrict__ q2buf,  // [B*S][2048] un-roped
    const float* __restrict__ kbuf,   // [B*S][NKV*64] roped
    const float* __restrict__ vbuf,   // [B*S][NKV*64]
    const float* __restrict__ kb_keys,
    const float* __restrict__ kb_values,
    const int* __restrict__ top_idx,  // [B][TOPK]
    const int* __restrict__ padflag,  // [B*S]
    float* __restrict__ attn,         // [B*S][2048]
    int B, int S) {
  const int nst = S >> 6;
  const int st = blockIdx.x % nst;
  const int h  = (blockIdx.x / nst) % NH;
  const int b  = blockIdx.x / (nst * NH);
  const int s0 = st * 64;
  const int g  = h / (NH / NKV);

  __shared__ unsigned short qt2[2][4096];  // [0]=q roped, [1]=q2 (64x64 bf16)
  __shared__ unsigned short kt[4096];      // K chunk   [key][d]
  __shared__ unsigned short vtt[4096];     // V^T chunk [d][key]
  __shared__ unsigned short pt[4][1024];   // per-wave P [row16][key64]
  __shared__ int idxs[TOPK];
  __shared__ int padf[64];

  const int t = threadIdx.x;
  const int w = t >> 6;
  const int li = t & 15;
  const int lg4 = (t & 63) >> 4;

  for (int slot = t; slot < 2048; slot += 256) {
    int sel = slot >> 10;
    int row = (slot >> 4) & 63;
    int d4 = (slot & 15) << 2;
    const float* src = sel ? q2buf : qbuf;
    float4 v = *(const float4*)&src[(size_t)(b * S + s0 + row) * (NH * HD) +
                                    h * 64 + d4];
    ushort4 o = {f2bf(v.x), f2bf(v.y), f2bf(v.z), f2bf(v.w)};
    *(ushort4*)((char*)qt2[sel] + swz(row, d4 >> 3) + ((d4 & 7) << 1)) = o;
  }
  if (t < TOPK) idxs[t] = top_idx[b * TOPK + t];
  if (t < 64) padf[t] = padflag[b * S + s0 + t];
  __syncthreads();

  bf16x8 aq0[2], aq2[2];
#pragma unroll
  for (int kc = 0; kc < 2; ++kc) {
    aq0[kc] = *(const bf16x8*)((const char*)qt2[0] + swz(w * 16 + li, kc * 4 + lg4));
    aq2[kc] = *(const bf16x8*)((const char*)qt2[1] + swz(w * 16 + li, kc * 4 + lg4));
  }

  float m_[4] = {-3.4e38f, -3.4e38f, -3.4e38f, -3.4e38f};
  float l_[4] = {};
  f32x4 acc[4] = {};

  const int nch = 2 + st + 1;
  for (int ch = 0; ch < nch; ++ch) {
    const bool iskb = ch < 2;
    const int j0 = iskb ? ch * 64 : (ch - 2) * 64;
    __syncthreads();
    for (int slot = t; slot < 1024; slot += 256) {
      int row = slot >> 4, d4 = (slot & 15) << 2;
      const float *kp, *vp;
      if (iskb) {
        kp = kb_keys + (size_t)(j0 + row) * KBROW + h * 64 + d4;
        vp = kb_values + (size_t)idxs[j0 + row] * KBROW + h * 64 + d4;
      } else {
        int js = j0 + row;
        kp = kbuf + ((size_t)(b * S + js) * NKV + g) * 64 + d4;
        vp = vbuf + ((size_t)(b * S + js) * NKV + g) * 64 + d4;
      }
      float4 kv = *(const float4*)kp;
      float4 vv = *(const float4*)vp;
      ushort4 ko = {f2bf(kv.x), f2bf(kv.y), f2bf(kv.z), f2bf(kv.w)};
      *(ushort4*)((char*)kt + swz(row, d4 >> 3) + ((d4 & 7) << 1)) = ko;
      unsigned short vo[4] = {f2bf(vv.x), f2bf(vv.y), f2bf(vv.z), f2bf(vv.w)};
#pragma unroll
      for (int i2 = 0; i2 < 4; ++i2) {
        int d = d4 + i2;
        *(unsigned short*)((char*)vtt + swz(d, row >> 3) + ((row & 7) << 1)) =
            vo[i2];
      }
    }
    __syncthreads();

    const bf16x8* aq = iskb ? aq2 : aq0;
    f32x4 cc[4];
#pragma unroll
    for (int cb = 0; cb < 4; ++cb) {
      bf16x8 b0 = *(const bf16x8*)((const char*)kt + swz(cb * 16 + li, lg4));
      bf16x8 b1 = *(const bf16x8*)((const char*)kt + swz(cb * 16 + li, 4 + lg4));
      f32x4 z = {};
      z = __builtin_amdgcn_mfma_f32_16x16x32_bf16(aq[0], b0, z, 0, 0, 0);
      z = __builtin_amdgcn_mfma_f32_16x16x32_bf16(aq[1], b1, z, 0, 0, 0);
      cc[cb] = z;
    }

    float lgv[4][4];
#pragma unroll
    for (int cb = 0; cb < 4; ++cb) {
#pragma unroll
      for (int j = 0; j < 4; ++j) {
        float v = SCALE * cc[cb][j];
        if (iskb) {
          v += C0F + (padf[w * 16 + lg4 * 4 + j] ? PADF : 0.f);
        } else {
          int key = j0 + cb * 16 + li;
          int srow = s0 + w * 16 + lg4 * 4 + j;
          v += (key <= srow) ? 0.f : PADF;
        }
        lgv[cb][j] = v;
      }
    }
#pragma unroll
    for (int j = 0; j < 4; ++j) {
      float rmax = fmaxf(fmaxf(lgv[0][j], lgv[1][j]), fmaxf(lgv[2][j], lgv[3][j]));
#pragma unroll
      for (int off = 8; off; off >>= 1) rmax = fmaxf(rmax, __shfl_xor(rmax, off));
      float mn = fmaxf(m_[j], rmax);
      float fs = __expf(m_[j] - mn);
      float csum = 0.f;
#pragma unroll
      for (int cb = 0; cb < 4; ++cb) {
        float p = __expf(lgv[cb][j] - mn);
        csum += p;
        int key = cb * 16 + li;
        int rloc = lg4 * 4 + j;
        *(unsigned short*)((char*)pt[w] + swz(rloc, key >> 3) +
                           ((key & 7) << 1)) = f2bf(p);
      }
#pragma unroll
      for (int off = 8; off; off >>= 1) csum += __shfl_xor(csum, off);
      m_[j] = mn;
      l_[j] = l_[j] * fs + csum;
#pragma unroll
      for (int db = 0; db < 4; ++db) acc[db][j] *= fs;
    }

    bf16x8 pa0 = *(const bf16x8*)((const char*)pt[w] + swz(li, lg4));
    bf16x8 pa1 = *(const bf16x8*)((const char*)pt[w] + swz(li, 4 + lg4));
#pragma unroll
    for (int db = 0; db < 4; ++db) {
      bf16x8 bv0 = *(const bf16x8*)((const char*)vtt + swz(db * 16 + li, lg4));
      bf16x8 bv1 = *(const bf16x8*)((const char*)vtt + swz(db * 16 + li, 4 + lg4));
      acc[db] = __builtin_amdgcn_mfma_f32_16x16x32_bf16(pa0, bv0, acc[db], 0, 0, 0);
      acc[db] = __builtin_amdgcn_mfma_f32_16x16x32_bf16(pa1, bv1, acc[db], 0, 0, 0);
    }
  }

#pragma unroll
  for (int j = 0; j < 4; ++j) {
    float inv = 1.f / l_[j];
    size_t o = (size_t)(b * S + s0 + w * 16 + lg4 * 4 + j) * (NH * HD) + h * 64 + li;
#pragma unroll
    for (int db = 0; db < 4; ++db) attn[o + db * 16] = acc[db][j] * inv;
  }
}

// ---------------------------------------------------------------------------
extern "C" void kernel_launch(void* const* d_in, const int* in_sizes, int n_in,
                              void* d_out, int out_size, void* d_ws, size_t ws_size,
                              hipStream_t stream) {
  const float* hidden = (const float*)d_in[0];
  const float* cosb   = (const float*)d_in[1];
  const float* sinb   = (const float*)d_in[2];
  const float* mask   = (const float*)d_in[3];
  const float* kbk    = (const float*)d_in[4];
  const float* kbv    = (const float*)d_in[5];
  const float* Wq     = (const float*)d_in[6];
  const float* Wq2    = (const float*)d_in[7];
  const float* Wk     = (const float*)d_in[8];
  const float* Wv     = (const float*)d_in[9];
  const float* Wo     = (const float*)d_in[10];
  float* out = (float*)d_out;

  const int H   = in_sizes[6] / (NH * HD);             // 2048
  const int KBL = in_sizes[4] / KBROW;                 // 400
  const long long BSll = (long long)in_sizes[0] / H;
  const int S = (int)((long long)in_sizes[3] / BSll);  // 1024
  const int B = (int)(BSll / S);                       // 2
  const int BS = B * S;
  const int NQ = NH * HD;                              // 2048
  const int NKVD = NKV * HD;                           // 512

  float* ws = (float*)d_ws;
  size_t off = 0;
  // f64-aligned partials first (d_ws base is 256B-aligned)
  double* hpart = (double*)(ws + off); off += (size_t)B * HCH * H * 2;
  float* qb   = ws + off; off += (size_t)BS * NQ;
  float* q2b  = ws + off; off += (size_t)BS * NQ;
  float* kb   = ws + off; off += (size_t)BS * NKVD;
  float* vb   = ws + off; off += (size_t)BS * NKVD;
  float* attn = ws + off; off += (size_t)BS * NQ;
  float* Hsum = ws + off; off += (size_t)B * H;
  float* Qs   = ws + off; off += (size_t)B * NQ;
  float* sc   = ws + off; off += (size_t)B * KBL;
  int* topi   = (int*)(ws + off); off += (size_t)B * TOPK;
  int* padfl  = (int*)(ws + off); off += (size_t)BS;
  unsigned short* hbf    = (unsigned short*)(ws + off); off += (size_t)BS * H / 2;
  unsigned short* wqbf   = (unsigned short*)(ws + off); off += (size_t)NQ * H / 2;
  unsigned short* wq2bf  = (unsigned short*)(ws + off); off += (size_t)NQ * H / 2;
  unsigned short* wkbf   = (unsigned short*)(ws + off); off += (size_t)NKVD * H / 2;
  unsigned short* wvbf   = (unsigned short*)(ws + off); off += (size_t)NKVD * H / 2;
  unsigned short* wobf   = (unsigned short*)(ws + off); off += (size_t)H * NQ / 2;
  unsigned short* attnbf = (unsigned short*)(ws + off); off += (size_t)BS * NQ / 2;
  (void)ws_size; (void)n_in; (void)out_size;

  // 0: fp32 -> bf16 conversions
  {
    int n;
    n = BS * H / 4;   f2bf_kernel<<<(n + 255) / 256, 256, 0, stream>>>(hidden, hbf, n);
    n = NQ * H / 4;   f2bf_kernel<<<(n + 255) / 256, 256, 0, stream>>>(Wq, wqbf, n);
    n = NQ * H / 4;   f2bf_kernel<<<(n + 255) / 256, 256, 0, stream>>>(Wq2, wq2bf, n);
    n = NKVD * H / 4; f2bf_kernel<<<(n + 255) / 256, 256, 0, stream>>>(Wk, wkbf, n);
    n = NKVD * H / 4; f2bf_kernel<<<(n + 255) / 256, 256, 0, stream>>>(Wv, wvbf, n);
    n = H * NQ / 4;   f2bf_kernel<<<(n + 255) / 256, 256, 0, stream>>>(Wo, wobf, n);
  }

  // 1-4: projections (bf16 MFMA)
  gemm_nt_bf16<<<dim3(NQ / 128, BS / 128), 256, 0, stream>>>(hbf, wqbf, qb, BS, NQ, H);
  gemm_nt_bf16<<<dim3(NQ / 128, BS / 128), 256, 0, stream>>>(hbf, wq2bf, q2b, BS, NQ, H);
  gemm_nt_bf16<<<dim3(NKVD / 128, BS / 128), 256, 0, stream>>>(hbf, wkbf, kb, BS, NKVD, H);
  gemm_nt_bf16<<<dim3(NKVD / 128, BS / 128), 256, 0, stream>>>(hbf, wvbf, vb, BS, NKVD, H);

  // 5-6: RoPE
  {
    int tq = BS * NH * 32;
    rope_kernel<<<(tq + 255) / 256, 256, 0, stream>>>(qb, cosb, sinb, BS, NH);
    int tk = BS * NKV * 32;
    rope_kernel<<<(tk + 255) / 256, 256, 0, stream>>>(kb, cosb, sinb, BS, NKV);
  }

  // 7-10: exact fp32 scores path (two-stage f64 colsum) + top-k + padding
  hsum1_kernel<<<B * HCH * (H / 256), 256, 0, stream>>>(hidden, hpart, B, S, H);
  hsum2_kernel<<<(B * H + 255) / 256, 256, 0, stream>>>(hpart, Hsum, B, H);
  qs_kernel<<<(B * NQ * 64 + 255) / 256, 256, 0, stream>>>(Hsum, Wq2, Qs, B, H);
  scores_kernel<<<(B * KBL * 64 + 255) / 256, 256, 0, stream>>>(Qs, kbk, sc, B, KBL);
  topk_kernel<<<B, 64, 0, stream>>>(sc, topi, KBL);
  padflag_kernel<<<(BS * 64 + 255) / 256, 256, 0, stream>>>(mask, padfl, BS, S);

  // 11: fused attention (bf16 MFMA)
  attn_mfma<<<B * NH * (S / 64), 256, 0, stream>>>(
      qb, q2b, kb, vb, kbk, kbv, topi, padfl, attn, B, S);

  // 12: output projection (bf16 MFMA)
  {
    int n = BS * NQ / 4;
    f2bf_kernel<<<(n + 255) / 256, 256, 0, stream>>>(attn, attnbf, n);
  }
  gemm_nt_bf16<<<dim3(H / 128, BS / 128), 256, 0, stream>>>(attnbf, wobf, out, BS, H, NQ);
}

// Round 7
// 486.376 us; speedup vs baseline: 6.1465x; 1.2765x over previous
//
#include <hip/hip_runtime.h>
#include <hip/hip_bf16.h>
#include <math.h>

#define NH 32
#define NKV 8
#define HD 64
#define NSLOTS 11
#define TOPK 128
#define KBROW (NSLOTS * NH * HD)   // 22528
#define PADF (-3.3895313892515355e+38f)
#define C0F  (-0.24686007793152578f)   // -ln(128)+ln(100)
#define SCALE 0.125f
#define HCH 32                         // S-chunks for hierarchical column sum

typedef __attribute__((ext_vector_type(8))) __bf16 bf16x8;
typedef __attribute__((ext_vector_type(4))) float f32x4;

#define GLDS16(gp, lp)                                                        \
  __builtin_amdgcn_global_load_lds(                                           \
      (__attribute__((address_space(1))) void*)(gp),                          \
      (__attribute__((address_space(3))) void*)(lp), 16, 0, 0)

__device__ __forceinline__ unsigned short f2bf(float f) {
  unsigned int u = __float_as_uint(f);
  u = (u + 0x7fffu + ((u >> 16) & 1u)) >> 16;
  return (unsigned short)u;
}

// byte offset into a 64-col bf16 tile (128 B/row) with XOR chunk swizzle
__device__ __forceinline__ int swz(int row, int chunk) {
  return row * 128 + ((chunk ^ (row & 7)) << 4);
}

// ---------------------------------------------------------------------------
// fp32 -> bf16 (RTNE), 4 elems/thread.
// ---------------------------------------------------------------------------
__global__ void f2bf_kernel(const float* __restrict__ in,
                            unsigned short* __restrict__ out, int n4) {
  int i = blockIdx.x * blockDim.x + threadIdx.x;
  if (i >= n4) return;
  float4 v = ((const float4*)in)[i];
  ushort4 o;
  o.x = f2bf(v.x); o.y = f2bf(v.y); o.z = f2bf(v.z); o.w = f2bf(v.w);
  ((ushort4*)out)[i] = o;
}

// ---------------------------------------------------------------------------
// bf16 MFMA GEMM (m97 structure): C[M,N] f32 = A[M,K] @ B[N,K]^T.
// Tile 128x128, BK=32, 4 waves (2x2), 16x16x32 MFMA. M,N %128, K %32.
// ---------------------------------------------------------------------------
__global__ __launch_bounds__(256) void gemm_nt_bf16(
    const unsigned short* __restrict__ A, const unsigned short* __restrict__ B,
    float* __restrict__ C, int M, int N, int K) {
  __shared__ unsigned short ldsA[128 * 32];
  __shared__ unsigned short ldsB[128 * 32];
  const int t = threadIdx.x;
  const int l = t & 63, w = t >> 6;
  const int wr = w >> 1, wc = w & 1;
  const int lr = l & 15;
  const int kb = (l >> 4) * 16;
  const int bm = blockIdx.y * 128, bn = blockIdx.x * 128;

  f32x4 acc[4][4] = {};

  for (int k0 = 0; k0 < K; k0 += 32) {
    __syncthreads();
#pragma unroll
    for (int it = 0; it < 2; ++it) {
      int s = it * 256 + t;
      int row = s >> 2, cs = (s & 3) * 8;
      GLDS16(A + (size_t)(bm + row) * K + k0 + cs,
             (char*)ldsA + (it * 4 + w) * 1024);
      GLDS16(B + (size_t)(bn + row) * K + k0 + cs,
             (char*)ldsB + (it * 4 + w) * 1024);
    }
    __syncthreads();

    bf16x8 a[4], b[4];
#pragma unroll
    for (int m = 0; m < 4; ++m)
      a[m] = *(const bf16x8*)((const char*)ldsA +
                              (wr * 64 + m * 16 + lr) * 64 + kb);
#pragma unroll
    for (int n = 0; n < 4; ++n)
      b[n] = *(const bf16x8*)((const char*)ldsB +
                              (wc * 64 + n * 16 + lr) * 64 + kb);
#pragma unroll
    for (int m = 0; m < 4; ++m)
#pragma unroll
      for (int n = 0; n < 4; ++n)
        acc[m][n] =
            __builtin_amdgcn_mfma_f32_16x16x32_bf16(a[m], b[n], acc[m][n], 0, 0, 0);
  }

#pragma unroll
  for (int m = 0; m < 4; ++m)
#pragma unroll
    for (int n = 0; n < 4; ++n) {
      int rbase = bm + wr * 64 + m * 16 + ((l >> 4) << 2);
      int cbase = bn + wc * 64 + n * 16 + lr;
#pragma unroll
      for (int j = 0; j < 4; ++j)
        C[(size_t)(rbase + j) * N + cbase] = acc[m][n][j];
    }
}

// ---------------------------------------------------------------------------
// RoPE in-place on x laid out [rows][nheads*64]; cos/sin are [rows][64].
// ---------------------------------------------------------------------------
__global__ void rope_kernel(float* __restrict__ x, const float* __restrict__ c,
                            const float* __restrict__ s, int rows, int nheads) {
  int tid = blockIdx.x * blockDim.x + threadIdx.x;
  int total = rows * nheads * 32;
  if (tid >= total) return;
  int d = tid & 31;
  int h = (tid >> 5) % nheads;
  int row = tid / (32 * nheads);
  float* xr = x + ((size_t)row * nheads + h) * 64;
  float c1 = c[(size_t)row * 64 + d], c2 = c[(size_t)row * 64 + d + 32];
  float s1 = s[(size_t)row * 64 + d], s2 = s[(size_t)row * 64 + d + 32];
  float x1 = xr[d], x2 = xr[d + 32];
  xr[d]      = x1 * c1 - x2 * s1;
  xr[d + 32] = x2 * c2 + x1 * s2;
}

// ---------------------------------------------------------------------------
// Column-sum stage 1: part[b][ch][c] = sum over 32-row chunk (f64).
// ---------------------------------------------------------------------------
__global__ __launch_bounds__(256) void hsum1_kernel(
    const float* __restrict__ hidden, double* __restrict__ part,
    int B, int S, int H) {
  const int nhb = H >> 8;
  int hb = blockIdx.x % nhb;
  int ch = (blockIdx.x / nhb) % HCH;
  int b  = blockIdx.x / (nhb * HCH);
  int c  = hb * 256 + threadIdx.x;
  int rows = S / HCH;
  const float* p = hidden + ((size_t)b * S + (size_t)ch * rows) * H + c;
  double acc = 0.0;
  for (int s = 0; s < rows; ++s) acc += (double)p[(size_t)s * H];
  part[((size_t)b * HCH + ch) * H + c] = acc;
}

// ---------------------------------------------------------------------------
// Column-sum stage 2: Hsum[b][c] = sum_ch part[b][ch][c] (f64, fixed order).
// ---------------------------------------------------------------------------
__global__ void hsum2_kernel(const double* __restrict__ part,
                             float* __restrict__ Hsum, int B, int H) {
  int idx = blockIdx.x * blockDim.x + threadIdx.x;
  if (idx >= B * H) return;
  int b = idx / H, c = idx % H;
  const double* p = part + (size_t)b * HCH * H + c;
  double acc = 0.0;
#pragma unroll
  for (int ch = 0; ch < HCH; ++ch) acc += p[(size_t)ch * H];
  Hsum[idx] = (float)acc;
}

// ---------------------------------------------------------------------------
// Qs[b][c] = sum_k Hsum[b][k] * Wq2[c][k]  (fp32 inputs, f64 accum).
// ---------------------------------------------------------------------------
__global__ void qs_kernel(const float* __restrict__ Hsum,
                          const float* __restrict__ Wq2,
                          float* __restrict__ Qs, int B, int H) {
  int task = (blockIdx.x * blockDim.x + threadIdx.x) >> 6;
  int lane = threadIdx.x & 63;
  if (task >= B * NH * HD) return;
  int b = task / (NH * HD), c = task % (NH * HD);
  const float* hs = Hsum + (size_t)b * H;
  const float* wr = Wq2 + (size_t)c * H;
  double acc = 0.0;
  for (int k = lane; k < H; k += 64) acc += (double)hs[k] * (double)wr[k];
#pragma unroll
  for (int off = 32; off; off >>= 1) acc += __shfl_xor(acc, off);
  if (lane == 0) Qs[task] = (float)acc;
}

// ---------------------------------------------------------------------------
// scores[b][l] = 0.125 * dot(Qs[b,:], kb_keys[l, 0:2048]) (f64 acc)
// ---------------------------------------------------------------------------
__global__ void scores_kernel(const float* __restrict__ Qs,
                              const float* __restrict__ kbk,
                              float* __restrict__ scores, int B, int KBL) {
  int task = (blockIdx.x * blockDim.x + threadIdx.x) >> 6;
  int lane = threadIdx.x & 63;
  if (task >= B * KBL) return;
  int b = task / KBL, l = task % KBL;
  const float* kr = kbk + (size_t)l * KBROW;
  const float* qd = Qs + (size_t)b * NH * HD;
  double acc = 0.0;
  for (int c = lane; c < NH * HD; c += 64) acc += (double)qd[c] * (double)kr[c];
#pragma unroll
  for (int off = 32; off; off >>= 1) acc += __shfl_xor(acc, off);
  if (lane == 0) scores[task] = (float)(0.125 * acc);
}

// ---------------------------------------------------------------------------
// Top-K by rank-counting: rank[l] = #{j: s[j]>s[l] or (s[j]==s[l] and j<l)}.
// Stable descending order == lax.top_k. One 256-thread block per batch.
// ---------------------------------------------------------------------------
__global__ __launch_bounds__(256) void topk_kernel(
    const float* __restrict__ scores, int* __restrict__ top_idx, int KBL) {
  __shared__ float ls[512];
  int b = blockIdx.x, t = threadIdx.x;
  for (int i = t; i < KBL; i += 256) ls[i] = scores[(size_t)b * KBL + i];
  __syncthreads();
  for (int l = t; l < KBL; l += 256) {
    float sl = ls[l];
    int rank = 0;
    for (int j = 0; j < KBL; ++j) {
      float sj = ls[j];
      rank += (sj > sl || (sj == sl && j < l)) ? 1 : 0;
    }
    if (rank < TOPK) top_idx[b * TOPK + rank] = l;
  }
}

// ---------------------------------------------------------------------------
// padflag[b*S+s] = all(mask[b,0,s,:] < 0)
// ---------------------------------------------------------------------------
__global__ void padflag_kernel(const float* __restrict__ mask,
                               int* __restrict__ flags, int BS, int S) {
  int w = (blockIdx.x * blockDim.x + threadIdx.x) >> 6;
  int lane = threadIdx.x & 63;
  if (w >= BS) return;
  const float* row = mask + (size_t)w * S;
  bool ok = true;
  for (int j = lane; j < S; j += 64) ok = ok && (row[j] < 0.f);
  int allv = __all(ok ? 1 : 0);
  if (lane == 0) flags[w] = allv;
}

// ---------------------------------------------------------------------------
// MFMA fused attention (unchanged). Block = 4 waves; 64 q-rows.
// ---------------------------------------------------------------------------
__global__ __launch_bounds__(256) void attn_mfma(
    const float* __restrict__ qbuf,   // [B*S][2048] roped
    const float* __restrict__ q2buf,  // [B*S][2048] un-roped
    const float* __restrict__ kbuf,   // [B*S][NKV*64] roped
    const float* __restrict__ vbuf,   // [B*S][NKV*64]
    const float* __restrict__ kb_keys,
    const float* __restrict__ kb_values,
    const int* __restrict__ top_idx,  // [B][TOPK]
    const int* __restrict__ padflag,  // [B*S]
    float* __restrict__ attn,         // [B*S][2048]
    int B, int S) {
  const int nst = S >> 6;
  const int st = blockIdx.x % nst;
  const int h  = (blockIdx.x / nst) % NH;
  const int b  = blockIdx.x / (nst * NH);
  const int s0 = st * 64;
  const int g  = h / (NH / NKV);

  __shared__ unsigned short qt2[2][4096];  // [0]=q roped, [1]=q2 (64x64 bf16)
  __shared__ unsigned short kt[4096];      // K chunk   [key][d]
  __shared__ unsigned short vtt[4096];     // V^T chunk [d][key]
  __shared__ unsigned short pt[4][1024];   // per-wave P [row16][key64]
  __shared__ int idxs[TOPK];
  __shared__ int padf[64];

  const int t = threadIdx.x;
  const int w = t >> 6;
  const int li = t & 15;
  const int lg4 = (t & 63) >> 4;

  for (int slot = t; slot < 2048; slot += 256) {
    int sel = slot >> 10;
    int row = (slot >> 4) & 63;
    int d4 = (slot & 15) << 2;
    const float* src = sel ? q2buf : qbuf;
    float4 v = *(const float4*)&src[(size_t)(b * S + s0 + row) * (NH * HD) +
                                    h * 64 + d4];
    ushort4 o = {f2bf(v.x), f2bf(v.y), f2bf(v.z), f2bf(v.w)};
    *(ushort4*)((char*)qt2[sel] + swz(row, d4 >> 3) + ((d4 & 7) << 1)) = o;
  }
  if (t < TOPK) idxs[t] = top_idx[b * TOPK + t];
  if (t < 64) padf[t] = padflag[b * S + s0 + t];
  __syncthreads();

  bf16x8 aq0[2], aq2[2];
#pragma unroll
  for (int kc = 0; kc < 2; ++kc) {
    aq0[kc] = *(const bf16x8*)((const char*)qt2[0] + swz(w * 16 + li, kc * 4 + lg4));
    aq2[kc] = *(const bf16x8*)((const char*)qt2[1] + swz(w * 16 + li, kc * 4 + lg4));
  }

  float m_[4] = {-3.4e38f, -3.4e38f, -3.4e38f, -3.4e38f};
  float l_[4] = {};
  f32x4 acc[4] = {};

  const int nch = 2 + st + 1;
  for (int ch = 0; ch < nch; ++ch) {
    const bool iskb = ch < 2;
    const int j0 = iskb ? ch * 64 : (ch - 2) * 64;
    __syncthreads();
    for (int slot = t; slot < 1024; slot += 256) {
      int row = slot >> 4, d4 = (slot & 15) << 2;
      const float *kp, *vp;
      if (iskb) {
        kp = kb_keys + (size_t)(j0 + row) * KBROW + h * 64 + d4;
        vp = kb_values + (size_t)idxs[j0 + row] * KBROW + h * 64 + d4;
      } else {
        int js = j0 + row;
        kp = kbuf + ((size_t)(b * S + js) * NKV + g) * 64 + d4;
        vp = vbuf + ((size_t)(b * S + js) * NKV + g) * 64 + d4;
      }
      float4 kv = *(const float4*)kp;
      float4 vv = *(const float4*)vp;
      ushort4 ko = {f2bf(kv.x), f2bf(kv.y), f2bf(kv.z), f2bf(kv.w)};
      *(ushort4*)((char*)kt + swz(row, d4 >> 3) + ((d4 & 7) << 1)) = ko;
      unsigned short vo[4] = {f2bf(vv.x), f2bf(vv.y), f2bf(vv.z), f2bf(vv.w)};
#pragma unroll
      for (int i2 = 0; i2 < 4; ++i2) {
        int d = d4 + i2;
        *(unsigned short*)((char*)vtt + swz(d, row >> 3) + ((row & 7) << 1)) =
            vo[i2];
      }
    }
    __syncthreads();

    const bf16x8* aq = iskb ? aq2 : aq0;
    f32x4 cc[4];
#pragma unroll
    for (int cb = 0; cb < 4; ++cb) {
      bf16x8 b0 = *(const bf16x8*)((const char*)kt + swz(cb * 16 + li, lg4));
      bf16x8 b1 = *(const bf16x8*)((const char*)kt + swz(cb * 16 + li, 4 + lg4));
      f32x4 z = {};
      z = __builtin_amdgcn_mfma_f32_16x16x32_bf16(aq[0], b0, z, 0, 0, 0);
      z = __builtin_amdgcn_mfma_f32_16x16x32_bf16(aq[1], b1, z, 0, 0, 0);
      cc[cb] = z;
    }

    float lgv[4][4];
#pragma unroll
    for (int cb = 0; cb < 4; ++cb) {
#pragma unroll
      for (int j = 0; j < 4; ++j) {
        float v = SCALE * cc[cb][j];
        if (iskb) {
          v += C0F + (padf[w * 16 + lg4 * 4 + j] ? PADF : 0.f);
        } else {
          int key = j0 + cb * 16 + li;
          int srow = s0 + w * 16 + lg4 * 4 + j;
          v += (key <= srow) ? 0.f : PADF;
        }
        lgv[cb][j] = v;
      }
    }
#pragma unroll
    for (int j = 0; j < 4; ++j) {
      float rmax = fmaxf(fmaxf(lgv[0][j], lgv[1][j]), fmaxf(lgv[2][j], lgv[3][j]));
#pragma unroll
      for (int off = 8; off; off >>= 1) rmax = fmaxf(rmax, __shfl_xor(rmax, off));
      float mn = fmaxf(m_[j], rmax);
      float fs = __expf(m_[j] - mn);
      float csum = 0.f;
#pragma unroll
      for (int cb = 0; cb < 4; ++cb) {
        float p = __expf(lgv[cb][j] - mn);
        csum += p;
        int key = cb * 16 + li;
        int rloc = lg4 * 4 + j;
        *(unsigned short*)((char*)pt[w] + swz(rloc, key >> 3) +
                           ((key & 7) << 1)) = f2bf(p);
      }
#pragma unroll
      for (int off = 8; off; off >>= 1) csum += __shfl_xor(csum, off);
      m_[j] = mn;
      l_[j] = l_[j] * fs + csum;
#pragma unroll
      for (int db = 0; db < 4; ++db) acc[db][j] *= fs;
    }

    bf16x8 pa0 = *(const bf16x8*)((const char*)pt[w] + swz(li, lg4));
    bf16x8 pa1 = *(const bf16x8*)((const char*)pt[w] + swz(li, 4 + lg4));
#pragma unroll
    for (int db = 0; db < 4; ++db) {
      bf16x8 bv0 = *(const bf16x8*)((const char*)vtt + swz(db * 16 + li, lg4));
      bf16x8 bv1 = *(const bf16x8*)((const char*)vtt + swz(db * 16 + li, 4 + lg4));
      acc[db] = __builtin_amdgcn_mfma_f32_16x16x32_bf16(pa0, bv0, acc[db], 0, 0, 0);
      acc[db] = __builtin_amdgcn_mfma_f32_16x16x32_bf16(pa1, bv1, acc[db], 0, 0, 0);
    }
  }

#pragma unroll
  for (int j = 0; j < 4; ++j) {
    float inv = 1.f / l_[j];
    size_t o = (size_t)(b * S + s0 + w * 16 + lg4 * 4 + j) * (NH * HD) + h * 64 + li;
#pragma unroll
    for (int db = 0; db < 4; ++db) attn[o + db * 16] = acc[db][j] * inv;
  }
}

// ---------------------------------------------------------------------------
extern "C" void kernel_launch(void* const* d_in, const int* in_sizes, int n_in,
                              void* d_out, int out_size, void* d_ws, size_t ws_size,
                              hipStream_t stream) {
  const float* hidden = (const float*)d_in[0];
  const float* cosb   = (const float*)d_in[1];
  const float* sinb   = (const float*)d_in[2];
  const float* mask   = (const float*)d_in[3];
  const float* kbk    = (const float*)d_in[4];
  const float* kbv    = (const float*)d_in[5];
  const float* Wq     = (const float*)d_in[6];
  const float* Wq2    = (const float*)d_in[7];
  const float* Wk     = (const float*)d_in[8];
  const float* Wv     = (const float*)d_in[9];
  const float* Wo     = (const float*)d_in[10];
  float* out = (float*)d_out;

  const int H   = in_sizes[6] / (NH * HD);             // 2048
  const int KBL = in_sizes[4] / KBROW;                 // 400
  const long long BSll = (long long)in_sizes[0] / H;
  const int S = (int)((long long)in_sizes[3] / BSll);  // 1024
  const int B = (int)(BSll / S);                       // 2
  const int BS = B * S;
  const int NQ = NH * HD;                              // 2048
  const int NKVD = NKV * HD;                           // 512

  float* ws = (float*)d_ws;
  size_t off = 0;
  double* hpart = (double*)(ws + off); off += (size_t)B * HCH * H * 2;
  float* qb   = ws + off; off += (size_t)BS * NQ;
  float* q2b  = ws + off; off += (size_t)BS * NQ;
  float* kb   = ws + off; off += (size_t)BS * NKVD;
  float* vb   = ws + off; off += (size_t)BS * NKVD;
  float* attn = ws + off; off += (size_t)BS * NQ;
  float* Hsum = ws + off; off += (size_t)B * H;
  float* Qs   = ws + off; off += (size_t)B * NQ;
  float* sc   = ws + off; off += (size_t)B * KBL;
  int* topi   = (int*)(ws + off); off += (size_t)B * TOPK;
  int* padfl  = (int*)(ws + off); off += (size_t)BS;
  unsigned short* hbf    = (unsigned short*)(ws + off); off += (size_t)BS * H / 2;
  unsigned short* wqbf   = (unsigned short*)(ws + off); off += (size_t)NQ * H / 2;
  unsigned short* wq2bf  = (unsigned short*)(ws + off); off += (size_t)NQ * H / 2;
  unsigned short* wkbf   = (unsigned short*)(ws + off); off += (size_t)NKVD * H / 2;
  unsigned short* wvbf   = (unsigned short*)(ws + off); off += (size_t)NKVD * H / 2;
  unsigned short* wobf   = (unsigned short*)(ws + off); off += (size_t)H * NQ / 2;
  unsigned short* attnbf = (unsigned short*)(ws + off); off += (size_t)BS * NQ / 2;
  (void)ws_size; (void)n_in; (void)out_size;

  // 0: fp32 -> bf16 conversions
  {
    int n;
    n = BS * H / 4;   f2bf_kernel<<<(n + 255) / 256, 256, 0, stream>>>(hidden, hbf, n);
    n = NQ * H / 4;   f2bf_kernel<<<(n + 255) / 256, 256, 0, stream>>>(Wq, wqbf, n);
    n = NQ * H / 4;   f2bf_kernel<<<(n + 255) / 256, 256, 0, stream>>>(Wq2, wq2bf, n);
    n = NKVD * H / 4; f2bf_kernel<<<(n + 255) / 256, 256, 0, stream>>>(Wk, wkbf, n);
    n = NKVD * H / 4; f2bf_kernel<<<(n + 255) / 256, 256, 0, stream>>>(Wv, wvbf, n);
    n = H * NQ / 4;   f2bf_kernel<<<(n + 255) / 256, 256, 0, stream>>>(Wo, wobf, n);
  }

  // 1-4: projections (bf16 MFMA)
  gemm_nt_bf16<<<dim3(NQ / 128, BS / 128), 256, 0, stream>>>(hbf, wqbf, qb, BS, NQ, H);
  gemm_nt_bf16<<<dim3(NQ / 128, BS / 128), 256, 0, stream>>>(hbf, wq2bf, q2b, BS, NQ, H);
  gemm_nt_bf16<<<dim3(NKVD / 128, BS / 128), 256, 0, stream>>>(hbf, wkbf, kb, BS, NKVD, H);
  gemm_nt_bf16<<<dim3(NKVD / 128, BS / 128), 256, 0, stream>>>(hbf, wvbf, vb, BS, NKVD, H);

  // 5-6: RoPE
  {
    int tq = BS * NH * 32;
    rope_kernel<<<(tq + 255) / 256, 256, 0, stream>>>(qb, cosb, sinb, BS, NH);
    int tk = BS * NKV * 32;
    rope_kernel<<<(tk + 255) / 256, 256, 0, stream>>>(kb, cosb, sinb, BS, NKV);
  }

  // 7-10: exact fp32 scores path (two-stage f64 colsum) + top-k + padding
  hsum1_kernel<<<B * HCH * (H / 256), 256, 0, stream>>>(hidden, hpart, B, S, H);
  hsum2_kernel<<<(B * H + 255) / 256, 256, 0, stream>>>(hpart, Hsum, B, H);
  qs_kernel<<<(B * NQ * 64 + 255) / 256, 256, 0, stream>>>(Hsum, Wq2, Qs, B, H);
  scores_kernel<<<(B * KBL * 64 + 255) / 256, 256, 0, stream>>>(Qs, kbk, sc, B, KBL);
  topk_kernel<<<B, 256, 0, stream>>>(sc, topi, KBL);
  padflag_kernel<<<(BS * 64 + 255) / 256, 256, 0, stream>>>(mask, padfl, BS, S);

  // 11: fused attention (bf16 MFMA)
  attn_mfma<<<B * NH * (S / 64), 256, 0, stream>>>(
      qb, q2b, kb, vb, kbk, kbv, topi, padfl, attn, B, S);

  // 12: output projection (bf16 MFMA)
  {
    int n = BS * NQ / 4;
    f2bf_kernel<<<(n + 255) / 256, 256, 0, stream>>>(attn, attnbf, n);
  }
  gemm_nt_bf16<<<dim3(H / 128, BS / 128), 256, 0, stream>>>(attnbf, wobf, out, BS, H, NQ);
}

// Round 8
// 423.998 us; speedup vs baseline: 7.0508x; 1.1471x over previous
//
#include <hip/hip_runtime.h>
#include <hip/hip_bf16.h>
#include <math.h>

#define NH 32
#define NKV 8
#define HD 64
#define NSLOTS 11
#define TOPK 128
#define KBROW (NSLOTS * NH * HD)   // 22528
#define PADF (-3.3895313892515355e+38f)
#define C0F  (-0.24686007793152578f)   // -ln(128)+ln(100)
#define SCALE 0.125f
#define HCH 32                         // S-chunks for hierarchical column sum

typedef __attribute__((ext_vector_type(8))) __bf16 bf16x8;
typedef __attribute__((ext_vector_type(8))) unsigned short u16x8;
typedef __attribute__((ext_vector_type(4))) float f32x4;

#define GLDS16(gp, lp)                                                        \
  __builtin_amdgcn_global_load_lds(                                           \
      (__attribute__((address_space(1))) void*)(gp),                          \
      (__attribute__((address_space(3))) void*)(lp), 16, 0, 0)

__device__ __forceinline__ unsigned short f2bf(float f) {
  unsigned int u = __float_as_uint(f);
  u = (u + 0x7fffu + ((u >> 16) & 1u)) >> 16;
  return (unsigned short)u;
}

// byte offset into a 64-col bf16 tile (128 B/row) with XOR chunk swizzle
__device__ __forceinline__ int swz(int row, int chunk) {
  return row * 128 + ((chunk ^ (row & 7)) << 4);
}

// ---------------------------------------------------------------------------
// fp32 -> bf16 (RTNE), 4 elems/thread.
// ---------------------------------------------------------------------------
__global__ void f2bf_kernel(const float* __restrict__ in,
                            unsigned short* __restrict__ out, int n4) {
  int i = blockIdx.x * blockDim.x + threadIdx.x;
  if (i >= n4) return;
  float4 v = ((const float4*)in)[i];
  ushort4 o;
  o.x = f2bf(v.x); o.y = f2bf(v.y); o.z = f2bf(v.z); o.w = f2bf(v.w);
  ((ushort4*)out)[i] = o;
}

// ---------------------------------------------------------------------------
// bf16 MFMA GEMM (m97 structure): C[M,N] = A[M,K] @ B[N,K]^T. Output f32 or
// bf16 (OBF). Tile 128x128, BK=32, 4 waves (2x2), 16x16x32 MFMA.
// ---------------------------------------------------------------------------
template <bool OBF>
__global__ __launch_bounds__(256) void gemm_nt_bf16(
    const unsigned short* __restrict__ A, const unsigned short* __restrict__ B,
    void* __restrict__ Cv, int M, int N, int K) {
  __shared__ unsigned short ldsA[128 * 32];
  __shared__ unsigned short ldsB[128 * 32];
  const int t = threadIdx.x;
  const int l = t & 63, w = t >> 6;
  const int wr = w >> 1, wc = w & 1;
  const int lr = l & 15;
  const int kb = (l >> 4) * 16;
  const int bm = blockIdx.y * 128, bn = blockIdx.x * 128;

  f32x4 acc[4][4] = {};

  for (int k0 = 0; k0 < K; k0 += 32) {
    __syncthreads();
#pragma unroll
    for (int it = 0; it < 2; ++it) {
      int s = it * 256 + t;
      int row = s >> 2, cs = (s & 3) * 8;
      GLDS16(A + (size_t)(bm + row) * K + k0 + cs,
             (char*)ldsA + (it * 4 + w) * 1024);
      GLDS16(B + (size_t)(bn + row) * K + k0 + cs,
             (char*)ldsB + (it * 4 + w) * 1024);
    }
    __syncthreads();

    bf16x8 a[4], b[4];
#pragma unroll
    for (int m = 0; m < 4; ++m)
      a[m] = *(const bf16x8*)((const char*)ldsA +
                              (wr * 64 + m * 16 + lr) * 64 + kb);
#pragma unroll
    for (int n = 0; n < 4; ++n)
      b[n] = *(const bf16x8*)((const char*)ldsB +
                              (wc * 64 + n * 16 + lr) * 64 + kb);
#pragma unroll
    for (int m = 0; m < 4; ++m)
#pragma unroll
      for (int n = 0; n < 4; ++n)
        acc[m][n] =
            __builtin_amdgcn_mfma_f32_16x16x32_bf16(a[m], b[n], acc[m][n], 0, 0, 0);
  }

#pragma unroll
  for (int m = 0; m < 4; ++m)
#pragma unroll
    for (int n = 0; n < 4; ++n) {
      int rbase = bm + wr * 64 + m * 16 + ((l >> 4) << 2);
      int cbase = bn + wc * 64 + n * 16 + lr;
#pragma unroll
      for (int j = 0; j < 4; ++j) {
        if constexpr (OBF)
          ((unsigned short*)Cv)[(size_t)(rbase + j) * N + cbase] =
              f2bf(acc[m][n][j]);
        else
          ((float*)Cv)[(size_t)(rbase + j) * N + cbase] = acc[m][n][j];
      }
    }
}

// ---------------------------------------------------------------------------
// RoPE: read f32 x [rows][nheads*64], write bf16 y (same layout).
// ---------------------------------------------------------------------------
__global__ void rope_bf16_kernel(const float* __restrict__ x,
                                 const float* __restrict__ c,
                                 const float* __restrict__ s,
                                 unsigned short* __restrict__ y,
                                 int rows, int nheads) {
  int tid = blockIdx.x * blockDim.x + threadIdx.x;
  int total = rows * nheads * 32;
  if (tid >= total) return;
  int d = tid & 31;
  int h = (tid >> 5) % nheads;
  int row = tid / (32 * nheads);
  const float* xr = x + ((size_t)row * nheads + h) * 64;
  unsigned short* yr = y + ((size_t)row * nheads + h) * 64;
  float c1 = c[(size_t)row * 64 + d], c2 = c[(size_t)row * 64 + d + 32];
  float s1 = s[(size_t)row * 64 + d], s2 = s[(size_t)row * 64 + d + 32];
  float x1 = xr[d], x2 = xr[d + 32];
  yr[d]      = f2bf(x1 * c1 - x2 * s1);
  yr[d + 32] = f2bf(x2 * c2 + x1 * s2);
}

// ---------------------------------------------------------------------------
// V transpose: vT[((b*NKV+g)*64+d)*S + s] = bf16(vbuf[((b*S+s)*NKV+g)*64+d])
// One block per (b, g, 64-row s-tile); LDS tile transpose.
// ---------------------------------------------------------------------------
__global__ __launch_bounds__(256) void vT_kernel(
    const float* __restrict__ vbuf, unsigned short* __restrict__ vT,
    int B, int S) {
  const int nst = S >> 6;
  int stile = blockIdx.x % nst;
  int g = (blockIdx.x / nst) % NKV;
  int b = blockIdx.x / (nst * NKV);
  int s0 = stile * 64;
  __shared__ float lt[64][68];
  int t = threadIdx.x;
#pragma unroll
  for (int it = 0; it < 4; ++it) {
    int slot = it * 256 + t;           // 64 s x 16 d4
    int sl = slot >> 4, d4 = (slot & 15) * 4;
    float4 v = *(const float4*)&vbuf[((size_t)(b * S + s0 + sl) * NKV + g) * 64 + d4];
    lt[sl][d4] = v.x; lt[sl][d4 + 1] = v.y; lt[sl][d4 + 2] = v.z; lt[sl][d4 + 3] = v.w;
  }
  __syncthreads();
#pragma unroll
  for (int it = 0; it < 2; ++it) {
    int slot = it * 256 + t;           // 64 d x 8 s8
    int d = slot >> 3, s8 = (slot & 7) * 8;
    u16x8 o;
#pragma unroll
    for (int j = 0; j < 8; ++j) o[j] = f2bf(lt[s8 + j][d]);
    *(u16x8*)&vT[(((size_t)b * NKV + g) * 64 + d) * S + s0 + s8] = o;
  }
}

// ---------------------------------------------------------------------------
// KB key slice: kbkh[j][c] = bf16(kb_keys[j*KBROW + c]), j<128, c<2048.
// ---------------------------------------------------------------------------
__global__ void kbkh_kernel(const float* __restrict__ kbk,
                            unsigned short* __restrict__ out) {
  int i = blockIdx.x * blockDim.x + threadIdx.x;
  if (i >= 128 * 512) return;
  int j = i >> 9, c4 = (i & 511) * 4;
  float4 v = *(const float4*)&kbk[(size_t)j * KBROW + c4];
  ushort4 o = {f2bf(v.x), f2bf(v.y), f2bf(v.z), f2bf(v.w)};
  *(ushort4*)&out[(size_t)j * 2048 + c4] = o;
}

// ---------------------------------------------------------------------------
// Gathered + transposed KB values:
// kbvgT[((b*NH+h)*64+d)*128 + j] = bf16(kbv[topi[b][j]*KBROW + h*64 + d]).
// One block per (b,h).
// ---------------------------------------------------------------------------
__global__ __launch_bounds__(256) void kbvgt_kernel(
    const float* __restrict__ kbv, const int* __restrict__ topi,
    unsigned short* __restrict__ kbvgT, int B) {
  int h = blockIdx.x % NH, b = blockIdx.x / NH;
  __shared__ unsigned short gt[128][72];
  __shared__ int lidx[TOPK];
  int t = threadIdx.x;
  if (t < TOPK) lidx[t] = topi[b * TOPK + t];
  __syncthreads();
#pragma unroll
  for (int it = 0; it < 8; ++it) {
    int slot = it * 256 + t;            // 128 j x 16 d4
    int j = slot >> 4, d4 = (slot & 15) * 4;
    float4 v = *(const float4*)&kbv[(size_t)lidx[j] * KBROW + h * 64 + d4];
    gt[j][d4] = f2bf(v.x); gt[j][d4 + 1] = f2bf(v.y);
    gt[j][d4 + 2] = f2bf(v.z); gt[j][d4 + 3] = f2bf(v.w);
  }
  __syncthreads();
#pragma unroll
  for (int it = 0; it < 4; ++it) {
    int slot = it * 256 + t;            // 64 d x 16 j8
    int d = slot >> 4, j8 = (slot & 15) * 8;
    u16x8 o;
#pragma unroll
    for (int j = 0; j < 8; ++j) o[j] = gt[j8 + j][d];
    *(u16x8*)&kbvgT[(((size_t)b * NH + h) * 64 + d) * 128 + j8] = o;
  }
}

// ---------------------------------------------------------------------------
// Column-sum stage 1: part[b][ch][c] = sum over 32-row chunk (f64).
// ---------------------------------------------------------------------------
__global__ __launch_bounds__(256) void hsum1_kernel(
    const float* __restrict__ hidden, double* __restrict__ part,
    int B, int S, int H) {
  const int nhb = H >> 8;
  int hb = blockIdx.x % nhb;
  int ch = (blockIdx.x / nhb) % HCH;
  int b  = blockIdx.x / (nhb * HCH);
  int c  = hb * 256 + threadIdx.x;
  int rows = S / HCH;
  const float* p = hidden + ((size_t)b * S + (size_t)ch * rows) * H + c;
  double acc = 0.0;
  for (int s = 0; s < rows; ++s) acc += (double)p[(size_t)s * H];
  part[((size_t)b * HCH + ch) * H + c] = acc;
}

// ---------------------------------------------------------------------------
// Column-sum stage 2: Hsum[b][c] = sum_ch part[b][ch][c] (f64, fixed order).
// ---------------------------------------------------------------------------
__global__ void hsum2_kernel(const double* __restrict__ part,
                             float* __restrict__ Hsum, int B, int H) {
  int idx = blockIdx.x * blockDim.x + threadIdx.x;
  if (idx >= B * H) return;
  int b = idx / H, c = idx % H;
  const double* p = part + (size_t)b * HCH * H + c;
  double acc = 0.0;
#pragma unroll
  for (int ch = 0; ch < HCH; ++ch) acc += p[(size_t)ch * H];
  Hsum[idx] = (float)acc;
}

// ---------------------------------------------------------------------------
// Qs[b][c] = sum_k Hsum[b][k] * Wq2[c][k]  (fp32 inputs, f64 accum).
// ---------------------------------------------------------------------------
__global__ void qs_kernel(const float* __restrict__ Hsum,
                          const float* __restrict__ Wq2,
                          float* __restrict__ Qs, int B, int H) {
  int task = (blockIdx.x * blockDim.x + threadIdx.x) >> 6;
  int lane = threadIdx.x & 63;
  if (task >= B * NH * HD) return;
  int b = task / (NH * HD), c = task % (NH * HD);
  const float* hs = Hsum + (size_t)b * H;
  const float* wr = Wq2 + (size_t)c * H;
  double acc = 0.0;
  for (int k = lane; k < H; k += 64) acc += (double)hs[k] * (double)wr[k];
#pragma unroll
  for (int off = 32; off; off >>= 1) acc += __shfl_xor(acc, off);
  if (lane == 0) Qs[task] = (float)acc;
}

// ---------------------------------------------------------------------------
// scores[b][l] = 0.125 * dot(Qs[b,:], kb_keys[l, 0:2048]) (f64 acc)
// ---------------------------------------------------------------------------
__global__ void scores_kernel(const float* __restrict__ Qs,
                              const float* __restrict__ kbk,
                              float* __restrict__ scores, int B, int KBL) {
  int task = (blockIdx.x * blockDim.x + threadIdx.x) >> 6;
  int lane = threadIdx.x & 63;
  if (task >= B * KBL) return;
  int b = task / KBL, l = task % KBL;
  const float* kr = kbk + (size_t)l * KBROW;
  const float* qd = Qs + (size_t)b * NH * HD;
  double acc = 0.0;
  for (int c = lane; c < NH * HD; c += 64) acc += (double)qd[c] * (double)kr[c];
#pragma unroll
  for (int off = 32; off; off >>= 1) acc += __shfl_xor(acc, off);
  if (lane == 0) scores[task] = (float)(0.125 * acc);
}

// ---------------------------------------------------------------------------
// Top-K by rank-counting (stable descending == lax.top_k).
// ---------------------------------------------------------------------------
__global__ __launch_bounds__(256) void topk_kernel(
    const float* __restrict__ scores, int* __restrict__ top_idx, int KBL) {
  __shared__ float ls[512];
  int b = blockIdx.x, t = threadIdx.x;
  for (int i = t; i < KBL; i += 256) ls[i] = scores[(size_t)b * KBL + i];
  __syncthreads();
  for (int l = t; l < KBL; l += 256) {
    float sl = ls[l];
    int rank = 0;
    for (int j = 0; j < KBL; ++j) {
      float sj = ls[j];
      rank += (sj > sl || (sj == sl && j < l)) ? 1 : 0;
    }
    if (rank < TOPK) top_idx[b * TOPK + rank] = l;
  }
}

// ---------------------------------------------------------------------------
// padflag[b*S+s] = all(mask[b,0,s,:] < 0)
// ---------------------------------------------------------------------------
__global__ void padflag_kernel(const float* __restrict__ mask,
                               int* __restrict__ flags, int BS, int S) {
  int w = (blockIdx.x * blockDim.x + threadIdx.x) >> 6;
  int lane = threadIdx.x & 63;
  if (w >= BS) return;
  const float* row = mask + (size_t)w * S;
  bool ok = true;
  for (int j = lane; j < S; j += 64) ok = ok && (row[j] < 0.f);
  int allv = __all(ok ? 1 : 0);
  if (lane == 0) flags[w] = allv;
}

// ---------------------------------------------------------------------------
// MFMA fused attention v2: all-bf16 inputs, pure b128 staging, shared smem
// for q-tiles then K/V tiles (q fragments hoisted to regs), bf16 output.
// Block = 4 waves; 64 q-rows of one (b,h).
// ---------------------------------------------------------------------------
__global__ __launch_bounds__(256) void attn_mfma(
    const unsigned short* __restrict__ qbf,    // [B*S][2048] roped bf16
    const unsigned short* __restrict__ q2bf,   // [B*S][2048] bf16
    const unsigned short* __restrict__ kbf,    // [B*S][512] roped bf16
    const unsigned short* __restrict__ vTb,    // [B][NKV][64][S] bf16
    const unsigned short* __restrict__ kbkh,   // [128][2048] bf16
    const unsigned short* __restrict__ kbvgT,  // [B][NH][64][128] bf16
    const int* __restrict__ padflag,           // [B*S]
    unsigned short* __restrict__ attnbf,       // [B*S][2048] bf16
    int B, int S) {
  const int nst = S >> 6;
  const int st = blockIdx.x % nst;
  const int h  = (blockIdx.x / nst) % NH;
  const int b  = blockIdx.x / (nst * NH);
  const int s0 = st * 64;
  const int g  = h / (NH / NKV);

  __shared__ unsigned short smem[8192];   // q|q2 tiles, then K|V^T tiles
  __shared__ unsigned short pt[4][1024];  // per-wave P [row16][key64]
  __shared__ int padf[64];

  const int t = threadIdx.x;
  const int w = t >> 6;
  const int li = t & 15;
  const int lg4 = (t & 63) >> 4;

  // ---- stage q/q2 tiles (swizzled b128 copies)
#pragma unroll
  for (int it = 0; it < 4; ++it) {
    int slot = it * 256 + t;                 // 2 tiles x 64 rows x 8 chunks
    int tile = slot >> 9, row = (slot >> 3) & 63, ck = slot & 7;
    const unsigned short* src = tile ? q2bf : qbf;
    bf16x8 v = *(const bf16x8*)(src + (size_t)(b * S + s0 + row) * (NH * HD) +
                                h * 64 + ck * 8);
    *(bf16x8*)((char*)smem + tile * 8192 + swz(row, ck)) = v;
  }
  if (t < 64) padf[t] = padflag[b * S + s0 + t];
  __syncthreads();

  // hoist q fragments (row = w*16+li), then smem is reusable
  bf16x8 aq0[2], aq2[2];
#pragma unroll
  for (int kc = 0; kc < 2; ++kc) {
    aq0[kc] = *(const bf16x8*)((char*)smem + swz(w * 16 + li, kc * 4 + lg4));
    aq2[kc] = *(const bf16x8*)((char*)smem + 8192 + swz(w * 16 + li, kc * 4 + lg4));
  }

  float m_[4] = {-3.4e38f, -3.4e38f, -3.4e38f, -3.4e38f};
  float l_[4] = {};
  f32x4 acc[4] = {};

  const int nch = 2 + st + 1;
  for (int ch = 0; ch < nch; ++ch) {
    const bool iskb = ch < 2;
    const int j0 = iskb ? ch * 64 : (ch - 2) * 64;
    __syncthreads();  // prev tiles consumed (and q-hoist done on first iter)
    // ---- stage K tile (bytes 0..8191) + V^T tile (8192..16383)
#pragma unroll
    for (int it = 0; it < 4; ++it) {
      int slot = it * 256 + t;
      int tile = slot >> 9, row = (slot >> 3) & 63, ck = slot & 7;
      const unsigned short* src;
      if (tile == 0) {
        src = iskb ? kbkh + (size_t)(j0 + row) * 2048 + h * 64 + ck * 8
                   : kbf + (size_t)(b * S + j0 + row) * 512 + g * 64 + ck * 8;
      } else {
        src = iskb ? kbvgT + (((size_t)b * NH + h) * 64 + row) * 128 + j0 + ck * 8
                   : vTb + (((size_t)b * NKV + g) * 64 + row) * (size_t)S + j0 + ck * 8;
      }
      bf16x8 v = *(const bf16x8*)src;
      *(bf16x8*)((char*)smem + tile * 8192 + swz(row, ck)) = v;
    }
    __syncthreads();

    // ---- QK^T
    const bf16x8* aq = iskb ? aq2 : aq0;
    f32x4 cc[4];
#pragma unroll
    for (int cb = 0; cb < 4; ++cb) {
      bf16x8 b0 = *(const bf16x8*)((char*)smem + swz(cb * 16 + li, lg4));
      bf16x8 b1 = *(const bf16x8*)((char*)smem + swz(cb * 16 + li, 4 + lg4));
      f32x4 z = {};
      z = __builtin_amdgcn_mfma_f32_16x16x32_bf16(aq[0], b0, z, 0, 0, 0);
      z = __builtin_amdgcn_mfma_f32_16x16x32_bf16(aq[1], b1, z, 0, 0, 0);
      cc[cb] = z;
    }

    // ---- logits + online softmax
    float lgv[4][4];
#pragma unroll
    for (int cb = 0; cb < 4; ++cb) {
#pragma unroll
      for (int j = 0; j < 4; ++j) {
        float v = SCALE * cc[cb][j];
        if (iskb) {
          v += C0F + (padf[w * 16 + lg4 * 4 + j] ? PADF : 0.f);
        } else {
          int key = j0 + cb * 16 + li;
          int srow = s0 + w * 16 + lg4 * 4 + j;
          v += (key <= srow) ? 0.f : PADF;
        }
        lgv[cb][j] = v;
      }
    }
#pragma unroll
    for (int j = 0; j < 4; ++j) {
      float rmax = fmaxf(fmaxf(lgv[0][j], lgv[1][j]), fmaxf(lgv[2][j], lgv[3][j]));
#pragma unroll
      for (int off = 8; off; off >>= 1) rmax = fmaxf(rmax, __shfl_xor(rmax, off));
      float mn = fmaxf(m_[j], rmax);
      float fs = __expf(m_[j] - mn);
      float csum = 0.f;
#pragma unroll
      for (int cb = 0; cb < 4; ++cb) {
        float p = __expf(lgv[cb][j] - mn);
        csum += p;
        int key = cb * 16 + li;
        int rloc = lg4 * 4 + j;
        *(unsigned short*)((char*)pt[w] + swz(rloc, key >> 3) +
                           ((key & 7) << 1)) = f2bf(p);
      }
#pragma unroll
      for (int off = 8; off; off >>= 1) csum += __shfl_xor(csum, off);
      m_[j] = mn;
      l_[j] = l_[j] * fs + csum;
#pragma unroll
      for (int db = 0; db < 4; ++db) acc[db][j] *= fs;
    }

    // ---- PV (V^T tile at byte 8192)
    bf16x8 pa0 = *(const bf16x8*)((const char*)pt[w] + swz(li, lg4));
    bf16x8 pa1 = *(const bf16x8*)((const char*)pt[w] + swz(li, 4 + lg4));
#pragma unroll
    for (int db = 0; db < 4; ++db) {
      bf16x8 bv0 = *(const bf16x8*)((char*)smem + 8192 + swz(db * 16 + li, lg4));
      bf16x8 bv1 = *(const bf16x8*)((char*)smem + 8192 + swz(db * 16 + li, 4 + lg4));
      acc[db] = __builtin_amdgcn_mfma_f32_16x16x32_bf16(pa0, bv0, acc[db], 0, 0, 0);
      acc[db] = __builtin_amdgcn_mfma_f32_16x16x32_bf16(pa1, bv1, acc[db], 0, 0, 0);
    }
  }

  // ---- epilogue: normalize, store bf16
#pragma unroll
  for (int j = 0; j < 4; ++j) {
    float inv = 1.f / l_[j];
    size_t o = (size_t)(b * S + s0 + w * 16 + lg4 * 4 + j) * (NH * HD) + h * 64 + li;
#pragma unroll
    for (int db = 0; db < 4; ++db) attnbf[o + db * 16] = f2bf(acc[db][j] * inv);
  }
}

// ---------------------------------------------------------------------------
extern "C" void kernel_launch(void* const* d_in, const int* in_sizes, int n_in,
                              void* d_out, int out_size, void* d_ws, size_t ws_size,
                              hipStream_t stream) {
  const float* hidden = (const float*)d_in[0];
  const float* cosb   = (const float*)d_in[1];
  const float* sinb   = (const float*)d_in[2];
  const float* mask   = (const float*)d_in[3];
  const float* kbk    = (const float*)d_in[4];
  const float* kbv    = (const float*)d_in[5];
  const float* Wq     = (const float*)d_in[6];
  const float* Wq2    = (const float*)d_in[7];
  const float* Wk     = (const float*)d_in[8];
  const float* Wv     = (const float*)d_in[9];
  const float* Wo     = (const float*)d_in[10];
  float* out = (float*)d_out;

  const int H   = in_sizes[6] / (NH * HD);             // 2048
  const int KBL = in_sizes[4] / KBROW;                 // 400
  const long long BSll = (long long)in_sizes[0] / H;
  const int S = (int)((long long)in_sizes[3] / BSll);  // 1024
  const int B = (int)(BSll / S);                       // 2
  const int BS = B * S;
  const int NQ = NH * HD;                              // 2048
  const int NKVD = NKV * HD;                           // 512

  float* ws = (float*)d_ws;
  size_t off = 0;
  double* hpart = (double*)(ws + off); off += (size_t)B * HCH * H * 2;
  float* qb   = ws + off; off += (size_t)BS * NQ;        // f32 q (pre-rope)
  float* kb   = ws + off; off += (size_t)BS * NKVD;      // f32 k (pre-rope)
  float* vb   = ws + off; off += (size_t)BS * NKVD;      // f32 v
  float* Hsum = ws + off; off += (size_t)B * H;
  float* Qs   = ws + off; off += (size_t)B * NQ;
  float* sc   = ws + off; off += (size_t)B * KBL;
  int* topi   = (int*)(ws + off); off += (size_t)B * TOPK;
  int* padfl  = (int*)(ws + off); off += (size_t)BS;
  unsigned short* hbf    = (unsigned short*)(ws + off); off += (size_t)BS * H / 2;
  unsigned short* wqbf   = (unsigned short*)(ws + off); off += (size_t)NQ * H / 2;
  unsigned short* wq2bf  = (unsigned short*)(ws + off); off += (size_t)NQ * H / 2;
  unsigned short* wkbf   = (unsigned short*)(ws + off); off += (size_t)NKVD * H / 2;
  unsigned short* wvbf   = (unsigned short*)(ws + off); off += (size_t)NKVD * H / 2;
  unsigned short* wobf   = (unsigned short*)(ws + off); off += (size_t)H * NQ / 2;
  unsigned short* attnbf = (unsigned short*)(ws + off); off += (size_t)BS * NQ / 2;
  unsigned short* qbf    = (unsigned short*)(ws + off); off += (size_t)BS * NQ / 2;
  unsigned short* q2bf   = (unsigned short*)(ws + off); off += (size_t)BS * NQ / 2;
  unsigned short* kbf    = (unsigned short*)(ws + off); off += (size_t)BS * NKVD / 2;
  unsigned short* vTb    = (unsigned short*)(ws + off); off += (size_t)BS * NKVD / 2;
  unsigned short* kbkh   = (unsigned short*)(ws + off); off += (size_t)128 * NQ / 2;
  unsigned short* kbvgT  = (unsigned short*)(ws + off); off += (size_t)B * NH * HD * TOPK / 2;
  (void)ws_size; (void)n_in; (void)out_size;

  // 0: fp32 -> bf16 conversions (GEMM inputs)
  {
    int n;
    n = BS * H / 4;   f2bf_kernel<<<(n + 255) / 256, 256, 0, stream>>>(hidden, hbf, n);
    n = NQ * H / 4;   f2bf_kernel<<<(n + 255) / 256, 256, 0, stream>>>(Wq, wqbf, n);
    n = NQ * H / 4;   f2bf_kernel<<<(n + 255) / 256, 256, 0, stream>>>(Wq2, wq2bf, n);
    n = NKVD * H / 4; f2bf_kernel<<<(n + 255) / 256, 256, 0, stream>>>(Wk, wkbf, n);
    n = NKVD * H / 4; f2bf_kernel<<<(n + 255) / 256, 256, 0, stream>>>(Wv, wvbf, n);
    n = H * NQ / 4;   f2bf_kernel<<<(n + 255) / 256, 256, 0, stream>>>(Wo, wobf, n);
  }

  // 1-4: projections (q, k, v -> f32; q2 -> bf16 directly)
  gemm_nt_bf16<false><<<dim3(NQ / 128, BS / 128), 256, 0, stream>>>(hbf, wqbf, qb, BS, NQ, H);
  gemm_nt_bf16<true><<<dim3(NQ / 128, BS / 128), 256, 0, stream>>>(hbf, wq2bf, q2bf, BS, NQ, H);
  gemm_nt_bf16<false><<<dim3(NKVD / 128, BS / 128), 256, 0, stream>>>(hbf, wkbf, kb, BS, NKVD, H);
  gemm_nt_bf16<false><<<dim3(NKVD / 128, BS / 128), 256, 0, stream>>>(hbf, wvbf, vb, BS, NKVD, H);

  // 5-7: RoPE -> bf16; V transpose -> bf16
  {
    int tq = BS * NH * 32;
    rope_bf16_kernel<<<(tq + 255) / 256, 256, 0, stream>>>(qb, cosb, sinb, qbf, BS, NH);
    int tk = BS * NKV * 32;
    rope_bf16_kernel<<<(tk + 255) / 256, 256, 0, stream>>>(kb, cosb, sinb, kbf, BS, NKV);
    vT_kernel<<<B * NKV * (S / 64), 256, 0, stream>>>(vb, vTb, B, S);
  }

  // 8-12: exact fp32 scores path + top-k + padding
  hsum1_kernel<<<B * HCH * (H / 256), 256, 0, stream>>>(hidden, hpart, B, S, H);
  hsum2_kernel<<<(B * H + 255) / 256, 256, 0, stream>>>(hpart, Hsum, B, H);
  qs_kernel<<<(B * NQ * 64 + 255) / 256, 256, 0, stream>>>(Hsum, Wq2, Qs, B, H);
  scores_kernel<<<(B * KBL * 64 + 255) / 256, 256, 0, stream>>>(Qs, kbk, sc, B, KBL);
  topk_kernel<<<B, 256, 0, stream>>>(sc, topi, KBL);
  padflag_kernel<<<(BS * 64 + 255) / 256, 256, 0, stream>>>(mask, padfl, BS, S);

  // 13-14: KB bf16 staging (keys slice; gathered+transposed values)
  kbkh_kernel<<<(128 * 512 + 255) / 256, 256, 0, stream>>>(kbk, kbkh);
  kbvgt_kernel<<<B * NH, 256, 0, stream>>>(kbv, topi, kbvgT, B);

  // 15: fused attention (bf16 MFMA) -> bf16
  attn_mfma<<<B * NH * (S / 64), 256, 0, stream>>>(
      qbf, q2bf, kbf, vTb, kbkh, kbvgT, padfl, attnbf, B, S);

  // 16: output projection
  gemm_nt_bf16<false><<<dim3(H / 128, BS / 128), 256, 0, stream>>>(attnbf, wobf, out, BS, H, NQ);
}

// Round 9
// 310.762 us; speedup vs baseline: 9.6200x; 1.3644x over previous
//
#include <hip/hip_runtime.h>
#include <hip/hip_bf16.h>
#include <math.h>

#define NH 32
#define NKV 8
#define HD 64
#define NSLOTS 11
#define TOPK 128
#define KBROW (NSLOTS * NH * HD)   // 22528
#define PADF (-3.3895313892515355e+38f)
#define C0F  (-0.24686007793152578f)   // -ln(128)+ln(100)
#define SCALE 0.125f
#define HCH 32                         // S-chunks for hierarchical column sum

typedef __attribute__((ext_vector_type(8))) __bf16 bf16x8;
typedef __attribute__((ext_vector_type(8))) unsigned short u16x8;
typedef __attribute__((ext_vector_type(4))) float f32x4;

#define GLDS16(gp, lp)                                                        \
  __builtin_amdgcn_global_load_lds(                                           \
      (__attribute__((address_space(1))) void*)(gp),                          \
      (__attribute__((address_space(3))) void*)(lp), 16, 0, 0)

__device__ __forceinline__ unsigned short f2bf(float f) {
  unsigned int u = __float_as_uint(f);
  u = (u + 0x7fffu + ((u >> 16) & 1u)) >> 16;
  return (unsigned short)u;
}

// byte offset into a 64-col bf16 tile (128 B/row) with XOR chunk swizzle
__device__ __forceinline__ int swz(int row, int chunk) {
  return row * 128 + ((chunk ^ (row & 7)) << 4);
}

// ---------------------------------------------------------------------------
// fp32 -> bf16 (RTNE), 4 elems/thread.
// ---------------------------------------------------------------------------
__global__ void f2bf_kernel(const float* __restrict__ in,
                            unsigned short* __restrict__ out, int n4) {
  int i = blockIdx.x * blockDim.x + threadIdx.x;
  if (i >= n4) return;
  float4 v = ((const float4*)in)[i];
  ushort4 o;
  o.x = f2bf(v.x); o.y = f2bf(v.y); o.z = f2bf(v.z); o.w = f2bf(v.w);
  ((ushort4*)out)[i] = o;
}

// ---------------------------------------------------------------------------
// fp32 -> bf16 for 4 concatenated sources into one dest (n in float4 units).
// ---------------------------------------------------------------------------
__global__ void f2bf4_kernel(const float* __restrict__ s0,
                             const float* __restrict__ s1,
                             const float* __restrict__ s2,
                             const float* __restrict__ s3,
                             int n0, int n1, int n2, int n3,
                             unsigned short* __restrict__ out) {
  int i = blockIdx.x * blockDim.x + threadIdx.x;
  int j = i;
  const float* src;
  if (j < n0) src = s0;
  else {
    j -= n0;
    if (j < n1) src = s1;
    else {
      j -= n1;
      if (j < n2) src = s2;
      else {
        j -= n2;
        if (j >= n3) return;
        src = s3;
      }
    }
  }
  float4 v = ((const float4*)src)[j];
  ushort4 o = {f2bf(v.x), f2bf(v.y), f2bf(v.z), f2bf(v.w)};
  ((ushort4*)out)[i] = o;
}

// ---------------------------------------------------------------------------
// bf16 MFMA GEMM (m97 structure): C[M,N] = A[M,K] @ B[N,K]^T, f32 out.
// Tile 128x128, BK=32, 4 waves (2x2), 16x16x32 MFMA.
// ---------------------------------------------------------------------------
__global__ __launch_bounds__(256) void gemm_nt_bf16(
    const unsigned short* __restrict__ A, const unsigned short* __restrict__ B,
    float* __restrict__ C, int M, int N, int K) {
  __shared__ unsigned short ldsA[128 * 32];
  __shared__ unsigned short ldsB[128 * 32];
  const int t = threadIdx.x;
  const int l = t & 63, w = t >> 6;
  const int wr = w >> 1, wc = w & 1;
  const int lr = l & 15;
  const int kb = (l >> 4) * 16;
  const int bm = blockIdx.y * 128, bn = blockIdx.x * 128;

  f32x4 acc[4][4] = {};

  for (int k0 = 0; k0 < K; k0 += 32) {
    __syncthreads();
#pragma unroll
    for (int it = 0; it < 2; ++it) {
      int s = it * 256 + t;
      int row = s >> 2, cs = (s & 3) * 8;
      GLDS16(A + (size_t)(bm + row) * K + k0 + cs,
             (char*)ldsA + (it * 4 + w) * 1024);
      GLDS16(B + (size_t)(bn + row) * K + k0 + cs,
             (char*)ldsB + (it * 4 + w) * 1024);
    }
    __syncthreads();

    bf16x8 a[4], b[4];
#pragma unroll
    for (int m = 0; m < 4; ++m)
      a[m] = *(const bf16x8*)((const char*)ldsA +
                              (wr * 64 + m * 16 + lr) * 64 + kb);
#pragma unroll
    for (int n = 0; n < 4; ++n)
      b[n] = *(const bf16x8*)((const char*)ldsB +
                              (wc * 64 + n * 16 + lr) * 64 + kb);
#pragma unroll
    for (int m = 0; m < 4; ++m)
#pragma unroll
      for (int n = 0; n < 4; ++n)
        acc[m][n] =
            __builtin_amdgcn_mfma_f32_16x16x32_bf16(a[m], b[n], acc[m][n], 0, 0, 0);
  }

#pragma unroll
  for (int m = 0; m < 4; ++m)
#pragma unroll
    for (int n = 0; n < 4; ++n) {
      int rbase = bm + wr * 64 + m * 16 + ((l >> 4) << 2);
      int cbase = bn + wc * 64 + n * 16 + lr;
#pragma unroll
      for (int j = 0; j < 4; ++j)
        C[(size_t)(rbase + j) * N + cbase] = acc[m][n][j];
    }
}

// ---------------------------------------------------------------------------
// Fused projection GEMM: A[M,K] @ Wall[5120,K]^T, segmented outputs:
// cols [0,2048)->qb f32; [2048,4096)->q2bf bf16; [4096,4608)->kb f32;
// [4608,5120)->vb f32. Same math/rounding as split GEMMs.
// ---------------------------------------------------------------------------
__global__ __launch_bounds__(256) void gemm_proj(
    const unsigned short* __restrict__ A, const unsigned short* __restrict__ Wall,
    float* __restrict__ qb, unsigned short* __restrict__ q2bf,
    float* __restrict__ kb, float* __restrict__ vb, int M, int K) {
  __shared__ unsigned short ldsA[128 * 32];
  __shared__ unsigned short ldsB[128 * 32];
  const int t = threadIdx.x;
  const int l = t & 63, w = t >> 6;
  const int wr = w >> 1, wc = w & 1;
  const int lr = l & 15;
  const int kb_ = (l >> 4) * 16;
  const int bm = blockIdx.y * 128, bn = blockIdx.x * 128;

  f32x4 acc[4][4] = {};

  for (int k0 = 0; k0 < K; k0 += 32) {
    __syncthreads();
#pragma unroll
    for (int it = 0; it < 2; ++it) {
      int s = it * 256 + t;
      int row = s >> 2, cs = (s & 3) * 8;
      GLDS16(A + (size_t)(bm + row) * K + k0 + cs,
             (char*)ldsA + (it * 4 + w) * 1024);
      GLDS16(Wall + (size_t)(bn + row) * K + k0 + cs,
             (char*)ldsB + (it * 4 + w) * 1024);
    }
    __syncthreads();

    bf16x8 a[4], b[4];
#pragma unroll
    for (int m = 0; m < 4; ++m)
      a[m] = *(const bf16x8*)((const char*)ldsA +
                              (wr * 64 + m * 16 + lr) * 64 + kb_);
#pragma unroll
    for (int n = 0; n < 4; ++n)
      b[n] = *(const bf16x8*)((const char*)ldsB +
                              (wc * 64 + n * 16 + lr) * 64 + kb_);
#pragma unroll
    for (int m = 0; m < 4; ++m)
#pragma unroll
      for (int n = 0; n < 4; ++n)
        acc[m][n] =
            __builtin_amdgcn_mfma_f32_16x16x32_bf16(a[m], b[n], acc[m][n], 0, 0, 0);
  }

#pragma unroll
  for (int m = 0; m < 4; ++m)
#pragma unroll
    for (int n = 0; n < 4; ++n) {
      int rbase = bm + wr * 64 + m * 16 + ((l >> 4) << 2);
      int cbase = bn + wc * 64 + n * 16 + lr;
#pragma unroll
      for (int j = 0; j < 4; ++j) {
        float v = acc[m][n][j];
        size_t r2 = (size_t)(rbase + j);
        if (cbase < 2048)
          qb[r2 * 2048 + cbase] = v;
        else if (cbase < 4096)
          q2bf[r2 * 2048 + (cbase - 2048)] = f2bf(v);
        else if (cbase < 4608)
          kb[r2 * 512 + (cbase - 4096)] = v;
        else
          vb[r2 * 512 + (cbase - 4608)] = v;
      }
    }
}

// ---------------------------------------------------------------------------
// RoPE: read f32 x [rows][nheads*64], write bf16 y (same layout).
// ---------------------------------------------------------------------------
__global__ void rope_bf16_kernel(const float* __restrict__ x,
                                 const float* __restrict__ c,
                                 const float* __restrict__ s,
                                 unsigned short* __restrict__ y,
                                 int rows, int nheads) {
  int tid = blockIdx.x * blockDim.x + threadIdx.x;
  int total = rows * nheads * 32;
  if (tid >= total) return;
  int d = tid & 31;
  int h = (tid >> 5) % nheads;
  int row = tid / (32 * nheads);
  const float* xr = x + ((size_t)row * nheads + h) * 64;
  unsigned short* yr = y + ((size_t)row * nheads + h) * 64;
  float c1 = c[(size_t)row * 64 + d], c2 = c[(size_t)row * 64 + d + 32];
  float s1 = s[(size_t)row * 64 + d], s2 = s[(size_t)row * 64 + d + 32];
  float x1 = xr[d], x2 = xr[d + 32];
  yr[d]      = f2bf(x1 * c1 - x2 * s1);
  yr[d + 32] = f2bf(x2 * c2 + x1 * s2);
}

// ---------------------------------------------------------------------------
// V transpose: vT[((b*NKV+g)*64+d)*S + s] = bf16(vbuf[((b*S+s)*NKV+g)*64+d])
// ---------------------------------------------------------------------------
__global__ __launch_bounds__(256) void vT_kernel(
    const float* __restrict__ vbuf, unsigned short* __restrict__ vT,
    int B, int S) {
  const int nst = S >> 6;
  int stile = blockIdx.x % nst;
  int g = (blockIdx.x / nst) % NKV;
  int b = blockIdx.x / (nst * NKV);
  int s0 = stile * 64;
  __shared__ float lt[64][68];
  int t = threadIdx.x;
#pragma unroll
  for (int it = 0; it < 4; ++it) {
    int slot = it * 256 + t;
    int sl = slot >> 4, d4 = (slot & 15) * 4;
    float4 v = *(const float4*)&vbuf[((size_t)(b * S + s0 + sl) * NKV + g) * 64 + d4];
    lt[sl][d4] = v.x; lt[sl][d4 + 1] = v.y; lt[sl][d4 + 2] = v.z; lt[sl][d4 + 3] = v.w;
  }
  __syncthreads();
#pragma unroll
  for (int it = 0; it < 2; ++it) {
    int slot = it * 256 + t;
    int d = slot >> 3, s8 = (slot & 7) * 8;
    u16x8 o;
#pragma unroll
    for (int j = 0; j < 8; ++j) o[j] = f2bf(lt[s8 + j][d]);
    *(u16x8*)&vT[(((size_t)b * NKV + g) * 64 + d) * S + s0 + s8] = o;
  }
}

// ---------------------------------------------------------------------------
// KB key slice: kbkh[j][c] = bf16(kb_keys[j*KBROW + c]), j<128, c<2048.
// ---------------------------------------------------------------------------
__global__ void kbkh_kernel(const float* __restrict__ kbk,
                            unsigned short* __restrict__ out) {
  int i = blockIdx.x * blockDim.x + threadIdx.x;
  if (i >= 128 * 512) return;
  int j = i >> 9, c4 = (i & 511) * 4;
  float4 v = *(const float4*)&kbk[(size_t)j * KBROW + c4];
  ushort4 o = {f2bf(v.x), f2bf(v.y), f2bf(v.z), f2bf(v.w)};
  *(ushort4*)&out[(size_t)j * 2048 + c4] = o;
}

// ---------------------------------------------------------------------------
// Gathered + transposed KB values -> [B][NH][64][128] bf16.
// ---------------------------------------------------------------------------
__global__ __launch_bounds__(256) void kbvgt_kernel(
    const float* __restrict__ kbv, const int* __restrict__ topi,
    unsigned short* __restrict__ kbvgT, int B) {
  int h = blockIdx.x % NH, b = blockIdx.x / NH;
  __shared__ unsigned short gt[128][72];
  __shared__ int lidx[TOPK];
  int t = threadIdx.x;
  if (t < TOPK) lidx[t] = topi[b * TOPK + t];
  __syncthreads();
#pragma unroll
  for (int it = 0; it < 8; ++it) {
    int slot = it * 256 + t;
    int j = slot >> 4, d4 = (slot & 15) * 4;
    float4 v = *(const float4*)&kbv[(size_t)lidx[j] * KBROW + h * 64 + d4];
    gt[j][d4] = f2bf(v.x); gt[j][d4 + 1] = f2bf(v.y);
    gt[j][d4 + 2] = f2bf(v.z); gt[j][d4 + 3] = f2bf(v.w);
  }
  __syncthreads();
#pragma unroll
  for (int it = 0; it < 4; ++it) {
    int slot = it * 256 + t;
    int d = slot >> 4, j8 = (slot & 15) * 8;
    u16x8 o;
#pragma unroll
    for (int j = 0; j < 8; ++j) o[j] = gt[j8 + j][d];
    *(u16x8*)&kbvgT[(((size_t)b * NH + h) * 64 + d) * 128 + j8] = o;
  }
}

// ---------------------------------------------------------------------------
// Column-sum stage 1: part[b][ch][c] = sum over 32-row chunk (f64).
// ---------------------------------------------------------------------------
__global__ __launch_bounds__(256) void hsum1_kernel(
    const float* __restrict__ hidden, double* __restrict__ part,
    int B, int S, int H) {
  const int nhb = H >> 8;
  int hb = blockIdx.x % nhb;
  int ch = (blockIdx.x / nhb) % HCH;
  int b  = blockIdx.x / (nhb * HCH);
  int c  = hb * 256 + threadIdx.x;
  int rows = S / HCH;
  const float* p = hidden + ((size_t)b * S + (size_t)ch * rows) * H + c;
  double acc = 0.0;
  for (int s = 0; s < rows; ++s) acc += (double)p[(size_t)s * H];
  part[((size_t)b * HCH + ch) * H + c] = acc;
}

// ---------------------------------------------------------------------------
// Column-sum stage 2: Hsum[b][c] = sum_ch part[b][ch][c] (f64, fixed order).
// ---------------------------------------------------------------------------
__global__ void hsum2_kernel(const double* __restrict__ part,
                             float* __restrict__ Hsum, int B, int H) {
  int idx = blockIdx.x * blockDim.x + threadIdx.x;
  if (idx >= B * H) return;
  int b = idx / H, c = idx % H;
  const double* p = part + (size_t)b * HCH * H + c;
  double acc = 0.0;
#pragma unroll
  for (int ch = 0; ch < HCH; ++ch) acc += p[(size_t)ch * H];
  Hsum[idx] = (float)acc;
}

// ---------------------------------------------------------------------------
// Qs[b][c] = sum_k Hsum[b][k] * Wq2[c][k]  (fp32 inputs, f64 accum).
// ---------------------------------------------------------------------------
__global__ void qs_kernel(const float* __restrict__ Hsum,
                          const float* __restrict__ Wq2,
                          float* __restrict__ Qs, int B, int H) {
  int task = (blockIdx.x * blockDim.x + threadIdx.x) >> 6;
  int lane = threadIdx.x & 63;
  if (task >= B * NH * HD) return;
  int b = task / (NH * HD), c = task % (NH * HD);
  const float* hs = Hsum + (size_t)b * H;
  const float* wr = Wq2 + (size_t)c * H;
  double acc = 0.0;
  for (int k = lane; k < H; k += 64) acc += (double)hs[k] * (double)wr[k];
#pragma unroll
  for (int off = 32; off; off >>= 1) acc += __shfl_xor(acc, off);
  if (lane == 0) Qs[task] = (float)acc;
}

// ---------------------------------------------------------------------------
// scores[b][l] = 0.125 * dot(Qs[b,:], kb_keys[l, 0:2048]) (f64 acc)
// ---------------------------------------------------------------------------
__global__ void scores_kernel(const float* __restrict__ Qs,
                              const float* __restrict__ kbk,
                              float* __restrict__ scores, int B, int KBL) {
  int task = (blockIdx.x * blockDim.x + threadIdx.x) >> 6;
  int lane = threadIdx.x & 63;
  if (task >= B * KBL) return;
  int b = task / KBL, l = task % KBL;
  const float* kr = kbk + (size_t)l * KBROW;
  const float* qd = Qs + (size_t)b * NH * HD;
  double acc = 0.0;
  for (int c = lane; c < NH * HD; c += 64) acc += (double)qd[c] * (double)kr[c];
#pragma unroll
  for (int off = 32; off; off >>= 1) acc += __shfl_xor(acc, off);
  if (lane == 0) scores[task] = (float)(0.125 * acc);
}

// ---------------------------------------------------------------------------
// Top-K by rank-counting (stable descending == lax.top_k).
// ---------------------------------------------------------------------------
__global__ __launch_bounds__(256) void topk_kernel(
    const float* __restrict__ scores, int* __restrict__ top_idx, int KBL) {
  __shared__ float ls[512];
  int b = blockIdx.x, t = threadIdx.x;
  for (int i = t; i < KBL; i += 256) ls[i] = scores[(size_t)b * KBL + i];
  __syncthreads();
  for (int l = t; l < KBL; l += 256) {
    float sl = ls[l];
    int rank = 0;
    for (int j = 0; j < KBL; ++j) {
      float sj = ls[j];
      rank += (sj > sl || (sj == sl && j < l)) ? 1 : 0;
    }
    if (rank < TOPK) top_idx[b * TOPK + rank] = l;
  }
}

// ---------------------------------------------------------------------------
// padflag[b*S+s] = all(mask[b,0,s,:] < 0)
// ---------------------------------------------------------------------------
__global__ void padflag_kernel(const float* __restrict__ mask,
                               int* __restrict__ flags, int BS, int S) {
  int w = (blockIdx.x * blockDim.x + threadIdx.x) >> 6;
  int lane = threadIdx.x & 63;
  if (w >= BS) return;
  const float* row = mask + (size_t)w * S;
  bool ok = true;
  for (int j = lane; j < S; j += 64) ok = ok && (row[j] < 0.f);
  int allv = __all(ok ? 1 : 0);
  if (lane == 0) flags[w] = allv;
}

// ---------------------------------------------------------------------------
// MFMA fused attention v2 (+ T5 setprio around MFMA clusters).
// ---------------------------------------------------------------------------
__global__ __launch_bounds__(256) void attn_mfma(
    const unsigned short* __restrict__ qbf,    // [B*S][2048] roped bf16
    const unsigned short* __restrict__ q2bf,   // [B*S][2048] bf16
    const unsigned short* __restrict__ kbf,    // [B*S][512] roped bf16
    const unsigned short* __restrict__ vTb,    // [B][NKV][64][S] bf16
    const unsigned short* __restrict__ kbkh,   // [128][2048] bf16
    const unsigned short* __restrict__ kbvgT,  // [B][NH][64][128] bf16
    const int* __restrict__ padflag,           // [B*S]
    unsigned short* __restrict__ attnbf,       // [B*S][2048] bf16
    int B, int S) {
  const int nst = S >> 6;
  const int st = blockIdx.x % nst;
  const int h  = (blockIdx.x / nst) % NH;
  const int b  = blockIdx.x / (nst * NH);
  const int s0 = st * 64;
  const int g  = h / (NH / NKV);

  __shared__ unsigned short smem[8192];   // q|q2 tiles, then K|V^T tiles
  __shared__ unsigned short pt[4][1024];  // per-wave P [row16][key64]
  __shared__ int padf[64];

  const int t = threadIdx.x;
  const int w = t >> 6;
  const int li = t & 15;
  const int lg4 = (t & 63) >> 4;

#pragma unroll
  for (int it = 0; it < 4; ++it) {
    int slot = it * 256 + t;
    int tile = slot >> 9, row = (slot >> 3) & 63, ck = slot & 7;
    const unsigned short* src = tile ? q2bf : qbf;
    bf16x8 v = *(const bf16x8*)(src + (size_t)(b * S + s0 + row) * (NH * HD) +
                                h * 64 + ck * 8);
    *(bf16x8*)((char*)smem + tile * 8192 + swz(row, ck)) = v;
  }
  if (t < 64) padf[t] = padflag[b * S + s0 + t];
  __syncthreads();

  bf16x8 aq0[2], aq2[2];
#pragma unroll
  for (int kc = 0; kc < 2; ++kc) {
    aq0[kc] = *(const bf16x8*)((char*)smem + swz(w * 16 + li, kc * 4 + lg4));
    aq2[kc] = *(const bf16x8*)((char*)smem + 8192 + swz(w * 16 + li, kc * 4 + lg4));
  }

  float m_[4] = {-3.4e38f, -3.4e38f, -3.4e38f, -3.4e38f};
  float l_[4] = {};
  f32x4 acc[4] = {};

  const int nch = 2 + st + 1;
  for (int ch = 0; ch < nch; ++ch) {
    const bool iskb = ch < 2;
    const int j0 = iskb ? ch * 64 : (ch - 2) * 64;
    __syncthreads();
#pragma unroll
    for (int it = 0; it < 4; ++it) {
      int slot = it * 256 + t;
      int tile = slot >> 9, row = (slot >> 3) & 63, ck = slot & 7;
      const unsigned short* src;
      if (tile == 0) {
        src = iskb ? kbkh + (size_t)(j0 + row) * 2048 + h * 64 + ck * 8
                   : kbf + (size_t)(b * S + j0 + row) * 512 + g * 64 + ck * 8;
      } else {
        src = iskb ? kbvgT + (((size_t)b * NH + h) * 64 + row) * 128 + j0 + ck * 8
                   : vTb + (((size_t)b * NKV + g) * 64 + row) * (size_t)S + j0 + ck * 8;
      }
      bf16x8 v = *(const bf16x8*)src;
      *(bf16x8*)((char*)smem + tile * 8192 + swz(row, ck)) = v;
    }
    __syncthreads();

    // ---- QK^T
    const bf16x8* aq = iskb ? aq2 : aq0;
    f32x4 cc[4];
    __builtin_amdgcn_s_setprio(1);
#pragma unroll
    for (int cb = 0; cb < 4; ++cb) {
      bf16x8 b0 = *(const bf16x8*)((char*)smem + swz(cb * 16 + li, lg4));
      bf16x8 b1 = *(const bf16x8*)((char*)smem + swz(cb * 16 + li, 4 + lg4));
      f32x4 z = {};
      z = __builtin_amdgcn_mfma_f32_16x16x32_bf16(aq[0], b0, z, 0, 0, 0);
      z = __builtin_amdgcn_mfma_f32_16x16x32_bf16(aq[1], b1, z, 0, 0, 0);
      cc[cb] = z;
    }
    __builtin_amdgcn_s_setprio(0);

    // ---- logits + online softmax
    float lgv[4][4];
#pragma unroll
    for (int cb = 0; cb < 4; ++cb) {
#pragma unroll
      for (int j = 0; j < 4; ++j) {
        float v = SCALE * cc[cb][j];
        if (iskb) {
          v += C0F + (padf[w * 16 + lg4 * 4 + j] ? PADF : 0.f);
        } else {
          int key = j0 + cb * 16 + li;
          int srow = s0 + w * 16 + lg4 * 4 + j;
          v += (key <= srow) ? 0.f : PADF;
        }
        lgv[cb][j] = v;
      }
    }
#pragma unroll
    for (int j = 0; j < 4; ++j) {
      float rmax = fmaxf(fmaxf(lgv[0][j], lgv[1][j]), fmaxf(lgv[2][j], lgv[3][j]));
#pragma unroll
      for (int off = 8; off; off >>= 1) rmax = fmaxf(rmax, __shfl_xor(rmax, off));
      float mn = fmaxf(m_[j], rmax);
      float fs = __expf(m_[j] - mn);
      float csum = 0.f;
#pragma unroll
      for (int cb = 0; cb < 4; ++cb) {
        float p = __expf(lgv[cb][j] - mn);
        csum += p;
        int key = cb * 16 + li;
        int rloc = lg4 * 4 + j;
        *(unsigned short*)((char*)pt[w] + swz(rloc, key >> 3) +
                           ((key & 7) << 1)) = f2bf(p);
      }
#pragma unroll
      for (int off = 8; off; off >>= 1) csum += __shfl_xor(csum, off);
      m_[j] = mn;
      l_[j] = l_[j] * fs + csum;
#pragma unroll
      for (int db = 0; db < 4; ++db) acc[db][j] *= fs;
    }

    // ---- PV (V^T tile at byte 8192)
    bf16x8 pa0 = *(const bf16x8*)((const char*)pt[w] + swz(li, lg4));
    bf16x8 pa1 = *(const bf16x8*)((const char*)pt[w] + swz(li, 4 + lg4));
    __builtin_amdgcn_s_setprio(1);
#pragma unroll
    for (int db = 0; db < 4; ++db) {
      bf16x8 bv0 = *(const bf16x8*)((char*)smem + 8192 + swz(db * 16 + li, lg4));
      bf16x8 bv1 = *(const bf16x8*)((char*)smem + 8192 + swz(db * 16 + li, 4 + lg4));
      acc[db] = __builtin_amdgcn_mfma_f32_16x16x32_bf16(pa0, bv0, acc[db], 0, 0, 0);
      acc[db] = __builtin_amdgcn_mfma_f32_16x16x32_bf16(pa1, bv1, acc[db], 0, 0, 0);
    }
    __builtin_amdgcn_s_setprio(0);
  }

#pragma unroll
  for (int j = 0; j < 4; ++j) {
    float inv = 1.f / l_[j];
    size_t o = (size_t)(b * S + s0 + w * 16 + lg4 * 4 + j) * (NH * HD) + h * 64 + li;
#pragma unroll
    for (int db = 0; db < 4; ++db) attnbf[o + db * 16] = f2bf(acc[db][j] * inv);
  }
}

// ---------------------------------------------------------------------------
extern "C" void kernel_launch(void* const* d_in, const int* in_sizes, int n_in,
                              void* d_out, int out_size, void* d_ws, size_t ws_size,
                              hipStream_t stream) {
  const float* hidden = (const float*)d_in[0];
  const float* cosb   = (const float*)d_in[1];
  const float* sinb   = (const float*)d_in[2];
  const float* mask   = (const float*)d_in[3];
  const float* kbk    = (const float*)d_in[4];
  const float* kbv    = (const float*)d_in[5];
  const float* Wq     = (const float*)d_in[6];
  const float* Wq2    = (const float*)d_in[7];
  const float* Wk     = (const float*)d_in[8];
  const float* Wv     = (const float*)d_in[9];
  const float* Wo     = (const float*)d_in[10];
  float* out = (float*)d_out;

  const int H   = in_sizes[6] / (NH * HD);             // 2048
  const int KBL = in_sizes[4] / KBROW;                 // 400
  const long long BSll = (long long)in_sizes[0] / H;
  const int S = (int)((long long)in_sizes[3] / BSll);  // 1024
  const int B = (int)(BSll / S);                       // 2
  const int BS = B * S;
  const int NQ = NH * HD;                              // 2048
  const int NKVD = NKV * HD;                           // 512
  const int NTOT = NQ + NQ + NKVD + NKVD;              // 5120

  float* ws = (float*)d_ws;
  size_t off = 0;
  double* hpart = (double*)(ws + off); off += (size_t)B * HCH * H * 2;
  float* qb   = ws + off; off += (size_t)BS * NQ;        // f32 q (pre-rope)
  float* kb   = ws + off; off += (size_t)BS * NKVD;      // f32 k (pre-rope)
  float* vb   = ws + off; off += (size_t)BS * NKVD;      // f32 v
  float* Hsum = ws + off; off += (size_t)B * H;
  float* Qs   = ws + off; off += (size_t)B * NQ;
  float* sc   = ws + off; off += (size_t)B * KBL;
  int* topi   = (int*)(ws + off); off += (size_t)B * TOPK;
  int* padfl  = (int*)(ws + off); off += (size_t)BS;
  unsigned short* hbf    = (unsigned short*)(ws + off); off += (size_t)BS * H / 2;
  // wall: [Wq | Wq2 | Wk | Wv] rows, contiguous [5120][H]
  unsigned short* wall   = (unsigned short*)(ws + off); off += (size_t)NTOT * H / 2;
  unsigned short* wobf   = (unsigned short*)(ws + off); off += (size_t)H * NQ / 2;
  unsigned short* attnbf = (unsigned short*)(ws + off); off += (size_t)BS * NQ / 2;
  unsigned short* qbf    = (unsigned short*)(ws + off); off += (size_t)BS * NQ / 2;
  unsigned short* q2bf   = (unsigned short*)(ws + off); off += (size_t)BS * NQ / 2;
  unsigned short* kbf    = (unsigned short*)(ws + off); off += (size_t)BS * NKVD / 2;
  unsigned short* vTb    = (unsigned short*)(ws + off); off += (size_t)BS * NKVD / 2;
  unsigned short* kbkh   = (unsigned short*)(ws + off); off += (size_t)128 * NQ / 2;
  unsigned short* kbvgT  = (unsigned short*)(ws + off); off += (size_t)B * NH * HD * TOPK / 2;
  (void)ws_size; (void)n_in; (void)out_size;

  // 0: fp32 -> bf16 conversions
  {
    int n = BS * H / 4;
    f2bf_kernel<<<(n + 255) / 256, 256, 0, stream>>>(hidden, hbf, n);
    int n0 = NQ * H / 4, n1 = NQ * H / 4, n2 = NKVD * H / 4, n3 = NKVD * H / 4;
    int ntot = n0 + n1 + n2 + n3;
    f2bf4_kernel<<<(ntot + 255) / 256, 256, 0, stream>>>(
        Wq, Wq2, Wk, Wv, n0, n1, n2, n3, wall);
    n = H * NQ / 4;
    f2bf_kernel<<<(n + 255) / 256, 256, 0, stream>>>(Wo, wobf, n);
  }

  // 1: fused projections (q->f32, q2->bf16, k->f32, v->f32)
  gemm_proj<<<dim3(NTOT / 128, BS / 128), 256, 0, stream>>>(
      hbf, wall, qb, q2bf, kb, vb, BS, H);

  // 2-4: RoPE -> bf16; V transpose -> bf16
  {
    int tq = BS * NH * 32;
    rope_bf16_kernel<<<(tq + 255) / 256, 256, 0, stream>>>(qb, cosb, sinb, qbf, BS, NH);
    int tk = BS * NKV * 32;
    rope_bf16_kernel<<<(tk + 255) / 256, 256, 0, stream>>>(kb, cosb, sinb, kbf, BS, NKV);
    vT_kernel<<<B * NKV * (S / 64), 256, 0, stream>>>(vb, vTb, B, S);
  }

  // 5-9: exact fp32 scores path + top-k + padding
  hsum1_kernel<<<B * HCH * (H / 256), 256, 0, stream>>>(hidden, hpart, B, S, H);
  hsum2_kernel<<<(B * H + 255) / 256, 256, 0, stream>>>(hpart, Hsum, B, H);
  qs_kernel<<<(B * NQ * 64 + 255) / 256, 256, 0, stream>>>(Hsum, Wq2, Qs, B, H);
  scores_kernel<<<(B * KBL * 64 + 255) / 256, 256, 0, stream>>>(Qs, kbk, sc, B, KBL);
  topk_kernel<<<B, 256, 0, stream>>>(sc, topi, KBL);
  padflag_kernel<<<(BS * 64 + 255) / 256, 256, 0, stream>>>(mask, padfl, BS, S);

  // 10-11: KB bf16 staging
  kbkh_kernel<<<(128 * 512 + 255) / 256, 256, 0, stream>>>(kbk, kbkh);
  kbvgt_kernel<<<B * NH, 256, 0, stream>>>(kbv, topi, kbvgT, B);

  // 12: fused attention (bf16 MFMA) -> bf16
  attn_mfma<<<B * NH * (S / 64), 256, 0, stream>>>(
      qbf, q2bf, kbf, vTb, kbkh, kbvgT, padfl, attnbf, B, S);

  // 13: output projection
  gemm_nt_bf16<<<dim3(H / 128, BS / 128), 256, 0, stream>>>(attnbf, wobf, out, BS, H, NQ);
}

// Round 10
// 282.264 us; speedup vs baseline: 10.5912x; 1.1010x over previous
//
#include <hip/hip_runtime.h>
#include <hip/hip_bf16.h>
#include <math.h>

#define NH 32
#define NKV 8
#define HD 64
#define NSLOTS 11
#define TOPK 128
#define KBROW (NSLOTS * NH * HD)   // 22528
#define PADF (-3.3895313892515355e+38f)
#define C0F  (-0.24686007793152578f)   // -ln(128)+ln(100)
#define SCALE 0.125f
#define HCH 32                         // S-chunks for hierarchical column sum

typedef __attribute__((ext_vector_type(8))) __bf16 bf16x8;
typedef __attribute__((ext_vector_type(8))) unsigned short u16x8;
typedef __attribute__((ext_vector_type(4))) float f32x4;

#define GLDS16(gp, lp)                                                        \
  __builtin_amdgcn_global_load_lds(                                           \
      (__attribute__((address_space(1))) void*)(gp),                          \
      (__attribute__((address_space(3))) void*)(lp), 16, 0, 0)

__device__ __forceinline__ unsigned short f2bf(float f) {
  unsigned int u = __float_as_uint(f);
  u = (u + 0x7fffu + ((u >> 16) & 1u)) >> 16;
  return (unsigned short)u;
}

// byte offset into a 64-col bf16 tile (128 B/row) with XOR chunk swizzle
__device__ __forceinline__ int swz(int row, int chunk) {
  return row * 128 + ((chunk ^ (row & 7)) << 4);
}

// ---------------------------------------------------------------------------
// fp32 -> bf16 (RTNE), 4 elems/thread.
// ---------------------------------------------------------------------------
__global__ void f2bf_kernel(const float* __restrict__ in,
                            unsigned short* __restrict__ out, int n4) {
  int i = blockIdx.x * blockDim.x + threadIdx.x;
  if (i >= n4) return;
  float4 v = ((const float4*)in)[i];
  ushort4 o;
  o.x = f2bf(v.x); o.y = f2bf(v.y); o.z = f2bf(v.z); o.w = f2bf(v.w);
  ((ushort4*)out)[i] = o;
}

// ---------------------------------------------------------------------------
// fp32 -> bf16 for 4 concatenated sources into one dest (n in float4 units).
// ---------------------------------------------------------------------------
__global__ void f2bf4_kernel(const float* __restrict__ s0,
                             const float* __restrict__ s1,
                             const float* __restrict__ s2,
                             const float* __restrict__ s3,
                             int n0, int n1, int n2, int n3,
                             unsigned short* __restrict__ out) {
  int i = blockIdx.x * blockDim.x + threadIdx.x;
  int j = i;
  const float* src;
  if (j < n0) src = s0;
  else {
    j -= n0;
    if (j < n1) src = s1;
    else {
      j -= n1;
      if (j < n2) src = s2;
      else {
        j -= n2;
        if (j >= n3) return;
        src = s3;
      }
    }
  }
  float4 v = ((const float4*)src)[j];
  ushort4 o = {f2bf(v.x), f2bf(v.y), f2bf(v.z), f2bf(v.w)};
  ((ushort4*)out)[i] = o;
}

// ---------------------------------------------------------------------------
// bf16 MFMA GEMM (m97 structure): C[M,N] = A[M,K] @ B[N,K]^T, f32 out.
// ---------------------------------------------------------------------------
__global__ __launch_bounds__(256) void gemm_nt_bf16(
    const unsigned short* __restrict__ A, const unsigned short* __restrict__ B,
    float* __restrict__ C, int M, int N, int K) {
  __shared__ unsigned short ldsA[128 * 32];
  __shared__ unsigned short ldsB[128 * 32];
  const int t = threadIdx.x;
  const int l = t & 63, w = t >> 6;
  const int wr = w >> 1, wc = w & 1;
  const int lr = l & 15;
  const int kb = (l >> 4) * 16;
  const int bm = blockIdx.y * 128, bn = blockIdx.x * 128;

  f32x4 acc[4][4] = {};

  for (int k0 = 0; k0 < K; k0 += 32) {
    __syncthreads();
#pragma unroll
    for (int it = 0; it < 2; ++it) {
      int s = it * 256 + t;
      int row = s >> 2, cs = (s & 3) * 8;
      GLDS16(A + (size_t)(bm + row) * K + k0 + cs,
             (char*)ldsA + (it * 4 + w) * 1024);
      GLDS16(B + (size_t)(bn + row) * K + k0 + cs,
             (char*)ldsB + (it * 4 + w) * 1024);
    }
    __syncthreads();

    bf16x8 a[4], b[4];
#pragma unroll
    for (int m = 0; m < 4; ++m)
      a[m] = *(const bf16x8*)((const char*)ldsA +
                              (wr * 64 + m * 16 + lr) * 64 + kb);
#pragma unroll
    for (int n = 0; n < 4; ++n)
      b[n] = *(const bf16x8*)((const char*)ldsB +
                              (wc * 64 + n * 16 + lr) * 64 + kb);
#pragma unroll
    for (int m = 0; m < 4; ++m)
#pragma unroll
      for (int n = 0; n < 4; ++n)
        acc[m][n] =
            __builtin_amdgcn_mfma_f32_16x16x32_bf16(a[m], b[n], acc[m][n], 0, 0, 0);
  }

#pragma unroll
  for (int m = 0; m < 4; ++m)
#pragma unroll
    for (int n = 0; n < 4; ++n) {
      int rbase = bm + wr * 64 + m * 16 + ((l >> 4) << 2);
      int cbase = bn + wc * 64 + n * 16 + lr;
#pragma unroll
      for (int j = 0; j < 4; ++j)
        C[(size_t)(rbase + j) * N + cbase] = acc[m][n][j];
    }
}

// ---------------------------------------------------------------------------
// Fused projection GEMM + RoPE epilogue.
// cols [0,2048)    -> rope -> qbf bf16
// cols [2048,4096) -> q2bf bf16
// cols [4096,4608) -> rope -> kbf bf16
// cols [4608,5120) -> vb f32
// RoPE pairs (d, d+32) live in fragments n and n+2 of the same lane.
// ---------------------------------------------------------------------------
__global__ __launch_bounds__(256) void gemm_proj(
    const unsigned short* __restrict__ A, const unsigned short* __restrict__ Wall,
    const float* __restrict__ cosb, const float* __restrict__ sinb,
    unsigned short* __restrict__ qbf, unsigned short* __restrict__ q2bf,
    unsigned short* __restrict__ kbf, float* __restrict__ vb, int M, int K) {
  __shared__ unsigned short ldsA[128 * 32];
  __shared__ unsigned short ldsB[128 * 32];
  const int t = threadIdx.x;
  const int l = t & 63, w = t >> 6;
  const int wr = w >> 1, wc = w & 1;
  const int lr = l & 15;
  const int kb_ = (l >> 4) * 16;
  const int bm = blockIdx.y * 128, bn = blockIdx.x * 128;

  f32x4 acc[4][4] = {};

  for (int k0 = 0; k0 < K; k0 += 32) {
    __syncthreads();
#pragma unroll
    for (int it = 0; it < 2; ++it) {
      int s = it * 256 + t;
      int row = s >> 2, cs = (s & 3) * 8;
      GLDS16(A + (size_t)(bm + row) * K + k0 + cs,
             (char*)ldsA + (it * 4 + w) * 1024);
      GLDS16(Wall + (size_t)(bn + row) * K + k0 + cs,
             (char*)ldsB + (it * 4 + w) * 1024);
    }
    __syncthreads();

    bf16x8 a[4], b[4];
#pragma unroll
    for (int m = 0; m < 4; ++m)
      a[m] = *(const bf16x8*)((const char*)ldsA +
                              (wr * 64 + m * 16 + lr) * 64 + kb_);
#pragma unroll
    for (int n = 0; n < 4; ++n)
      b[n] = *(const bf16x8*)((const char*)ldsB +
                              (wc * 64 + n * 16 + lr) * 64 + kb_);
#pragma unroll
    for (int m = 0; m < 4; ++m)
#pragma unroll
      for (int n = 0; n < 4; ++n)
        acc[m][n] =
            __builtin_amdgcn_mfma_f32_16x16x32_bf16(a[m], b[n], acc[m][n], 0, 0, 0);
  }

#pragma unroll
  for (int m = 0; m < 4; ++m) {
    int rbase = bm + wr * 64 + m * 16 + ((l >> 4) << 2);
    if (bn < 2048 || (bn >= 4096 && bn < 4608)) {
      const bool isq = bn < 2048;
#pragma unroll
      for (int j = 0; j < 4; ++j) {
        int row = rbase + j;
        const float* cr = cosb + (size_t)row * 64;
        const float* sr = sinb + (size_t)row * 64;
        float c0 = cr[lr], c1 = cr[16 + lr], c2 = cr[32 + lr], c3 = cr[48 + lr];
        float sa = sr[lr], sb = sr[16 + lr], sc_ = sr[32 + lr], sd = sr[48 + lr];
        float x0 = acc[m][0][j], x1 = acc[m][1][j];
        float x2 = acc[m][2][j], x3 = acc[m][3][j];
        float y0 = x0 * c0 - x2 * sa;
        float y1 = x1 * c1 - x3 * sb;
        float y2 = x2 * c2 + x0 * sc_;
        float y3 = x3 * c3 + x1 * sd;
        if (isq) {
          size_t ro = (size_t)row * 2048 + bn + wc * 64 + lr;
          qbf[ro] = f2bf(y0); qbf[ro + 16] = f2bf(y1);
          qbf[ro + 32] = f2bf(y2); qbf[ro + 48] = f2bf(y3);
        } else {
          size_t ro = (size_t)row * 512 + (bn - 4096) + wc * 64 + lr;
          kbf[ro] = f2bf(y0); kbf[ro + 16] = f2bf(y1);
          kbf[ro + 32] = f2bf(y2); kbf[ro + 48] = f2bf(y3);
        }
      }
    } else if (bn < 4096) {  // q2 -> bf16
#pragma unroll
      for (int n = 0; n < 4; ++n) {
        int cbase = bn + wc * 64 + n * 16 + lr;
#pragma unroll
        for (int j = 0; j < 4; ++j)
          q2bf[(size_t)(rbase + j) * 2048 + (cbase - 2048)] = f2bf(acc[m][n][j]);
      }
    } else {  // v -> f32
#pragma unroll
      for (int n = 0; n < 4; ++n) {
        int cbase = bn + wc * 64 + n * 16 + lr;
#pragma unroll
        for (int j = 0; j < 4; ++j)
          vb[(size_t)(rbase + j) * 512 + (cbase - 4608)] = acc[m][n][j];
      }
    }
  }
}

// ---------------------------------------------------------------------------
// V transpose: vT[((b*NKV+g)*64+d)*S + s] = bf16(vbuf[((b*S+s)*NKV+g)*64+d])
// ---------------------------------------------------------------------------
__global__ __launch_bounds__(256) void vT_kernel(
    const float* __restrict__ vbuf, unsigned short* __restrict__ vT,
    int B, int S) {
  const int nst = S >> 6;
  int stile = blockIdx.x % nst;
  int g = (blockIdx.x / nst) % NKV;
  int b = blockIdx.x / (nst * NKV);
  int s0 = stile * 64;
  __shared__ float lt[64][68];
  int t = threadIdx.x;
#pragma unroll
  for (int it = 0; it < 4; ++it) {
    int slot = it * 256 + t;
    int sl = slot >> 4, d4 = (slot & 15) * 4;
    float4 v = *(const float4*)&vbuf[((size_t)(b * S + s0 + sl) * NKV + g) * 64 + d4];
    lt[sl][d4] = v.x; lt[sl][d4 + 1] = v.y; lt[sl][d4 + 2] = v.z; lt[sl][d4 + 3] = v.w;
  }
  __syncthreads();
#pragma unroll
  for (int it = 0; it < 2; ++it) {
    int slot = it * 256 + t;
    int d = slot >> 3, s8 = (slot & 7) * 8;
    u16x8 o;
#pragma unroll
    for (int j = 0; j < 8; ++j) o[j] = f2bf(lt[s8 + j][d]);
    *(u16x8*)&vT[(((size_t)b * NKV + g) * 64 + d) * S + s0 + s8] = o;
  }
}

// ---------------------------------------------------------------------------
// KB key slice: kbkh[j][c] = bf16(kb_keys[j*KBROW + c]), j<128, c<2048.
// ---------------------------------------------------------------------------
__global__ void kbkh_kernel(const float* __restrict__ kbk,
                            unsigned short* __restrict__ out) {
  int i = blockIdx.x * blockDim.x + threadIdx.x;
  if (i >= 128 * 512) return;
  int j = i >> 9, c4 = (i & 511) * 4;
  float4 v = *(const float4*)&kbk[(size_t)j * KBROW + c4];
  ushort4 o = {f2bf(v.x), f2bf(v.y), f2bf(v.z), f2bf(v.w)};
  *(ushort4*)&out[(size_t)j * 2048 + c4] = o;
}

// ---------------------------------------------------------------------------
// Gathered + transposed KB values -> [B][NH][64][128] bf16.
// ---------------------------------------------------------------------------
__global__ __launch_bounds__(256) void kbvgt_kernel(
    const float* __restrict__ kbv, const int* __restrict__ topi,
    unsigned short* __restrict__ kbvgT, int B) {
  int h = blockIdx.x % NH, b = blockIdx.x / NH;
  __shared__ unsigned short gt[128][72];
  __shared__ int lidx[TOPK];
  int t = threadIdx.x;
  if (t < TOPK) lidx[t] = topi[b * TOPK + t];
  __syncthreads();
#pragma unroll
  for (int it = 0; it < 8; ++it) {
    int slot = it * 256 + t;
    int j = slot >> 4, d4 = (slot & 15) * 4;
    float4 v = *(const float4*)&kbv[(size_t)lidx[j] * KBROW + h * 64 + d4];
    gt[j][d4] = f2bf(v.x); gt[j][d4 + 1] = f2bf(v.y);
    gt[j][d4 + 2] = f2bf(v.z); gt[j][d4 + 3] = f2bf(v.w);
  }
  __syncthreads();
#pragma unroll
  for (int it = 0; it < 4; ++it) {
    int slot = it * 256 + t;
    int d = slot >> 4, j8 = (slot & 15) * 8;
    u16x8 o;
#pragma unroll
    for (int j = 0; j < 8; ++j) o[j] = gt[j8 + j][d];
    *(u16x8*)&kbvgT[(((size_t)b * NH + h) * 64 + d) * 128 + j8] = o;
  }
}

// ---------------------------------------------------------------------------
// Column-sum stage 1: part[b][ch][c] = sum over 32-row chunk (f64).
// ---------------------------------------------------------------------------
__global__ __launch_bounds__(256) void hsum1_kernel(
    const float* __restrict__ hidden, double* __restrict__ part,
    int B, int S, int H) {
  const int nhb = H >> 8;
  int hb = blockIdx.x % nhb;
  int ch = (blockIdx.x / nhb) % HCH;
  int b  = blockIdx.x / (nhb * HCH);
  int c  = hb * 256 + threadIdx.x;
  int rows = S / HCH;
  const float* p = hidden + ((size_t)b * S + (size_t)ch * rows) * H + c;
  double acc = 0.0;
  for (int s = 0; s < rows; ++s) acc += (double)p[(size_t)s * H];
  part[((size_t)b * HCH + ch) * H + c] = acc;
}

// ---------------------------------------------------------------------------
// Column-sum stage 2: Hsum[b][c] = sum_ch part[b][ch][c] (f64, fixed order).
// ---------------------------------------------------------------------------
__global__ void hsum2_kernel(const double* __restrict__ part,
                             float* __restrict__ Hsum, int B, int H) {
  int idx = blockIdx.x * blockDim.x + threadIdx.x;
  if (idx >= B * H) return;
  int b = idx / H, c = idx % H;
  const double* p = part + (size_t)b * HCH * H + c;
  double acc = 0.0;
#pragma unroll
  for (int ch = 0; ch < HCH; ++ch) acc += p[(size_t)ch * H];
  Hsum[idx] = (float)acc;
}

// ---------------------------------------------------------------------------
// Qs[b][c] = sum_k Hsum[b][k] * Wq2[c][k]  (fp32 inputs, f64 accum).
// ---------------------------------------------------------------------------
__global__ void qs_kernel(const float* __restrict__ Hsum,
                          const float* __restrict__ Wq2,
                          float* __restrict__ Qs, int B, int H) {
  int task = (blockIdx.x * blockDim.x + threadIdx.x) >> 6;
  int lane = threadIdx.x & 63;
  if (task >= B * NH * HD) return;
  int b = task / (NH * HD), c = task % (NH * HD);
  const float* hs = Hsum + (size_t)b * H;
  const float* wr = Wq2 + (size_t)c * H;
  double acc = 0.0;
  for (int k = lane; k < H; k += 64) acc += (double)hs[k] * (double)wr[k];
#pragma unroll
  for (int off = 32; off; off >>= 1) acc += __shfl_xor(acc, off);
  if (lane == 0) Qs[task] = (float)acc;
}

// ---------------------------------------------------------------------------
// scores[b][l] = 0.125 * dot(Qs[b,:], kb_keys[l, 0:2048]) (f64 acc)
// ---------------------------------------------------------------------------
__global__ void scores_kernel(const float* __restrict__ Qs,
                              const float* __restrict__ kbk,
                              float* __restrict__ scores, int B, int KBL) {
  int task = (blockIdx.x * blockDim.x + threadIdx.x) >> 6;
  int lane = threadIdx.x & 63;
  if (task >= B * KBL) return;
  int b = task / KBL, l = task % KBL;
  const float* kr = kbk + (size_t)l * KBROW;
  const float* qd = Qs + (size_t)b * NH * HD;
  double acc = 0.0;
  for (int c = lane; c < NH * HD; c += 64) acc += (double)qd[c] * (double)kr[c];
#pragma unroll
  for (int off = 32; off; off >>= 1) acc += __shfl_xor(acc, off);
  if (lane == 0) scores[task] = (float)(0.125 * acc);
}

// ---------------------------------------------------------------------------
// Top-K by rank-counting (stable descending == lax.top_k).
// ---------------------------------------------------------------------------
__global__ __launch_bounds__(256) void topk_kernel(
    const float* __restrict__ scores, int* __restrict__ top_idx, int KBL) {
  __shared__ float ls[512];
  int b = blockIdx.x, t = threadIdx.x;
  for (int i = t; i < KBL; i += 256) ls[i] = scores[(size_t)b * KBL + i];
  __syncthreads();
  for (int l = t; l < KBL; l += 256) {
    float sl = ls[l];
    int rank = 0;
    for (int j = 0; j < KBL; ++j) {
      float sj = ls[j];
      rank += (sj > sl || (sj == sl && j < l)) ? 1 : 0;
    }
    if (rank < TOPK) top_idx[b * TOPK + rank] = l;
  }
}

// ---------------------------------------------------------------------------
// padflag[b*S+s] = all(mask[b,0,s,:] < 0)
// ---------------------------------------------------------------------------
__global__ void padflag_kernel(const float* __restrict__ mask,
                               int* __restrict__ flags, int BS, int S) {
  int w = (blockIdx.x * blockDim.x + threadIdx.x) >> 6;
  int lane = threadIdx.x & 63;
  if (w >= BS) return;
  const float* row = mask + (size_t)w * S;
  bool ok = true;
  for (int j = lane; j < S; j += 64) ok = ok && (row[j] < 0.f);
  int allv = __all(ok ? 1 : 0);
  if (lane == 0) flags[w] = allv;
}

// ---------------------------------------------------------------------------
// One chunk of QK^T -> online softmax -> PV for one q-tile.
// ---------------------------------------------------------------------------
__device__ __forceinline__ void attn_step(
    const char* smem, char* ptw, const int* padfb, const bf16x8* aq,
    bool iskb, int j0, int s0, int w, int li, int lg4,
    float* m_, float* l_, f32x4* acc) {
  f32x4 cc[4];
  __builtin_amdgcn_s_setprio(1);
#pragma unroll
  for (int cb = 0; cb < 4; ++cb) {
    bf16x8 b0 = *(const bf16x8*)(smem + swz(cb * 16 + li, lg4));
    bf16x8 b1 = *(const bf16x8*)(smem + swz(cb * 16 + li, 4 + lg4));
    f32x4 z = {};
    z = __builtin_amdgcn_mfma_f32_16x16x32_bf16(aq[0], b0, z, 0, 0, 0);
    z = __builtin_amdgcn_mfma_f32_16x16x32_bf16(aq[1], b1, z, 0, 0, 0);
    cc[cb] = z;
  }
  __builtin_amdgcn_s_setprio(0);

  float lgv[4][4];
#pragma unroll
  for (int cb = 0; cb < 4; ++cb)
#pragma unroll
    for (int j = 0; j < 4; ++j) {
      float v = SCALE * cc[cb][j];
      if (iskb) {
        v += C0F + (padfb[w * 16 + lg4 * 4 + j] ? PADF : 0.f);
      } else {
        int key = j0 + cb * 16 + li;
        int srow = s0 + w * 16 + lg4 * 4 + j;
        v += (key <= srow) ? 0.f : PADF;
      }
      lgv[cb][j] = v;
    }
#pragma unroll
  for (int j = 0; j < 4; ++j) {
    float rmax = fmaxf(fmaxf(lgv[0][j], lgv[1][j]), fmaxf(lgv[2][j], lgv[3][j]));
#pragma unroll
    for (int off = 8; off; off >>= 1) rmax = fmaxf(rmax, __shfl_xor(rmax, off));
    float mn = fmaxf(m_[j], rmax);
    float fs = __expf(m_[j] - mn);
    float csum = 0.f;
#pragma unroll
    for (int cb = 0; cb < 4; ++cb) {
      float pv = __expf(lgv[cb][j] - mn);
      csum += pv;
      int key = cb * 16 + li;
      int rloc = lg4 * 4 + j;
      *(unsigned short*)(ptw + swz(rloc, key >> 3) + ((key & 7) << 1)) = f2bf(pv);
    }
#pragma unroll
    for (int off = 8; off; off >>= 1) csum += __shfl_xor(csum, off);
    m_[j] = mn;
    l_[j] = l_[j] * fs + csum;
#pragma unroll
    for (int db = 0; db < 4; ++db) acc[db][j] *= fs;
  }

  bf16x8 pa0 = *(const bf16x8*)(ptw + swz(li, lg4));
  bf16x8 pa1 = *(const bf16x8*)(ptw + swz(li, 4 + lg4));
  __builtin_amdgcn_s_setprio(1);
#pragma unroll
  for (int db = 0; db < 4; ++db) {
    bf16x8 bv0 = *(const bf16x8*)(smem + 8192 + swz(db * 16 + li, lg4));
    bf16x8 bv1 = *(const bf16x8*)(smem + 8192 + swz(db * 16 + li, 4 + lg4));
    acc[db] = __builtin_amdgcn_mfma_f32_16x16x32_bf16(pa0, bv0, acc[db], 0, 0, 0);
    acc[db] = __builtin_amdgcn_mfma_f32_16x16x32_bf16(pa1, bv1, acc[db], 0, 0, 0);
  }
  __builtin_amdgcn_s_setprio(0);
}

// ---------------------------------------------------------------------------
// MFMA fused attention v3: diagonal tile-pairing for load balance.
// Block handles tiles stA=p and stB=nst-1-p (constant total work); one K/V
// staging per chunk feeds both tiles.
// ---------------------------------------------------------------------------
__global__ __launch_bounds__(256) void attn_mfma(
    const unsigned short* __restrict__ qbf,    // [B*S][2048] roped bf16
    const unsigned short* __restrict__ q2bf,   // [B*S][2048] bf16
    const unsigned short* __restrict__ kbf,    // [B*S][512] roped bf16
    const unsigned short* __restrict__ vTb,    // [B][NKV][64][S] bf16
    const unsigned short* __restrict__ kbkh,   // [128][2048] bf16
    const unsigned short* __restrict__ kbvgT,  // [B][NH][64][128] bf16
    const int* __restrict__ padflag,           // [B*S]
    unsigned short* __restrict__ attnbf,       // [B*S][2048] bf16
    int B, int S) {
  const int nst = S >> 6;
  const int npair = (nst + 1) >> 1;
  const int p = blockIdx.x % npair;
  const int h = (blockIdx.x / npair) % NH;
  const int b = blockIdx.x / (npair * NH);
  const int stA = p, stB = nst - 1 - p;
  const bool hasB = (stB != stA);
  const int s0A = stA * 64, s0B = stB * 64;
  const int g = h / (NH / NKV);

  __shared__ unsigned short smem[8192];   // 16 KB: K tile | V^T tile
  __shared__ unsigned short pt[4][1024];  // per-wave P [row16][key64]
  __shared__ int padf[128];               // [0..63]=A rows, [64..127]=B rows

  const int t = threadIdx.x;
  const int w = t >> 6;
  const int li = t & 15;
  const int lg4 = (t & 63) >> 4;

  if (t < 64) padf[t] = padflag[b * S + s0A + t];
  else if (t < 128) padf[t] = padflag[b * S + s0B + (t - 64)];

  // stage q/q2 for tile A then tile B, hoisting fragments to registers
  bf16x8 aq0A[2], aq2A[2], aq0B[2], aq2B[2];
#pragma unroll
  for (int pass = 0; pass < 2; ++pass) {
    int s0 = pass ? s0B : s0A;
#pragma unroll
    for (int it = 0; it < 4; ++it) {
      int slot = it * 256 + t;
      int tile = slot >> 9, row = (slot >> 3) & 63, ck = slot & 7;
      const unsigned short* src = tile ? q2bf : qbf;
      bf16x8 v = *(const bf16x8*)(src + (size_t)(b * S + s0 + row) * (NH * HD) +
                                  h * 64 + ck * 8);
      *(bf16x8*)((char*)smem + tile * 8192 + swz(row, ck)) = v;
    }
    __syncthreads();
#pragma unroll
    for (int kc = 0; kc < 2; ++kc) {
      bf16x8 v0 = *(const bf16x8*)((char*)smem + swz(w * 16 + li, kc * 4 + lg4));
      bf16x8 v2 = *(const bf16x8*)((char*)smem + 8192 + swz(w * 16 + li, kc * 4 + lg4));
      if (pass == 0) { aq0A[kc] = v0; aq2A[kc] = v2; }
      else           { aq0B[kc] = v0; aq2B[kc] = v2; }
    }
    __syncthreads();
  }

  float mA[4] = {-3.4e38f, -3.4e38f, -3.4e38f, -3.4e38f};
  float mB[4] = {-3.4e38f, -3.4e38f, -3.4e38f, -3.4e38f};
  float lA[4] = {}, lB[4] = {};
  f32x4 accA[4] = {}, accB[4] = {};

  const int nch = 2 + stB + 1;
  for (int ch = 0; ch < nch; ++ch) {
    const bool iskb = ch < 2;
    const int j0 = iskb ? ch * 64 : (ch - 2) * 64;
    if (ch) __syncthreads();  // prev chunk fully consumed
    // ---- stage K tile (0..8191) + V^T tile (8192..16383)
#pragma unroll
    for (int it = 0; it < 4; ++it) {
      int slot = it * 256 + t;
      int tile = slot >> 9, row = (slot >> 3) & 63, ck = slot & 7;
      const unsigned short* src;
      if (tile == 0) {
        src = iskb ? kbkh + (size_t)(j0 + row) * 2048 + h * 64 + ck * 8
                   : kbf + (size_t)(b * S + j0 + row) * 512 + g * 64 + ck * 8;
      } else {
        src = iskb ? kbvgT + (((size_t)b * NH + h) * 64 + row) * 128 + j0 + ck * 8
                   : vTb + (((size_t)b * NKV + g) * 64 + row) * (size_t)S + j0 + ck * 8;
      }
      bf16x8 v = *(const bf16x8*)src;
      *(bf16x8*)((char*)smem + tile * 8192 + swz(row, ck)) = v;
    }
    __syncthreads();

    // tile A (KB chunks always; seq chunks only up to its diagonal)
    if (iskb || (ch - 2) <= stA)
      attn_step((const char*)smem, (char*)pt[w], padf, iskb ? aq2A : aq0A,
                iskb, j0, s0A, w, li, lg4, mA, lA, accA);
    // tile B (all staged chunks apply)
    if (hasB)
      attn_step((const char*)smem, (char*)pt[w], padf + 64, iskb ? aq2B : aq0B,
                iskb, j0, s0B, w, li, lg4, mB, lB, accB);
  }

  // ---- epilogue: normalize, store bf16
#pragma unroll
  for (int j = 0; j < 4; ++j) {
    float inv = 1.f / lA[j];
    size_t o = (size_t)(b * S + s0A + w * 16 + lg4 * 4 + j) * (NH * HD) + h * 64 + li;
#pragma unroll
    for (int db = 0; db < 4; ++db) attnbf[o + db * 16] = f2bf(accA[db][j] * inv);
  }
  if (hasB) {
#pragma unroll
    for (int j = 0; j < 4; ++j) {
      float inv = 1.f / lB[j];
      size_t o = (size_t)(b * S + s0B + w * 16 + lg4 * 4 + j) * (NH * HD) + h * 64 + li;
#pragma unroll
      for (int db = 0; db < 4; ++db) attnbf[o + db * 16] = f2bf(accB[db][j] * inv);
    }
  }
}

// ---------------------------------------------------------------------------
extern "C" void kernel_launch(void* const* d_in, const int* in_sizes, int n_in,
                              void* d_out, int out_size, void* d_ws, size_t ws_size,
                              hipStream_t stream) {
  const float* hidden = (const float*)d_in[0];
  const float* cosb   = (const float*)d_in[1];
  const float* sinb   = (const float*)d_in[2];
  const float* mask   = (const float*)d_in[3];
  const float* kbk    = (const float*)d_in[4];
  const float* kbv    = (const float*)d_in[5];
  const float* Wq     = (const float*)d_in[6];
  const float* Wq2    = (const float*)d_in[7];
  const float* Wk     = (const float*)d_in[8];
  const float* Wv     = (const float*)d_in[9];
  const float* Wo     = (const float*)d_in[10];
  float* out = (float*)d_out;

  const int H   = in_sizes[6] / (NH * HD);             // 2048
  const int KBL = in_sizes[4] / KBROW;                 // 400
  const long long BSll = (long long)in_sizes[0] / H;
  const int S = (int)((long long)in_sizes[3] / BSll);  // 1024
  const int B = (int)(BSll / S);                       // 2
  const int BS = B * S;
  const int NQ = NH * HD;                              // 2048
  const int NKVD = NKV * HD;                           // 512
  const int NTOT = NQ + NQ + NKVD + NKVD;              // 5120

  float* ws = (float*)d_ws;
  size_t off = 0;
  double* hpart = (double*)(ws + off); off += (size_t)B * HCH * H * 2;
  float* vb   = ws + off; off += (size_t)BS * NKVD;      // f32 v
  float* Hsum = ws + off; off += (size_t)B * H;
  float* Qs   = ws + off; off += (size_t)B * NQ;
  float* sc   = ws + off; off += (size_t)B * KBL;
  int* topi   = (int*)(ws + off); off += (size_t)B * TOPK;
  int* padfl  = (int*)(ws + off); off += (size_t)BS;
  unsigned short* hbf    = (unsigned short*)(ws + off); off += (size_t)BS * H / 2;
  unsigned short* wall   = (unsigned short*)(ws + off); off += (size_t)NTOT * H / 2;
  unsigned short* wobf   = (unsigned short*)(ws + off); off += (size_t)H * NQ / 2;
  unsigned short* attnbf = (unsigned short*)(ws + off); off += (size_t)BS * NQ / 2;
  unsigned short* qbf    = (unsigned short*)(ws + off); off += (size_t)BS * NQ / 2;
  unsigned short* q2bf   = (unsigned short*)(ws + off); off += (size_t)BS * NQ / 2;
  unsigned short* kbf    = (unsigned short*)(ws + off); off += (size_t)BS * NKVD / 2;
  unsigned short* vTb    = (unsigned short*)(ws + off); off += (size_t)BS * NKVD / 2;
  unsigned short* kbkh   = (unsigned short*)(ws + off); off += (size_t)128 * NQ / 2;
  unsigned short* kbvgT  = (unsigned short*)(ws + off); off += (size_t)B * NH * HD * TOPK / 2;
  (void)ws_size; (void)n_in; (void)out_size;

  // 0: fp32 -> bf16 conversions
  {
    int n = BS * H / 4;
    f2bf_kernel<<<(n + 255) / 256, 256, 0, stream>>>(hidden, hbf, n);
    int n0 = NQ * H / 4, n1 = NQ * H / 4, n2 = NKVD * H / 4, n3 = NKVD * H / 4;
    int ntot = n0 + n1 + n2 + n3;
    f2bf4_kernel<<<(ntot + 255) / 256, 256, 0, stream>>>(
        Wq, Wq2, Wk, Wv, n0, n1, n2, n3, wall);
    n = H * NQ / 4;
    f2bf_kernel<<<(n + 255) / 256, 256, 0, stream>>>(Wo, wobf, n);
  }

  // 1: fused projections + RoPE epilogue (q->qbf, q2->q2bf, k->kbf, v->vb)
  gemm_proj<<<dim3(NTOT / 128, BS / 128), 256, 0, stream>>>(
      hbf, wall, cosb, sinb, qbf, q2bf, kbf, vb, BS, H);

  // 2: V transpose -> bf16
  vT_kernel<<<B * NKV * (S / 64), 256, 0, stream>>>(vb, vTb, B, S);

  // 3-7: exact fp32 scores path + top-k + padding
  hsum1_kernel<<<B * HCH * (H / 256), 256, 0, stream>>>(hidden, hpart, B, S, H);
  hsum2_kernel<<<(B * H + 255) / 256, 256, 0, stream>>>(hpart, Hsum, B, H);
  qs_kernel<<<(B * NQ * 64 + 255) / 256, 256, 0, stream>>>(Hsum, Wq2, Qs, B, H);
  scores_kernel<<<(B * KBL * 64 + 255) / 256, 256, 0, stream>>>(Qs, kbk, sc, B, KBL);
  topk_kernel<<<B, 256, 0, stream>>>(sc, topi, KBL);
  padflag_kernel<<<(BS * 64 + 255) / 256, 256, 0, stream>>>(mask, padfl, BS, S);

  // 8-9: KB bf16 staging
  kbkh_kernel<<<(128 * 512 + 255) / 256, 256, 0, stream>>>(kbk, kbkh);
  kbvgt_kernel<<<B * NH, 256, 0, stream>>>(kbv, topi, kbvgT, B);

  // 10: fused attention (paired tiles)
  {
    int nst = S / 64;
    int npair = (nst + 1) / 2;
    attn_mfma<<<B * NH * npair, 256, 0, stream>>>(
        qbf, q2bf, kbf, vTb, kbkh, kbvgT, padfl, attnbf, B, S);
  }

  // 11: output projection
  gemm_nt_bf16<<<dim3(H / 128, BS / 128), 256, 0, stream>>>(attnbf, wobf, out, BS, H, NQ);
}

// Round 11
// 265.160 us; speedup vs baseline: 11.2744x; 1.0645x over previous
//
#include <hip/hip_runtime.h>
#include <hip/hip_bf16.h>
#include <math.h>

#define NH 32
#define NKV 8
#define HD 64
#define NSLOTS 11
#define TOPK 128
#define KBROW (NSLOTS * NH * HD)   // 22528
#define PADF (-3.3895313892515355e+38f)
#define C0F  (-0.24686007793152578f)   // -ln(128)+ln(100)
#define SCALE 0.125f
#define HCH 32                         // S-chunks for hierarchical column sum

typedef __attribute__((ext_vector_type(8))) __bf16 bf16x8;
typedef __attribute__((ext_vector_type(8))) unsigned short u16x8;
typedef __attribute__((ext_vector_type(4))) float f32x4;

#define GLDS16(gp, lp)                                                        \
  __builtin_amdgcn_global_load_lds(                                           \
      (__attribute__((address_space(1))) void*)(gp),                          \
      (__attribute__((address_space(3))) void*)(lp), 16, 0, 0)

__device__ __forceinline__ unsigned short f2bf(float f) {
  unsigned int u = __float_as_uint(f);
  u = (u + 0x7fffu + ((u >> 16) & 1u)) >> 16;
  return (unsigned short)u;
}

// byte offset into a 64-col bf16 tile (128 B/row) with XOR chunk swizzle
__device__ __forceinline__ int swz(int row, int chunk) {
  return row * 128 + ((chunk ^ (row & 7)) << 4);
}

// ---------------------------------------------------------------------------
// fp32 -> bf16 for 6 concatenated sources into one contiguous dest.
// Units are float4 (n counts in float4).
// ---------------------------------------------------------------------------
__global__ void f2bf_all(const float* __restrict__ s0, const float* __restrict__ s1,
                         const float* __restrict__ s2, const float* __restrict__ s3,
                         const float* __restrict__ s4, const float* __restrict__ s5,
                         int n0, int n1, int n2, int n3, int n4_, int n5,
                         unsigned short* __restrict__ out) {
  int i = blockIdx.x * blockDim.x + threadIdx.x;
  int j = i;
  const float* src;
  if (j < n0) src = s0;
  else { j -= n0; if (j < n1) src = s1;
  else { j -= n1; if (j < n2) src = s2;
  else { j -= n2; if (j < n3) src = s3;
  else { j -= n3; if (j < n4_) src = s4;
  else { j -= n4_; if (j >= n5) return; src = s5; }}}}}
  float4 v = ((const float4*)src)[j];
  ushort4 o = {f2bf(v.x), f2bf(v.y), f2bf(v.z), f2bf(v.w)};
  ((ushort4*)out)[i] = o;
}

// ---------------------------------------------------------------------------
// bf16 MFMA GEMM, split-K=2 (blockIdx.z selects K-half and partial buffer).
// C_z[M,N] f32 = A[M, z*K/2 : (z+1)*K/2] @ B[., same]^T.
// ---------------------------------------------------------------------------
__global__ __launch_bounds__(256) void gemm_nt_splitk(
    const unsigned short* __restrict__ A, const unsigned short* __restrict__ B,
    float* __restrict__ C0, float* __restrict__ C1, int M, int N, int K) {
  __shared__ unsigned short ldsA[128 * 32];
  __shared__ unsigned short ldsB[128 * 32];
  const int t = threadIdx.x;
  const int l = t & 63, w = t >> 6;
  const int wr = w >> 1, wc = w & 1;
  const int lr = l & 15;
  const int kb = (l >> 4) * 16;
  const int bm = blockIdx.y * 128, bn = blockIdx.x * 128;
  float* C = blockIdx.z ? C1 : C0;
  const int k0base = blockIdx.z * (K >> 1);
  const int kend = k0base + (K >> 1);

  f32x4 acc[4][4] = {};

  for (int k0 = k0base; k0 < kend; k0 += 32) {
    __syncthreads();
#pragma unroll
    for (int it = 0; it < 2; ++it) {
      int s = it * 256 + t;
      int row = s >> 2, cs = (s & 3) * 8;
      GLDS16(A + (size_t)(bm + row) * K + k0 + cs,
             (char*)ldsA + (it * 4 + w) * 1024);
      GLDS16(B + (size_t)(bn + row) * K + k0 + cs,
             (char*)ldsB + (it * 4 + w) * 1024);
    }
    __syncthreads();

    bf16x8 a[4], b[4];
#pragma unroll
    for (int m = 0; m < 4; ++m)
      a[m] = *(const bf16x8*)((const char*)ldsA +
                              (wr * 64 + m * 16 + lr) * 64 + kb);
#pragma unroll
    for (int n = 0; n < 4; ++n)
      b[n] = *(const bf16x8*)((const char*)ldsB +
                              (wc * 64 + n * 16 + lr) * 64 + kb);
#pragma unroll
    for (int m = 0; m < 4; ++m)
#pragma unroll
      for (int n = 0; n < 4; ++n)
        acc[m][n] =
            __builtin_amdgcn_mfma_f32_16x16x32_bf16(a[m], b[n], acc[m][n], 0, 0, 0);
  }

#pragma unroll
  for (int m = 0; m < 4; ++m)
#pragma unroll
    for (int n = 0; n < 4; ++n) {
      int rbase = bm + wr * 64 + m * 16 + ((l >> 4) << 2);
      int cbase = bn + wc * 64 + n * 16 + lr;
#pragma unroll
      for (int j = 0; j < 4; ++j)
        C[(size_t)(rbase + j) * N + cbase] = acc[m][n][j];
    }
}

// ---------------------------------------------------------------------------
// out = a + b (float4 units)
// ---------------------------------------------------------------------------
__global__ void add2_kernel(const float* __restrict__ a,
                            const float* __restrict__ b,
                            float* __restrict__ o, int n4) {
  int i = blockIdx.x * blockDim.x + threadIdx.x;
  if (i >= n4) return;
  float4 x = ((const float4*)a)[i], y = ((const float4*)b)[i];
  ((float4*)o)[i] = make_float4(x.x + y.x, x.y + y.y, x.z + y.z, x.w + y.w);
}

// ---------------------------------------------------------------------------
// Fused projection GEMM + RoPE epilogue + direct V^T output.
// cols [0,2048)    -> rope -> qbf bf16
// cols [2048,4096) -> q2bf bf16
// cols [4096,4608) -> rope -> kbf bf16
// cols [4608,5120) -> vTb bf16 transposed [B][NKV][64][S]
// ---------------------------------------------------------------------------
__global__ __launch_bounds__(256) void gemm_proj(
    const unsigned short* __restrict__ A, const unsigned short* __restrict__ Wall,
    const float* __restrict__ cosb, const float* __restrict__ sinb,
    unsigned short* __restrict__ qbf, unsigned short* __restrict__ q2bf,
    unsigned short* __restrict__ kbf, unsigned short* __restrict__ vTb,
    int M, int K, int S) {
  __shared__ unsigned short ldsA[128 * 32];
  __shared__ unsigned short ldsB[128 * 32];
  const int t = threadIdx.x;
  const int l = t & 63, w = t >> 6;
  const int wr = w >> 1, wc = w & 1;
  const int lr = l & 15;
  const int kb_ = (l >> 4) * 16;
  const int bm = blockIdx.y * 128, bn = blockIdx.x * 128;

  f32x4 acc[4][4] = {};

  for (int k0 = 0; k0 < K; k0 += 32) {
    __syncthreads();
#pragma unroll
    for (int it = 0; it < 2; ++it) {
      int s = it * 256 + t;
      int row = s >> 2, cs = (s & 3) * 8;
      GLDS16(A + (size_t)(bm + row) * K + k0 + cs,
             (char*)ldsA + (it * 4 + w) * 1024);
      GLDS16(Wall + (size_t)(bn + row) * K + k0 + cs,
             (char*)ldsB + (it * 4 + w) * 1024);
    }
    __syncthreads();

    bf16x8 a[4], b[4];
#pragma unroll
    for (int m = 0; m < 4; ++m)
      a[m] = *(const bf16x8*)((const char*)ldsA +
                              (wr * 64 + m * 16 + lr) * 64 + kb_);
#pragma unroll
    for (int n = 0; n < 4; ++n)
      b[n] = *(const bf16x8*)((const char*)ldsB +
                              (wc * 64 + n * 16 + lr) * 64 + kb_);
#pragma unroll
    for (int m = 0; m < 4; ++m)
#pragma unroll
      for (int n = 0; n < 4; ++n)
        acc[m][n] =
            __builtin_amdgcn_mfma_f32_16x16x32_bf16(a[m], b[n], acc[m][n], 0, 0, 0);
  }

#pragma unroll
  for (int m = 0; m < 4; ++m) {
    int rbase = bm + wr * 64 + m * 16 + ((l >> 4) << 2);
    if (bn < 2048 || (bn >= 4096 && bn < 4608)) {
      const bool isq = bn < 2048;
#pragma unroll
      for (int j = 0; j < 4; ++j) {
        int row = rbase + j;
        const float* cr = cosb + (size_t)row * 64;
        const float* sr = sinb + (size_t)row * 64;
        float c0 = cr[lr], c1 = cr[16 + lr], c2 = cr[32 + lr], c3 = cr[48 + lr];
        float sa = sr[lr], sb = sr[16 + lr], sc_ = sr[32 + lr], sd = sr[48 + lr];
        float x0 = acc[m][0][j], x1 = acc[m][1][j];
        float x2 = acc[m][2][j], x3 = acc[m][3][j];
        float y0 = x0 * c0 - x2 * sa;
        float y1 = x1 * c1 - x3 * sb;
        float y2 = x2 * c2 + x0 * sc_;
        float y3 = x3 * c3 + x1 * sd;
        if (isq) {
          size_t ro = (size_t)row * 2048 + bn + wc * 64 + lr;
          qbf[ro] = f2bf(y0); qbf[ro + 16] = f2bf(y1);
          qbf[ro + 32] = f2bf(y2); qbf[ro + 48] = f2bf(y3);
        } else {
          size_t ro = (size_t)row * 512 + (bn - 4096) + wc * 64 + lr;
          kbf[ro] = f2bf(y0); kbf[ro + 16] = f2bf(y1);
          kbf[ro + 32] = f2bf(y2); kbf[ro + 48] = f2bf(y3);
        }
      }
    } else if (bn < 4096) {  // q2 -> bf16
#pragma unroll
      for (int n = 0; n < 4; ++n) {
        int cbase = bn + wc * 64 + n * 16 + lr;
#pragma unroll
        for (int j = 0; j < 4; ++j)
          q2bf[(size_t)(rbase + j) * 2048 + (cbase - 2048)] = f2bf(acc[m][n][j]);
      }
    } else {  // v -> vT bf16 direct (j=0..3 are consecutive s)
      int b_ = rbase / S, s = rbase % S;
#pragma unroll
      for (int n = 0; n < 4; ++n) {
        int col = (bn - 4608) + wc * 64 + n * 16 + lr;
        int gg = col >> 6, d = col & 63;
        ushort4 o = {f2bf(acc[m][n][0]), f2bf(acc[m][n][1]),
                     f2bf(acc[m][n][2]), f2bf(acc[m][n][3])};
        *(ushort4*)&vTb[(((size_t)b_ * NKV + gg) * 64 + d) * S + s] = o;
      }
    }
  }
}

// ---------------------------------------------------------------------------
// KB key slice: kbkh[j][c] = bf16(kb_keys[j*KBROW + c]), j<128, c<2048.
// ---------------------------------------------------------------------------
__global__ void kbkh_kernel(const float* __restrict__ kbk,
                            unsigned short* __restrict__ out) {
  int i = blockIdx.x * blockDim.x + threadIdx.x;
  if (i >= 128 * 512) return;
  int j = i >> 9, c4 = (i & 511) * 4;
  float4 v = *(const float4*)&kbk[(size_t)j * KBROW + c4];
  ushort4 o = {f2bf(v.x), f2bf(v.y), f2bf(v.z), f2bf(v.w)};
  *(ushort4*)&out[(size_t)j * 2048 + c4] = o;
}

// ---------------------------------------------------------------------------
// Gathered + transposed KB values -> [B][NH][64][128] bf16.
// ---------------------------------------------------------------------------
__global__ __launch_bounds__(256) void kbvgt_kernel(
    const float* __restrict__ kbv, const int* __restrict__ topi,
    unsigned short* __restrict__ kbvgT, int B) {
  int h = blockIdx.x % NH, b = blockIdx.x / NH;
  __shared__ unsigned short gt[128][72];
  __shared__ int lidx[TOPK];
  int t = threadIdx.x;
  if (t < TOPK) lidx[t] = topi[b * TOPK + t];
  __syncthreads();
#pragma unroll
  for (int it = 0; it < 8; ++it) {
    int slot = it * 256 + t;
    int j = slot >> 4, d4 = (slot & 15) * 4;
    float4 v = *(const float4*)&kbv[(size_t)lidx[j] * KBROW + h * 64 + d4];
    gt[j][d4] = f2bf(v.x); gt[j][d4 + 1] = f2bf(v.y);
    gt[j][d4 + 2] = f2bf(v.z); gt[j][d4 + 3] = f2bf(v.w);
  }
  __syncthreads();
#pragma unroll
  for (int it = 0; it < 4; ++it) {
    int slot = it * 256 + t;
    int d = slot >> 4, j8 = (slot & 15) * 8;
    u16x8 o;
#pragma unroll
    for (int j = 0; j < 8; ++j) o[j] = gt[j8 + j][d];
    *(u16x8*)&kbvgT[(((size_t)b * NH + h) * 64 + d) * 128 + j8] = o;
  }
}

// ---------------------------------------------------------------------------
// Column-sum stage 1: part[b][ch][c] = sum over 32-row chunk (f64).
// ---------------------------------------------------------------------------
__global__ __launch_bounds__(256) void hsum1_kernel(
    const float* __restrict__ hidden, double* __restrict__ part,
    int B, int S, int H) {
  const int nhb = H >> 8;
  int hb = blockIdx.x % nhb;
  int ch = (blockIdx.x / nhb) % HCH;
  int b  = blockIdx.x / (nhb * HCH);
  int c  = hb * 256 + threadIdx.x;
  int rows = S / HCH;
  const float* p = hidden + ((size_t)b * S + (size_t)ch * rows) * H + c;
  double acc = 0.0;
  for (int s = 0; s < rows; ++s) acc += (double)p[(size_t)s * H];
  part[((size_t)b * HCH + ch) * H + c] = acc;
}

// ---------------------------------------------------------------------------
// Column-sum stage 2: Hsum[b][c] = sum_ch part[b][ch][c] (f64, fixed order).
// ---------------------------------------------------------------------------
__global__ void hsum2_kernel(const double* __restrict__ part,
                             float* __restrict__ Hsum, int B, int H) {
  int idx = blockIdx.x * blockDim.x + threadIdx.x;
  if (idx >= B * H) return;
  int b = idx / H, c = idx % H;
  const double* p = part + (size_t)b * HCH * H + c;
  double acc = 0.0;
#pragma unroll
  for (int ch = 0; ch < HCH; ++ch) acc += p[(size_t)ch * H];
  Hsum[idx] = (float)acc;
}

// ---------------------------------------------------------------------------
// Qs[b][c] = sum_k Hsum[b][k] * Wq2[c][k]  (fp32 inputs, f64 accum).
// ---------------------------------------------------------------------------
__global__ void qs_kernel(const float* __restrict__ Hsum,
                          const float* __restrict__ Wq2,
                          float* __restrict__ Qs, int B, int H) {
  int task = (blockIdx.x * blockDim.x + threadIdx.x) >> 6;
  int lane = threadIdx.x & 63;
  if (task >= B * NH * HD) return;
  int b = task / (NH * HD), c = task % (NH * HD);
  const float* hs = Hsum + (size_t)b * H;
  const float* wr = Wq2 + (size_t)c * H;
  double acc = 0.0;
  for (int k = lane; k < H; k += 64) acc += (double)hs[k] * (double)wr[k];
#pragma unroll
  for (int off = 32; off; off >>= 1) acc += __shfl_xor(acc, off);
  if (lane == 0) Qs[task] = (float)acc;
}

// ---------------------------------------------------------------------------
// scores[b][l] = 0.125 * dot(Qs[b,:], kb_keys[l, 0:2048]) (f64 acc)
// ---------------------------------------------------------------------------
__global__ void scores_kernel(const float* __restrict__ Qs,
                              const float* __restrict__ kbk,
                              float* __restrict__ scores, int B, int KBL) {
  int task = (blockIdx.x * blockDim.x + threadIdx.x) >> 6;
  int lane = threadIdx.x & 63;
  if (task >= B * KBL) return;
  int b = task / KBL, l = task % KBL;
  const float* kr = kbk + (size_t)l * KBROW;
  const float* qd = Qs + (size_t)b * NH * HD;
  double acc = 0.0;
  for (int c = lane; c < NH * HD; c += 64) acc += (double)qd[c] * (double)kr[c];
#pragma unroll
  for (int off = 32; off; off >>= 1) acc += __shfl_xor(acc, off);
  if (lane == 0) scores[task] = (float)(0.125 * acc);
}

// ---------------------------------------------------------------------------
// Top-K by rank-counting (stable descending == lax.top_k).
// ---------------------------------------------------------------------------
__global__ __launch_bounds__(256) void topk_kernel(
    const float* __restrict__ scores, int* __restrict__ top_idx, int KBL) {
  __shared__ float ls[512];
  int b = blockIdx.x, t = threadIdx.x;
  for (int i = t; i < KBL; i += 256) ls[i] = scores[(size_t)b * KBL + i];
  __syncthreads();
  for (int l = t; l < KBL; l += 256) {
    float sl = ls[l];
    int rank = 0;
    for (int j = 0; j < KBL; ++j) {
      float sj = ls[j];
      rank += (sj > sl || (sj == sl && j < l)) ? 1 : 0;
    }
    if (rank < TOPK) top_idx[b * TOPK + rank] = l;
  }
}

// ---------------------------------------------------------------------------
// padflag[b*S+s] = all(mask[b,0,s,:] < 0)
// ---------------------------------------------------------------------------
__global__ void padflag_kernel(const float* __restrict__ mask,
                               int* __restrict__ flags, int BS, int S) {
  int w = (blockIdx.x * blockDim.x + threadIdx.x) >> 6;
  int lane = threadIdx.x & 63;
  if (w >= BS) return;
  const float* row = mask + (size_t)w * S;
  bool ok = true;
  for (int j = lane; j < S; j += 64) ok = ok && (row[j] < 0.f);
  int allv = __all(ok ? 1 : 0);
  if (lane == 0) flags[w] = allv;
}

// ---------------------------------------------------------------------------
// Load one K/V chunk's staged data into registers (4 x bf16x8 per thread).
// ---------------------------------------------------------------------------
__device__ __forceinline__ void load_chunk(
    int ch, int t, int b, int h, int g, int S,
    const unsigned short* __restrict__ kbf, const unsigned short* __restrict__ vTb,
    const unsigned short* __restrict__ kbkh, const unsigned short* __restrict__ kbvgT,
    bf16x8* st) {
  bool iskb = ch < 2;
  int j0 = iskb ? ch * 64 : (ch - 2) * 64;
#pragma unroll
  for (int it = 0; it < 4; ++it) {
    int slot = it * 256 + t;
    int tile = slot >> 9, row = (slot >> 3) & 63, ck = slot & 7;
    const unsigned short* src;
    if (tile == 0)
      src = iskb ? kbkh + (size_t)(j0 + row) * 2048 + h * 64 + ck * 8
                 : kbf + (size_t)(b * S + j0 + row) * 512 + g * 64 + ck * 8;
    else
      src = iskb ? kbvgT + (((size_t)b * NH + h) * 64 + row) * 128 + j0 + ck * 8
                 : vTb + (((size_t)b * NKV + g) * 64 + row) * (size_t)S + j0 + ck * 8;
    st[it] = *(const bf16x8*)src;
  }
}

// ---------------------------------------------------------------------------
// One chunk of QK^T -> online softmax -> PV for one q-tile.
// ---------------------------------------------------------------------------
__device__ __forceinline__ void attn_step(
    const char* smem, char* ptw, const int* padfb, const bf16x8* aq,
    bool iskb, int j0, int s0, int w, int li, int lg4,
    float* m_, float* l_, f32x4* acc) {
  f32x4 cc[4];
  __builtin_amdgcn_s_setprio(1);
#pragma unroll
  for (int cb = 0; cb < 4; ++cb) {
    bf16x8 b0 = *(const bf16x8*)(smem + swz(cb * 16 + li, lg4));
    bf16x8 b1 = *(const bf16x8*)(smem + swz(cb * 16 + li, 4 + lg4));
    f32x4 z = {};
    z = __builtin_amdgcn_mfma_f32_16x16x32_bf16(aq[0], b0, z, 0, 0, 0);
    z = __builtin_amdgcn_mfma_f32_16x16x32_bf16(aq[1], b1, z, 0, 0, 0);
    cc[cb] = z;
  }
  __builtin_amdgcn_s_setprio(0);

  float lgv[4][4];
#pragma unroll
  for (int cb = 0; cb < 4; ++cb)
#pragma unroll
    for (int j = 0; j < 4; ++j) {
      float v = SCALE * cc[cb][j];
      if (iskb) {
        v += C0F + (padfb[w * 16 + lg4 * 4 + j] ? PADF : 0.f);
      } else {
        int key = j0 + cb * 16 + li;
        int srow = s0 + w * 16 + lg4 * 4 + j;
        v += (key <= srow) ? 0.f : PADF;
      }
      lgv[cb][j] = v;
    }
#pragma unroll
  for (int j = 0; j < 4; ++j) {
    float rmax = fmaxf(fmaxf(lgv[0][j], lgv[1][j]), fmaxf(lgv[2][j], lgv[3][j]));
#pragma unroll
    for (int off = 8; off; off >>= 1) rmax = fmaxf(rmax, __shfl_xor(rmax, off));
    float mn = fmaxf(m_[j], rmax);
    float fs = __expf(m_[j] - mn);
    float csum = 0.f;
#pragma unroll
    for (int cb = 0; cb < 4; ++cb) {
      float pv = __expf(lgv[cb][j] - mn);
      csum += pv;
      int key = cb * 16 + li;
      int rloc = lg4 * 4 + j;
      *(unsigned short*)(ptw + swz(rloc, key >> 3) + ((key & 7) << 1)) = f2bf(pv);
    }
#pragma unroll
    for (int off = 8; off; off >>= 1) csum += __shfl_xor(csum, off);
    m_[j] = mn;
    l_[j] = l_[j] * fs + csum;
#pragma unroll
    for (int db = 0; db < 4; ++db) acc[db][j] *= fs;
  }

  bf16x8 pa0 = *(const bf16x8*)(ptw + swz(li, lg4));
  bf16x8 pa1 = *(const bf16x8*)(ptw + swz(li, 4 + lg4));
  __builtin_amdgcn_s_setprio(1);
#pragma unroll
  for (int db = 0; db < 4; ++db) {
    bf16x8 bv0 = *(const bf16x8*)(smem + 8192 + swz(db * 16 + li, lg4));
    bf16x8 bv1 = *(const bf16x8*)(smem + 8192 + swz(db * 16 + li, 4 + lg4));
    acc[db] = __builtin_amdgcn_mfma_f32_16x16x32_bf16(pa0, bv0, acc[db], 0, 0, 0);
    acc[db] = __builtin_amdgcn_mfma_f32_16x16x32_bf16(pa1, bv1, acc[db], 0, 0, 0);
  }
  __builtin_amdgcn_s_setprio(0);
}

// ---------------------------------------------------------------------------
// MFMA fused attention v4: diagonal pairing + async reg-staged K/V prefetch
// (T14) + direct-global q fragments (no q LDS staging).
// ---------------------------------------------------------------------------
__global__ __launch_bounds__(256) void attn_mfma(
    const unsigned short* __restrict__ qbf,    // [B*S][2048] roped bf16
    const unsigned short* __restrict__ q2bf,   // [B*S][2048] bf16
    const unsigned short* __restrict__ kbf,    // [B*S][512] roped bf16
    const unsigned short* __restrict__ vTb,    // [B][NKV][64][S] bf16
    const unsigned short* __restrict__ kbkh,   // [128][2048] bf16
    const unsigned short* __restrict__ kbvgT,  // [B][NH][64][128] bf16
    const int* __restrict__ padflag,           // [B*S]
    unsigned short* __restrict__ attnbf,       // [B*S][2048] bf16
    int B, int S) {
  const int nst = S >> 6;
  const int npair = (nst + 1) >> 1;
  const int p = blockIdx.x % npair;
  const int h = (blockIdx.x / npair) % NH;
  const int b = blockIdx.x / (npair * NH);
  const int stA = p, stB = nst - 1 - p;
  const bool hasB = (stB != stA);
  const int s0A = stA * 64, s0B = stB * 64;
  const int g = h / (NH / NKV);

  __shared__ unsigned short smem[8192];   // 16 KB: K tile | V^T tile
  __shared__ unsigned short pt[4][1024];  // per-wave P [row16][key64]
  __shared__ int padf[128];               // [0..63]=A rows, [64..127]=B rows

  const int t = threadIdx.x;
  const int w = t >> 6;
  const int li = t & 15;
  const int lg4 = (t & 63) >> 4;

  const int nch = 2 + stB + 1;

  // prefetch chunk 0 into registers (latency hides under q-frag loads)
  bf16x8 st[4];
  load_chunk(0, t, b, h, g, S, kbf, vTb, kbkh, kbvgT, st);

  // direct-global q/q2 MFMA A-fragments (layout matches 16x16x32 a-frag)
  bf16x8 aq0A[2], aq2A[2], aq0B[2], aq2B[2];
  {
    size_t rowA = (size_t)(b * S + s0A + w * 16 + li) * (NH * HD);
    size_t rowB = (size_t)(b * S + s0B + w * 16 + li) * (NH * HD);
#pragma unroll
    for (int kc = 0; kc < 2; ++kc) {
      size_t o = h * 64 + kc * 32 + lg4 * 8;
      aq0A[kc] = *(const bf16x8*)(qbf + rowA + o);
      aq2A[kc] = *(const bf16x8*)(q2bf + rowA + o);
      aq0B[kc] = *(const bf16x8*)(qbf + rowB + o);
      aq2B[kc] = *(const bf16x8*)(q2bf + rowB + o);
    }
  }
  if (t < 64) padf[t] = padflag[b * S + s0A + t];
  else if (t < 128) padf[t] = padflag[b * S + s0B + (t - 64)];

  float mA[4] = {-3.4e38f, -3.4e38f, -3.4e38f, -3.4e38f};
  float mB[4] = {-3.4e38f, -3.4e38f, -3.4e38f, -3.4e38f};
  float lA[4] = {}, lB[4] = {};
  f32x4 accA[4] = {}, accB[4] = {};

  for (int ch = 0; ch < nch; ++ch) {
    const bool iskb = ch < 2;
    const int j0 = iskb ? ch * 64 : (ch - 2) * 64;
    if (ch) __syncthreads();  // prev chunk fully consumed (smem writable)
    // write prefetched regs -> LDS (K tile 0..8191, V^T tile 8192..16383)
#pragma unroll
    for (int it = 0; it < 4; ++it) {
      int slot = it * 256 + t;
      int tile = slot >> 9, row = (slot >> 3) & 63, ck = slot & 7;
      *(bf16x8*)((char*)smem + tile * 8192 + swz(row, ck)) = st[it];
    }
    __syncthreads();  // tiles visible (and padf on ch==0)
    // issue next chunk's loads; latency hides under compute below
    if (ch + 1 < nch) load_chunk(ch + 1, t, b, h, g, S, kbf, vTb, kbkh, kbvgT, st);

    if (iskb || (ch - 2) <= stA)
      attn_step((const char*)smem, (char*)pt[w], padf, iskb ? aq2A : aq0A,
                iskb, j0, s0A, w, li, lg4, mA, lA, accA);
    if (hasB)
      attn_step((const char*)smem, (char*)pt[w], padf + 64, iskb ? aq2B : aq0B,
                iskb, j0, s0B, w, li, lg4, mB, lB, accB);
  }

  // epilogue: normalize, store bf16
#pragma unroll
  for (int j = 0; j < 4; ++j) {
    float inv = 1.f / lA[j];
    size_t o = (size_t)(b * S + s0A + w * 16 + lg4 * 4 + j) * (NH * HD) + h * 64 + li;
#pragma unroll
    for (int db = 0; db < 4; ++db) attnbf[o + db * 16] = f2bf(accA[db][j] * inv);
  }
  if (hasB) {
#pragma unroll
    for (int j = 0; j < 4; ++j) {
      float inv = 1.f / lB[j];
      size_t o = (size_t)(b * S + s0B + w * 16 + lg4 * 4 + j) * (NH * HD) + h * 64 + li;
#pragma unroll
      for (int db = 0; db < 4; ++db) attnbf[o + db * 16] = f2bf(accB[db][j] * inv);
    }
  }
}

// ---------------------------------------------------------------------------
extern "C" void kernel_launch(void* const* d_in, const int* in_sizes, int n_in,
                              void* d_out, int out_size, void* d_ws, size_t ws_size,
                              hipStream_t stream) {
  const float* hidden = (const float*)d_in[0];
  const float* cosb   = (const float*)d_in[1];
  const float* sinb   = (const float*)d_in[2];
  const float* mask   = (const float*)d_in[3];
  const float* kbk    = (const float*)d_in[4];
  const float* kbv    = (const float*)d_in[5];
  const float* Wq     = (const float*)d_in[6];
  const float* Wq2    = (const float*)d_in[7];
  const float* Wk     = (const float*)d_in[8];
  const float* Wv     = (const float*)d_in[9];
  const float* Wo     = (const float*)d_in[10];
  float* out = (float*)d_out;

  const int H   = in_sizes[6] / (NH * HD);             // 2048
  const int KBL = in_sizes[4] / KBROW;                 // 400
  const long long BSll = (long long)in_sizes[0] / H;
  const int S = (int)((long long)in_sizes[3] / BSll);  // 1024
  const int B = (int)(BSll / S);                       // 2
  const int BS = B * S;
  const int NQ = NH * HD;                              // 2048
  const int NKVD = NKV * HD;                           // 512
  const int NTOT = NQ + NQ + NKVD + NKVD;              // 5120

  float* ws = (float*)d_ws;
  size_t off = 0;
  double* hpart = (double*)(ws + off); off += (size_t)B * HCH * H * 2;
  float* Hsum = ws + off; off += (size_t)B * H;
  float* Qs   = ws + off; off += (size_t)B * NQ;
  float* sc   = ws + off; off += (size_t)B * KBL;
  int* topi   = (int*)(ws + off); off += (size_t)B * TOPK;
  int* padfl  = (int*)(ws + off); off += (size_t)BS;
  // hbf | wall | wobf contiguous (single f2bf_all dest)
  unsigned short* hbf    = (unsigned short*)(ws + off); off += (size_t)BS * H / 2;
  unsigned short* wall   = (unsigned short*)(ws + off); off += (size_t)NTOT * H / 2;
  unsigned short* wobf   = (unsigned short*)(ws + off); off += (size_t)H * NQ / 2;
  unsigned short* attnbf = (unsigned short*)(ws + off); off += (size_t)BS * NQ / 2;
  unsigned short* qbf    = (unsigned short*)(ws + off); off += (size_t)BS * NQ / 2;
  unsigned short* q2bf   = (unsigned short*)(ws + off); off += (size_t)BS * NQ / 2;
  unsigned short* kbf    = (unsigned short*)(ws + off); off += (size_t)BS * NKVD / 2;
  unsigned short* vTb    = (unsigned short*)(ws + off); off += (size_t)BS * NKVD / 2;
  unsigned short* kbkh   = (unsigned short*)(ws + off); off += (size_t)128 * NQ / 2;
  unsigned short* kbvgT  = (unsigned short*)(ws + off); off += (size_t)B * NH * HD * TOPK / 2;
  // split-K partials alias dead regions: qbf+q2bf (4.19M f) and wall (5.24M f)
  float* c0 = (float*)qbf;   // dead after attn_mfma
  float* c1 = (float*)wall;  // dead after gemm_proj
  (void)ws_size; (void)n_in; (void)out_size;

  // 0: all fp32 -> bf16 conversions in one kernel (dest hbf|wall|wobf)
  {
    int n0 = BS * H / 4, n1 = NQ * H / 4, n2 = NQ * H / 4;
    int n3 = NKVD * H / 4, n4_ = NKVD * H / 4, n5 = H * NQ / 4;
    int ntot = n0 + n1 + n2 + n3 + n4_ + n5;
    f2bf_all<<<(ntot + 255) / 256, 256, 0, stream>>>(
        hidden, Wq, Wq2, Wk, Wv, Wo, n0, n1, n2, n3, n4_, n5, hbf);
  }

  // 1: fused projections + RoPE + direct V^T
  gemm_proj<<<dim3(NTOT / 128, BS / 128), 256, 0, stream>>>(
      hbf, wall, cosb, sinb, qbf, q2bf, kbf, vTb, BS, H, S);

  // 2-6: exact fp32 scores path + top-k + padding
  hsum1_kernel<<<B * HCH * (H / 256), 256, 0, stream>>>(hidden, hpart, B, S, H);
  hsum2_kernel<<<(B * H + 255) / 256, 256, 0, stream>>>(hpart, Hsum, B, H);
  qs_kernel<<<(B * NQ * 64 + 255) / 256, 256, 0, stream>>>(Hsum, Wq2, Qs, B, H);
  scores_kernel<<<(B * KBL * 64 + 255) / 256, 256, 0, stream>>>(Qs, kbk, sc, B, KBL);
  topk_kernel<<<B, 256, 0, stream>>>(sc, topi, KBL);
  padflag_kernel<<<(BS * 64 + 255) / 256, 256, 0, stream>>>(mask, padfl, BS, S);

  // 7-8: KB bf16 staging
  kbkh_kernel<<<(128 * 512 + 255) / 256, 256, 0, stream>>>(kbk, kbkh);
  kbvgt_kernel<<<B * NH, 256, 0, stream>>>(kbv, topi, kbvgT, B);

  // 9: fused attention (paired tiles, async prefetch)
  {
    int nst = S / 64;
    int npair = (nst + 1) / 2;
    attn_mfma<<<B * NH * npair, 256, 0, stream>>>(
        qbf, q2bf, kbf, vTb, kbkh, kbvgT, padfl, attnbf, B, S);
  }

  // 10-11: output projection, split-K=2 + partial add
  gemm_nt_splitk<<<dim3(H / 128, BS / 128, 2), 256, 0, stream>>>(
      attnbf, wobf, c0, c1, BS, H, NQ);
  add2_kernel<<<(BS * H / 4 + 255) / 256, 256, 0, stream>>>(c0, c1, out, BS * H / 4);
}

// Round 12
// 262.806 us; speedup vs baseline: 11.3754x; 1.0090x over previous
//
#include <hip/hip_runtime.h>
#include <hip/hip_bf16.h>
#include <math.h>

#define NH 32
#define NKV 8
#define HD 64
#define NSLOTS 11
#define TOPK 128
#define KBROW (NSLOTS * NH * HD)   // 22528
#define PADF (-3.3895313892515355e+38f)
#define C0F  (-0.24686007793152578f)   // -ln(128)+ln(100)
#define SCALE 0.125f
#define HCH 32                         // S-chunks for hierarchical column sum

typedef __attribute__((ext_vector_type(8))) __bf16 bf16x8;
typedef __attribute__((ext_vector_type(8))) unsigned short u16x8;
typedef __attribute__((ext_vector_type(4))) float f32x4;

#define GLDS16(gp, lp)                                                        \
  __builtin_amdgcn_global_load_lds(                                           \
      (__attribute__((address_space(1))) void*)(gp),                          \
      (__attribute__((address_space(3))) void*)(lp), 16, 0, 0)

__device__ __forceinline__ unsigned short f2bf(float f) {
  unsigned int u = __float_as_uint(f);
  u = (u + 0x7fffu + ((u >> 16) & 1u)) >> 16;
  return (unsigned short)u;
}

// byte offset into a 64-col bf16 tile (128 B/row) with XOR chunk swizzle
__device__ __forceinline__ int swz(int row, int chunk) {
  return row * 128 + ((chunk ^ (row & 7)) << 4);
}

// ---------------------------------------------------------------------------
// fp32 -> bf16 for 6 concatenated sources into one contiguous dest.
// ---------------------------------------------------------------------------
__global__ void f2bf_all(const float* __restrict__ s0, const float* __restrict__ s1,
                         const float* __restrict__ s2, const float* __restrict__ s3,
                         const float* __restrict__ s4, const float* __restrict__ s5,
                         int n0, int n1, int n2, int n3, int n4_, int n5,
                         unsigned short* __restrict__ out) {
  int i = blockIdx.x * blockDim.x + threadIdx.x;
  int j = i;
  const float* src;
  if (j < n0) src = s0;
  else { j -= n0; if (j < n1) src = s1;
  else { j -= n1; if (j < n2) src = s2;
  else { j -= n2; if (j < n3) src = s3;
  else { j -= n3; if (j < n4_) src = s4;
  else { j -= n4_; if (j >= n5) return; src = s5; }}}}}
  float4 v = ((const float4*)src)[j];
  ushort4 o = {f2bf(v.x), f2bf(v.y), f2bf(v.z), f2bf(v.w)};
  ((ushort4*)out)[i] = o;
}

// ---------------------------------------------------------------------------
// bf16 MFMA GEMM, split-K=2 (m97 structure) — used for the Wo projection.
// ---------------------------------------------------------------------------
__global__ __launch_bounds__(256) void gemm_nt_splitk(
    const unsigned short* __restrict__ A, const unsigned short* __restrict__ B,
    float* __restrict__ C0, float* __restrict__ C1, int M, int N, int K) {
  __shared__ unsigned short ldsA[128 * 32];
  __shared__ unsigned short ldsB[128 * 32];
  const int t = threadIdx.x;
  const int l = t & 63, w = t >> 6;
  const int wr = w >> 1, wc = w & 1;
  const int lr = l & 15;
  const int kb = (l >> 4) * 16;
  const int bm = blockIdx.y * 128, bn = blockIdx.x * 128;
  float* C = blockIdx.z ? C1 : C0;
  const int k0base = blockIdx.z * (K >> 1);
  const int kend = k0base + (K >> 1);

  f32x4 acc[4][4] = {};

  for (int k0 = k0base; k0 < kend; k0 += 32) {
    __syncthreads();
#pragma unroll
    for (int it = 0; it < 2; ++it) {
      int s = it * 256 + t;
      int row = s >> 2, cs = (s & 3) * 8;
      GLDS16(A + (size_t)(bm + row) * K + k0 + cs,
             (char*)ldsA + (it * 4 + w) * 1024);
      GLDS16(B + (size_t)(bn + row) * K + k0 + cs,
             (char*)ldsB + (it * 4 + w) * 1024);
    }
    __syncthreads();

    bf16x8 a[4], b[4];
#pragma unroll
    for (int m = 0; m < 4; ++m)
      a[m] = *(const bf16x8*)((const char*)ldsA +
                              (wr * 64 + m * 16 + lr) * 64 + kb);
#pragma unroll
    for (int n = 0; n < 4; ++n)
      b[n] = *(const bf16x8*)((const char*)ldsB +
                              (wc * 64 + n * 16 + lr) * 64 + kb);
#pragma unroll
    for (int m = 0; m < 4; ++m)
#pragma unroll
      for (int n = 0; n < 4; ++n)
        acc[m][n] =
            __builtin_amdgcn_mfma_f32_16x16x32_bf16(a[m], b[n], acc[m][n], 0, 0, 0);
  }

#pragma unroll
  for (int m = 0; m < 4; ++m)
#pragma unroll
    for (int n = 0; n < 4; ++n) {
      int rbase = bm + wr * 64 + m * 16 + ((l >> 4) << 2);
      int cbase = bn + wc * 64 + n * 16 + lr;
#pragma unroll
      for (int j = 0; j < 4; ++j)
        C[(size_t)(rbase + j) * N + cbase] = acc[m][n][j];
    }
}

// ---------------------------------------------------------------------------
// out = a + b (float4 units)
// ---------------------------------------------------------------------------
__global__ void add2_kernel(const float* __restrict__ a,
                            const float* __restrict__ b,
                            float* __restrict__ o, int n4) {
  int i = blockIdx.x * blockDim.x + threadIdx.x;
  if (i >= n4) return;
  float4 x = ((const float4*)a)[i], y = ((const float4*)b)[i];
  ((float4*)o)[i] = make_float4(x.x + y.x, x.y + y.y, x.z + y.z, x.w + y.w);
}

// ---------------------------------------------------------------------------
// 8-wave 256x256 deep-pipelined projection GEMM + RoPE epilogue + direct V^T.
// BK=64 split into 2 K-slices of 32; LDS K-slice-major [kk][row][32e] with
// XOR chunk swizzle (chunk ^= (row>>1)&3). Double-buffered; staging runs one
// K-tile ahead in 4 units (A0,B0,A1,B1), counted vmcnt(4) at phases 1,3.
// cols [0,2048) -> rope -> qbf ; [2048,4096) -> q2bf ; [4096,4608) -> rope ->
// kbf ; [4608,5120) -> vTb transposed.
// ---------------------------------------------------------------------------
__global__ __launch_bounds__(512) void gemm_proj8(
    const unsigned short* __restrict__ A,      // hbf [M][K]
    const unsigned short* __restrict__ Wall,   // [5120][K]
    const float* __restrict__ cosb, const float* __restrict__ sinb,
    unsigned short* __restrict__ qbf, unsigned short* __restrict__ q2bf,
    unsigned short* __restrict__ kbf, unsigned short* __restrict__ vTb,
    int M, int K, int S) {
  __shared__ char lds[131072];  // 2 buffers x (A 32KB | B 32KB)
  const int t = threadIdx.x;
  const int w = t >> 6;
  const int wm = w >> 2, wn = w & 3;
  const int l = t & 63;
  const int li = l & 15, lg4 = l >> 4;
  const int bm = blockIdx.y * 256, bn = blockIdx.x * 256;
  const int NK = K >> 6;

  f32x4 acc[8][4] = {};

  // stage unit u of K-tile kt1 into buffer nb. u&1: 0=A,1=B; u>>1 = K-slice.
#define STAGE_UNIT(kt1, nb, u)                                                \
  {                                                                           \
    const int slice_ = (u) >> 1;                                              \
    const unsigned short* mat_ = ((u) & 1) ? Wall : A;                        \
    const int tb_ = ((u) & 1) ? bn : bm;                                      \
    char* base_ = lds + (nb) * 65536 + (((u) & 1) ? 32768 : 0) +              \
                  slice_ * 16384;                                             \
    _Pragma("unroll")                                                         \
    for (int i_ = 0; i_ < 2; ++i_) {                                          \
      int ss_ = i_ * 512 + t;                                                 \
      int row_ = ss_ >> 2, cc_ = ss_ & 3;                                     \
      int chunk_ = cc_ ^ ((row_ >> 1) & 3);                                   \
      GLDS16(mat_ + (size_t)(tb_ + row_) * K + (kt1) * 64 + slice_ * 32 +     \
                 chunk_ * 8,                                                  \
             base_ + i_ * 8192 + w * 1024);                                   \
    }                                                                         \
  }

  // prologue: stage tile 0 fully into buffer 0; A0,B0 must land.
  STAGE_UNIT(0, 0, 0); STAGE_UNIT(0, 0, 1);
  STAGE_UNIT(0, 0, 2); STAGE_UNIT(0, 0, 3);
  asm volatile("s_waitcnt vmcnt(4)" ::: "memory");
  asm volatile("s_barrier" ::: "memory");

  for (int kt = 0; kt < NK; ++kt) {
    const int cur = kt & 1;
    const bool stg = (kt + 1 < NK);
    char* curA = lds + cur * 65536;
    char* curB = curA + 32768;
#pragma unroll
    for (int q = 0; q < 4; ++q) {
      const int kk = q >> 1, mh = q & 1;
      if (stg) {
        if (q == 0)      STAGE_UNIT(kt + 1, cur ^ 1, 0)
        else if (q == 1) STAGE_UNIT(kt + 1, cur ^ 1, 1)
        else if (q == 2) STAGE_UNIT(kt + 1, cur ^ 1, 2)
        else             STAGE_UNIT(kt + 1, cur ^ 1, 3)
      }
      bf16x8 af[4], bfr[4];
#pragma unroll
      for (int mi = 0; mi < 4; ++mi) {
        int row = wm * 128 + (mh * 4 + mi) * 16 + li;
        af[mi] = *(const bf16x8*)(curA + kk * 16384 + row * 64 +
                                  ((lg4 ^ ((row >> 1) & 3)) << 4));
      }
#pragma unroll
      for (int n = 0; n < 4; ++n) {
        int row = wn * 64 + n * 16 + li;
        bfr[n] = *(const bf16x8*)(curB + kk * 16384 + row * 64 +
                                  ((lg4 ^ ((row >> 1) & 3)) << 4));
      }
      __builtin_amdgcn_s_setprio(1);
#pragma unroll
      for (int mi = 0; mi < 4; ++mi)
#pragma unroll
        for (int n = 0; n < 4; ++n)
          acc[mh * 4 + mi][n] = __builtin_amdgcn_mfma_f32_16x16x32_bf16(
              af[mi], bfr[n], acc[mh * 4 + mi][n], 0, 0, 0);
      __builtin_amdgcn_s_setprio(0);
      // counted vmcnt: unit needed next was issued 3 phases ago; the newest
      // unit (4 loads) may stay in flight. Drain fully on the last tile.
      if (q == 1) {
        if (kt == NK - 1) asm volatile("s_waitcnt vmcnt(0)" ::: "memory");
        else              asm volatile("s_waitcnt vmcnt(4)" ::: "memory");
      } else if (q == 3 && stg) {
        asm volatile("s_waitcnt vmcnt(4)" ::: "memory");
      }
      asm volatile("s_barrier" ::: "memory");
    }
  }
#undef STAGE_UNIT

  // ---- epilogue: segmented outputs with RoPE (8-wave fragment mapping)
  const int seg = bn;  // block-uniform
#pragma unroll
  for (int m = 0; m < 8; ++m) {
    const int row0 = bm + wm * 128 + m * 16 + lg4 * 4;
    if (seg < 2048 || (seg >= 4096 && seg < 4608)) {
      const bool isq = seg < 2048;
#pragma unroll
      for (int j = 0; j < 4; ++j) {
        int row = row0 + j;
        const float* cr = cosb + (size_t)row * 64;
        const float* sr = sinb + (size_t)row * 64;
        float c0 = cr[li], c1 = cr[16 + li], c2 = cr[32 + li], c3 = cr[48 + li];
        float sa = sr[li], sb = sr[16 + li], sc_ = sr[32 + li], sd = sr[48 + li];
        float x0 = acc[m][0][j], x1 = acc[m][1][j];
        float x2 = acc[m][2][j], x3 = acc[m][3][j];
        float y0 = x0 * c0 - x2 * sa;
        float y1 = x1 * c1 - x3 * sb;
        float y2 = x2 * c2 + x0 * sc_;
        float y3 = x3 * c3 + x1 * sd;
        if (isq) {
          size_t ro = (size_t)row * 2048 + bn + wn * 64 + li;
          qbf[ro] = f2bf(y0); qbf[ro + 16] = f2bf(y1);
          qbf[ro + 32] = f2bf(y2); qbf[ro + 48] = f2bf(y3);
        } else {
          size_t ro = (size_t)row * 512 + (bn - 4096) + wn * 64 + li;
          kbf[ro] = f2bf(y0); kbf[ro + 16] = f2bf(y1);
          kbf[ro + 32] = f2bf(y2); kbf[ro + 48] = f2bf(y3);
        }
      }
    } else if (seg < 4096) {  // q2 -> bf16
#pragma unroll
      for (int n = 0; n < 4; ++n) {
        int col = bn - 2048 + wn * 64 + n * 16 + li;
#pragma unroll
        for (int j = 0; j < 4; ++j)
          q2bf[(size_t)(row0 + j) * 2048 + col] = f2bf(acc[m][n][j]);
      }
    } else {  // v -> vT bf16 direct (j=0..3 consecutive s)
      int b_ = row0 / S, s = row0 % S;
#pragma unroll
      for (int n = 0; n < 4; ++n) {
        int col = (bn - 4608) + wn * 64 + n * 16 + li;
        int gg = col >> 6, d = col & 63;
        ushort4 o = {f2bf(acc[m][n][0]), f2bf(acc[m][n][1]),
                     f2bf(acc[m][n][2]), f2bf(acc[m][n][3])};
        *(ushort4*)&vTb[(((size_t)b_ * NKV + gg) * 64 + d) * S + s] = o;
      }
    }
  }
}

// ---------------------------------------------------------------------------
// KB key slice: kbkh[j][c] = bf16(kb_keys[j*KBROW + c]), j<128, c<2048.
// ---------------------------------------------------------------------------
__global__ void kbkh_kernel(const float* __restrict__ kbk,
                            unsigned short* __restrict__ out) {
  int i = blockIdx.x * blockDim.x + threadIdx.x;
  if (i >= 128 * 512) return;
  int j = i >> 9, c4 = (i & 511) * 4;
  float4 v = *(const float4*)&kbk[(size_t)j * KBROW + c4];
  ushort4 o = {f2bf(v.x), f2bf(v.y), f2bf(v.z), f2bf(v.w)};
  *(ushort4*)&out[(size_t)j * 2048 + c4] = o;
}

// ---------------------------------------------------------------------------
// Gathered + transposed KB values -> [B][NH][64][128] bf16.
// ---------------------------------------------------------------------------
__global__ __launch_bounds__(256) void kbvgt_kernel(
    const float* __restrict__ kbv, const int* __restrict__ topi,
    unsigned short* __restrict__ kbvgT, int B) {
  int h = blockIdx.x % NH, b = blockIdx.x / NH;
  __shared__ unsigned short gt[128][72];
  __shared__ int lidx[TOPK];
  int t = threadIdx.x;
  if (t < TOPK) lidx[t] = topi[b * TOPK + t];
  __syncthreads();
#pragma unroll
  for (int it = 0; it < 8; ++it) {
    int slot = it * 256 + t;
    int j = slot >> 4, d4 = (slot & 15) * 4;
    float4 v = *(const float4*)&kbv[(size_t)lidx[j] * KBROW + h * 64 + d4];
    gt[j][d4] = f2bf(v.x); gt[j][d4 + 1] = f2bf(v.y);
    gt[j][d4 + 2] = f2bf(v.z); gt[j][d4 + 3] = f2bf(v.w);
  }
  __syncthreads();
#pragma unroll
  for (int it = 0; it < 4; ++it) {
    int slot = it * 256 + t;
    int d = slot >> 4, j8 = (slot & 15) * 8;
    u16x8 o;
#pragma unroll
    for (int j = 0; j < 8; ++j) o[j] = gt[j8 + j][d];
    *(u16x8*)&kbvgT[(((size_t)b * NH + h) * 64 + d) * 128 + j8] = o;
  }
}

// ---------------------------------------------------------------------------
// Column-sum stage 1: part[b][ch][c] = sum over 32-row chunk (f64).
// ---------------------------------------------------------------------------
__global__ __launch_bounds__(256) void hsum1_kernel(
    const float* __restrict__ hidden, double* __restrict__ part,
    int B, int S, int H) {
  const int nhb = H >> 8;
  int hb = blockIdx.x % nhb;
  int ch = (blockIdx.x / nhb) % HCH;
  int b  = blockIdx.x / (nhb * HCH);
  int c  = hb * 256 + threadIdx.x;
  int rows = S / HCH;
  const float* p = hidden + ((size_t)b * S + (size_t)ch * rows) * H + c;
  double acc = 0.0;
  for (int s = 0; s < rows; ++s) acc += (double)p[(size_t)s * H];
  part[((size_t)b * HCH + ch) * H + c] = acc;
}

// ---------------------------------------------------------------------------
// Column-sum stage 2: Hsum[b][c] = sum_ch part[b][ch][c] (f64, fixed order).
// ---------------------------------------------------------------------------
__global__ void hsum2_kernel(const double* __restrict__ part,
                             float* __restrict__ Hsum, int B, int H) {
  int idx = blockIdx.x * blockDim.x + threadIdx.x;
  if (idx >= B * H) return;
  int b = idx / H, c = idx % H;
  const double* p = part + (size_t)b * HCH * H + c;
  double acc = 0.0;
#pragma unroll
  for (int ch = 0; ch < HCH; ++ch) acc += p[(size_t)ch * H];
  Hsum[idx] = (float)acc;
}

// ---------------------------------------------------------------------------
// Qs[b][c] = sum_k Hsum[b][k] * Wq2[c][k]  (fp32 inputs, f64 accum).
// ---------------------------------------------------------------------------
__global__ void qs_kernel(const float* __restrict__ Hsum,
                          const float* __restrict__ Wq2,
                          float* __restrict__ Qs, int B, int H) {
  int task = (blockIdx.x * blockDim.x + threadIdx.x) >> 6;
  int lane = threadIdx.x & 63;
  if (task >= B * NH * HD) return;
  int b = task / (NH * HD), c = task % (NH * HD);
  const float* hs = Hsum + (size_t)b * H;
  const float* wr = Wq2 + (size_t)c * H;
  double acc = 0.0;
  for (int k = lane; k < H; k += 64) acc += (double)hs[k] * (double)wr[k];
#pragma unroll
  for (int off = 32; off; off >>= 1) acc += __shfl_xor(acc, off);
  if (lane == 0) Qs[task] = (float)acc;
}

// ---------------------------------------------------------------------------
// scores[b][l] = 0.125 * dot(Qs[b,:], kb_keys[l, 0:2048]) (f64 acc)
// ---------------------------------------------------------------------------
__global__ void scores_kernel(const float* __restrict__ Qs,
                              const float* __restrict__ kbk,
                              float* __restrict__ scores, int B, int KBL) {
  int task = (blockIdx.x * blockDim.x + threadIdx.x) >> 6;
  int lane = threadIdx.x & 63;
  if (task >= B * KBL) return;
  int b = task / KBL, l = task % KBL;
  const float* kr = kbk + (size_t)l * KBROW;
  const float* qd = Qs + (size_t)b * NH * HD;
  double acc = 0.0;
  for (int c = lane; c < NH * HD; c += 64) acc += (double)qd[c] * (double)kr[c];
#pragma unroll
  for (int off = 32; off; off >>= 1) acc += __shfl_xor(acc, off);
  if (lane == 0) scores[task] = (float)(0.125 * acc);
}

// ---------------------------------------------------------------------------
// Top-K by rank-counting (stable descending == lax.top_k).
// ---------------------------------------------------------------------------
__global__ __launch_bounds__(256) void topk_kernel(
    const float* __restrict__ scores, int* __restrict__ top_idx, int KBL) {
  __shared__ float ls[512];
  int b = blockIdx.x, t = threadIdx.x;
  for (int i = t; i < KBL; i += 256) ls[i] = scores[(size_t)b * KBL + i];
  __syncthreads();
  for (int l = t; l < KBL; l += 256) {
    float sl = ls[l];
    int rank = 0;
    for (int j = 0; j < KBL; ++j) {
      float sj = ls[j];
      rank += (sj > sl || (sj == sl && j < l)) ? 1 : 0;
    }
    if (rank < TOPK) top_idx[b * TOPK + rank] = l;
  }
}

// ---------------------------------------------------------------------------
// padflag[b*S+s] = all(mask[b,0,s,:] < 0)
// ---------------------------------------------------------------------------
__global__ void padflag_kernel(const float* __restrict__ mask,
                               int* __restrict__ flags, int BS, int S) {
  int w = (blockIdx.x * blockDim.x + threadIdx.x) >> 6;
  int lane = threadIdx.x & 63;
  if (w >= BS) return;
  const float* row = mask + (size_t)w * S;
  bool ok = true;
  for (int j = lane; j < S; j += 64) ok = ok && (row[j] < 0.f);
  int allv = __all(ok ? 1 : 0);
  if (lane == 0) flags[w] = allv;
}

// ---------------------------------------------------------------------------
// Load one K/V chunk's staged data into registers (4 x bf16x8 per thread).
// ---------------------------------------------------------------------------
__device__ __forceinline__ void load_chunk(
    int ch, int t, int b, int h, int g, int S,
    const unsigned short* __restrict__ kbf, const unsigned short* __restrict__ vTb,
    const unsigned short* __restrict__ kbkh, const unsigned short* __restrict__ kbvgT,
    bf16x8* st) {
  bool iskb = ch < 2;
  int j0 = iskb ? ch * 64 : (ch - 2) * 64;
#pragma unroll
  for (int it = 0; it < 4; ++it) {
    int slot = it * 256 + t;
    int tile = slot >> 9, row = (slot >> 3) & 63, ck = slot & 7;
    const unsigned short* src;
    if (tile == 0)
      src = iskb ? kbkh + (size_t)(j0 + row) * 2048 + h * 64 + ck * 8
                 : kbf + (size_t)(b * S + j0 + row) * 512 + g * 64 + ck * 8;
    else
      src = iskb ? kbvgT + (((size_t)b * NH + h) * 64 + row) * 128 + j0 + ck * 8
                 : vTb + (((size_t)b * NKV + g) * 64 + row) * (size_t)S + j0 + ck * 8;
    st[it] = *(const bf16x8*)src;
  }
}

// ---------------------------------------------------------------------------
// One chunk of QK^T -> online softmax -> PV for one q-tile.
// ---------------------------------------------------------------------------
__device__ __forceinline__ void attn_step(
    const char* smem, char* ptw, const int* padfb, const bf16x8* aq,
    bool iskb, int j0, int s0, int w, int li, int lg4,
    float* m_, float* l_, f32x4* acc) {
  f32x4 cc[4];
  __builtin_amdgcn_s_setprio(1);
#pragma unroll
  for (int cb = 0; cb < 4; ++cb) {
    bf16x8 b0 = *(const bf16x8*)(smem + swz(cb * 16 + li, lg4));
    bf16x8 b1 = *(const bf16x8*)(smem + swz(cb * 16 + li, 4 + lg4));
    f32x4 z = {};
    z = __builtin_amdgcn_mfma_f32_16x16x32_bf16(aq[0], b0, z, 0, 0, 0);
    z = __builtin_amdgcn_mfma_f32_16x16x32_bf16(aq[1], b1, z, 0, 0, 0);
    cc[cb] = z;
  }
  __builtin_amdgcn_s_setprio(0);

  float lgv[4][4];
#pragma unroll
  for (int cb = 0; cb < 4; ++cb)
#pragma unroll
    for (int j = 0; j < 4; ++j) {
      float v = SCALE * cc[cb][j];
      if (iskb) {
        v += C0F + (padfb[w * 16 + lg4 * 4 + j] ? PADF : 0.f);
      } else {
        int key = j0 + cb * 16 + li;
        int srow = s0 + w * 16 + lg4 * 4 + j;
        v += (key <= srow) ? 0.f : PADF;
      }
      lgv[cb][j] = v;
    }
#pragma unroll
  for (int j = 0; j < 4; ++j) {
    float rmax = fmaxf(fmaxf(lgv[0][j], lgv[1][j]), fmaxf(lgv[2][j], lgv[3][j]));
#pragma unroll
    for (int off = 8; off; off >>= 1) rmax = fmaxf(rmax, __shfl_xor(rmax, off));
    float mn = fmaxf(m_[j], rmax);
    float fs = __expf(m_[j] - mn);
    float csum = 0.f;
#pragma unroll
    for (int cb = 0; cb < 4; ++cb) {
      float pv = __expf(lgv[cb][j] - mn);
      csum += pv;
      int key = cb * 16 + li;
      int rloc = lg4 * 4 + j;
      *(unsigned short*)(ptw + swz(rloc, key >> 3) + ((key & 7) << 1)) = f2bf(pv);
    }
#pragma unroll
    for (int off = 8; off; off >>= 1) csum += __shfl_xor(csum, off);
    m_[j] = mn;
    l_[j] = l_[j] * fs + csum;
#pragma unroll
    for (int db = 0; db < 4; ++db) acc[db][j] *= fs;
  }

  bf16x8 pa0 = *(const bf16x8*)(ptw + swz(li, lg4));
  bf16x8 pa1 = *(const bf16x8*)(ptw + swz(li, 4 + lg4));
  __builtin_amdgcn_s_setprio(1);
#pragma unroll
  for (int db = 0; db < 4; ++db) {
    bf16x8 bv0 = *(const bf16x8*)(smem + 8192 + swz(db * 16 + li, lg4));
    bf16x8 bv1 = *(const bf16x8*)(smem + 8192 + swz(db * 16 + li, 4 + lg4));
    acc[db] = __builtin_amdgcn_mfma_f32_16x16x32_bf16(pa0, bv0, acc[db], 0, 0, 0);
    acc[db] = __builtin_amdgcn_mfma_f32_16x16x32_bf16(pa1, bv1, acc[db], 0, 0, 0);
  }
  __builtin_amdgcn_s_setprio(0);
}

// ---------------------------------------------------------------------------
// MFMA fused attention v4 (unchanged from R11): diagonal pairing + async
// reg-staged K/V prefetch + direct-global q fragments.
// ---------------------------------------------------------------------------
__global__ __launch_bounds__(256) void attn_mfma(
    const unsigned short* __restrict__ qbf,    // [B*S][2048] roped bf16
    const unsigned short* __restrict__ q2bf,   // [B*S][2048] bf16
    const unsigned short* __restrict__ kbf,    // [B*S][512] roped bf16
    const unsigned short* __restrict__ vTb,    // [B][NKV][64][S] bf16
    const unsigned short* __restrict__ kbkh,   // [128][2048] bf16
    const unsigned short* __restrict__ kbvgT,  // [B][NH][64][128] bf16
    const int* __restrict__ padflag,           // [B*S]
    unsigned short* __restrict__ attnbf,       // [B*S][2048] bf16
    int B, int S) {
  const int nst = S >> 6;
  const int npair = (nst + 1) >> 1;
  const int p = blockIdx.x % npair;
  const int h = (blockIdx.x / npair) % NH;
  const int b = blockIdx.x / (npair * NH);
  const int stA = p, stB = nst - 1 - p;
  const bool hasB = (stB != stA);
  const int s0A = stA * 64, s0B = stB * 64;
  const int g = h / (NH / NKV);

  __shared__ unsigned short smem[8192];
  __shared__ unsigned short pt[4][1024];
  __shared__ int padf[128];

  const int t = threadIdx.x;
  const int w = t >> 6;
  const int li = t & 15;
  const int lg4 = (t & 63) >> 4;

  const int nch = 2 + stB + 1;

  bf16x8 st[4];
  load_chunk(0, t, b, h, g, S, kbf, vTb, kbkh, kbvgT, st);

  bf16x8 aq0A[2], aq2A[2], aq0B[2], aq2B[2];
  {
    size_t rowA = (size_t)(b * S + s0A + w * 16 + li) * (NH * HD);
    size_t rowB = (size_t)(b * S + s0B + w * 16 + li) * (NH * HD);
#pragma unroll
    for (int kc = 0; kc < 2; ++kc) {
      size_t o = h * 64 + kc * 32 + lg4 * 8;
      aq0A[kc] = *(const bf16x8*)(qbf + rowA + o);
      aq2A[kc] = *(const bf16x8*)(q2bf + rowA + o);
      aq0B[kc] = *(const bf16x8*)(qbf + rowB + o);
      aq2B[kc] = *(const bf16x8*)(q2bf + rowB + o);
    }
  }
  if (t < 64) padf[t] = padflag[b * S + s0A + t];
  else if (t < 128) padf[t] = padflag[b * S + s0B + (t - 64)];

  float mA[4] = {-3.4e38f, -3.4e38f, -3.4e38f, -3.4e38f};
  float mB[4] = {-3.4e38f, -3.4e38f, -3.4e38f, -3.4e38f};
  float lA[4] = {}, lB[4] = {};
  f32x4 accA[4] = {}, accB[4] = {};

  for (int ch = 0; ch < nch; ++ch) {
    const bool iskb = ch < 2;
    const int j0 = iskb ? ch * 64 : (ch - 2) * 64;
    if (ch) __syncthreads();
#pragma unroll
    for (int it = 0; it < 4; ++it) {
      int slot = it * 256 + t;
      int tile = slot >> 9, row = (slot >> 3) & 63, ck = slot & 7;
      *(bf16x8*)((char*)smem + tile * 8192 + swz(row, ck)) = st[it];
    }
    __syncthreads();
    if (ch + 1 < nch) load_chunk(ch + 1, t, b, h, g, S, kbf, vTb, kbkh, kbvgT, st);

    if (iskb || (ch - 2) <= stA)
      attn_step((const char*)smem, (char*)pt[w], padf, iskb ? aq2A : aq0A,
                iskb, j0, s0A, w, li, lg4, mA, lA, accA);
    if (hasB)
      attn_step((const char*)smem, (char*)pt[w], padf + 64, iskb ? aq2B : aq0B,
                iskb, j0, s0B, w, li, lg4, mB, lB, accB);
  }

#pragma unroll
  for (int j = 0; j < 4; ++j) {
    float inv = 1.f / lA[j];
    size_t o = (size_t)(b * S + s0A + w * 16 + lg4 * 4 + j) * (NH * HD) + h * 64 + li;
#pragma unroll
    for (int db = 0; db < 4; ++db) attnbf[o + db * 16] = f2bf(accA[db][j] * inv);
  }
  if (hasB) {
#pragma unroll
    for (int j = 0; j < 4; ++j) {
      float inv = 1.f / lB[j];
      size_t o = (size_t)(b * S + s0B + w * 16 + lg4 * 4 + j) * (NH * HD) + h * 64 + li;
#pragma unroll
      for (int db = 0; db < 4; ++db) attnbf[o + db * 16] = f2bf(accB[db][j] * inv);
    }
  }
}

// ---------------------------------------------------------------------------
extern "C" void kernel_launch(void* const* d_in, const int* in_sizes, int n_in,
                              void* d_out, int out_size, void* d_ws, size_t ws_size,
                              hipStream_t stream) {
  const float* hidden = (const float*)d_in[0];
  const float* cosb   = (const float*)d_in[1];
  const float* sinb   = (const float*)d_in[2];
  const float* mask   = (const float*)d_in[3];
  const float* kbk    = (const float*)d_in[4];
  const float* kbv    = (const float*)d_in[5];
  const float* Wq     = (const float*)d_in[6];
  const float* Wq2    = (const float*)d_in[7];
  const float* Wk     = (const float*)d_in[8];
  const float* Wv     = (const float*)d_in[9];
  const float* Wo     = (const float*)d_in[10];
  float* out = (float*)d_out;

  const int H   = in_sizes[6] / (NH * HD);             // 2048
  const int KBL = in_sizes[4] / KBROW;                 // 400
  const long long BSll = (long long)in_sizes[0] / H;
  const int S = (int)((long long)in_sizes[3] / BSll);  // 1024
  const int B = (int)(BSll / S);                       // 2
  const int BS = B * S;
  const int NQ = NH * HD;                              // 2048
  const int NKVD = NKV * HD;                           // 512
  const int NTOT = NQ + NQ + NKVD + NKVD;              // 5120

  float* ws = (float*)d_ws;
  size_t off = 0;
  double* hpart = (double*)(ws + off); off += (size_t)B * HCH * H * 2;
  float* Hsum = ws + off; off += (size_t)B * H;
  float* Qs   = ws + off; off += (size_t)B * NQ;
  float* sc   = ws + off; off += (size_t)B * KBL;
  int* topi   = (int*)(ws + off); off += (size_t)B * TOPK;
  int* padfl  = (int*)(ws + off); off += (size_t)BS;
  unsigned short* hbf    = (unsigned short*)(ws + off); off += (size_t)BS * H / 2;
  unsigned short* wall   = (unsigned short*)(ws + off); off += (size_t)NTOT * H / 2;
  unsigned short* wobf   = (unsigned short*)(ws + off); off += (size_t)H * NQ / 2;
  unsigned short* attnbf = (unsigned short*)(ws + off); off += (size_t)BS * NQ / 2;
  unsigned short* qbf    = (unsigned short*)(ws + off); off += (size_t)BS * NQ / 2;
  unsigned short* q2bf   = (unsigned short*)(ws + off); off += (size_t)BS * NQ / 2;
  unsigned short* kbf    = (unsigned short*)(ws + off); off += (size_t)BS * NKVD / 2;
  unsigned short* vTb    = (unsigned short*)(ws + off); off += (size_t)BS * NKVD / 2;
  unsigned short* kbkh   = (unsigned short*)(ws + off); off += (size_t)128 * NQ / 2;
  unsigned short* kbvgT  = (unsigned short*)(ws + off); off += (size_t)B * NH * HD * TOPK / 2;
  // split-K partials alias dead regions
  float* c0 = (float*)qbf;   // dead after attn_mfma
  float* c1 = (float*)wall;  // dead after gemm_proj8
  (void)ws_size; (void)n_in; (void)out_size;

  // 0: all fp32 -> bf16 conversions (dest hbf|wall|wobf contiguous)
  {
    int n0 = BS * H / 4, n1 = NQ * H / 4, n2 = NQ * H / 4;
    int n3 = NKVD * H / 4, n4_ = NKVD * H / 4, n5 = H * NQ / 4;
    int ntot = n0 + n1 + n2 + n3 + n4_ + n5;
    f2bf_all<<<(ntot + 255) / 256, 256, 0, stream>>>(
        hidden, Wq, Wq2, Wk, Wv, Wo, n0, n1, n2, n3, n4_, n5, hbf);
  }

  // 1: fused projections + RoPE + direct V^T (8-wave deep-pipelined)
  gemm_proj8<<<dim3(NTOT / 256, BS / 256), 512, 0, stream>>>(
      hbf, wall, cosb, sinb, qbf, q2bf, kbf, vTb, BS, H, S);

  // 2-6: exact fp32 scores path + top-k + padding
  hsum1_kernel<<<B * HCH * (H / 256), 256, 0, stream>>>(hidden, hpart, B, S, H);
  hsum2_kernel<<<(B * H + 255) / 256, 256, 0, stream>>>(hpart, Hsum, B, H);
  qs_kernel<<<(B * NQ * 64 + 255) / 256, 256, 0, stream>>>(Hsum, Wq2, Qs, B, H);
  scores_kernel<<<(B * KBL * 64 + 255) / 256, 256, 0, stream>>>(Qs, kbk, sc, B, KBL);
  topk_kernel<<<B, 256, 0, stream>>>(sc, topi, KBL);
  padflag_kernel<<<(BS * 64 + 255) / 256, 256, 0, stream>>>(mask, padfl, BS, S);

  // 7-8: KB bf16 staging
  kbkh_kernel<<<(128 * 512 + 255) / 256, 256, 0, stream>>>(kbk, kbkh);
  kbvgt_kernel<<<B * NH, 256, 0, stream>>>(kbv, topi, kbvgT, B);

  // 9: fused attention (paired tiles, async prefetch)
  {
    int nst = S / 64;
    int npair = (nst + 1) / 2;
    attn_mfma<<<B * NH * npair, 256, 0, stream>>>(
        qbf, q2bf, kbf, vTb, kbkh, kbvgT, padfl, attnbf, B, S);
  }

  // 10-11: output projection, split-K=2 + partial add
  gemm_nt_splitk<<<dim3(H / 128, BS / 128, 2), 256, 0, stream>>>(
      attnbf, wobf, c0, c1, BS, H, NQ);
  add2_kernel<<<(BS * H / 4 + 255) / 256, 256, 0, stream>>>(c0, c1, out, BS * H / 4);
}

// Round 13
// 256.237 us; speedup vs baseline: 11.6670x; 1.0256x over previous
//
#include <hip/hip_runtime.h>
#include <hip/hip_bf16.h>
#include <math.h>

#define NH 32
#define NKV 8
#define HD 64
#define NSLOTS 11
#define TOPK 128
#define KBROW (NSLOTS * NH * HD)   // 22528
#define PADF (-3.3895313892515355e+38f)
#define C0F  (-0.24686007793152578f)   // -ln(128)+ln(100)
#define SCALE 0.125f
#define HCH 32                         // S-chunks for hierarchical column sum

typedef __attribute__((ext_vector_type(8))) __bf16 bf16x8;
typedef __attribute__((ext_vector_type(8))) unsigned short u16x8;
typedef __attribute__((ext_vector_type(4))) float f32x4;

#define GLDS16(gp, lp)                                                        \
  __builtin_amdgcn_global_load_lds(                                           \
      (__attribute__((address_space(1))) void*)(gp),                          \
      (__attribute__((address_space(3))) void*)(lp), 16, 0, 0)

__device__ __forceinline__ unsigned short f2bf(float f) {
  unsigned int u = __float_as_uint(f);
  u = (u + 0x7fffu + ((u >> 16) & 1u)) >> 16;
  return (unsigned short)u;
}

// byte offset into a 64-col bf16 tile (128 B/row) with XOR chunk swizzle
__device__ __forceinline__ int swz(int row, int chunk) {
  return row * 128 + ((chunk ^ (row & 7)) << 4);
}

// ---------------------------------------------------------------------------
// fp32 -> bf16 for 6 concatenated sources into one contiguous dest.
// ---------------------------------------------------------------------------
__global__ void f2bf_all(const float* __restrict__ s0, const float* __restrict__ s1,
                         const float* __restrict__ s2, const float* __restrict__ s3,
                         const float* __restrict__ s4, const float* __restrict__ s5,
                         int n0, int n1, int n2, int n3, int n4_, int n5,
                         unsigned short* __restrict__ out) {
  int i = blockIdx.x * blockDim.x + threadIdx.x;
  int j = i;
  const float* src;
  if (j < n0) src = s0;
  else { j -= n0; if (j < n1) src = s1;
  else { j -= n1; if (j < n2) src = s2;
  else { j -= n2; if (j < n3) src = s3;
  else { j -= n3; if (j < n4_) src = s4;
  else { j -= n4_; if (j >= n5) return; src = s5; }}}}}
  float4 v = ((const float4*)src)[j];
  ushort4 o = {f2bf(v.x), f2bf(v.y), f2bf(v.z), f2bf(v.w)};
  ((ushort4*)out)[i] = o;
}

// ---------------------------------------------------------------------------
// bf16 MFMA GEMM, split-K=2 (m97 structure) — used for the Wo projection.
// ---------------------------------------------------------------------------
__global__ __launch_bounds__(256) void gemm_nt_splitk(
    const unsigned short* __restrict__ A, const unsigned short* __restrict__ B,
    float* __restrict__ C0, float* __restrict__ C1, int M, int N, int K) {
  __shared__ unsigned short ldsA[128 * 32];
  __shared__ unsigned short ldsB[128 * 32];
  const int t = threadIdx.x;
  const int l = t & 63, w = t >> 6;
  const int wr = w >> 1, wc = w & 1;
  const int lr = l & 15;
  const int kb = (l >> 4) * 16;
  const int bm = blockIdx.y * 128, bn = blockIdx.x * 128;
  float* C = blockIdx.z ? C1 : C0;
  const int k0base = blockIdx.z * (K >> 1);
  const int kend = k0base + (K >> 1);

  f32x4 acc[4][4] = {};

  for (int k0 = k0base; k0 < kend; k0 += 32) {
    __syncthreads();
#pragma unroll
    for (int it = 0; it < 2; ++it) {
      int s = it * 256 + t;
      int row = s >> 2, cs = (s & 3) * 8;
      GLDS16(A + (size_t)(bm + row) * K + k0 + cs,
             (char*)ldsA + (it * 4 + w) * 1024);
      GLDS16(B + (size_t)(bn + row) * K + k0 + cs,
             (char*)ldsB + (it * 4 + w) * 1024);
    }
    __syncthreads();

    bf16x8 a[4], b[4];
#pragma unroll
    for (int m = 0; m < 4; ++m)
      a[m] = *(const bf16x8*)((const char*)ldsA +
                              (wr * 64 + m * 16 + lr) * 64 + kb);
#pragma unroll
    for (int n = 0; n < 4; ++n)
      b[n] = *(const bf16x8*)((const char*)ldsB +
                              (wc * 64 + n * 16 + lr) * 64 + kb);
#pragma unroll
    for (int m = 0; m < 4; ++m)
#pragma unroll
      for (int n = 0; n < 4; ++n)
        acc[m][n] =
            __builtin_amdgcn_mfma_f32_16x16x32_bf16(a[m], b[n], acc[m][n], 0, 0, 0);
  }

#pragma unroll
  for (int m = 0; m < 4; ++m)
#pragma unroll
    for (int n = 0; n < 4; ++n) {
      int rbase = bm + wr * 64 + m * 16 + ((l >> 4) << 2);
      int cbase = bn + wc * 64 + n * 16 + lr;
#pragma unroll
      for (int j = 0; j < 4; ++j)
        C[(size_t)(rbase + j) * N + cbase] = acc[m][n][j];
    }
}

// ---------------------------------------------------------------------------
// out = a + b (float4 units)
// ---------------------------------------------------------------------------
__global__ void add2_kernel(const float* __restrict__ a,
                            const float* __restrict__ b,
                            float* __restrict__ o, int n4) {
  int i = blockIdx.x * blockDim.x + threadIdx.x;
  if (i >= n4) return;
  float4 x = ((const float4*)a)[i], y = ((const float4*)b)[i];
  ((float4*)o)[i] = make_float4(x.x + y.x, x.y + y.y, x.z + y.z, x.w + y.w);
}

// ---------------------------------------------------------------------------
// 8-wave 256x256 deep-pipelined projection GEMM + RoPE epilogue + direct V^T.
// v3: read-ahead ds_reads (issued one phase before their MFMA), B-fragment
// reuse across the two mh phases of each kk, 2 barriers/K-tile (only the
// vmcnt-visibility points). Staging ledger identical to v2 (verified).
// ---------------------------------------------------------------------------
__global__ __launch_bounds__(512) void gemm_proj8(
    const unsigned short* __restrict__ A,      // hbf [M][K]
    const unsigned short* __restrict__ Wall,   // [5120][K]
    const float* __restrict__ cosb, const float* __restrict__ sinb,
    unsigned short* __restrict__ qbf, unsigned short* __restrict__ q2bf,
    unsigned short* __restrict__ kbf, unsigned short* __restrict__ vTb,
    int M, int K, int S) {
  __shared__ char lds[131072];  // 2 buffers x (A 32KB | B 32KB)
  const int t = threadIdx.x;
  const int w = t >> 6;
  const int wm = w >> 2, wn = w & 3;
  const int l = t & 63;
  const int li = l & 15, lg4 = l >> 4;
  const int bm = blockIdx.y * 256, bn = blockIdx.x * 256;
  const int NK = K >> 6;

  f32x4 acc[8][4] = {};

  // stage unit u of K-tile kt1 into buffer nb. u&1: 0=A,1=B; u>>1 = K-slice.
#define STAGE_UNIT(kt1, nb, u)                                                \
  {                                                                           \
    const int slice_ = (u) >> 1;                                              \
    const unsigned short* mat_ = ((u) & 1) ? Wall : A;                        \
    const int tb_ = ((u) & 1) ? bn : bm;                                      \
    char* base_ = lds + (nb) * 65536 + (((u) & 1) ? 32768 : 0) +              \
                  slice_ * 16384;                                             \
    _Pragma("unroll")                                                         \
    for (int i_ = 0; i_ < 2; ++i_) {                                          \
      int ss_ = i_ * 512 + t;                                                 \
      int row_ = ss_ >> 2, cc_ = ss_ & 3;                                     \
      int chunk_ = cc_ ^ ((row_ >> 1) & 3);                                   \
      GLDS16(mat_ + (size_t)(tb_ + row_) * K + (kt1) * 64 + slice_ * 32 +     \
                 chunk_ * 8,                                                  \
             base_ + i_ * 8192 + w * 1024);                                   \
    }                                                                         \
  }

  // prologue: stage tile 0 fully into buffer 0; A0,B0 (units 0,1) must land.
  STAGE_UNIT(0, 0, 0); STAGE_UNIT(0, 0, 1);
  STAGE_UNIT(0, 0, 2); STAGE_UNIT(0, 0, 3);
  asm volatile("s_waitcnt vmcnt(4)" ::: "memory");
  asm volatile("s_barrier" ::: "memory");

  for (int kt = 0; kt < NK; ++kt) {
    const int cur = kt & 1;
    const bool stg = (kt + 1 < NK);
    char* curA = lds + cur * 65536;
    char* curB = curA + 32768;
#pragma unroll
    for (int kk = 0; kk < 2; ++kk) {
      // reads for this kk (units kk*2, kk*2+1 are barrier-visible here)
      bf16x8 bfr[4], af_a[4], af_b[4];
#pragma unroll
      for (int n = 0; n < 4; ++n) {
        int row = wn * 64 + n * 16 + li;
        bfr[n] = *(const bf16x8*)(curB + kk * 16384 + row * 64 +
                                  ((lg4 ^ ((row >> 1) & 3)) << 4));
      }
#pragma unroll
      for (int mi = 0; mi < 4; ++mi) {
        int row = wm * 128 + mi * 16 + li;
        af_a[mi] = *(const bf16x8*)(curA + kk * 16384 + row * 64 +
                                    ((lg4 ^ ((row >> 1) & 3)) << 4));
      }
      // phase A (mh=0): stage next-tile unit kk*2
      if (stg) STAGE_UNIT(kt + 1, cur ^ 1, kk * 2)
      // read-ahead for phase B (mh=1) — consumed after phase A's MFMAs
#pragma unroll
      for (int mi = 0; mi < 4; ++mi) {
        int row = wm * 128 + (4 + mi) * 16 + li;
        af_b[mi] = *(const bf16x8*)(curA + kk * 16384 + row * 64 +
                                    ((lg4 ^ ((row >> 1) & 3)) << 4));
      }
      __builtin_amdgcn_s_setprio(1);
#pragma unroll
      for (int mi = 0; mi < 4; ++mi)
#pragma unroll
        for (int n = 0; n < 4; ++n)
          acc[mi][n] = __builtin_amdgcn_mfma_f32_16x16x32_bf16(
              af_a[mi], bfr[n], acc[mi][n], 0, 0, 0);
      __builtin_amdgcn_s_setprio(0);
      // phase B (mh=1): stage next-tile unit kk*2+1, MFMA on read-ahead regs
      if (stg) STAGE_UNIT(kt + 1, cur ^ 1, kk * 2 + 1)
      __builtin_amdgcn_s_setprio(1);
#pragma unroll
      for (int mi = 0; mi < 4; ++mi)
#pragma unroll
        for (int n = 0; n < 4; ++n)
          acc[4 + mi][n] = __builtin_amdgcn_mfma_f32_16x16x32_bf16(
              af_b[mi], bfr[n], acc[4 + mi][n], 0, 0, 0);
      __builtin_amdgcn_s_setprio(0);
      // vmcnt ledger (identical to v2): after kk=0 ensure units 2,3 of cur;
      // after kk=1 ensure units 0,1 of next tile. Never 0 mid-loop.
      if (kk == 0) {
        if (kt == NK - 1) asm volatile("s_waitcnt vmcnt(0)" ::: "memory");
        else              asm volatile("s_waitcnt vmcnt(4)" ::: "memory");
        asm volatile("s_barrier" ::: "memory");
      } else {
        if (stg) {
          asm volatile("s_waitcnt vmcnt(4)" ::: "memory");
          asm volatile("s_barrier" ::: "memory");
        }
      }
    }
  }
#undef STAGE_UNIT

  // ---- epilogue: segmented outputs with RoPE (8-wave fragment mapping)
  const int seg = bn;  // block-uniform
#pragma unroll
  for (int m = 0; m < 8; ++m) {
    const int row0 = bm + wm * 128 + m * 16 + lg4 * 4;
    if (seg < 2048 || (seg >= 4096 && seg < 4608)) {
      const bool isq = seg < 2048;
#pragma unroll
      for (int j = 0; j < 4; ++j) {
        int row = row0 + j;
        const float* cr = cosb + (size_t)row * 64;
        const float* sr = sinb + (size_t)row * 64;
        float c0 = cr[li], c1 = cr[16 + li], c2 = cr[32 + li], c3 = cr[48 + li];
        float sa = sr[li], sb = sr[16 + li], sc_ = sr[32 + li], sd = sr[48 + li];
        float x0 = acc[m][0][j], x1 = acc[m][1][j];
        float x2 = acc[m][2][j], x3 = acc[m][3][j];
        float y0 = x0 * c0 - x2 * sa;
        float y1 = x1 * c1 - x3 * sb;
        float y2 = x2 * c2 + x0 * sc_;
        float y3 = x3 * c3 + x1 * sd;
        if (isq) {
          size_t ro = (size_t)row * 2048 + bn + wn * 64 + li;
          qbf[ro] = f2bf(y0); qbf[ro + 16] = f2bf(y1);
          qbf[ro + 32] = f2bf(y2); qbf[ro + 48] = f2bf(y3);
        } else {
          size_t ro = (size_t)row * 512 + (bn - 4096) + wn * 64 + li;
          kbf[ro] = f2bf(y0); kbf[ro + 16] = f2bf(y1);
          kbf[ro + 32] = f2bf(y2); kbf[ro + 48] = f2bf(y3);
        }
      }
    } else if (seg < 4096) {  // q2 -> bf16
#pragma unroll
      for (int n = 0; n < 4; ++n) {
        int col = bn - 2048 + wn * 64 + n * 16 + li;
#pragma unroll
        for (int j = 0; j < 4; ++j)
          q2bf[(size_t)(row0 + j) * 2048 + col] = f2bf(acc[m][n][j]);
      }
    } else {  // v -> vT bf16 direct (j=0..3 consecutive s)
      int b_ = row0 / S, s = row0 % S;
#pragma unroll
      for (int n = 0; n < 4; ++n) {
        int col = (bn - 4608) + wn * 64 + n * 16 + li;
        int gg = col >> 6, d = col & 63;
        ushort4 o = {f2bf(acc[m][n][0]), f2bf(acc[m][n][1]),
                     f2bf(acc[m][n][2]), f2bf(acc[m][n][3])};
        *(ushort4*)&vTb[(((size_t)b_ * NKV + gg) * 64 + d) * S + s] = o;
      }
    }
  }
}

// ---------------------------------------------------------------------------
// KB key slice: kbkh[j][c] = bf16(kb_keys[j*KBROW + c]), j<128, c<2048.
// ---------------------------------------------------------------------------
__global__ void kbkh_kernel(const float* __restrict__ kbk,
                            unsigned short* __restrict__ out) {
  int i = blockIdx.x * blockDim.x + threadIdx.x;
  if (i >= 128 * 512) return;
  int j = i >> 9, c4 = (i & 511) * 4;
  float4 v = *(const float4*)&kbk[(size_t)j * KBROW + c4];
  ushort4 o = {f2bf(v.x), f2bf(v.y), f2bf(v.z), f2bf(v.w)};
  *(ushort4*)&out[(size_t)j * 2048 + c4] = o;
}

// ---------------------------------------------------------------------------
// Gathered + transposed KB values -> [B][NH][64][128] bf16.
// ---------------------------------------------------------------------------
__global__ __launch_bounds__(256) void kbvgt_kernel(
    const float* __restrict__ kbv, const int* __restrict__ topi,
    unsigned short* __restrict__ kbvgT, int B) {
  int h = blockIdx.x % NH, b = blockIdx.x / NH;
  __shared__ unsigned short gt[128][72];
  __shared__ int lidx[TOPK];
  int t = threadIdx.x;
  if (t < TOPK) lidx[t] = topi[b * TOPK + t];
  __syncthreads();
#pragma unroll
  for (int it = 0; it < 8; ++it) {
    int slot = it * 256 + t;
    int j = slot >> 4, d4 = (slot & 15) * 4;
    float4 v = *(const float4*)&kbv[(size_t)lidx[j] * KBROW + h * 64 + d4];
    gt[j][d4] = f2bf(v.x); gt[j][d4 + 1] = f2bf(v.y);
    gt[j][d4 + 2] = f2bf(v.z); gt[j][d4 + 3] = f2bf(v.w);
  }
  __syncthreads();
#pragma unroll
  for (int it = 0; it < 4; ++it) {
    int slot = it * 256 + t;
    int d = slot >> 4, j8 = (slot & 15) * 8;
    u16x8 o;
#pragma unroll
    for (int j = 0; j < 8; ++j) o[j] = gt[j8 + j][d];
    *(u16x8*)&kbvgT[(((size_t)b * NH + h) * 64 + d) * 128 + j8] = o;
  }
}

// ---------------------------------------------------------------------------
// Column-sum stage 1: part[b][ch][c] = sum over 32-row chunk (f64).
// ---------------------------------------------------------------------------
__global__ __launch_bounds__(256) void hsum1_kernel(
    const float* __restrict__ hidden, double* __restrict__ part,
    int B, int S, int H) {
  const int nhb = H >> 8;
  int hb = blockIdx.x % nhb;
  int ch = (blockIdx.x / nhb) % HCH;
  int b  = blockIdx.x / (nhb * HCH);
  int c  = hb * 256 + threadIdx.x;
  int rows = S / HCH;
  const float* p = hidden + ((size_t)b * S + (size_t)ch * rows) * H + c;
  double acc = 0.0;
  for (int s = 0; s < rows; ++s) acc += (double)p[(size_t)s * H];
  part[((size_t)b * HCH + ch) * H + c] = acc;
}

// ---------------------------------------------------------------------------
// Column-sum stage 2: Hsum[b][c] = sum_ch part[b][ch][c] (f64, fixed order).
// ---------------------------------------------------------------------------
__global__ void hsum2_kernel(const double* __restrict__ part,
                             float* __restrict__ Hsum, int B, int H) {
  int idx = blockIdx.x * blockDim.x + threadIdx.x;
  if (idx >= B * H) return;
  int b = idx / H, c = idx % H;
  const double* p = part + (size_t)b * HCH * H + c;
  double acc = 0.0;
#pragma unroll
  for (int ch = 0; ch < HCH; ++ch) acc += p[(size_t)ch * H];
  Hsum[idx] = (float)acc;
}

// ---------------------------------------------------------------------------
// Qs[b][c] = sum_k Hsum[b][k] * Wq2[c][k]  (fp32 inputs, f64 accum).
// ---------------------------------------------------------------------------
__global__ void qs_kernel(const float* __restrict__ Hsum,
                          const float* __restrict__ Wq2,
                          float* __restrict__ Qs, int B, int H) {
  int task = (blockIdx.x * blockDim.x + threadIdx.x) >> 6;
  int lane = threadIdx.x & 63;
  if (task >= B * NH * HD) return;
  int b = task / (NH * HD), c = task % (NH * HD);
  const float* hs = Hsum + (size_t)b * H;
  const float* wr = Wq2 + (size_t)c * H;
  double acc = 0.0;
  for (int k = lane; k < H; k += 64) acc += (double)hs[k] * (double)wr[k];
#pragma unroll
  for (int off = 32; off; off >>= 1) acc += __shfl_xor(acc, off);
  if (lane == 0) Qs[task] = (float)acc;
}

// ---------------------------------------------------------------------------
// scores[b][l] = 0.125 * dot(Qs[b,:], kb_keys[l, 0:2048]) (f64 acc)
// ---------------------------------------------------------------------------
__global__ void scores_kernel(const float* __restrict__ Qs,
                              const float* __restrict__ kbk,
                              float* __restrict__ scores, int B, int KBL) {
  int task = (blockIdx.x * blockDim.x + threadIdx.x) >> 6;
  int lane = threadIdx.x & 63;
  if (task >= B * KBL) return;
  int b = task / KBL, l = task % KBL;
  const float* kr = kbk + (size_t)l * KBROW;
  const float* qd = Qs + (size_t)b * NH * HD;
  double acc = 0.0;
  for (int c = lane; c < NH * HD; c += 64) acc += (double)qd[c] * (double)kr[c];
#pragma unroll
  for (int off = 32; off; off >>= 1) acc += __shfl_xor(acc, off);
  if (lane == 0) scores[task] = (float)(0.125 * acc);
}

// ---------------------------------------------------------------------------
// Top-K by rank-counting (stable descending == lax.top_k).
// ---------------------------------------------------------------------------
__global__ __launch_bounds__(256) void topk_kernel(
    const float* __restrict__ scores, int* __restrict__ top_idx, int KBL) {
  __shared__ float ls[512];
  int b = blockIdx.x, t = threadIdx.x;
  for (int i = t; i < KBL; i += 256) ls[i] = scores[(size_t)b * KBL + i];
  __syncthreads();
  for (int l = t; l < KBL; l += 256) {
    float sl = ls[l];
    int rank = 0;
    for (int j = 0; j < KBL; ++j) {
      float sj = ls[j];
      rank += (sj > sl || (sj == sl && j < l)) ? 1 : 0;
    }
    if (rank < TOPK) top_idx[b * TOPK + rank] = l;
  }
}

// ---------------------------------------------------------------------------
// padflag[b*S+s] = all(mask[b,0,s,:] < 0)
// ---------------------------------------------------------------------------
__global__ void padflag_kernel(const float* __restrict__ mask,
                               int* __restrict__ flags, int BS, int S) {
  int w = (blockIdx.x * blockDim.x + threadIdx.x) >> 6;
  int lane = threadIdx.x & 63;
  if (w >= BS) return;
  const float* row = mask + (size_t)w * S;
  bool ok = true;
  for (int j = lane; j < S; j += 64) ok = ok && (row[j] < 0.f);
  int allv = __all(ok ? 1 : 0);
  if (lane == 0) flags[w] = allv;
}

// ---------------------------------------------------------------------------
// Load one K/V chunk's staged data into registers (4 x bf16x8 per thread).
// ---------------------------------------------------------------------------
__device__ __forceinline__ void load_chunk(
    int ch, int t, int b, int h, int g, int S,
    const unsigned short* __restrict__ kbf, const unsigned short* __restrict__ vTb,
    const unsigned short* __restrict__ kbkh, const unsigned short* __restrict__ kbvgT,
    bf16x8* st) {
  bool iskb = ch < 2;
  int j0 = iskb ? ch * 64 : (ch - 2) * 64;
#pragma unroll
  for (int it = 0; it < 4; ++it) {
    int slot = it * 256 + t;
    int tile = slot >> 9, row = (slot >> 3) & 63, ck = slot & 7;
    const unsigned short* src;
    if (tile == 0)
      src = iskb ? kbkh + (size_t)(j0 + row) * 2048 + h * 64 + ck * 8
                 : kbf + (size_t)(b * S + j0 + row) * 512 + g * 64 + ck * 8;
    else
      src = iskb ? kbvgT + (((size_t)b * NH + h) * 64 + row) * 128 + j0 + ck * 8
                 : vTb + (((size_t)b * NKV + g) * 64 + row) * (size_t)S + j0 + ck * 8;
    st[it] = *(const bf16x8*)src;
  }
}

// ---------------------------------------------------------------------------
// One chunk of QK^T -> online softmax -> PV for one q-tile.
// ---------------------------------------------------------------------------
__device__ __forceinline__ void attn_step(
    const char* smem, char* ptw, const int* padfb, const bf16x8* aq,
    bool iskb, int j0, int s0, int w, int li, int lg4,
    float* m_, float* l_, f32x4* acc) {
  f32x4 cc[4];
  __builtin_amdgcn_s_setprio(1);
#pragma unroll
  for (int cb = 0; cb < 4; ++cb) {
    bf16x8 b0 = *(const bf16x8*)(smem + swz(cb * 16 + li, lg4));
    bf16x8 b1 = *(const bf16x8*)(smem + swz(cb * 16 + li, 4 + lg4));
    f32x4 z = {};
    z = __builtin_amdgcn_mfma_f32_16x16x32_bf16(aq[0], b0, z, 0, 0, 0);
    z = __builtin_amdgcn_mfma_f32_16x16x32_bf16(aq[1], b1, z, 0, 0, 0);
    cc[cb] = z;
  }
  __builtin_amdgcn_s_setprio(0);

  float lgv[4][4];
#pragma unroll
  for (int cb = 0; cb < 4; ++cb)
#pragma unroll
    for (int j = 0; j < 4; ++j) {
      float v = SCALE * cc[cb][j];
      if (iskb) {
        v += C0F + (padfb[w * 16 + lg4 * 4 + j] ? PADF : 0.f);
      } else {
        int key = j0 + cb * 16 + li;
        int srow = s0 + w * 16 + lg4 * 4 + j;
        v += (key <= srow) ? 0.f : PADF;
      }
      lgv[cb][j] = v;
    }
#pragma unroll
  for (int j = 0; j < 4; ++j) {
    float rmax = fmaxf(fmaxf(lgv[0][j], lgv[1][j]), fmaxf(lgv[2][j], lgv[3][j]));
#pragma unroll
    for (int off = 8; off; off >>= 1) rmax = fmaxf(rmax, __shfl_xor(rmax, off));
    float mn = fmaxf(m_[j], rmax);
    float fs = __expf(m_[j] - mn);
    float csum = 0.f;
#pragma unroll
    for (int cb = 0; cb < 4; ++cb) {
      float pv = __expf(lgv[cb][j] - mn);
      csum += pv;
      int key = cb * 16 + li;
      int rloc = lg4 * 4 + j;
      *(unsigned short*)(ptw + swz(rloc, key >> 3) + ((key & 7) << 1)) = f2bf(pv);
    }
#pragma unroll
    for (int off = 8; off; off >>= 1) csum += __shfl_xor(csum, off);
    m_[j] = mn;
    l_[j] = l_[j] * fs + csum;
#pragma unroll
    for (int db = 0; db < 4; ++db) acc[db][j] *= fs;
  }

  bf16x8 pa0 = *(const bf16x8*)(ptw + swz(li, lg4));
  bf16x8 pa1 = *(const bf16x8*)(ptw + swz(li, 4 + lg4));
  __builtin_amdgcn_s_setprio(1);
#pragma unroll
  for (int db = 0; db < 4; ++db) {
    bf16x8 bv0 = *(const bf16x8*)(smem + 8192 + swz(db * 16 + li, lg4));
    bf16x8 bv1 = *(const bf16x8*)(smem + 8192 + swz(db * 16 + li, 4 + lg4));
    acc[db] = __builtin_amdgcn_mfma_f32_16x16x32_bf16(pa0, bv0, acc[db], 0, 0, 0);
    acc[db] = __builtin_amdgcn_mfma_f32_16x16x32_bf16(pa1, bv1, acc[db], 0, 0, 0);
  }
  __builtin_amdgcn_s_setprio(0);
}

// ---------------------------------------------------------------------------
// MFMA fused attention v4 (unchanged): diagonal pairing + async reg-staged
// K/V prefetch + direct-global q fragments.
// ---------------------------------------------------------------------------
__global__ __launch_bounds__(256) void attn_mfma(
    const unsigned short* __restrict__ qbf,    // [B*S][2048] roped bf16
    const unsigned short* __restrict__ q2bf,   // [B*S][2048] bf16
    const unsigned short* __restrict__ kbf,    // [B*S][512] roped bf16
    const unsigned short* __restrict__ vTb,    // [B][NKV][64][S] bf16
    const unsigned short* __restrict__ kbkh,   // [128][2048] bf16
    const unsigned short* __restrict__ kbvgT,  // [B][NH][64][128] bf16
    const int* __restrict__ padflag,           // [B*S]
    unsigned short* __restrict__ attnbf,       // [B*S][2048] bf16
    int B, int S) {
  const int nst = S >> 6;
  const int npair = (nst + 1) >> 1;
  const int p = blockIdx.x % npair;
  const int h = (blockIdx.x / npair) % NH;
  const int b = blockIdx.x / (npair * NH);
  const int stA = p, stB = nst - 1 - p;
  const bool hasB = (stB != stA);
  const int s0A = stA * 64, s0B = stB * 64;
  const int g = h / (NH / NKV);

  __shared__ unsigned short smem[8192];
  __shared__ unsigned short pt[4][1024];
  __shared__ int padf[128];

  const int t = threadIdx.x;
  const int w = t >> 6;
  const int li = t & 15;
  const int lg4 = (t & 63) >> 4;

  const int nch = 2 + stB + 1;

  bf16x8 st[4];
  load_chunk(0, t, b, h, g, S, kbf, vTb, kbkh, kbvgT, st);

  bf16x8 aq0A[2], aq2A[2], aq0B[2], aq2B[2];
  {
    size_t rowA = (size_t)(b * S + s0A + w * 16 + li) * (NH * HD);
    size_t rowB = (size_t)(b * S + s0B + w * 16 + li) * (NH * HD);
#pragma unroll
    for (int kc = 0; kc < 2; ++kc) {
      size_t o = h * 64 + kc * 32 + lg4 * 8;
      aq0A[kc] = *(const bf16x8*)(qbf + rowA + o);
      aq2A[kc] = *(const bf16x8*)(q2bf + rowA + o);
      aq0B[kc] = *(const bf16x8*)(qbf + rowB + o);
      aq2B[kc] = *(const bf16x8*)(q2bf + rowB + o);
    }
  }
  if (t < 64) padf[t] = padflag[b * S + s0A + t];
  else if (t < 128) padf[t] = padflag[b * S + s0B + (t - 64)];

  float mA[4] = {-3.4e38f, -3.4e38f, -3.4e38f, -3.4e38f};
  float mB[4] = {-3.4e38f, -3.4e38f, -3.4e38f, -3.4e38f};
  float lA[4] = {}, lB[4] = {};
  f32x4 accA[4] = {}, accB[4] = {};

  for (int ch = 0; ch < nch; ++ch) {
    const bool iskb = ch < 2;
    const int j0 = iskb ? ch * 64 : (ch - 2) * 64;
    if (ch) __syncthreads();
#pragma unroll
    for (int it = 0; it < 4; ++it) {
      int slot = it * 256 + t;
      int tile = slot >> 9, row = (slot >> 3) & 63, ck = slot & 7;
      *(bf16x8*)((char*)smem + tile * 8192 + swz(row, ck)) = st[it];
    }
    __syncthreads();
    if (ch + 1 < nch) load_chunk(ch + 1, t, b, h, g, S, kbf, vTb, kbkh, kbvgT, st);

    if (iskb || (ch - 2) <= stA)
      attn_step((const char*)smem, (char*)pt[w], padf, iskb ? aq2A : aq0A,
                iskb, j0, s0A, w, li, lg4, mA, lA, accA);
    if (hasB)
      attn_step((const char*)smem, (char*)pt[w], padf + 64, iskb ? aq2B : aq0B,
                iskb, j0, s0B, w, li, lg4, mB, lB, accB);
  }

#pragma unroll
  for (int j = 0; j < 4; ++j) {
    float inv = 1.f / lA[j];
    size_t o = (size_t)(b * S + s0A + w * 16 + lg4 * 4 + j) * (NH * HD) + h * 64 + li;
#pragma unroll
    for (int db = 0; db < 4; ++db) attnbf[o + db * 16] = f2bf(accA[db][j] * inv);
  }
  if (hasB) {
#pragma unroll
    for (int j = 0; j < 4; ++j) {
      float inv = 1.f / lB[j];
      size_t o = (size_t)(b * S + s0B + w * 16 + lg4 * 4 + j) * (NH * HD) + h * 64 + li;
#pragma unroll
      for (int db = 0; db < 4; ++db) attnbf[o + db * 16] = f2bf(accB[db][j] * inv);
    }
  }
}

// ---------------------------------------------------------------------------
extern "C" void kernel_launch(void* const* d_in, const int* in_sizes, int n_in,
                              void* d_out, int out_size, void* d_ws, size_t ws_size,
                              hipStream_t stream) {
  const float* hidden = (const float*)d_in[0];
  const float* cosb   = (const float*)d_in[1];
  const float* sinb   = (const float*)d_in[2];
  const float* mask   = (const float*)d_in[3];
  const float* kbk    = (const float*)d_in[4];
  const float* kbv    = (const float*)d_in[5];
  const float* Wq     = (const float*)d_in[6];
  const float* Wq2    = (const float*)d_in[7];
  const float* Wk     = (const float*)d_in[8];
  const float* Wv     = (const float*)d_in[9];
  const float* Wo     = (const float*)d_in[10];
  float* out = (float*)d_out;

  const int H   = in_sizes[6] / (NH * HD);             // 2048
  const int KBL = in_sizes[4] / KBROW;                 // 400
  const long long BSll = (long long)in_sizes[0] / H;
  const int S = (int)((long long)in_sizes[3] / BSll);  // 1024
  const int B = (int)(BSll / S);                       // 2
  const int BS = B * S;
  const int NQ = NH * HD;                              // 2048
  const int NKVD = NKV * HD;                           // 512
  const int NTOT = NQ + NQ + NKVD + NKVD;              // 5120

  float* ws = (float*)d_ws;
  size_t off = 0;
  double* hpart = (double*)(ws + off); off += (size_t)B * HCH * H * 2;
  float* Hsum = ws + off; off += (size_t)B * H;
  float* Qs   = ws + off; off += (size_t)B * NQ;
  float* sc   = ws + off; off += (size_t)B * KBL;
  int* topi   = (int*)(ws + off); off += (size_t)B * TOPK;
  int* padfl  = (int*)(ws + off); off += (size_t)BS;
  unsigned short* hbf    = (unsigned short*)(ws + off); off += (size_t)BS * H / 2;
  unsigned short* wall   = (unsigned short*)(ws + off); off += (size_t)NTOT * H / 2;
  unsigned short* wobf   = (unsigned short*)(ws + off); off += (size_t)H * NQ / 2;
  unsigned short* attnbf = (unsigned short*)(ws + off); off += (size_t)BS * NQ / 2;
  unsigned short* qbf    = (unsigned short*)(ws + off); off += (size_t)BS * NQ / 2;
  unsigned short* q2bf   = (unsigned short*)(ws + off); off += (size_t)BS * NQ / 2;
  unsigned short* kbf    = (unsigned short*)(ws + off); off += (size_t)BS * NKVD / 2;
  unsigned short* vTb    = (unsigned short*)(ws + off); off += (size_t)BS * NKVD / 2;
  unsigned short* kbkh   = (unsigned short*)(ws + off); off += (size_t)128 * NQ / 2;
  unsigned short* kbvgT  = (unsigned short*)(ws + off); off += (size_t)B * NH * HD * TOPK / 2;
  float* c0 = (float*)qbf;   // dead after attn_mfma
  float* c1 = (float*)wall;  // dead after gemm_proj8
  (void)ws_size; (void)n_in; (void)out_size;

  // 0: all fp32 -> bf16 conversions (dest hbf|wall|wobf contiguous)
  {
    int n0 = BS * H / 4, n1 = NQ * H / 4, n2 = NQ * H / 4;
    int n3 = NKVD * H / 4, n4_ = NKVD * H / 4, n5 = H * NQ / 4;
    int ntot = n0 + n1 + n2 + n3 + n4_ + n5;
    f2bf_all<<<(ntot + 255) / 256, 256, 0, stream>>>(
        hidden, Wq, Wq2, Wk, Wv, Wo, n0, n1, n2, n3, n4_, n5, hbf);
  }

  // 1: fused projections + RoPE + direct V^T (8-wave, read-ahead pipeline)
  gemm_proj8<<<dim3(NTOT / 256, BS / 256), 512, 0, stream>>>(
      hbf, wall, cosb, sinb, qbf, q2bf, kbf, vTb, BS, H, S);

  // 2-6: exact fp32 scores path + top-k + padding
  hsum1_kernel<<<B * HCH * (H / 256), 256, 0, stream>>>(hidden, hpart, B, S, H);
  hsum2_kernel<<<(B * H + 255) / 256, 256, 0, stream>>>(hpart, Hsum, B, H);
  qs_kernel<<<(B * NQ * 64 + 255) / 256, 256, 0, stream>>>(Hsum, Wq2, Qs, B, H);
  scores_kernel<<<(B * KBL * 64 + 255) / 256, 256, 0, stream>>>(Qs, kbk, sc, B, KBL);
  topk_kernel<<<B, 256, 0, stream>>>(sc, topi, KBL);
  padflag_kernel<<<(BS * 64 + 255) / 256, 256, 0, stream>>>(mask, padfl, BS, S);

  // 7-8: KB bf16 staging
  kbkh_kernel<<<(128 * 512 + 255) / 256, 256, 0, stream>>>(kbk, kbkh);
  kbvgt_kernel<<<B * NH, 256, 0, stream>>>(kbv, topi, kbvgT, B);

  // 9: fused attention (paired tiles, async prefetch)
  {
    int nst = S / 64;
    int npair = (nst + 1) / 2;
    attn_mfma<<<B * NH * npair, 256, 0, stream>>>(
        qbf, q2bf, kbf, vTb, kbkh, kbvgT, padfl, attnbf, B, S);
  }

  // 10-11: output projection, split-K=2 + partial add
  gemm_nt_splitk<<<dim3(H / 128, BS / 128, 2), 256, 0, stream>>>(
      attnbf, wobf, c0, c1, BS, H, NQ);
  add2_kernel<<<(BS * H / 4 + 255) / 256, 256, 0, stream>>>(c0, c1, out, BS * H / 4);
}

// Round 14
// 250.380 us; speedup vs baseline: 11.9400x; 1.0234x over previous
//
#include <hip/hip_runtime.h>
#include <hip/hip_bf16.h>
#include <math.h>

#define NH 32
#define NKV 8
#define HD 64
#define NSLOTS 11
#define TOPK 128
#define KBROW (NSLOTS * NH * HD)   // 22528
#define PADF (-3.3895313892515355e+38f)
#define C0F  (-0.24686007793152578f)   // -ln(128)+ln(100)
#define SCALE 0.125f
#define HCH 32                         // S-chunks for hierarchical column sum

typedef __attribute__((ext_vector_type(8))) __bf16 bf16x8;
typedef __attribute__((ext_vector_type(8))) unsigned short u16x8;
typedef __attribute__((ext_vector_type(4))) float f32x4;

#define GLDS16(gp, lp)                                                        \
  __builtin_amdgcn_global_load_lds(                                           \
      (__attribute__((address_space(1))) void*)(gp),                          \
      (__attribute__((address_space(3))) void*)(lp), 16, 0, 0)

__device__ __forceinline__ unsigned short f2bf(float f) {
  unsigned int u = __float_as_uint(f);
  u = (u + 0x7fffu + ((u >> 16) & 1u)) >> 16;
  return (unsigned short)u;
}

// byte offset into a 64-col bf16 tile (128 B/row) with XOR chunk swizzle
__device__ __forceinline__ int swz(int row, int chunk) {
  return row * 128 + ((chunk ^ (row & 7)) << 4);
}

// ---------------------------------------------------------------------------
// fp32 -> bf16 for 5 concatenated weight sources into one contiguous dest
// (wall | wobf). Units are float4.
// ---------------------------------------------------------------------------
__global__ void f2bf_all(const float* __restrict__ s0, const float* __restrict__ s1,
                         const float* __restrict__ s2, const float* __restrict__ s3,
                         const float* __restrict__ s4,
                         int n0, int n1, int n2, int n3, int n4_,
                         unsigned short* __restrict__ out) {
  int i = blockIdx.x * blockDim.x + threadIdx.x;
  int j = i;
  const float* src;
  if (j < n0) src = s0;
  else { j -= n0; if (j < n1) src = s1;
  else { j -= n1; if (j < n2) src = s2;
  else { j -= n2; if (j < n3) src = s3;
  else { j -= n3; if (j >= n4_) return; src = s4; }}}}
  float4 v = ((const float4*)src)[j];
  ushort4 o = {f2bf(v.x), f2bf(v.y), f2bf(v.z), f2bf(v.w)};
  ((ushort4*)out)[i] = o;
}

// ---------------------------------------------------------------------------
// bf16 MFMA GEMM, split-K=2 (m97 structure) — used for the Wo projection.
// ---------------------------------------------------------------------------
__global__ __launch_bounds__(256) void gemm_nt_splitk(
    const unsigned short* __restrict__ A, const unsigned short* __restrict__ B,
    float* __restrict__ C0, float* __restrict__ C1, int M, int N, int K) {
  __shared__ unsigned short ldsA[128 * 32];
  __shared__ unsigned short ldsB[128 * 32];
  const int t = threadIdx.x;
  const int l = t & 63, w = t >> 6;
  const int wr = w >> 1, wc = w & 1;
  const int lr = l & 15;
  const int kb = (l >> 4) * 16;
  const int bm = blockIdx.y * 128, bn = blockIdx.x * 128;
  float* C = blockIdx.z ? C1 : C0;
  const int k0base = blockIdx.z * (K >> 1);
  const int kend = k0base + (K >> 1);

  f32x4 acc[4][4] = {};

  for (int k0 = k0base; k0 < kend; k0 += 32) {
    __syncthreads();
#pragma unroll
    for (int it = 0; it < 2; ++it) {
      int s = it * 256 + t;
      int row = s >> 2, cs = (s & 3) * 8;
      GLDS16(A + (size_t)(bm + row) * K + k0 + cs,
             (char*)ldsA + (it * 4 + w) * 1024);
      GLDS16(B + (size_t)(bn + row) * K + k0 + cs,
             (char*)ldsB + (it * 4 + w) * 1024);
    }
    __syncthreads();

    bf16x8 a[4], b[4];
#pragma unroll
    for (int m = 0; m < 4; ++m)
      a[m] = *(const bf16x8*)((const char*)ldsA +
                              (wr * 64 + m * 16 + lr) * 64 + kb);
#pragma unroll
    for (int n = 0; n < 4; ++n)
      b[n] = *(const bf16x8*)((const char*)ldsB +
                              (wc * 64 + n * 16 + lr) * 64 + kb);
#pragma unroll
    for (int m = 0; m < 4; ++m)
#pragma unroll
      for (int n = 0; n < 4; ++n)
        acc[m][n] =
            __builtin_amdgcn_mfma_f32_16x16x32_bf16(a[m], b[n], acc[m][n], 0, 0, 0);
  }

#pragma unroll
  for (int m = 0; m < 4; ++m)
#pragma unroll
    for (int n = 0; n < 4; ++n) {
      int rbase = bm + wr * 64 + m * 16 + ((l >> 4) << 2);
      int cbase = bn + wc * 64 + n * 16 + lr;
#pragma unroll
      for (int j = 0; j < 4; ++j)
        C[(size_t)(rbase + j) * N + cbase] = acc[m][n][j];
    }
}

// ---------------------------------------------------------------------------
// out = a + b (float4 units)
// ---------------------------------------------------------------------------
__global__ void add2_kernel(const float* __restrict__ a,
                            const float* __restrict__ b,
                            float* __restrict__ o, int n4) {
  int i = blockIdx.x * blockDim.x + threadIdx.x;
  if (i >= n4) return;
  float4 x = ((const float4*)a)[i], y = ((const float4*)b)[i];
  ((float4*)o)[i] = make_float4(x.x + y.x, x.y + y.y, x.z + y.z, x.w + y.w);
}

// ---------------------------------------------------------------------------
// 8-wave 256x256 deep-pipelined projection GEMM + RoPE epilogue + direct V^T.
// v4: XCD-chunked block swizzle (each XCD owns one A row-panel); setprio
// removed (lockstep-barrier regime = m190 null). Pipeline as v3.
// ---------------------------------------------------------------------------
__global__ __launch_bounds__(512) void gemm_proj8(
    const unsigned short* __restrict__ A,      // hbf [M][K]
    const unsigned short* __restrict__ Wall,   // [5120][K]
    const float* __restrict__ cosb, const float* __restrict__ sinb,
    unsigned short* __restrict__ qbf, unsigned short* __restrict__ q2bf,
    unsigned short* __restrict__ kbf, unsigned short* __restrict__ vTb,
    int M, int K, int S) {
  __shared__ char lds[131072];  // 2 buffers x (A 32KB | B 32KB)
  const int t = threadIdx.x;
  const int w = t >> 6;
  const int wm = w >> 2, wn = w & 3;
  const int l = t & 63;
  const int li = l & 15, lg4 = l >> 4;
  // XCD-chunked swizzle: linear id (x-fastest) -> XCD k owns 20 contiguous
  // work ids = one A row-panel. nwg = 20*8 = 160, 160 % 8 == 0 (bijective).
  const int nwgx = gridDim.x;                       // 20
  const int cpx = (nwgx * gridDim.y) >> 3;          // 20 per XCD
  int linear = blockIdx.x + nwgx * blockIdx.y;
  int wid = (linear & 7) * cpx + (linear >> 3);
  const int bm = (wid / nwgx) * 256, bn = (wid % nwgx) * 256;
  const int NK = K >> 6;

  f32x4 acc[8][4] = {};

#define STAGE_UNIT(kt1, nb, u)                                                \
  {                                                                           \
    const int slice_ = (u) >> 1;                                              \
    const unsigned short* mat_ = ((u) & 1) ? Wall : A;                        \
    const int tb_ = ((u) & 1) ? bn : bm;                                      \
    char* base_ = lds + (nb) * 65536 + (((u) & 1) ? 32768 : 0) +              \
                  slice_ * 16384;                                             \
    _Pragma("unroll")                                                         \
    for (int i_ = 0; i_ < 2; ++i_) {                                          \
      int ss_ = i_ * 512 + t;                                                 \
      int row_ = ss_ >> 2, cc_ = ss_ & 3;                                     \
      int chunk_ = cc_ ^ ((row_ >> 1) & 3);                                   \
      GLDS16(mat_ + (size_t)(tb_ + row_) * K + (kt1) * 64 + slice_ * 32 +     \
                 chunk_ * 8,                                                  \
             base_ + i_ * 8192 + w * 1024);                                   \
    }                                                                         \
  }

  // prologue: stage tile 0 fully into buffer 0; A0,B0 (units 0,1) must land.
  STAGE_UNIT(0, 0, 0); STAGE_UNIT(0, 0, 1);
  STAGE_UNIT(0, 0, 2); STAGE_UNIT(0, 0, 3);
  asm volatile("s_waitcnt vmcnt(4)" ::: "memory");
  asm volatile("s_barrier" ::: "memory");

  for (int kt = 0; kt < NK; ++kt) {
    const int cur = kt & 1;
    const bool stg = (kt + 1 < NK);
    char* curA = lds + cur * 65536;
    char* curB = curA + 32768;
#pragma unroll
    for (int kk = 0; kk < 2; ++kk) {
      bf16x8 bfr[4], af_a[4], af_b[4];
#pragma unroll
      for (int n = 0; n < 4; ++n) {
        int row = wn * 64 + n * 16 + li;
        bfr[n] = *(const bf16x8*)(curB + kk * 16384 + row * 64 +
                                  ((lg4 ^ ((row >> 1) & 3)) << 4));
      }
#pragma unroll
      for (int mi = 0; mi < 4; ++mi) {
        int row = wm * 128 + mi * 16 + li;
        af_a[mi] = *(const bf16x8*)(curA + kk * 16384 + row * 64 +
                                    ((lg4 ^ ((row >> 1) & 3)) << 4));
      }
      if (stg) STAGE_UNIT(kt + 1, cur ^ 1, kk * 2)
#pragma unroll
      for (int mi = 0; mi < 4; ++mi) {
        int row = wm * 128 + (4 + mi) * 16 + li;
        af_b[mi] = *(const bf16x8*)(curA + kk * 16384 + row * 64 +
                                    ((lg4 ^ ((row >> 1) & 3)) << 4));
      }
#pragma unroll
      for (int mi = 0; mi < 4; ++mi)
#pragma unroll
        for (int n = 0; n < 4; ++n)
          acc[mi][n] = __builtin_amdgcn_mfma_f32_16x16x32_bf16(
              af_a[mi], bfr[n], acc[mi][n], 0, 0, 0);
      if (stg) STAGE_UNIT(kt + 1, cur ^ 1, kk * 2 + 1)
#pragma unroll
      for (int mi = 0; mi < 4; ++mi)
#pragma unroll
        for (int n = 0; n < 4; ++n)
          acc[4 + mi][n] = __builtin_amdgcn_mfma_f32_16x16x32_bf16(
              af_b[mi], bfr[n], acc[4 + mi][n], 0, 0, 0);
      // vmcnt ledger: after kk=0 ensure units 2,3 of cur; after kk=1 ensure
      // units 0,1 of next tile. Never 0 mid-loop.
      if (kk == 0) {
        if (kt == NK - 1) asm volatile("s_waitcnt vmcnt(0)" ::: "memory");
        else              asm volatile("s_waitcnt vmcnt(4)" ::: "memory");
        asm volatile("s_barrier" ::: "memory");
      } else {
        if (stg) {
          asm volatile("s_waitcnt vmcnt(4)" ::: "memory");
          asm volatile("s_barrier" ::: "memory");
        }
      }
    }
  }
#undef STAGE_UNIT

  // ---- epilogue: segmented outputs with RoPE (8-wave fragment mapping)
  const int seg = bn;  // block-uniform
#pragma unroll
  for (int m = 0; m < 8; ++m) {
    const int row0 = bm + wm * 128 + m * 16 + lg4 * 4;
    if (seg < 2048 || (seg >= 4096 && seg < 4608)) {
      const bool isq = seg < 2048;
#pragma unroll
      for (int j = 0; j < 4; ++j) {
        int row = row0 + j;
        const float* cr = cosb + (size_t)row * 64;
        const float* sr = sinb + (size_t)row * 64;
        float c0 = cr[li], c1 = cr[16 + li], c2 = cr[32 + li], c3 = cr[48 + li];
        float sa = sr[li], sb = sr[16 + li], sc_ = sr[32 + li], sd = sr[48 + li];
        float x0 = acc[m][0][j], x1 = acc[m][1][j];
        float x2 = acc[m][2][j], x3 = acc[m][3][j];
        float y0 = x0 * c0 - x2 * sa;
        float y1 = x1 * c1 - x3 * sb;
        float y2 = x2 * c2 + x0 * sc_;
        float y3 = x3 * c3 + x1 * sd;
        if (isq) {
          size_t ro = (size_t)row * 2048 + bn + wn * 64 + li;
          qbf[ro] = f2bf(y0); qbf[ro + 16] = f2bf(y1);
          qbf[ro + 32] = f2bf(y2); qbf[ro + 48] = f2bf(y3);
        } else {
          size_t ro = (size_t)row * 512 + (bn - 4096) + wn * 64 + li;
          kbf[ro] = f2bf(y0); kbf[ro + 16] = f2bf(y1);
          kbf[ro + 32] = f2bf(y2); kbf[ro + 48] = f2bf(y3);
        }
      }
    } else if (seg < 4096) {  // q2 -> bf16
#pragma unroll
      for (int n = 0; n < 4; ++n) {
        int col = bn - 2048 + wn * 64 + n * 16 + li;
#pragma unroll
        for (int j = 0; j < 4; ++j)
          q2bf[(size_t)(row0 + j) * 2048 + col] = f2bf(acc[m][n][j]);
      }
    } else {  // v -> vT bf16 direct (j=0..3 consecutive s)
      int b_ = row0 / S, s = row0 % S;
#pragma unroll
      for (int n = 0; n < 4; ++n) {
        int col = (bn - 4608) + wn * 64 + n * 16 + li;
        int gg = col >> 6, d = col & 63;
        ushort4 o = {f2bf(acc[m][n][0]), f2bf(acc[m][n][1]),
                     f2bf(acc[m][n][2]), f2bf(acc[m][n][3])};
        *(ushort4*)&vTb[(((size_t)b_ * NKV + gg) * 64 + d) * S + s] = o;
      }
    }
  }
}

// ---------------------------------------------------------------------------
// KB key slice: kbkh[j][c] = bf16(kb_keys[j*KBROW + c]), j<128, c<2048.
// ---------------------------------------------------------------------------
__global__ void kbkh_kernel(const float* __restrict__ kbk,
                            unsigned short* __restrict__ out) {
  int i = blockIdx.x * blockDim.x + threadIdx.x;
  if (i >= 128 * 512) return;
  int j = i >> 9, c4 = (i & 511) * 4;
  float4 v = *(const float4*)&kbk[(size_t)j * KBROW + c4];
  ushort4 o = {f2bf(v.x), f2bf(v.y), f2bf(v.z), f2bf(v.w)};
  *(ushort4*)&out[(size_t)j * 2048 + c4] = o;
}

// ---------------------------------------------------------------------------
// Gathered + transposed KB values -> [B][NH][64][128] bf16.
// ---------------------------------------------------------------------------
__global__ __launch_bounds__(256) void kbvgt_kernel(
    const float* __restrict__ kbv, const int* __restrict__ topi,
    unsigned short* __restrict__ kbvgT, int B) {
  int h = blockIdx.x % NH, b = blockIdx.x / NH;
  __shared__ unsigned short gt[128][72];
  __shared__ int lidx[TOPK];
  int t = threadIdx.x;
  if (t < TOPK) lidx[t] = topi[b * TOPK + t];
  __syncthreads();
#pragma unroll
  for (int it = 0; it < 8; ++it) {
    int slot = it * 256 + t;
    int j = slot >> 4, d4 = (slot & 15) * 4;
    float4 v = *(const float4*)&kbv[(size_t)lidx[j] * KBROW + h * 64 + d4];
    gt[j][d4] = f2bf(v.x); gt[j][d4 + 1] = f2bf(v.y);
    gt[j][d4 + 2] = f2bf(v.z); gt[j][d4 + 3] = f2bf(v.w);
  }
  __syncthreads();
#pragma unroll
  for (int it = 0; it < 4; ++it) {
    int slot = it * 256 + t;
    int d = slot >> 4, j8 = (slot & 15) * 8;
    u16x8 o;
#pragma unroll
    for (int j = 0; j < 8; ++j) o[j] = gt[j8 + j][d];
    *(u16x8*)&kbvgT[(((size_t)b * NH + h) * 64 + d) * 128 + j8] = o;
  }
}

// ---------------------------------------------------------------------------
// Column-sum stage 1 + fused hidden f2bf: part[b][ch][c] = f64 chunk sum,
// and hbf = bf16(hidden) (coalesced writes, hidden read exactly once here).
// ---------------------------------------------------------------------------
__global__ __launch_bounds__(256) void hsum1_kernel(
    const float* __restrict__ hidden, double* __restrict__ part,
    unsigned short* __restrict__ hbf, int B, int S, int H) {
  const int nhb = H >> 8;
  int hb = blockIdx.x % nhb;
  int ch = (blockIdx.x / nhb) % HCH;
  int b  = blockIdx.x / (nhb * HCH);
  int c  = hb * 256 + threadIdx.x;
  int rows = S / HCH;
  size_t base = ((size_t)b * S + (size_t)ch * rows) * H + c;
  const float* p = hidden + base;
  double acc = 0.0;
  for (int s = 0; s < rows; ++s) {
    float v = p[(size_t)s * H];
    acc += (double)v;
    hbf[base + (size_t)s * H] = f2bf(v);
  }
  part[((size_t)b * HCH + ch) * H + c] = acc;
}

// ---------------------------------------------------------------------------
// Column-sum stage 2: Hsum[b][c] = sum_ch part[b][ch][c] (f64, fixed order).
// ---------------------------------------------------------------------------
__global__ void hsum2_kernel(const double* __restrict__ part,
                             float* __restrict__ Hsum, int B, int H) {
  int idx = blockIdx.x * blockDim.x + threadIdx.x;
  if (idx >= B * H) return;
  int b = idx / H, c = idx % H;
  const double* p = part + (size_t)b * HCH * H + c;
  double acc = 0.0;
#pragma unroll
  for (int ch = 0; ch < HCH; ++ch) acc += p[(size_t)ch * H];
  Hsum[idx] = (float)acc;
}

// ---------------------------------------------------------------------------
// Qs[b][c] = sum_k Hsum[b][k] * Wq2[c][k]  (fp32 inputs, f64 accum).
// ---------------------------------------------------------------------------
__global__ void qs_kernel(const float* __restrict__ Hsum,
                          const float* __restrict__ Wq2,
                          float* __restrict__ Qs, int B, int H) {
  int task = (blockIdx.x * blockDim.x + threadIdx.x) >> 6;
  int lane = threadIdx.x & 63;
  if (task >= B * NH * HD) return;
  int b = task / (NH * HD), c = task % (NH * HD);
  const float* hs = Hsum + (size_t)b * H;
  const float* wr = Wq2 + (size_t)c * H;
  double acc = 0.0;
  for (int k = lane; k < H; k += 64) acc += (double)hs[k] * (double)wr[k];
#pragma unroll
  for (int off = 32; off; off >>= 1) acc += __shfl_xor(acc, off);
  if (lane == 0) Qs[task] = (float)acc;
}

// ---------------------------------------------------------------------------
// scores[b][l] = 0.125 * dot(Qs[b,:], kb_keys[l, 0:2048]) (f64 acc)
// ---------------------------------------------------------------------------
__global__ void scores_kernel(const float* __restrict__ Qs,
                              const float* __restrict__ kbk,
                              float* __restrict__ scores, int B, int KBL) {
  int task = (blockIdx.x * blockDim.x + threadIdx.x) >> 6;
  int lane = threadIdx.x & 63;
  if (task >= B * KBL) return;
  int b = task / KBL, l = task % KBL;
  const float* kr = kbk + (size_t)l * KBROW;
  const float* qd = Qs + (size_t)b * NH * HD;
  double acc = 0.0;
  for (int c = lane; c < NH * HD; c += 64) acc += (double)qd[c] * (double)kr[c];
#pragma unroll
  for (int off = 32; off; off >>= 1) acc += __shfl_xor(acc, off);
  if (lane == 0) scores[task] = (float)(0.125 * acc);
}

// ---------------------------------------------------------------------------
// Top-K by rank-counting (stable descending == lax.top_k).
// ---------------------------------------------------------------------------
__global__ __launch_bounds__(256) void topk_kernel(
    const float* __restrict__ scores, int* __restrict__ top_idx, int KBL) {
  __shared__ float ls[512];
  int b = blockIdx.x, t = threadIdx.x;
  for (int i = t; i < KBL; i += 256) ls[i] = scores[(size_t)b * KBL + i];
  __syncthreads();
  for (int l = t; l < KBL; l += 256) {
    float sl = ls[l];
    int rank = 0;
    for (int j = 0; j < KBL; ++j) {
      float sj = ls[j];
      rank += (sj > sl || (sj == sl && j < l)) ? 1 : 0;
    }
    if (rank < TOPK) top_idx[b * TOPK + rank] = l;
  }
}

// ---------------------------------------------------------------------------
// padflag[b*S+s] = all(mask[b,0,s,:] < 0)
// ---------------------------------------------------------------------------
__global__ void padflag_kernel(const float* __restrict__ mask,
                               int* __restrict__ flags, int BS, int S) {
  int w = (blockIdx.x * blockDim.x + threadIdx.x) >> 6;
  int lane = threadIdx.x & 63;
  if (w >= BS) return;
  const float* row = mask + (size_t)w * S;
  bool ok = true;
  for (int j = lane; j < S; j += 64) ok = ok && (row[j] < 0.f);
  int allv = __all(ok ? 1 : 0);
  if (lane == 0) flags[w] = allv;
}

// ---------------------------------------------------------------------------
// Load one K/V chunk's staged data into registers (4 x bf16x8 per thread).
// ---------------------------------------------------------------------------
__device__ __forceinline__ void load_chunk(
    int ch, int t, int b, int h, int g, int S,
    const unsigned short* __restrict__ kbf, const unsigned short* __restrict__ vTb,
    const unsigned short* __restrict__ kbkh, const unsigned short* __restrict__ kbvgT,
    bf16x8* st) {
  bool iskb = ch < 2;
  int j0 = iskb ? ch * 64 : (ch - 2) * 64;
#pragma unroll
  for (int it = 0; it < 4; ++it) {
    int slot = it * 256 + t;
    int tile = slot >> 9, row = (slot >> 3) & 63, ck = slot & 7;
    const unsigned short* src;
    if (tile == 0)
      src = iskb ? kbkh + (size_t)(j0 + row) * 2048 + h * 64 + ck * 8
                 : kbf + (size_t)(b * S + j0 + row) * 512 + g * 64 + ck * 8;
    else
      src = iskb ? kbvgT + (((size_t)b * NH + h) * 64 + row) * 128 + j0 + ck * 8
                 : vTb + (((size_t)b * NKV + g) * 64 + row) * (size_t)S + j0 + ck * 8;
    st[it] = *(const bf16x8*)src;
  }
}

// ---------------------------------------------------------------------------
// One chunk of QK^T -> online softmax -> PV for one q-tile.
// ---------------------------------------------------------------------------
__device__ __forceinline__ void attn_step(
    const char* smem, char* ptw, const int* padfb, const bf16x8* aq,
    bool iskb, int j0, int s0, int w, int li, int lg4,
    float* m_, float* l_, f32x4* acc) {
  f32x4 cc[4];
  __builtin_amdgcn_s_setprio(1);
#pragma unroll
  for (int cb = 0; cb < 4; ++cb) {
    bf16x8 b0 = *(const bf16x8*)(smem + swz(cb * 16 + li, lg4));
    bf16x8 b1 = *(const bf16x8*)(smem + swz(cb * 16 + li, 4 + lg4));
    f32x4 z = {};
    z = __builtin_amdgcn_mfma_f32_16x16x32_bf16(aq[0], b0, z, 0, 0, 0);
    z = __builtin_amdgcn_mfma_f32_16x16x32_bf16(aq[1], b1, z, 0, 0, 0);
    cc[cb] = z;
  }
  __builtin_amdgcn_s_setprio(0);

  float lgv[4][4];
#pragma unroll
  for (int cb = 0; cb < 4; ++cb)
#pragma unroll
    for (int j = 0; j < 4; ++j) {
      float v = SCALE * cc[cb][j];
      if (iskb) {
        v += C0F + (padfb[w * 16 + lg4 * 4 + j] ? PADF : 0.f);
      } else {
        int key = j0 + cb * 16 + li;
        int srow = s0 + w * 16 + lg4 * 4 + j;
        v += (key <= srow) ? 0.f : PADF;
      }
      lgv[cb][j] = v;
    }
#pragma unroll
  for (int j = 0; j < 4; ++j) {
    float rmax = fmaxf(fmaxf(lgv[0][j], lgv[1][j]), fmaxf(lgv[2][j], lgv[3][j]));
#pragma unroll
    for (int off = 8; off; off >>= 1) rmax = fmaxf(rmax, __shfl_xor(rmax, off));
    float mn = fmaxf(m_[j], rmax);
    float fs = __expf(m_[j] - mn);
    float csum = 0.f;
#pragma unroll
    for (int cb = 0; cb < 4; ++cb) {
      float pv = __expf(lgv[cb][j] - mn);
      csum += pv;
      int key = cb * 16 + li;
      int rloc = lg4 * 4 + j;
      *(unsigned short*)(ptw + swz(rloc, key >> 3) + ((key & 7) << 1)) = f2bf(pv);
    }
#pragma unroll
    for (int off = 8; off; off >>= 1) csum += __shfl_xor(csum, off);
    m_[j] = mn;
    l_[j] = l_[j] * fs + csum;
#pragma unroll
    for (int db = 0; db < 4; ++db) acc[db][j] *= fs;
  }

  bf16x8 pa0 = *(const bf16x8*)(ptw + swz(li, lg4));
  bf16x8 pa1 = *(const bf16x8*)(ptw + swz(li, 4 + lg4));
  __builtin_amdgcn_s_setprio(1);
#pragma unroll
  for (int db = 0; db < 4; ++db) {
    bf16x8 bv0 = *(const bf16x8*)(smem + 8192 + swz(db * 16 + li, lg4));
    bf16x8 bv1 = *(const bf16x8*)(smem + 8192 + swz(db * 16 + li, 4 + lg4));
    acc[db] = __builtin_amdgcn_mfma_f32_16x16x32_bf16(pa0, bv0, acc[db], 0, 0, 0);
    acc[db] = __builtin_amdgcn_mfma_f32_16x16x32_bf16(pa1, bv1, acc[db], 0, 0, 0);
  }
  __builtin_amdgcn_s_setprio(0);
}

// ---------------------------------------------------------------------------
// MFMA fused attention v4 (unchanged): diagonal pairing + async reg-staged
// K/V prefetch + direct-global q fragments.
// ---------------------------------------------------------------------------
__global__ __launch_bounds__(256) void attn_mfma(
    const unsigned short* __restrict__ qbf,    // [B*S][2048] roped bf16
    const unsigned short* __restrict__ q2bf,   // [B*S][2048] bf16
    const unsigned short* __restrict__ kbf,    // [B*S][512] roped bf16
    const unsigned short* __restrict__ vTb,    // [B][NKV][64][S] bf16
    const unsigned short* __restrict__ kbkh,   // [128][2048] bf16
    const unsigned short* __restrict__ kbvgT,  // [B][NH][64][128] bf16
    const int* __restrict__ padflag,           // [B*S]
    unsigned short* __restrict__ attnbf,       // [B*S][2048] bf16
    int B, int S) {
  const int nst = S >> 6;
  const int npair = (nst + 1) >> 1;
  const int p = blockIdx.x % npair;
  const int h = (blockIdx.x / npair) % NH;
  const int b = blockIdx.x / (npair * NH);
  const int stA = p, stB = nst - 1 - p;
  const bool hasB = (stB != stA);
  const int s0A = stA * 64, s0B = stB * 64;
  const int g = h / (NH / NKV);

  __shared__ unsigned short smem[8192];
  __shared__ unsigned short pt[4][1024];
  __shared__ int padf[128];

  const int t = threadIdx.x;
  const int w = t >> 6;
  const int li = t & 15;
  const int lg4 = (t & 63) >> 4;

  const int nch = 2 + stB + 1;

  bf16x8 st[4];
  load_chunk(0, t, b, h, g, S, kbf, vTb, kbkh, kbvgT, st);

  bf16x8 aq0A[2], aq2A[2], aq0B[2], aq2B[2];
  {
    size_t rowA = (size_t)(b * S + s0A + w * 16 + li) * (NH * HD);
    size_t rowB = (size_t)(b * S + s0B + w * 16 + li) * (NH * HD);
#pragma unroll
    for (int kc = 0; kc < 2; ++kc) {
      size_t o = h * 64 + kc * 32 + lg4 * 8;
      aq0A[kc] = *(const bf16x8*)(qbf + rowA + o);
      aq2A[kc] = *(const bf16x8*)(q2bf + rowA + o);
      aq0B[kc] = *(const bf16x8*)(qbf + rowB + o);
      aq2B[kc] = *(const bf16x8*)(q2bf + rowB + o);
    }
  }
  if (t < 64) padf[t] = padflag[b * S + s0A + t];
  else if (t < 128) padf[t] = padflag[b * S + s0B + (t - 64)];

  float mA[4] = {-3.4e38f, -3.4e38f, -3.4e38f, -3.4e38f};
  float mB[4] = {-3.4e38f, -3.4e38f, -3.4e38f, -3.4e38f};
  float lA[4] = {}, lB[4] = {};
  f32x4 accA[4] = {}, accB[4] = {};

  for (int ch = 0; ch < nch; ++ch) {
    const bool iskb = ch < 2;
    const int j0 = iskb ? ch * 64 : (ch - 2) * 64;
    if (ch) __syncthreads();
#pragma unroll
    for (int it = 0; it < 4; ++it) {
      int slot = it * 256 + t;
      int tile = slot >> 9, row = (slot >> 3) & 63, ck = slot & 7;
      *(bf16x8*)((char*)smem + tile * 8192 + swz(row, ck)) = st[it];
    }
    __syncthreads();
    if (ch + 1 < nch) load_chunk(ch + 1, t, b, h, g, S, kbf, vTb, kbkh, kbvgT, st);

    if (iskb || (ch - 2) <= stA)
      attn_step((const char*)smem, (char*)pt[w], padf, iskb ? aq2A : aq0A,
                iskb, j0, s0A, w, li, lg4, mA, lA, accA);
    if (hasB)
      attn_step((const char*)smem, (char*)pt[w], padf + 64, iskb ? aq2B : aq0B,
                iskb, j0, s0B, w, li, lg4, mB, lB, accB);
  }

#pragma unroll
  for (int j = 0; j < 4; ++j) {
    float inv = 1.f / lA[j];
    size_t o = (size_t)(b * S + s0A + w * 16 + lg4 * 4 + j) * (NH * HD) + h * 64 + li;
#pragma unroll
    for (int db = 0; db < 4; ++db) attnbf[o + db * 16] = f2bf(accA[db][j] * inv);
  }
  if (hasB) {
#pragma unroll
    for (int j = 0; j < 4; ++j) {
      float inv = 1.f / lB[j];
      size_t o = (size_t)(b * S + s0B + w * 16 + lg4 * 4 + j) * (NH * HD) + h * 64 + li;
#pragma unroll
      for (int db = 0; db < 4; ++db) attnbf[o + db * 16] = f2bf(accB[db][j] * inv);
    }
  }
}

// ---------------------------------------------------------------------------
extern "C" void kernel_launch(void* const* d_in, const int* in_sizes, int n_in,
                              void* d_out, int out_size, void* d_ws, size_t ws_size,
                              hipStream_t stream) {
  const float* hidden = (const float*)d_in[0];
  const float* cosb   = (const float*)d_in[1];
  const float* sinb   = (const float*)d_in[2];
  const float* mask   = (const float*)d_in[3];
  const float* kbk    = (const float*)d_in[4];
  const float* kbv    = (const float*)d_in[5];
  const float* Wq     = (const float*)d_in[6];
  const float* Wq2    = (const float*)d_in[7];
  const float* Wk     = (const float*)d_in[8];
  const float* Wv     = (const float*)d_in[9];
  const float* Wo     = (const float*)d_in[10];
  float* out = (float*)d_out;

  const int H   = in_sizes[6] / (NH * HD);             // 2048
  const int KBL = in_sizes[4] / KBROW;                 // 400
  const long long BSll = (long long)in_sizes[0] / H;
  const int S = (int)((long long)in_sizes[3] / BSll);  // 1024
  const int B = (int)(BSll / S);                       // 2
  const int BS = B * S;
  const int NQ = NH * HD;                              // 2048
  const int NKVD = NKV * HD;                           // 512
  const int NTOT = NQ + NQ + NKVD + NKVD;              // 5120

  float* ws = (float*)d_ws;
  size_t off = 0;
  double* hpart = (double*)(ws + off); off += (size_t)B * HCH * H * 2;
  float* Hsum = ws + off; off += (size_t)B * H;
  float* Qs   = ws + off; off += (size_t)B * NQ;
  float* sc   = ws + off; off += (size_t)B * KBL;
  int* topi   = (int*)(ws + off); off += (size_t)B * TOPK;
  int* padfl  = (int*)(ws + off); off += (size_t)BS;
  unsigned short* hbf    = (unsigned short*)(ws + off); off += (size_t)BS * H / 2;
  unsigned short* wall   = (unsigned short*)(ws + off); off += (size_t)NTOT * H / 2;
  unsigned short* wobf   = (unsigned short*)(ws + off); off += (size_t)H * NQ / 2;
  unsigned short* attnbf = (unsigned short*)(ws + off); off += (size_t)BS * NQ / 2;
  unsigned short* qbf    = (unsigned short*)(ws + off); off += (size_t)BS * NQ / 2;
  unsigned short* q2bf   = (unsigned short*)(ws + off); off += (size_t)BS * NQ / 2;
  unsigned short* kbf    = (unsigned short*)(ws + off); off += (size_t)BS * NKVD / 2;
  unsigned short* vTb    = (unsigned short*)(ws + off); off += (size_t)BS * NKVD / 2;
  unsigned short* kbkh   = (unsigned short*)(ws + off); off += (size_t)128 * NQ / 2;
  unsigned short* kbvgT  = (unsigned short*)(ws + off); off += (size_t)B * NH * HD * TOPK / 2;
  float* c0 = (float*)qbf;   // dead after attn_mfma
  float* c1 = (float*)wall;  // dead after gemm_proj8
  (void)ws_size; (void)n_in; (void)out_size;

  // 0: weight fp32 -> bf16 (dest wall|wobf contiguous)
  {
    int n1 = NQ * H / 4, n2 = NQ * H / 4;
    int n3 = NKVD * H / 4, n4_ = NKVD * H / 4, n5 = H * NQ / 4;
    int ntot = n1 + n2 + n3 + n4_ + n5;
    f2bf_all<<<(ntot + 255) / 256, 256, 0, stream>>>(
        Wq, Wq2, Wk, Wv, Wo, n1, n2, n3, n4_, n5, wall);
  }

  // 1: hidden column-sum stage 1 + fused hidden f2bf (produces hbf)
  hsum1_kernel<<<B * HCH * (H / 256), 256, 0, stream>>>(hidden, hpart, hbf, B, S, H);

  // 2: fused projections + RoPE + direct V^T (8-wave, XCD-swizzled)
  gemm_proj8<<<dim3(NTOT / 256, BS / 256), 512, 0, stream>>>(
      hbf, wall, cosb, sinb, qbf, q2bf, kbf, vTb, BS, H, S);

  // 3-6: exact fp32 scores path + top-k + padding
  hsum2_kernel<<<(B * H + 255) / 256, 256, 0, stream>>>(hpart, Hsum, B, H);
  qs_kernel<<<(B * NQ * 64 + 255) / 256, 256, 0, stream>>>(Hsum, Wq2, Qs, B, H);
  scores_kernel<<<(B * KBL * 64 + 255) / 256, 256, 0, stream>>>(Qs, kbk, sc, B, KBL);
  topk_kernel<<<B, 256, 0, stream>>>(sc, topi, KBL);
  padflag_kernel<<<(BS * 64 + 255) / 256, 256, 0, stream>>>(mask, padfl, BS, S);

  // 7-8: KB bf16 staging
  kbkh_kernel<<<(128 * 512 + 255) / 256, 256, 0, stream>>>(kbk, kbkh);
  kbvgt_kernel<<<B * NH, 256, 0, stream>>>(kbv, topi, kbvgT, B);

  // 9: fused attention (paired tiles, async prefetch)
  {
    int nst = S / 64;
    int npair = (nst + 1) / 2;
    attn_mfma<<<B * NH * npair, 256, 0, stream>>>(
        qbf, q2bf, kbf, vTb, kbkh, kbvgT, padfl, attnbf, B, S);
  }

  // 10-11: output projection, split-K=2 + partial add
  gemm_nt_splitk<<<dim3(H / 128, BS / 128, 2), 256, 0, stream>>>(
      attnbf, wobf, c0, c1, BS, H, NQ);
  add2_kernel<<<(BS * H / 4 + 255) / 256, 256, 0, stream>>>(c0, c1, out, BS * H / 4);
}

// Round 15
// 247.560 us; speedup vs baseline: 12.0760x; 1.0114x over previous
//
#include <hip/hip_runtime.h>
#include <hip/hip_bf16.h>
#include <math.h>

#define NH 32
#define NKV 8
#define HD 64
#define NSLOTS 11
#define TOPK 128
#define KBROW (NSLOTS * NH * HD)   // 22528
#define PADF (-3.3895313892515355e+38f)
#define C0F  (-0.24686007793152578f)   // -ln(128)+ln(100)
#define SCALE 0.125f
#define HCH 32                         // S-chunks for hierarchical column sum

typedef __attribute__((ext_vector_type(8))) __bf16 bf16x8;
typedef __attribute__((ext_vector_type(8))) unsigned short u16x8;
typedef __attribute__((ext_vector_type(4))) float f32x4;

#define GLDS16(gp, lp)                                                        \
  __builtin_amdgcn_global_load_lds(                                           \
      (__attribute__((address_space(1))) void*)(gp),                          \
      (__attribute__((address_space(3))) void*)(lp), 16, 0, 0)

__device__ __forceinline__ unsigned short f2bf(float f) {
  unsigned int u = __float_as_uint(f);
  u = (u + 0x7fffu + ((u >> 16) & 1u)) >> 16;
  return (unsigned short)u;
}

// byte offset into a 64-col bf16 tile (128 B/row) with XOR chunk swizzle
__device__ __forceinline__ int swz(int row, int chunk) {
  return row * 128 + ((chunk ^ (row & 7)) << 4);
}

// ---------------------------------------------------------------------------
// fp32 -> bf16 for 5 concatenated weight sources into one contiguous dest
// (wall | wobf). Units are float4.
// ---------------------------------------------------------------------------
__global__ void f2bf_all(const float* __restrict__ s0, const float* __restrict__ s1,
                         const float* __restrict__ s2, const float* __restrict__ s3,
                         const float* __restrict__ s4,
                         int n0, int n1, int n2, int n3, int n4_,
                         unsigned short* __restrict__ out) {
  int i = blockIdx.x * blockDim.x + threadIdx.x;
  int j = i;
  const float* src;
  if (j < n0) src = s0;
  else { j -= n0; if (j < n1) src = s1;
  else { j -= n1; if (j < n2) src = s2;
  else { j -= n2; if (j < n3) src = s3;
  else { j -= n3; if (j >= n4_) return; src = s4; }}}}
  float4 v = ((const float4*)src)[j];
  ushort4 o = {f2bf(v.x), f2bf(v.y), f2bf(v.z), f2bf(v.w)};
  ((ushort4*)out)[i] = o;
}

// ---------------------------------------------------------------------------
// bf16 MFMA GEMM, split-K=2 (m97 structure) — used for the Wo projection.
// ---------------------------------------------------------------------------
__global__ __launch_bounds__(256) void gemm_nt_splitk(
    const unsigned short* __restrict__ A, const unsigned short* __restrict__ B,
    float* __restrict__ C0, float* __restrict__ C1, int M, int N, int K) {
  __shared__ unsigned short ldsA[128 * 32];
  __shared__ unsigned short ldsB[128 * 32];
  const int t = threadIdx.x;
  const int l = t & 63, w = t >> 6;
  const int wr = w >> 1, wc = w & 1;
  const int lr = l & 15;
  const int kb = (l >> 4) * 16;
  const int bm = blockIdx.y * 128, bn = blockIdx.x * 128;
  float* C = blockIdx.z ? C1 : C0;
  const int k0base = blockIdx.z * (K >> 1);
  const int kend = k0base + (K >> 1);

  f32x4 acc[4][4] = {};

  for (int k0 = k0base; k0 < kend; k0 += 32) {
    __syncthreads();
#pragma unroll
    for (int it = 0; it < 2; ++it) {
      int s = it * 256 + t;
      int row = s >> 2, cs = (s & 3) * 8;
      GLDS16(A + (size_t)(bm + row) * K + k0 + cs,
             (char*)ldsA + (it * 4 + w) * 1024);
      GLDS16(B + (size_t)(bn + row) * K + k0 + cs,
             (char*)ldsB + (it * 4 + w) * 1024);
    }
    __syncthreads();

    bf16x8 a[4], b[4];
#pragma unroll
    for (int m = 0; m < 4; ++m)
      a[m] = *(const bf16x8*)((const char*)ldsA +
                              (wr * 64 + m * 16 + lr) * 64 + kb);
#pragma unroll
    for (int n = 0; n < 4; ++n)
      b[n] = *(const bf16x8*)((const char*)ldsB +
                              (wc * 64 + n * 16 + lr) * 64 + kb);
#pragma unroll
    for (int m = 0; m < 4; ++m)
#pragma unroll
      for (int n = 0; n < 4; ++n)
        acc[m][n] =
            __builtin_amdgcn_mfma_f32_16x16x32_bf16(a[m], b[n], acc[m][n], 0, 0, 0);
  }

#pragma unroll
  for (int m = 0; m < 4; ++m)
#pragma unroll
    for (int n = 0; n < 4; ++n) {
      int rbase = bm + wr * 64 + m * 16 + ((l >> 4) << 2);
      int cbase = bn + wc * 64 + n * 16 + lr;
#pragma unroll
      for (int j = 0; j < 4; ++j)
        C[(size_t)(rbase + j) * N + cbase] = acc[m][n][j];
    }
}

// ---------------------------------------------------------------------------
// out = a + b (float4 units)
// ---------------------------------------------------------------------------
__global__ void add2_kernel(const float* __restrict__ a,
                            const float* __restrict__ b,
                            float* __restrict__ o, int n4) {
  int i = blockIdx.x * blockDim.x + threadIdx.x;
  if (i >= n4) return;
  float4 x = ((const float4*)a)[i], y = ((const float4*)b)[i];
  ((float4*)o)[i] = make_float4(x.x + y.x, x.y + y.y, x.z + y.z, x.w + y.w);
}

// ---------------------------------------------------------------------------
// 8-wave 256x256 deep-pipelined projection GEMM + RoPE epilogue + direct V^T.
// v5: linear block mapping (XCD swizzle reverted — it tripled Wall re-fetch).
// Pipeline as v3/v4: read-ahead ds_reads, counted vmcnt, 2 barriers/K-tile.
// ---------------------------------------------------------------------------
__global__ __launch_bounds__(512) void gemm_proj8(
    const unsigned short* __restrict__ A,      // hbf [M][K]
    const unsigned short* __restrict__ Wall,   // [5120][K]
    const float* __restrict__ cosb, const float* __restrict__ sinb,
    unsigned short* __restrict__ qbf, unsigned short* __restrict__ q2bf,
    unsigned short* __restrict__ kbf, unsigned short* __restrict__ vTb,
    int M, int K, int S) {
  __shared__ char lds[131072];  // 2 buffers x (A 32KB | B 32KB)
  const int t = threadIdx.x;
  const int w = t >> 6;
  const int wm = w >> 2, wn = w & 3;
  const int l = t & 63;
  const int li = l & 15, lg4 = l >> 4;
  const int bm = blockIdx.y * 256, bn = blockIdx.x * 256;
  const int NK = K >> 6;

  f32x4 acc[8][4] = {};

#define STAGE_UNIT(kt1, nb, u)                                                \
  {                                                                           \
    const int slice_ = (u) >> 1;                                              \
    const unsigned short* mat_ = ((u) & 1) ? Wall : A;                        \
    const int tb_ = ((u) & 1) ? bn : bm;                                      \
    char* base_ = lds + (nb) * 65536 + (((u) & 1) ? 32768 : 0) +              \
                  slice_ * 16384;                                             \
    _Pragma("unroll")                                                         \
    for (int i_ = 0; i_ < 2; ++i_) {                                          \
      int ss_ = i_ * 512 + t;                                                 \
      int row_ = ss_ >> 2, cc_ = ss_ & 3;                                     \
      int chunk_ = cc_ ^ ((row_ >> 1) & 3);                                   \
      GLDS16(mat_ + (size_t)(tb_ + row_) * K + (kt1) * 64 + slice_ * 32 +     \
                 chunk_ * 8,                                                  \
             base_ + i_ * 8192 + w * 1024);                                   \
    }                                                                         \
  }

  // prologue: stage tile 0 fully into buffer 0; A0,B0 (units 0,1) must land.
  STAGE_UNIT(0, 0, 0); STAGE_UNIT(0, 0, 1);
  STAGE_UNIT(0, 0, 2); STAGE_UNIT(0, 0, 3);
  asm volatile("s_waitcnt vmcnt(4)" ::: "memory");
  asm volatile("s_barrier" ::: "memory");

  for (int kt = 0; kt < NK; ++kt) {
    const int cur = kt & 1;
    const bool stg = (kt + 1 < NK);
    char* curA = lds + cur * 65536;
    char* curB = curA + 32768;
#pragma unroll
    for (int kk = 0; kk < 2; ++kk) {
      bf16x8 bfr[4], af_a[4], af_b[4];
#pragma unroll
      for (int n = 0; n < 4; ++n) {
        int row = wn * 64 + n * 16 + li;
        bfr[n] = *(const bf16x8*)(curB + kk * 16384 + row * 64 +
                                  ((lg4 ^ ((row >> 1) & 3)) << 4));
      }
#pragma unroll
      for (int mi = 0; mi < 4; ++mi) {
        int row = wm * 128 + mi * 16 + li;
        af_a[mi] = *(const bf16x8*)(curA + kk * 16384 + row * 64 +
                                    ((lg4 ^ ((row >> 1) & 3)) << 4));
      }
      if (stg) STAGE_UNIT(kt + 1, cur ^ 1, kk * 2)
#pragma unroll
      for (int mi = 0; mi < 4; ++mi) {
        int row = wm * 128 + (4 + mi) * 16 + li;
        af_b[mi] = *(const bf16x8*)(curA + kk * 16384 + row * 64 +
                                    ((lg4 ^ ((row >> 1) & 3)) << 4));
      }
#pragma unroll
      for (int mi = 0; mi < 4; ++mi)
#pragma unroll
        for (int n = 0; n < 4; ++n)
          acc[mi][n] = __builtin_amdgcn_mfma_f32_16x16x32_bf16(
              af_a[mi], bfr[n], acc[mi][n], 0, 0, 0);
      if (stg) STAGE_UNIT(kt + 1, cur ^ 1, kk * 2 + 1)
#pragma unroll
      for (int mi = 0; mi < 4; ++mi)
#pragma unroll
        for (int n = 0; n < 4; ++n)
          acc[4 + mi][n] = __builtin_amdgcn_mfma_f32_16x16x32_bf16(
              af_b[mi], bfr[n], acc[4 + mi][n], 0, 0, 0);
      // vmcnt ledger: after kk=0 ensure units 2,3 of cur; after kk=1 ensure
      // units 0,1 of next tile. Never 0 mid-loop.
      if (kk == 0) {
        if (kt == NK - 1) asm volatile("s_waitcnt vmcnt(0)" ::: "memory");
        else              asm volatile("s_waitcnt vmcnt(4)" ::: "memory");
        asm volatile("s_barrier" ::: "memory");
      } else {
        if (stg) {
          asm volatile("s_waitcnt vmcnt(4)" ::: "memory");
          asm volatile("s_barrier" ::: "memory");
        }
      }
    }
  }
#undef STAGE_UNIT

  // ---- epilogue: segmented outputs with RoPE (8-wave fragment mapping)
  const int seg = bn;  // block-uniform
#pragma unroll
  for (int m = 0; m < 8; ++m) {
    const int row0 = bm + wm * 128 + m * 16 + lg4 * 4;
    if (seg < 2048 || (seg >= 4096 && seg < 4608)) {
      const bool isq = seg < 2048;
#pragma unroll
      for (int j = 0; j < 4; ++j) {
        int row = row0 + j;
        const float* cr = cosb + (size_t)row * 64;
        const float* sr = sinb + (size_t)row * 64;
        float c0 = cr[li], c1 = cr[16 + li], c2 = cr[32 + li], c3 = cr[48 + li];
        float sa = sr[li], sb = sr[16 + li], sc_ = sr[32 + li], sd = sr[48 + li];
        float x0 = acc[m][0][j], x1 = acc[m][1][j];
        float x2 = acc[m][2][j], x3 = acc[m][3][j];
        float y0 = x0 * c0 - x2 * sa;
        float y1 = x1 * c1 - x3 * sb;
        float y2 = x2 * c2 + x0 * sc_;
        float y3 = x3 * c3 + x1 * sd;
        if (isq) {
          size_t ro = (size_t)row * 2048 + bn + wn * 64 + li;
          qbf[ro] = f2bf(y0); qbf[ro + 16] = f2bf(y1);
          qbf[ro + 32] = f2bf(y2); qbf[ro + 48] = f2bf(y3);
        } else {
          size_t ro = (size_t)row * 512 + (bn - 4096) + wn * 64 + li;
          kbf[ro] = f2bf(y0); kbf[ro + 16] = f2bf(y1);
          kbf[ro + 32] = f2bf(y2); kbf[ro + 48] = f2bf(y3);
        }
      }
    } else if (seg < 4096) {  // q2 -> bf16
#pragma unroll
      for (int n = 0; n < 4; ++n) {
        int col = bn - 2048 + wn * 64 + n * 16 + li;
#pragma unroll
        for (int j = 0; j < 4; ++j)
          q2bf[(size_t)(row0 + j) * 2048 + col] = f2bf(acc[m][n][j]);
      }
    } else {  // v -> vT bf16 direct (j=0..3 consecutive s)
      int b_ = row0 / S, s = row0 % S;
#pragma unroll
      for (int n = 0; n < 4; ++n) {
        int col = (bn - 4608) + wn * 64 + n * 16 + li;
        int gg = col >> 6, d = col & 63;
        ushort4 o = {f2bf(acc[m][n][0]), f2bf(acc[m][n][1]),
                     f2bf(acc[m][n][2]), f2bf(acc[m][n][3])};
        *(ushort4*)&vTb[(((size_t)b_ * NKV + gg) * 64 + d) * S + s] = o;
      }
    }
  }
}

// ---------------------------------------------------------------------------
// KB key slice: kbkh[j][c] = bf16(kb_keys[j*KBROW + c]), j<128, c<2048.
// ---------------------------------------------------------------------------
__global__ void kbkh_kernel(const float* __restrict__ kbk,
                            unsigned short* __restrict__ out) {
  int i = blockIdx.x * blockDim.x + threadIdx.x;
  if (i >= 128 * 512) return;
  int j = i >> 9, c4 = (i & 511) * 4;
  float4 v = *(const float4*)&kbk[(size_t)j * KBROW + c4];
  ushort4 o = {f2bf(v.x), f2bf(v.y), f2bf(v.z), f2bf(v.w)};
  *(ushort4*)&out[(size_t)j * 2048 + c4] = o;
}

// ---------------------------------------------------------------------------
// Gathered + transposed KB values -> [B][NH][64][128] bf16.
// ---------------------------------------------------------------------------
__global__ __launch_bounds__(256) void kbvgt_kernel(
    const float* __restrict__ kbv, const int* __restrict__ topi,
    unsigned short* __restrict__ kbvgT, int B) {
  int h = blockIdx.x % NH, b = blockIdx.x / NH;
  __shared__ unsigned short gt[128][72];
  __shared__ int lidx[TOPK];
  int t = threadIdx.x;
  if (t < TOPK) lidx[t] = topi[b * TOPK + t];
  __syncthreads();
#pragma unroll
  for (int it = 0; it < 8; ++it) {
    int slot = it * 256 + t;
    int j = slot >> 4, d4 = (slot & 15) * 4;
    float4 v = *(const float4*)&kbv[(size_t)lidx[j] * KBROW + h * 64 + d4];
    gt[j][d4] = f2bf(v.x); gt[j][d4 + 1] = f2bf(v.y);
    gt[j][d4 + 2] = f2bf(v.z); gt[j][d4 + 3] = f2bf(v.w);
  }
  __syncthreads();
#pragma unroll
  for (int it = 0; it < 4; ++it) {
    int slot = it * 256 + t;
    int d = slot >> 4, j8 = (slot & 15) * 8;
    u16x8 o;
#pragma unroll
    for (int j = 0; j < 8; ++j) o[j] = gt[j8 + j][d];
    *(u16x8*)&kbvgT[(((size_t)b * NH + h) * 64 + d) * 128 + j8] = o;
  }
}

// ---------------------------------------------------------------------------
// Column-sum stage 1 + fused hidden f2bf.
// ---------------------------------------------------------------------------
__global__ __launch_bounds__(256) void hsum1_kernel(
    const float* __restrict__ hidden, double* __restrict__ part,
    unsigned short* __restrict__ hbf, int B, int S, int H) {
  const int nhb = H >> 8;
  int hb = blockIdx.x % nhb;
  int ch = (blockIdx.x / nhb) % HCH;
  int b  = blockIdx.x / (nhb * HCH);
  int c  = hb * 256 + threadIdx.x;
  int rows = S / HCH;
  size_t base = ((size_t)b * S + (size_t)ch * rows) * H + c;
  const float* p = hidden + base;
  double acc = 0.0;
  for (int s = 0; s < rows; ++s) {
    float v = p[(size_t)s * H];
    acc += (double)v;
    hbf[base + (size_t)s * H] = f2bf(v);
  }
  part[((size_t)b * HCH + ch) * H + c] = acc;
}

// ---------------------------------------------------------------------------
// Column-sum stage 2: Hsum[b][c] = sum_ch part[b][ch][c] (f64, fixed order).
// ---------------------------------------------------------------------------
__global__ void hsum2_kernel(const double* __restrict__ part,
                             float* __restrict__ Hsum, int B, int H) {
  int idx = blockIdx.x * blockDim.x + threadIdx.x;
  if (idx >= B * H) return;
  int b = idx / H, c = idx % H;
  const double* p = part + (size_t)b * HCH * H + c;
  double acc = 0.0;
#pragma unroll
  for (int ch = 0; ch < HCH; ++ch) acc += p[(size_t)ch * H];
  Hsum[idx] = (float)acc;
}

// ---------------------------------------------------------------------------
// Qs[b][c] = sum_k Hsum[b][k] * Wq2[c][k]  (fp32 inputs, f64 accum).
// ---------------------------------------------------------------------------
__global__ void qs_kernel(const float* __restrict__ Hsum,
                          const float* __restrict__ Wq2,
                          float* __restrict__ Qs, int B, int H) {
  int task = (blockIdx.x * blockDim.x + threadIdx.x) >> 6;
  int lane = threadIdx.x & 63;
  if (task >= B * NH * HD) return;
  int b = task / (NH * HD), c = task % (NH * HD);
  const float* hs = Hsum + (size_t)b * H;
  const float* wr = Wq2 + (size_t)c * H;
  double acc = 0.0;
  for (int k = lane; k < H; k += 64) acc += (double)hs[k] * (double)wr[k];
#pragma unroll
  for (int off = 32; off; off >>= 1) acc += __shfl_xor(acc, off);
  if (lane == 0) Qs[task] = (float)acc;
}

// ---------------------------------------------------------------------------
// scores[b][l] = 0.125 * dot(Qs[b,:], kb_keys[l, 0:2048]) (f64 acc)
// ---------------------------------------------------------------------------
__global__ void scores_kernel(const float* __restrict__ Qs,
                              const float* __restrict__ kbk,
                              float* __restrict__ scores, int B, int KBL) {
  int task = (blockIdx.x * blockDim.x + threadIdx.x) >> 6;
  int lane = threadIdx.x & 63;
  if (task >= B * KBL) return;
  int b = task / KBL, l = task % KBL;
  const float* kr = kbk + (size_t)l * KBROW;
  const float* qd = Qs + (size_t)b * NH * HD;
  double acc = 0.0;
  for (int c = lane; c < NH * HD; c += 64) acc += (double)qd[c] * (double)kr[c];
#pragma unroll
  for (int off = 32; off; off >>= 1) acc += __shfl_xor(acc, off);
  if (lane == 0) scores[task] = (float)(0.125 * acc);
}

// ---------------------------------------------------------------------------
// Top-K by rank-counting (stable descending == lax.top_k).
// ---------------------------------------------------------------------------
__global__ __launch_bounds__(256) void topk_kernel(
    const float* __restrict__ scores, int* __restrict__ top_idx, int KBL) {
  __shared__ float ls[512];
  int b = blockIdx.x, t = threadIdx.x;
  for (int i = t; i < KBL; i += 256) ls[i] = scores[(size_t)b * KBL + i];
  __syncthreads();
  for (int l = t; l < KBL; l += 256) {
    float sl = ls[l];
    int rank = 0;
    for (int j = 0; j < KBL; ++j) {
      float sj = ls[j];
      rank += (sj > sl || (sj == sl && j < l)) ? 1 : 0;
    }
    if (rank < TOPK) top_idx[b * TOPK + rank] = l;
  }
}

// ---------------------------------------------------------------------------
// padflag[b*S+s] = all(mask[b,0,s,:] < 0)
// ---------------------------------------------------------------------------
__global__ void padflag_kernel(const float* __restrict__ mask,
                               int* __restrict__ flags, int BS, int S) {
  int w = (blockIdx.x * blockDim.x + threadIdx.x) >> 6;
  int lane = threadIdx.x & 63;
  if (w >= BS) return;
  const float* row = mask + (size_t)w * S;
  bool ok = true;
  for (int j = lane; j < S; j += 64) ok = ok && (row[j] < 0.f);
  int allv = __all(ok ? 1 : 0);
  if (lane == 0) flags[w] = allv;
}

// ---------------------------------------------------------------------------
// Load one K/V chunk's staged data into registers (4 x bf16x8 per thread).
// ---------------------------------------------------------------------------
__device__ __forceinline__ void load_chunk(
    int ch, int t, int b, int h, int g, int S,
    const unsigned short* __restrict__ kbf, const unsigned short* __restrict__ vTb,
    const unsigned short* __restrict__ kbkh, const unsigned short* __restrict__ kbvgT,
    bf16x8* st) {
  bool iskb = ch < 2;
  int j0 = iskb ? ch * 64 : (ch - 2) * 64;
#pragma unroll
  for (int it = 0; it < 4; ++it) {
    int slot = it * 256 + t;
    int tile = slot >> 9, row = (slot >> 3) & 63, ck = slot & 7;
    const unsigned short* src;
    if (tile == 0)
      src = iskb ? kbkh + (size_t)(j0 + row) * 2048 + h * 64 + ck * 8
                 : kbf + (size_t)(b * S + j0 + row) * 512 + g * 64 + ck * 8;
    else
      src = iskb ? kbvgT + (((size_t)b * NH + h) * 64 + row) * 128 + j0 + ck * 8
                 : vTb + (((size_t)b * NKV + g) * 64 + row) * (size_t)S + j0 + ck * 8;
    st[it] = *(const bf16x8*)src;
  }
}

// ---------------------------------------------------------------------------
// One chunk of QK^T -> online softmax -> PV for one q-tile.
// cbuf points at this chunk's 16 KB buffer (K at +0, V^T at +8192).
// ---------------------------------------------------------------------------
__device__ __forceinline__ void attn_step(
    const char* cbuf, char* ptw, const int* padfb, const bf16x8* aq,
    bool iskb, int j0, int s0, int w, int li, int lg4,
    float* m_, float* l_, f32x4* acc) {
  f32x4 cc[4];
  __builtin_amdgcn_s_setprio(1);
#pragma unroll
  for (int cb = 0; cb < 4; ++cb) {
    bf16x8 b0 = *(const bf16x8*)(cbuf + swz(cb * 16 + li, lg4));
    bf16x8 b1 = *(const bf16x8*)(cbuf + swz(cb * 16 + li, 4 + lg4));
    f32x4 z = {};
    z = __builtin_amdgcn_mfma_f32_16x16x32_bf16(aq[0], b0, z, 0, 0, 0);
    z = __builtin_amdgcn_mfma_f32_16x16x32_bf16(aq[1], b1, z, 0, 0, 0);
    cc[cb] = z;
  }
  __builtin_amdgcn_s_setprio(0);

  float lgv[4][4];
#pragma unroll
  for (int cb = 0; cb < 4; ++cb)
#pragma unroll
    for (int j = 0; j < 4; ++j) {
      float v = SCALE * cc[cb][j];
      if (iskb) {
        v += C0F + (padfb[w * 16 + lg4 * 4 + j] ? PADF : 0.f);
      } else {
        int key = j0 + cb * 16 + li;
        int srow = s0 + w * 16 + lg4 * 4 + j;
        v += (key <= srow) ? 0.f : PADF;
      }
      lgv[cb][j] = v;
    }
#pragma unroll
  for (int j = 0; j < 4; ++j) {
    float rmax = fmaxf(fmaxf(lgv[0][j], lgv[1][j]), fmaxf(lgv[2][j], lgv[3][j]));
#pragma unroll
    for (int off = 8; off; off >>= 1) rmax = fmaxf(rmax, __shfl_xor(rmax, off));
    float mn = fmaxf(m_[j], rmax);
    float fs = __expf(m_[j] - mn);
    float csum = 0.f;
#pragma unroll
    for (int cb = 0; cb < 4; ++cb) {
      float pv = __expf(lgv[cb][j] - mn);
      csum += pv;
      int key = cb * 16 + li;
      int rloc = lg4 * 4 + j;
      *(unsigned short*)(ptw + swz(rloc, key >> 3) + ((key & 7) << 1)) = f2bf(pv);
    }
#pragma unroll
    for (int off = 8; off; off >>= 1) csum += __shfl_xor(csum, off);
    m_[j] = mn;
    l_[j] = l_[j] * fs + csum;
#pragma unroll
    for (int db = 0; db < 4; ++db) acc[db][j] *= fs;
  }

  bf16x8 pa0 = *(const bf16x8*)(ptw + swz(li, lg4));
  bf16x8 pa1 = *(const bf16x8*)(ptw + swz(li, 4 + lg4));
  __builtin_amdgcn_s_setprio(1);
#pragma unroll
  for (int db = 0; db < 4; ++db) {
    bf16x8 bv0 = *(const bf16x8*)(cbuf + 8192 + swz(db * 16 + li, lg4));
    bf16x8 bv1 = *(const bf16x8*)(cbuf + 8192 + swz(db * 16 + li, 4 + lg4));
    acc[db] = __builtin_amdgcn_mfma_f32_16x16x32_bf16(pa0, bv0, acc[db], 0, 0, 0);
    acc[db] = __builtin_amdgcn_mfma_f32_16x16x32_bf16(pa1, bv1, acc[db], 0, 0, 0);
  }
  __builtin_amdgcn_s_setprio(0);
}

// ---------------------------------------------------------------------------
// MFMA fused attention v5: diagonal pairing + async reg-staged prefetch +
// DOUBLE-BUFFERED K/V LDS -> single barrier per chunk. Iteration ch:
//   write st (chunk ch+1 data) -> buf[(ch+1)&1]   (prev consumer of that
//     buffer finished at the ch-1 barrier)
//   issue global loads for chunk ch+2 -> st       (latency spans compute)
//   compute chunk ch from buf[ch&1]
//   barrier                                        (publishes ch+1's writes)
// ---------------------------------------------------------------------------
__global__ __launch_bounds__(256) void attn_mfma(
    const unsigned short* __restrict__ qbf,    // [B*S][2048] roped bf16
    const unsigned short* __restrict__ q2bf,   // [B*S][2048] bf16
    const unsigned short* __restrict__ kbf,    // [B*S][512] roped bf16
    const unsigned short* __restrict__ vTb,    // [B][NKV][64][S] bf16
    const unsigned short* __restrict__ kbkh,   // [128][2048] bf16
    const unsigned short* __restrict__ kbvgT,  // [B][NH][64][128] bf16
    const int* __restrict__ padflag,           // [B*S]
    unsigned short* __restrict__ attnbf,       // [B*S][2048] bf16
    int B, int S) {
  const int nst = S >> 6;
  const int npair = (nst + 1) >> 1;
  const int p = blockIdx.x % npair;
  const int h = (blockIdx.x / npair) % NH;
  const int b = blockIdx.x / (npair * NH);
  const int stA = p, stB = nst - 1 - p;
  const bool hasB = (stB != stA);
  const int s0A = stA * 64, s0B = stB * 64;
  const int g = h / (NH / NKV);

  __shared__ unsigned short smem[2][8192];  // double-buffered K|V^T tiles
  __shared__ unsigned short pt[4][1024];    // per-wave P [row16][key64]
  __shared__ int padf[128];

  const int t = threadIdx.x;
  const int w = t >> 6;
  const int li = t & 15;
  const int lg4 = (t & 63) >> 4;

  const int nch = 2 + stB + 1;

  // prologue: chunk 0 -> regs -> buf0; chunk 1 -> regs; q frags; padf
  bf16x8 st[4];
  load_chunk(0, t, b, h, g, S, kbf, vTb, kbkh, kbvgT, st);

  bf16x8 aq0A[2], aq2A[2], aq0B[2], aq2B[2];
  {
    size_t rowA = (size_t)(b * S + s0A + w * 16 + li) * (NH * HD);
    size_t rowB = (size_t)(b * S + s0B + w * 16 + li) * (NH * HD);
#pragma unroll
    for (int kc = 0; kc < 2; ++kc) {
      size_t o = h * 64 + kc * 32 + lg4 * 8;
      aq0A[kc] = *(const bf16x8*)(qbf + rowA + o);
      aq2A[kc] = *(const bf16x8*)(q2bf + rowA + o);
      aq0B[kc] = *(const bf16x8*)(qbf + rowB + o);
      aq2B[kc] = *(const bf16x8*)(q2bf + rowB + o);
    }
  }
  if (t < 64) padf[t] = padflag[b * S + s0A + t];
  else if (t < 128) padf[t] = padflag[b * S + s0B + (t - 64)];

#pragma unroll
  for (int it = 0; it < 4; ++it) {
    int slot = it * 256 + t;
    int tile = slot >> 9, row = (slot >> 3) & 63, ck = slot & 7;
    *(bf16x8*)((char*)smem[0] + tile * 8192 + swz(row, ck)) = st[it];
  }
  load_chunk(1, t, b, h, g, S, kbf, vTb, kbkh, kbvgT, st);
  __syncthreads();  // buf0 + padf visible

  float mA[4] = {-3.4e38f, -3.4e38f, -3.4e38f, -3.4e38f};
  float mB[4] = {-3.4e38f, -3.4e38f, -3.4e38f, -3.4e38f};
  float lA[4] = {}, lB[4] = {};
  f32x4 accA[4] = {}, accB[4] = {};

  for (int ch = 0; ch < nch; ++ch) {
    const bool iskb = ch < 2;
    const int j0 = iskb ? ch * 64 : (ch - 2) * 64;
    // write chunk ch+1 (already in regs) into the other buffer; prefetch ch+2
    if (ch + 1 < nch) {
      char* nb = (char*)smem[(ch + 1) & 1];
#pragma unroll
      for (int it = 0; it < 4; ++it) {
        int slot = it * 256 + t;
        int tile = slot >> 9, row = (slot >> 3) & 63, ck = slot & 7;
        *(bf16x8*)(nb + tile * 8192 + swz(row, ck)) = st[it];
      }
      if (ch + 2 < nch)
        load_chunk(ch + 2, t, b, h, g, S, kbf, vTb, kbkh, kbvgT, st);
    }
    const char* cb = (const char*)smem[ch & 1];
    if (iskb || (ch - 2) <= stA)
      attn_step(cb, (char*)pt[w], padf, iskb ? aq2A : aq0A,
                iskb, j0, s0A, w, li, lg4, mA, lA, accA);
    if (hasB)
      attn_step(cb, (char*)pt[w], padf + 64, iskb ? aq2B : aq0B,
                iskb, j0, s0B, w, li, lg4, mB, lB, accB);
    __syncthreads();  // publish ch+1's writes; all waves done with buf[ch&1]
  }

#pragma unroll
  for (int j = 0; j < 4; ++j) {
    float inv = 1.f / lA[j];
    size_t o = (size_t)(b * S + s0A + w * 16 + lg4 * 4 + j) * (NH * HD) + h * 64 + li;
#pragma unroll
    for (int db = 0; db < 4; ++db) attnbf[o + db * 16] = f2bf(accA[db][j] * inv);
  }
  if (hasB) {
#pragma unroll
    for (int j = 0; j < 4; ++j) {
      float inv = 1.f / lB[j];
      size_t o = (size_t)(b * S + s0B + w * 16 + lg4 * 4 + j) * (NH * HD) + h * 64 + li;
#pragma unroll
      for (int db = 0; db < 4; ++db) attnbf[o + db * 16] = f2bf(accB[db][j] * inv);
    }
  }
}

// ---------------------------------------------------------------------------
extern "C" void kernel_launch(void* const* d_in, const int* in_sizes, int n_in,
                              void* d_out, int out_size, void* d_ws, size_t ws_size,
                              hipStream_t stream) {
  const float* hidden = (const float*)d_in[0];
  const float* cosb   = (const float*)d_in[1];
  const float* sinb   = (const float*)d_in[2];
  const float* mask   = (const float*)d_in[3];
  const float* kbk    = (const float*)d_in[4];
  const float* kbv    = (const float*)d_in[5];
  const float* Wq     = (const float*)d_in[6];
  const float* Wq2    = (const float*)d_in[7];
  const float* Wk     = (const float*)d_in[8];
  const float* Wv     = (const float*)d_in[9];
  const float* Wo     = (const float*)d_in[10];
  float* out = (float*)d_out;

  const int H   = in_sizes[6] / (NH * HD);             // 2048
  const int KBL = in_sizes[4] / KBROW;                 // 400
  const long long BSll = (long long)in_sizes[0] / H;
  const int S = (int)((long long)in_sizes[3] / BSll);  // 1024
  const int B = (int)(BSll / S);                       // 2
  const int BS = B * S;
  const int NQ = NH * HD;                              // 2048
  const int NKVD = NKV * HD;                           // 512
  const int NTOT = NQ + NQ + NKVD + NKVD;              // 5120

  float* ws = (float*)d_ws;
  size_t off = 0;
  double* hpart = (double*)(ws + off); off += (size_t)B * HCH * H * 2;
  float* Hsum = ws + off; off += (size_t)B * H;
  float* Qs   = ws + off; off += (size_t)B * NQ;
  float* sc   = ws + off; off += (size_t)B * KBL;
  int* topi   = (int*)(ws + off); off += (size_t)B * TOPK;
  int* padfl  = (int*)(ws + off); off += (size_t)BS;
  unsigned short* hbf    = (unsigned short*)(ws + off); off += (size_t)BS * H / 2;
  unsigned short* wall   = (unsigned short*)(ws + off); off += (size_t)NTOT * H / 2;
  unsigned short* wobf   = (unsigned short*)(ws + off); off += (size_t)H * NQ / 2;
  unsigned short* attnbf = (unsigned short*)(ws + off); off += (size_t)BS * NQ / 2;
  unsigned short* qbf    = (unsigned short*)(ws + off); off += (size_t)BS * NQ / 2;
  unsigned short* q2bf   = (unsigned short*)(ws + off); off += (size_t)BS * NQ / 2;
  unsigned short* kbf    = (unsigned short*)(ws + off); off += (size_t)BS * NKVD / 2;
  unsigned short* vTb    = (unsigned short*)(ws + off); off += (size_t)BS * NKVD / 2;
  unsigned short* kbkh   = (unsigned short*)(ws + off); off += (size_t)128 * NQ / 2;
  unsigned short* kbvgT  = (unsigned short*)(ws + off); off += (size_t)B * NH * HD * TOPK / 2;
  float* c0 = (float*)qbf;   // dead after attn_mfma
  float* c1 = (float*)wall;  // dead after gemm_proj8
  (void)ws_size; (void)n_in; (void)out_size;

  // 0: weight fp32 -> bf16 (dest wall|wobf contiguous)
  {
    int n1 = NQ * H / 4, n2 = NQ * H / 4;
    int n3 = NKVD * H / 4, n4_ = NKVD * H / 4, n5 = H * NQ / 4;
    int ntot = n1 + n2 + n3 + n4_ + n5;
    f2bf_all<<<(ntot + 255) / 256, 256, 0, stream>>>(
        Wq, Wq2, Wk, Wv, Wo, n1, n2, n3, n4_, n5, wall);
  }

  // 1: hidden column-sum stage 1 + fused hidden f2bf (produces hbf)
  hsum1_kernel<<<B * HCH * (H / 256), 256, 0, stream>>>(hidden, hpart, hbf, B, S, H);

  // 2: fused projections + RoPE + direct V^T (8-wave, linear mapping)
  gemm_proj8<<<dim3(NTOT / 256, BS / 256), 512, 0, stream>>>(
      hbf, wall, cosb, sinb, qbf, q2bf, kbf, vTb, BS, H, S);

  // 3-6: exact fp32 scores path + top-k + padding
  hsum2_kernel<<<(B * H + 255) / 256, 256, 0, stream>>>(hpart, Hsum, B, H);
  qs_kernel<<<(B * NQ * 64 + 255) / 256, 256, 0, stream>>>(Hsum, Wq2, Qs, B, H);
  scores_kernel<<<(B * KBL * 64 + 255) / 256, 256, 0, stream>>>(Qs, kbk, sc, B, KBL);
  topk_kernel<<<B, 256, 0, stream>>>(sc, topi, KBL);
  padflag_kernel<<<(BS * 64 + 255) / 256, 256, 0, stream>>>(mask, padfl, BS, S);

  // 7-8: KB bf16 staging
  kbkh_kernel<<<(128 * 512 + 255) / 256, 256, 0, stream>>>(kbk, kbkh);
  kbvgt_kernel<<<B * NH, 256, 0, stream>>>(kbv, topi, kbvgT, B);

  // 9: fused attention (paired tiles, double-buffered, 1 barrier/chunk)
  {
    int nst = S / 64;
    int npair = (nst + 1) / 2;
    attn_mfma<<<B * NH * npair, 256, 0, stream>>>(
        qbf, q2bf, kbf, vTb, kbkh, kbvgT, padfl, attnbf, B, S);
  }

  // 10-11: output projection, split-K=2 + partial add
  gemm_nt_splitk<<<dim3(H / 128, BS / 128, 2), 256, 0, stream>>>(
      attnbf, wobf, c0, c1, BS, H, NQ);
  add2_kernel<<<(BS * H / 4 + 255) / 256, 256, 0, stream>>>(c0, c1, out, BS * H / 4);
}

// Round 16
// 245.257 us; speedup vs baseline: 12.1894x; 1.0094x over previous
//
#include <hip/hip_runtime.h>
#include <hip/hip_bf16.h>
#include <math.h>

#define NH 32
#define NKV 8
#define HD 64
#define NSLOTS 11
#define TOPK 128
#define KBROW (NSLOTS * NH * HD)   // 22528
#define PADF (-3.3895313892515355e+38f)
#define C0F  (-0.24686007793152578f)   // -ln(128)+ln(100)
#define SCALE 0.125f
#define HCH 32                         // S-chunks for hierarchical column sum

typedef __attribute__((ext_vector_type(8))) __bf16 bf16x8;
typedef __attribute__((ext_vector_type(8))) unsigned short u16x8;
typedef __attribute__((ext_vector_type(4))) float f32x4;

#define GLDS16(gp, lp)                                                        \
  __builtin_amdgcn_global_load_lds(                                           \
      (__attribute__((address_space(1))) void*)(gp),                          \
      (__attribute__((address_space(3))) void*)(lp), 16, 0, 0)

__device__ __forceinline__ unsigned short f2bf(float f) {
  unsigned int u = __float_as_uint(f);
  u = (u + 0x7fffu + ((u >> 16) & 1u)) >> 16;
  return (unsigned short)u;
}

// byte offset into a 64-col bf16 tile (128 B/row) with XOR chunk swizzle
__device__ __forceinline__ int swz(int row, int chunk) {
  return row * 128 + ((chunk ^ (row & 7)) << 4);
}

// ---------------------------------------------------------------------------
// fp32 -> bf16 for 5 concatenated weight sources into one contiguous dest.
// ---------------------------------------------------------------------------
__global__ void f2bf_all(const float* __restrict__ s0, const float* __restrict__ s1,
                         const float* __restrict__ s2, const float* __restrict__ s3,
                         const float* __restrict__ s4,
                         int n0, int n1, int n2, int n3, int n4_,
                         unsigned short* __restrict__ out) {
  int i = blockIdx.x * blockDim.x + threadIdx.x;
  int j = i;
  const float* src;
  if (j < n0) src = s0;
  else { j -= n0; if (j < n1) src = s1;
  else { j -= n1; if (j < n2) src = s2;
  else { j -= n2; if (j < n3) src = s3;
  else { j -= n3; if (j >= n4_) return; src = s4; }}}}
  float4 v = ((const float4*)src)[j];
  ushort4 o = {f2bf(v.x), f2bf(v.y), f2bf(v.z), f2bf(v.w)};
  ((ushort4*)out)[i] = o;
}

// ---------------------------------------------------------------------------
// bf16 MFMA GEMM, split-K=2 (m97 structure) — used for the Wo projection.
// ---------------------------------------------------------------------------
__global__ __launch_bounds__(256) void gemm_nt_splitk(
    const unsigned short* __restrict__ A, const unsigned short* __restrict__ B,
    float* __restrict__ C0, float* __restrict__ C1, int M, int N, int K) {
  __shared__ unsigned short ldsA[128 * 32];
  __shared__ unsigned short ldsB[128 * 32];
  const int t = threadIdx.x;
  const int l = t & 63, w = t >> 6;
  const int wr = w >> 1, wc = w & 1;
  const int lr = l & 15;
  const int kb = (l >> 4) * 16;
  const int bm = blockIdx.y * 128, bn = blockIdx.x * 128;
  float* C = blockIdx.z ? C1 : C0;
  const int k0base = blockIdx.z * (K >> 1);
  const int kend = k0base + (K >> 1);

  f32x4 acc[4][4] = {};

  for (int k0 = k0base; k0 < kend; k0 += 32) {
    __syncthreads();
#pragma unroll
    for (int it = 0; it < 2; ++it) {
      int s = it * 256 + t;
      int row = s >> 2, cs = (s & 3) * 8;
      GLDS16(A + (size_t)(bm + row) * K + k0 + cs,
             (char*)ldsA + (it * 4 + w) * 1024);
      GLDS16(B + (size_t)(bn + row) * K + k0 + cs,
             (char*)ldsB + (it * 4 + w) * 1024);
    }
    __syncthreads();

    bf16x8 a[4], b[4];
#pragma unroll
    for (int m = 0; m < 4; ++m)
      a[m] = *(const bf16x8*)((const char*)ldsA +
                              (wr * 64 + m * 16 + lr) * 64 + kb);
#pragma unroll
    for (int n = 0; n < 4; ++n)
      b[n] = *(const bf16x8*)((const char*)ldsB +
                              (wc * 64 + n * 16 + lr) * 64 + kb);
#pragma unroll
    for (int m = 0; m < 4; ++m)
#pragma unroll
      for (int n = 0; n < 4; ++n)
        acc[m][n] =
            __builtin_amdgcn_mfma_f32_16x16x32_bf16(a[m], b[n], acc[m][n], 0, 0, 0);
  }

#pragma unroll
  for (int m = 0; m < 4; ++m)
#pragma unroll
    for (int n = 0; n < 4; ++n) {
      int rbase = bm + wr * 64 + m * 16 + ((l >> 4) << 2);
      int cbase = bn + wc * 64 + n * 16 + lr;
#pragma unroll
      for (int j = 0; j < 4; ++j)
        C[(size_t)(rbase + j) * N + cbase] = acc[m][n][j];
    }
}

// ---------------------------------------------------------------------------
// out = a + b (float4 units)
// ---------------------------------------------------------------------------
__global__ void add2_kernel(const float* __restrict__ a,
                            const float* __restrict__ b,
                            float* __restrict__ o, int n4) {
  int i = blockIdx.x * blockDim.x + threadIdx.x;
  if (i >= n4) return;
  float4 x = ((const float4*)a)[i], y = ((const float4*)b)[i];
  ((float4*)o)[i] = make_float4(x.x + y.x, x.y + y.y, x.z + y.z, x.w + y.w);
}

// ---------------------------------------------------------------------------
// 16-wave 256x256 deep-pipelined projection GEMM + RoPE epilogue + direct
// V^T. v6: 1024 threads = 4 waves/SIMD (was 2) for intra-CU latency hiding.
// Wave grid 4M x 4N, wave tile 64x64, acc 4x4. BK=64 in 2 K-slices.
// Staging: 4 units/tile (A0,B0,A1,B1), 1 global_load_lds/thread/unit;
// counted vmcnt(2) at phase ends (ledger verified), 2 barriers/tile.
// ---------------------------------------------------------------------------
__global__ __launch_bounds__(1024) void gemm_proj8(
    const unsigned short* __restrict__ A,      // hbf [M][K]
    const unsigned short* __restrict__ Wall,   // [5120][K]
    const float* __restrict__ cosb, const float* __restrict__ sinb,
    unsigned short* __restrict__ qbf, unsigned short* __restrict__ q2bf,
    unsigned short* __restrict__ kbf, unsigned short* __restrict__ vTb,
    int M, int K, int S) {
  __shared__ char lds[131072];  // 2 buffers x (A 32KB | B 32KB)
  const int t = threadIdx.x;
  const int w = t >> 6;                 // 0..15
  const int wm = w >> 2, wn = w & 3;    // 4M x 4N
  const int l = t & 63;
  const int li = l & 15, lg4 = l >> 4;
  const int bm = blockIdx.y * 256, bn = blockIdx.x * 256;
  const int NK = K >> 6;

  f32x4 acc[4][4] = {};

  // stage unit u of K-tile kt1 into buffer nb. u&1: 0=A,1=B; u>>1 = K-slice.
  // One 16B load per thread (1024 threads x 16B = 16KB unit).
#define STAGE_UNIT(kt1, nb, u)                                                \
  {                                                                           \
    const int slice_ = (u) >> 1;                                              \
    const unsigned short* mat_ = ((u) & 1) ? Wall : A;                        \
    const int tb_ = ((u) & 1) ? bn : bm;                                      \
    char* base_ = lds + (nb) * 65536 + (((u) & 1) ? 32768 : 0) +              \
                  slice_ * 16384;                                             \
    int row_ = t >> 2, cc_ = t & 3;                                           \
    int chunk_ = cc_ ^ ((row_ >> 1) & 3);                                     \
    GLDS16(mat_ + (size_t)(tb_ + row_) * K + (kt1) * 64 + slice_ * 32 +       \
               chunk_ * 8,                                                    \
           base_ + w * 1024);                                                 \
  }

  // prologue: stage tile 0 into buffer 0; units 0,1 (slice 0) must land.
  STAGE_UNIT(0, 0, 0); STAGE_UNIT(0, 0, 1);
  STAGE_UNIT(0, 0, 2); STAGE_UNIT(0, 0, 3);
  asm volatile("s_waitcnt vmcnt(2)" ::: "memory");
  asm volatile("s_barrier" ::: "memory");

  for (int kt = 0; kt < NK; ++kt) {
    const int cur = kt & 1;
    const bool stg = (kt + 1 < NK);
    char* curA = lds + cur * 65536;
    char* curB = curA + 32768;
#pragma unroll
    for (int kk = 0; kk < 2; ++kk) {
      bf16x8 bfr[4], af[4];
#pragma unroll
      for (int n = 0; n < 4; ++n) {
        int row = wn * 64 + n * 16 + li;
        bfr[n] = *(const bf16x8*)(curB + kk * 16384 + row * 64 +
                                  ((lg4 ^ ((row >> 1) & 3)) << 4));
      }
#pragma unroll
      for (int mi = 0; mi < 4; ++mi) {
        int row = wm * 64 + mi * 16 + li;
        af[mi] = *(const bf16x8*)(curA + kk * 16384 + row * 64 +
                                  ((lg4 ^ ((row >> 1) & 3)) << 4));
      }
      if (stg) {
        STAGE_UNIT(kt + 1, cur ^ 1, kk * 2)
        STAGE_UNIT(kt + 1, cur ^ 1, kk * 2 + 1)
      }
#pragma unroll
      for (int mi = 0; mi < 4; ++mi)
#pragma unroll
        for (int n = 0; n < 4; ++n)
          acc[mi][n] = __builtin_amdgcn_mfma_f32_16x16x32_bf16(
              af[mi], bfr[n], acc[mi][n], 0, 0, 0);
      // ledger: after kk=0 need units 2,3 of cur (issued one phase earlier);
      // newest 2 loads (units kk*2,kk*2+1 of next) may stay in flight.
      // After kk=1 need units 0,1 of next tile; newest 2 (units 2,3) fly.
      if (kk == 0) {
        if (kt == NK - 1) asm volatile("s_waitcnt vmcnt(0)" ::: "memory");
        else              asm volatile("s_waitcnt vmcnt(2)" ::: "memory");
        asm volatile("s_barrier" ::: "memory");
      } else {
        if (stg) {
          asm volatile("s_waitcnt vmcnt(2)" ::: "memory");
          asm volatile("s_barrier" ::: "memory");
        }
      }
    }
  }
#undef STAGE_UNIT

  // ---- epilogue: segmented outputs with RoPE (16-wave fragment mapping)
  const int seg = bn;  // block-uniform
#pragma unroll
  for (int m = 0; m < 4; ++m) {
    const int row0 = bm + wm * 64 + m * 16 + lg4 * 4;
    if (seg < 2048 || (seg >= 4096 && seg < 4608)) {
      const bool isq = seg < 2048;
#pragma unroll
      for (int j = 0; j < 4; ++j) {
        int row = row0 + j;
        const float* cr = cosb + (size_t)row * 64;
        const float* sr = sinb + (size_t)row * 64;
        float c0 = cr[li], c1 = cr[16 + li], c2 = cr[32 + li], c3 = cr[48 + li];
        float sa = sr[li], sb = sr[16 + li], sc_ = sr[32 + li], sd = sr[48 + li];
        float x0 = acc[m][0][j], x1 = acc[m][1][j];
        float x2 = acc[m][2][j], x3 = acc[m][3][j];
        float y0 = x0 * c0 - x2 * sa;
        float y1 = x1 * c1 - x3 * sb;
        float y2 = x2 * c2 + x0 * sc_;
        float y3 = x3 * c3 + x1 * sd;
        if (isq) {
          size_t ro = (size_t)row * 2048 + bn + wn * 64 + li;
          qbf[ro] = f2bf(y0); qbf[ro + 16] = f2bf(y1);
          qbf[ro + 32] = f2bf(y2); qbf[ro + 48] = f2bf(y3);
        } else {
          size_t ro = (size_t)row * 512 + (bn - 4096) + wn * 64 + li;
          kbf[ro] = f2bf(y0); kbf[ro + 16] = f2bf(y1);
          kbf[ro + 32] = f2bf(y2); kbf[ro + 48] = f2bf(y3);
        }
      }
    } else if (seg < 4096) {  // q2 -> bf16
#pragma unroll
      for (int n = 0; n < 4; ++n) {
        int col = bn - 2048 + wn * 64 + n * 16 + li;
#pragma unroll
        for (int j = 0; j < 4; ++j)
          q2bf[(size_t)(row0 + j) * 2048 + col] = f2bf(acc[m][n][j]);
      }
    } else {  // v -> vT bf16 direct (j=0..3 consecutive s)
      int b_ = row0 / S, s = row0 % S;
#pragma unroll
      for (int n = 0; n < 4; ++n) {
        int col = (bn - 4608) + wn * 64 + n * 16 + li;
        int gg = col >> 6, d = col & 63;
        ushort4 o = {f2bf(acc[m][n][0]), f2bf(acc[m][n][1]),
                     f2bf(acc[m][n][2]), f2bf(acc[m][n][3])};
        *(ushort4*)&vTb[(((size_t)b_ * NKV + gg) * 64 + d) * S + s] = o;
      }
    }
  }
}

// ---------------------------------------------------------------------------
// KB key slice: kbkh[j][c] = bf16(kb_keys[j*KBROW + c]), j<128, c<2048.
// ---------------------------------------------------------------------------
__global__ void kbkh_kernel(const float* __restrict__ kbk,
                            unsigned short* __restrict__ out) {
  int i = blockIdx.x * blockDim.x + threadIdx.x;
  if (i >= 128 * 512) return;
  int j = i >> 9, c4 = (i & 511) * 4;
  float4 v = *(const float4*)&kbk[(size_t)j * KBROW + c4];
  ushort4 o = {f2bf(v.x), f2bf(v.y), f2bf(v.z), f2bf(v.w)};
  *(ushort4*)&out[(size_t)j * 2048 + c4] = o;
}

// ---------------------------------------------------------------------------
// Gathered + transposed KB values -> [B][NH][64][128] bf16.
// ---------------------------------------------------------------------------
__global__ __launch_bounds__(256) void kbvgt_kernel(
    const float* __restrict__ kbv, const int* __restrict__ topi,
    unsigned short* __restrict__ kbvgT, int B) {
  int h = blockIdx.x % NH, b = blockIdx.x / NH;
  __shared__ unsigned short gt[128][72];
  __shared__ int lidx[TOPK];
  int t = threadIdx.x;
  if (t < TOPK) lidx[t] = topi[b * TOPK + t];
  __syncthreads();
#pragma unroll
  for (int it = 0; it < 8; ++it) {
    int slot = it * 256 + t;
    int j = slot >> 4, d4 = (slot & 15) * 4;
    float4 v = *(const float4*)&kbv[(size_t)lidx[j] * KBROW + h * 64 + d4];
    gt[j][d4] = f2bf(v.x); gt[j][d4 + 1] = f2bf(v.y);
    gt[j][d4 + 2] = f2bf(v.z); gt[j][d4 + 3] = f2bf(v.w);
  }
  __syncthreads();
#pragma unroll
  for (int it = 0; it < 4; ++it) {
    int slot = it * 256 + t;
    int d = slot >> 4, j8 = (slot & 15) * 8;
    u16x8 o;
#pragma unroll
    for (int j = 0; j < 8; ++j) o[j] = gt[j8 + j][d];
    *(u16x8*)&kbvgT[(((size_t)b * NH + h) * 64 + d) * 128 + j8] = o;
  }
}

// ---------------------------------------------------------------------------
// Column-sum stage 1 + fused hidden f2bf.
// ---------------------------------------------------------------------------
__global__ __launch_bounds__(256) void hsum1_kernel(
    const float* __restrict__ hidden, double* __restrict__ part,
    unsigned short* __restrict__ hbf, int B, int S, int H) {
  const int nhb = H >> 8;
  int hb = blockIdx.x % nhb;
  int ch = (blockIdx.x / nhb) % HCH;
  int b  = blockIdx.x / (nhb * HCH);
  int c  = hb * 256 + threadIdx.x;
  int rows = S / HCH;
  size_t base = ((size_t)b * S + (size_t)ch * rows) * H + c;
  const float* p = hidden + base;
  double acc = 0.0;
  for (int s = 0; s < rows; ++s) {
    float v = p[(size_t)s * H];
    acc += (double)v;
    hbf[base + (size_t)s * H] = f2bf(v);
  }
  part[((size_t)b * HCH + ch) * H + c] = acc;
}

// ---------------------------------------------------------------------------
// Column-sum stage 2: Hsum[b][c] = sum_ch part[b][ch][c] (f64, fixed order).
// ---------------------------------------------------------------------------
__global__ void hsum2_kernel(const double* __restrict__ part,
                             float* __restrict__ Hsum, int B, int H) {
  int idx = blockIdx.x * blockDim.x + threadIdx.x;
  if (idx >= B * H) return;
  int b = idx / H, c = idx % H;
  const double* p = part + (size_t)b * HCH * H + c;
  double acc = 0.0;
#pragma unroll
  for (int ch = 0; ch < HCH; ++ch) acc += p[(size_t)ch * H];
  Hsum[idx] = (float)acc;
}

// ---------------------------------------------------------------------------
// Qs[b][c] = sum_k Hsum[b][k] * Wq2[c][k]  (fp32 inputs, f64 accum).
// ---------------------------------------------------------------------------
__global__ void qs_kernel(const float* __restrict__ Hsum,
                          const float* __restrict__ Wq2,
                          float* __restrict__ Qs, int B, int H) {
  int task = (blockIdx.x * blockDim.x + threadIdx.x) >> 6;
  int lane = threadIdx.x & 63;
  if (task >= B * NH * HD) return;
  int b = task / (NH * HD), c = task % (NH * HD);
  const float* hs = Hsum + (size_t)b * H;
  const float* wr = Wq2 + (size_t)c * H;
  double acc = 0.0;
  for (int k = lane; k < H; k += 64) acc += (double)hs[k] * (double)wr[k];
#pragma unroll
  for (int off = 32; off; off >>= 1) acc += __shfl_xor(acc, off);
  if (lane == 0) Qs[task] = (float)acc;
}

// ---------------------------------------------------------------------------
// scores[b][l] = 0.125 * dot(Qs[b,:], kb_keys[l, 0:2048]) (f64 acc)
// ---------------------------------------------------------------------------
__global__ void scores_kernel(const float* __restrict__ Qs,
                              const float* __restrict__ kbk,
                              float* __restrict__ scores, int B, int KBL) {
  int task = (blockIdx.x * blockDim.x + threadIdx.x) >> 6;
  int lane = threadIdx.x & 63;
  if (task >= B * KBL) return;
  int b = task / KBL, l = task % KBL;
  const float* kr = kbk + (size_t)l * KBROW;
  const float* qd = Qs + (size_t)b * NH * HD;
  double acc = 0.0;
  for (int c = lane; c < NH * HD; c += 64) acc += (double)qd[c] * (double)kr[c];
#pragma unroll
  for (int off = 32; off; off >>= 1) acc += __shfl_xor(acc, off);
  if (lane == 0) scores[task] = (float)(0.125 * acc);
}

// ---------------------------------------------------------------------------
// Top-K by rank-counting (stable descending == lax.top_k).
// ---------------------------------------------------------------------------
__global__ __launch_bounds__(256) void topk_kernel(
    const float* __restrict__ scores, int* __restrict__ top_idx, int KBL) {
  __shared__ float ls[512];
  int b = blockIdx.x, t = threadIdx.x;
  for (int i = t; i < KBL; i += 256) ls[i] = scores[(size_t)b * KBL + i];
  __syncthreads();
  for (int l = t; l < KBL; l += 256) {
    float sl = ls[l];
    int rank = 0;
    for (int j = 0; j < KBL; ++j) {
      float sj = ls[j];
      rank += (sj > sl || (sj == sl && j < l)) ? 1 : 0;
    }
    if (rank < TOPK) top_idx[b * TOPK + rank] = l;
  }
}

// ---------------------------------------------------------------------------
// padflag[b*S+s] = all(mask[b,0,s,:] < 0)
// ---------------------------------------------------------------------------
__global__ void padflag_kernel(const float* __restrict__ mask,
                               int* __restrict__ flags, int BS, int S) {
  int w = (blockIdx.x * blockDim.x + threadIdx.x) >> 6;
  int lane = threadIdx.x & 63;
  if (w >= BS) return;
  const float* row = mask + (size_t)w * S;
  bool ok = true;
  for (int j = lane; j < S; j += 64) ok = ok && (row[j] < 0.f);
  int allv = __all(ok ? 1 : 0);
  if (lane == 0) flags[w] = allv;
}

// ---------------------------------------------------------------------------
// Load one K/V chunk's staged data into registers (4 x bf16x8 per thread).
// ---------------------------------------------------------------------------
__device__ __forceinline__ void load_chunk(
    int ch, int t, int b, int h, int g, int S,
    const unsigned short* __restrict__ kbf, const unsigned short* __restrict__ vTb,
    const unsigned short* __restrict__ kbkh, const unsigned short* __restrict__ kbvgT,
    bf16x8* st) {
  bool iskb = ch < 2;
  int j0 = iskb ? ch * 64 : (ch - 2) * 64;
#pragma unroll
  for (int it = 0; it < 4; ++it) {
    int slot = it * 256 + t;
    int tile = slot >> 9, row = (slot >> 3) & 63, ck = slot & 7;
    const unsigned short* src;
    if (tile == 0)
      src = iskb ? kbkh + (size_t)(j0 + row) * 2048 + h * 64 + ck * 8
                 : kbf + (size_t)(b * S + j0 + row) * 512 + g * 64 + ck * 8;
    else
      src = iskb ? kbvgT + (((size_t)b * NH + h) * 64 + row) * 128 + j0 + ck * 8
                 : vTb + (((size_t)b * NKV + g) * 64 + row) * (size_t)S + j0 + ck * 8;
    st[it] = *(const bf16x8*)src;
  }
}

// ---------------------------------------------------------------------------
// One chunk of QK^T -> online softmax -> PV for one q-tile.
// ---------------------------------------------------------------------------
__device__ __forceinline__ void attn_step(
    const char* cbuf, char* ptw, const int* padfb, const bf16x8* aq,
    bool iskb, int j0, int s0, int w, int li, int lg4,
    float* m_, float* l_, f32x4* acc) {
  f32x4 cc[4];
  __builtin_amdgcn_s_setprio(1);
#pragma unroll
  for (int cb = 0; cb < 4; ++cb) {
    bf16x8 b0 = *(const bf16x8*)(cbuf + swz(cb * 16 + li, lg4));
    bf16x8 b1 = *(const bf16x8*)(cbuf + swz(cb * 16 + li, 4 + lg4));
    f32x4 z = {};
    z = __builtin_amdgcn_mfma_f32_16x16x32_bf16(aq[0], b0, z, 0, 0, 0);
    z = __builtin_amdgcn_mfma_f32_16x16x32_bf16(aq[1], b1, z, 0, 0, 0);
    cc[cb] = z;
  }
  __builtin_amdgcn_s_setprio(0);

  float lgv[4][4];
#pragma unroll
  for (int cb = 0; cb < 4; ++cb)
#pragma unroll
    for (int j = 0; j < 4; ++j) {
      float v = SCALE * cc[cb][j];
      if (iskb) {
        v += C0F + (padfb[w * 16 + lg4 * 4 + j] ? PADF : 0.f);
      } else {
        int key = j0 + cb * 16 + li;
        int srow = s0 + w * 16 + lg4 * 4 + j;
        v += (key <= srow) ? 0.f : PADF;
      }
      lgv[cb][j] = v;
    }
#pragma unroll
  for (int j = 0; j < 4; ++j) {
    float rmax = fmaxf(fmaxf(lgv[0][j], lgv[1][j]), fmaxf(lgv[2][j], lgv[3][j]));
#pragma unroll
    for (int off = 8; off; off >>= 1) rmax = fmaxf(rmax, __shfl_xor(rmax, off));
    float mn = fmaxf(m_[j], rmax);
    float fs = __expf(m_[j] - mn);
    float csum = 0.f;
#pragma unroll
    for (int cb = 0; cb < 4; ++cb) {
      float pv = __expf(lgv[cb][j] - mn);
      csum += pv;
      int key = cb * 16 + li;
      int rloc = lg4 * 4 + j;
      *(unsigned short*)(ptw + swz(rloc, key >> 3) + ((key & 7) << 1)) = f2bf(pv);
    }
#pragma unroll
    for (int off = 8; off; off >>= 1) csum += __shfl_xor(csum, off);
    m_[j] = mn;
    l_[j] = l_[j] * fs + csum;
#pragma unroll
    for (int db = 0; db < 4; ++db) acc[db][j] *= fs;
  }

  bf16x8 pa0 = *(const bf16x8*)(ptw + swz(li, lg4));
  bf16x8 pa1 = *(const bf16x8*)(ptw + swz(li, 4 + lg4));
  __builtin_amdgcn_s_setprio(1);
#pragma unroll
  for (int db = 0; db < 4; ++db) {
    bf16x8 bv0 = *(const bf16x8*)(cbuf + 8192 + swz(db * 16 + li, lg4));
    bf16x8 bv1 = *(const bf16x8*)(cbuf + 8192 + swz(db * 16 + li, 4 + lg4));
    acc[db] = __builtin_amdgcn_mfma_f32_16x16x32_bf16(pa0, bv0, acc[db], 0, 0, 0);
    acc[db] = __builtin_amdgcn_mfma_f32_16x16x32_bf16(pa1, bv1, acc[db], 0, 0, 0);
  }
  __builtin_amdgcn_s_setprio(0);
}

// ---------------------------------------------------------------------------
// MFMA fused attention v5 (unchanged from R15): diagonal pairing + async
// reg-staged prefetch + double-buffered K/V LDS (1 barrier/chunk).
// ---------------------------------------------------------------------------
__global__ __launch_bounds__(256) void attn_mfma(
    const unsigned short* __restrict__ qbf,    // [B*S][2048] roped bf16
    const unsigned short* __restrict__ q2bf,   // [B*S][2048] bf16
    const unsigned short* __restrict__ kbf,    // [B*S][512] roped bf16
    const unsigned short* __restrict__ vTb,    // [B][NKV][64][S] bf16
    const unsigned short* __restrict__ kbkh,   // [128][2048] bf16
    const unsigned short* __restrict__ kbvgT,  // [B][NH][64][128] bf16
    const int* __restrict__ padflag,           // [B*S]
    unsigned short* __restrict__ attnbf,       // [B*S][2048] bf16
    int B, int S) {
  const int nst = S >> 6;
  const int npair = (nst + 1) >> 1;
  const int p = blockIdx.x % npair;
  const int h = (blockIdx.x / npair) % NH;
  const int b = blockIdx.x / (npair * NH);
  const int stA = p, stB = nst - 1 - p;
  const bool hasB = (stB != stA);
  const int s0A = stA * 64, s0B = stB * 64;
  const int g = h / (NH / NKV);

  __shared__ unsigned short smem[2][8192];
  __shared__ unsigned short pt[4][1024];
  __shared__ int padf[128];

  const int t = threadIdx.x;
  const int w = t >> 6;
  const int li = t & 15;
  const int lg4 = (t & 63) >> 4;

  const int nch = 2 + stB + 1;

  bf16x8 st[4];
  load_chunk(0, t, b, h, g, S, kbf, vTb, kbkh, kbvgT, st);

  bf16x8 aq0A[2], aq2A[2], aq0B[2], aq2B[2];
  {
    size_t rowA = (size_t)(b * S + s0A + w * 16 + li) * (NH * HD);
    size_t rowB = (size_t)(b * S + s0B + w * 16 + li) * (NH * HD);
#pragma unroll
    for (int kc = 0; kc < 2; ++kc) {
      size_t o = h * 64 + kc * 32 + lg4 * 8;
      aq0A[kc] = *(const bf16x8*)(qbf + rowA + o);
      aq2A[kc] = *(const bf16x8*)(q2bf + rowA + o);
      aq0B[kc] = *(const bf16x8*)(qbf + rowB + o);
      aq2B[kc] = *(const bf16x8*)(q2bf + rowB + o);
    }
  }
  if (t < 64) padf[t] = padflag[b * S + s0A + t];
  else if (t < 128) padf[t] = padflag[b * S + s0B + (t - 64)];

#pragma unroll
  for (int it = 0; it < 4; ++it) {
    int slot = it * 256 + t;
    int tile = slot >> 9, row = (slot >> 3) & 63, ck = slot & 7;
    *(bf16x8*)((char*)smem[0] + tile * 8192 + swz(row, ck)) = st[it];
  }
  load_chunk(1, t, b, h, g, S, kbf, vTb, kbkh, kbvgT, st);
  __syncthreads();

  float mA[4] = {-3.4e38f, -3.4e38f, -3.4e38f, -3.4e38f};
  float mB[4] = {-3.4e38f, -3.4e38f, -3.4e38f, -3.4e38f};
  float lA[4] = {}, lB[4] = {};
  f32x4 accA[4] = {}, accB[4] = {};

  for (int ch = 0; ch < nch; ++ch) {
    const bool iskb = ch < 2;
    const int j0 = iskb ? ch * 64 : (ch - 2) * 64;
    if (ch + 1 < nch) {
      char* nb = (char*)smem[(ch + 1) & 1];
#pragma unroll
      for (int it = 0; it < 4; ++it) {
        int slot = it * 256 + t;
        int tile = slot >> 9, row = (slot >> 3) & 63, ck = slot & 7;
        *(bf16x8*)(nb + tile * 8192 + swz(row, ck)) = st[it];
      }
      if (ch + 2 < nch)
        load_chunk(ch + 2, t, b, h, g, S, kbf, vTb, kbkh, kbvgT, st);
    }
    const char* cb = (const char*)smem[ch & 1];
    if (iskb || (ch - 2) <= stA)
      attn_step(cb, (char*)pt[w], padf, iskb ? aq2A : aq0A,
                iskb, j0, s0A, w, li, lg4, mA, lA, accA);
    if (hasB)
      attn_step(cb, (char*)pt[w], padf + 64, iskb ? aq2B : aq0B,
                iskb, j0, s0B, w, li, lg4, mB, lB, accB);
    __syncthreads();
  }

#pragma unroll
  for (int j = 0; j < 4; ++j) {
    float inv = 1.f / lA[j];
    size_t o = (size_t)(b * S + s0A + w * 16 + lg4 * 4 + j) * (NH * HD) + h * 64 + li;
#pragma unroll
    for (int db = 0; db < 4; ++db) attnbf[o + db * 16] = f2bf(accA[db][j] * inv);
  }
  if (hasB) {
#pragma unroll
    for (int j = 0; j < 4; ++j) {
      float inv = 1.f / lB[j];
      size_t o = (size_t)(b * S + s0B + w * 16 + lg4 * 4 + j) * (NH * HD) + h * 64 + li;
#pragma unroll
      for (int db = 0; db < 4; ++db) attnbf[o + db * 16] = f2bf(accB[db][j] * inv);
    }
  }
}

// ---------------------------------------------------------------------------
extern "C" void kernel_launch(void* const* d_in, const int* in_sizes, int n_in,
                              void* d_out, int out_size, void* d_ws, size_t ws_size,
                              hipStream_t stream) {
  const float* hidden = (const float*)d_in[0];
  const float* cosb   = (const float*)d_in[1];
  const float* sinb   = (const float*)d_in[2];
  const float* mask   = (const float*)d_in[3];
  const float* kbk    = (const float*)d_in[4];
  const float* kbv    = (const float*)d_in[5];
  const float* Wq     = (const float*)d_in[6];
  const float* Wq2    = (const float*)d_in[7];
  const float* Wk     = (const float*)d_in[8];
  const float* Wv     = (const float*)d_in[9];
  const float* Wo     = (const float*)d_in[10];
  float* out = (float*)d_out;

  const int H   = in_sizes[6] / (NH * HD);             // 2048
  const int KBL = in_sizes[4] / KBROW;                 // 400
  const long long BSll = (long long)in_sizes[0] / H;
  const int S = (int)((long long)in_sizes[3] / BSll);  // 1024
  const int B = (int)(BSll / S);                       // 2
  const int BS = B * S;
  const int NQ = NH * HD;                              // 2048
  const int NKVD = NKV * HD;                           // 512
  const int NTOT = NQ + NQ + NKVD + NKVD;              // 5120

  float* ws = (float*)d_ws;
  size_t off = 0;
  double* hpart = (double*)(ws + off); off += (size_t)B * HCH * H * 2;
  float* Hsum = ws + off; off += (size_t)B * H;
  float* Qs   = ws + off; off += (size_t)B * NQ;
  float* sc   = ws + off; off += (size_t)B * KBL;
  int* topi   = (int*)(ws + off); off += (size_t)B * TOPK;
  int* padfl  = (int*)(ws + off); off += (size_t)BS;
  unsigned short* hbf    = (unsigned short*)(ws + off); off += (size_t)BS * H / 2;
  unsigned short* wall   = (unsigned short*)(ws + off); off += (size_t)NTOT * H / 2;
  unsigned short* wobf   = (unsigned short*)(ws + off); off += (size_t)H * NQ / 2;
  unsigned short* attnbf = (unsigned short*)(ws + off); off += (size_t)BS * NQ / 2;
  unsigned short* qbf    = (unsigned short*)(ws + off); off += (size_t)BS * NQ / 2;
  unsigned short* q2bf   = (unsigned short*)(ws + off); off += (size_t)BS * NQ / 2;
  unsigned short* kbf    = (unsigned short*)(ws + off); off += (size_t)BS * NKVD / 2;
  unsigned short* vTb    = (unsigned short*)(ws + off); off += (size_t)BS * NKVD / 2;
  unsigned short* kbkh   = (unsigned short*)(ws + off); off += (size_t)128 * NQ / 2;
  unsigned short* kbvgT  = (unsigned short*)(ws + off); off += (size_t)B * NH * HD * TOPK / 2;
  float* c0 = (float*)qbf;   // dead after attn_mfma
  float* c1 = (float*)wall;  // dead after gemm_proj8
  (void)ws_size; (void)n_in; (void)out_size;

  // 0: weight fp32 -> bf16 (dest wall|wobf contiguous)
  {
    int n1 = NQ * H / 4, n2 = NQ * H / 4;
    int n3 = NKVD * H / 4, n4_ = NKVD * H / 4, n5 = H * NQ / 4;
    int ntot = n1 + n2 + n3 + n4_ + n5;
    f2bf_all<<<(ntot + 255) / 256, 256, 0, stream>>>(
        Wq, Wq2, Wk, Wv, Wo, n1, n2, n3, n4_, n5, wall);
  }

  // 1: hidden column-sum stage 1 + fused hidden f2bf (produces hbf)
  hsum1_kernel<<<B * HCH * (H / 256), 256, 0, stream>>>(hidden, hpart, hbf, B, S, H);

  // 2: fused projections + RoPE + direct V^T (16-wave, 4 waves/SIMD)
  gemm_proj8<<<dim3(NTOT / 256, BS / 256), 1024, 0, stream>>>(
      hbf, wall, cosb, sinb, qbf, q2bf, kbf, vTb, BS, H, S);

  // 3-6: exact fp32 scores path + top-k + padding
  hsum2_kernel<<<(B * H + 255) / 256, 256, 0, stream>>>(hpart, Hsum, B, H);
  qs_kernel<<<(B * NQ * 64 + 255) / 256, 256, 0, stream>>>(Hsum, Wq2, Qs, B, H);
  scores_kernel<<<(B * KBL * 64 + 255) / 256, 256, 0, stream>>>(Qs, kbk, sc, B, KBL);
  topk_kernel<<<B, 256, 0, stream>>>(sc, topi, KBL);
  padflag_kernel<<<(BS * 64 + 255) / 256, 256, 0, stream>>>(mask, padfl, BS, S);

  // 7-8: KB bf16 staging
  kbkh_kernel<<<(128 * 512 + 255) / 256, 256, 0, stream>>>(kbk, kbkh);
  kbvgt_kernel<<<B * NH, 256, 0, stream>>>(kbv, topi, kbvgT, B);

  // 9: fused attention (paired tiles, double-buffered, 1 barrier/chunk)
  {
    int nst = S / 64;
    int npair = (nst + 1) / 2;
    attn_mfma<<<B * NH * npair, 256, 0, stream>>>(
        qbf, q2bf, kbf, vTb, kbkh, kbvgT, padfl, attnbf, B, S);
  }

  // 10-11: output projection, split-K=2 + partial add
  gemm_nt_splitk<<<dim3(H / 128, BS / 128, 2), 256, 0, stream>>>(
      attnbf, wobf, c0, c1, BS, H, NQ);
  add2_kernel<<<(BS * H / 4 + 255) / 256, 256, 0, stream>>>(c0, c1, out, BS * H / 4);
}